// Round 1
// baseline (3470.455 us; speedup 1.0000x reference)
//
#include <hip/hip_runtime.h>
#include <math.h>

#define N_NODES 100000
#define N_EDGES 600000
#define N_GRAPHS 4096
#define DIM 128

// ---------------------------------------------------------------- atom encoder
__global__ void k_atom_encode(const int* __restrict__ x, const float* __restrict__ at,
                              float* __restrict__ h) {
    int n = blockIdx.x * 2 + (threadIdx.x >> 7);
    int d = threadIdx.x & 127;
    if (n >= N_NODES) return;
    const int* xr = x + n * 9;
    float s = 0.f;
#pragma unroll
    for (int f = 0; f < 9; ++f) {
        int v = xr[f];
        s += at[(f * 100 + v) * 128 + d];
    }
    h[(size_t)n * 128 + d] = s;
}

// ------------------------------------------------- message + scatter-add (agg)
// one wave per edge; bond tables for this layer staged in LDS (12 KB)
__global__ void k_msg_scatter(const float* __restrict__ h, const int* __restrict__ ei,
                              const int* __restrict__ ea, const float* __restrict__ bt_g,
                              float* __restrict__ agg) {
    __shared__ float bt[3 * 8 * 128];
    for (int i = threadIdx.x; i < 3 * 8 * 128; i += 256) bt[i] = bt_g[i];
    __syncthreads();
    int lane = threadIdx.x & 63;
    int gw = blockIdx.x * 4 + (threadIdx.x >> 6);
    int nw = gridDim.x * 4;
    for (int e = gw; e < N_EDGES; e += nw) {
        int r = ei[e], c = ei[N_EDGES + e];
        int a0 = ea[e * 3 + 0], a1 = ea[e * 3 + 1], a2 = ea[e * 3 + 2];
        float2 hv = ((const float2*)(h + (size_t)r * 128))[lane];
        float2 e0 = ((const float2*)(bt + a0 * 128))[lane];
        float2 e1 = ((const float2*)(bt + 1024 + a1 * 128))[lane];
        float2 e2 = ((const float2*)(bt + 2048 + a2 * 128))[lane];
        float mx = fmaxf(hv.x + e0.x + e1.x + e2.x, 0.f);
        float my = fmaxf(hv.y + e0.y + e1.y + e2.y, 0.f);
        float* ap = agg + (size_t)c * 128 + lane * 2;
        atomicAdd(ap, mx);
        atomicAdd(ap + 1, my);
    }
}

// ------------------------------------------------------- GEMM1: t = z@W1 + b1
// z = (1+eps)*h + agg fused into the LDS load. M=100000,K=128,Ncol=256
__global__ __launch_bounds__(256) void k_gemm1(
    const float* __restrict__ h, const float* __restrict__ agg,
    const float* __restrict__ eps, int l,
    const float* __restrict__ W, const float* __restrict__ bias,
    float* __restrict__ t) {
    __shared__ float zs[32 * 128];
    int n0 = blockIdx.x * 32;
    float el = 1.0f + eps[l];
    for (int i = threadIdx.x; i < 4096; i += 256) {
        int r = i >> 7, k = i & 127;
        size_t g = (size_t)(n0 + r) * 128 + k;
        zs[i] = el * h[g] + agg[g];
    }
    __syncthreads();
    int j = threadIdx.x;
    float acc[32];
#pragma unroll
    for (int r = 0; r < 32; ++r) acc[r] = 0.f;
    const float* Wj = W + j;
    const float4* z4 = (const float4*)zs;
    for (int k4 = 0; k4 < 32; ++k4) {
        int k = k4 * 4;
        float w0 = Wj[(k + 0) * 256], w1 = Wj[(k + 1) * 256];
        float w2 = Wj[(k + 2) * 256], w3 = Wj[(k + 3) * 256];
#pragma unroll
        for (int r = 0; r < 32; ++r) {
            float4 z = z4[r * 32 + k4];
            acc[r] = fmaf(z.w, w3, fmaf(z.z, w2, fmaf(z.y, w1, fmaf(z.x, w0, acc[r]))));
        }
    }
    float b = bias[j];
    for (int r = 0; r < 32; ++r) t[(size_t)(n0 + r) * 256 + j] = acc[r] + b;
}

// ------------------------------------------------- BN1 stats: column sum/sumsq
__global__ void k_bn_stats256(const float* __restrict__ t, float* __restrict__ stats) {
    int j = threadIdx.x;
    int r0 = blockIdx.x * 391;
    int r1 = min(r0 + 391, N_NODES);
    float s = 0.f, q = 0.f;
    for (int r = r0; r < r1; ++r) {
        float v = t[(size_t)r * 256 + j];
        s += v;
        q += v * v;
    }
    atomicAdd(&stats[j], s);
    atomicAdd(&stats[256 + j], q);
}

// ---------------------------------------------- BN finalize -> scale/shift
__global__ void k_bn_final(const float* __restrict__ sums, int C,
                           const float* __restrict__ g, const float* __restrict__ b,
                           float* __restrict__ scale, float* __restrict__ shift) {
    int j = threadIdx.x;
    if (j >= C) return;
    float m = sums[j] * (1.0f / N_NODES);
    float var = sums[C + j] * (1.0f / N_NODES) - m * m;
    float sc = g[j] / sqrtf(var + 1e-5f);
    scale[j] = sc;
    shift[j] = b[j] - m * sc;
}

// -------------------- GEMM2: u = relu(BN1(t))@W2 + b2, fused BN2 stat partials
__global__ __launch_bounds__(128) void k_gemm2(
    const float* __restrict__ t,
    const float* __restrict__ scale1, const float* __restrict__ shift1,
    const float* __restrict__ W, const float* __restrict__ bias,
    float* __restrict__ u, float* __restrict__ osum, float* __restrict__ osq) {
    __shared__ float ts[32 * 256];
    int n0 = blockIdx.x * 32;
    for (int i = threadIdx.x; i < 8192; i += 128) {
        int k = i & 255;
        float v = scale1[k] * t[(size_t)n0 * 256 + i] + shift1[k];
        ts[i] = fmaxf(v, 0.f);
    }
    __syncthreads();
    int j = threadIdx.x;
    float acc[32];
#pragma unroll
    for (int r = 0; r < 32; ++r) acc[r] = 0.f;
    const float* Wj = W + j;
    const float4* t4 = (const float4*)ts;
    for (int k4 = 0; k4 < 64; ++k4) {
        int k = k4 * 4;
        float w0 = Wj[(k + 0) * 128], w1 = Wj[(k + 1) * 128];
        float w2 = Wj[(k + 2) * 128], w3 = Wj[(k + 3) * 128];
#pragma unroll
        for (int r = 0; r < 32; ++r) {
            float4 z = t4[r * 64 + k4];
            acc[r] = fmaf(z.w, w3, fmaf(z.z, w2, fmaf(z.y, w1, fmaf(z.x, w0, acc[r]))));
        }
    }
    float b = bias[j];
    float s = 0.f, q = 0.f;
    for (int r = 0; r < 32; ++r) {
        float v = acc[r] + b;
        u[(size_t)(n0 + r) * 128 + j] = v;
        s += v;
        q += v * v;
    }
    atomicAdd(&osum[j], s);
    atomicAdd(&osq[j], q);
}

// --------------------------------------- h += maybe_relu(BN2(u))  (elementwise)
__global__ void k_update_h(float* __restrict__ h, const float* __restrict__ u,
                           const float* __restrict__ scale2, const float* __restrict__ shift2,
                           int relu) {
    int i = blockIdx.x * 256 + threadIdx.x;  // float4 index, total N*128/4
    int d4 = i & 31;
    float4 uv = ((const float4*)u)[i];
    float4 sc = ((const float4*)scale2)[d4];
    float4 sh = ((const float4*)shift2)[d4];
    float4 hv = ((const float4*)h)[i];
    float vx = fmaf(sc.x, uv.x, sh.x);
    float vy = fmaf(sc.y, uv.y, sh.y);
    float vz = fmaf(sc.z, uv.z, sh.z);
    float vw = fmaf(sc.w, uv.w, sh.w);
    if (relu) {
        vx = fmaxf(vx, 0.f); vy = fmaxf(vy, 0.f);
        vz = fmaxf(vz, 0.f); vw = fmaxf(vw, 0.f);
    }
    hv.x += vx; hv.y += vy; hv.z += vz; hv.w += vw;
    ((float4*)h)[i] = hv;
}

// --------------------------------------- init the 4 G-sized segment-sum outputs
__global__ void k_init_seg(float* __restrict__ out) {
    int i = blockIdx.x * 256 + threadIdx.x;
    if (i < 4 * N_GRAPHS) out[N_NODES + N_EDGES + i] = 1e-8f;
}

// ------------- node head: node_key + per-node dots p,q + node segment sums
__global__ void k_node_out(const float* __restrict__ h, const int* __restrict__ batch,
                           const float* __restrict__ nW, const float* __restrict__ nb,
                           const float* __restrict__ eW,
                           float* __restrict__ out, float* __restrict__ p,
                           float* __restrict__ q) {
    int n = blockIdx.x * 4 + (threadIdx.x >> 6);
    int lane = threadIdx.x & 63;
    if (n >= N_NODES) return;
    float2 hv = ((const float2*)(h + (size_t)n * 128))[lane];
    float2 wn = ((const float2*)nW)[lane];
    float2 wa = ((const float2*)eW)[lane];
    float2 wb = ((const float2*)eW)[64 + lane];
    float dn = hv.x * wn.x + hv.y * wn.y;
    float da = hv.x * wa.x + hv.y * wa.y;
    float db = hv.x * wb.x + hv.y * wb.y;
#pragma unroll
    for (int off = 32; off; off >>= 1) {
        dn += __shfl_xor(dn, off);
        da += __shfl_xor(da, off);
        db += __shfl_xor(db, off);
    }
    if (lane == 0) {
        float nk = 1.f / (1.f + expf(-(dn + nb[0])));
        out[n] = nk;
        int g = batch[n];
        atomicAdd(&out[N_NODES + N_EDGES + g], nk);
        atomicAdd(&out[N_NODES + N_EDGES + N_GRAPHS + g], 1.0f - nk);
        p[n] = da;
        q[n] = db;
    }
}

// ------------- edge head: edge_key = sigmoid(p[row]+q[col]+b) + edge seg sums
__global__ void k_edge_out(const int* __restrict__ ei, const int* __restrict__ batch,
                           const float* __restrict__ p, const float* __restrict__ q,
                           const float* __restrict__ eb, float* __restrict__ out) {
    int e = blockIdx.x * 256 + threadIdx.x;
    if (e >= N_EDGES) return;
    int r = ei[e], c = ei[N_EDGES + e];
    float ek = 1.f / (1.f + expf(-(p[r] + q[c] + eb[0])));
    out[N_NODES + e] = ek;
    int g = batch[r];
    atomicAdd(&out[N_NODES + N_EDGES + 2 * N_GRAPHS + g], ek);
    atomicAdd(&out[N_NODES + N_EDGES + 3 * N_GRAPHS + g], 1.0f - ek);
}

extern "C" void kernel_launch(void* const* d_in, const int* in_sizes, int n_in,
                              void* d_out, int out_size, void* d_ws, size_t ws_size,
                              hipStream_t stream) {
    const int*   x     = (const int*)d_in[0];
    const int*   ei    = (const int*)d_in[1];
    const int*   ea    = (const int*)d_in[2];
    const int*   batch = (const int*)d_in[3];
    const float* at    = (const float*)d_in[4];
    const float* bt    = (const float*)d_in[5];
    const float* eps   = (const float*)d_in[6];
    const float* W1    = (const float*)d_in[7];
    const float* b1    = (const float*)d_in[8];
    const float* bn1g  = (const float*)d_in[9];
    const float* bn1b  = (const float*)d_in[10];
    const float* W2    = (const float*)d_in[11];
    const float* b2    = (const float*)d_in[12];
    const float* obng  = (const float*)d_in[13];
    const float* obnb  = (const float*)d_in[14];
    const float* nW    = (const float*)d_in[15];
    const float* nb    = (const float*)d_in[16];
    const float* eW    = (const float*)d_in[17];
    const float* eb    = (const float*)d_in[18];
    float* out = (float*)d_out;

    float* ws   = (float*)d_ws;
    float* h    = ws;                    // N*128 = 12,800,000
    float* t    = h + 12800000;          // N*256 = 25,600,000
    float* aggu = t + 25600000;          // N*128 (agg, then reused as u)
    float* stats = aggu + 12800000;      // 1536 floats
    float* p    = stats + 1536;          // N
    float* q    = p + N_NODES;           // N
    // stats layout: [sum256][sq256][osum128][osq128][scale1 256][shift1 256][scale2 128][shift2 128]

    k_atom_encode<<<50000, 256, 0, stream>>>(x, at, h);

    for (int l = 0; l < 3; ++l) {
        hipMemsetAsync(aggu, 0, (size_t)N_NODES * 128 * 4, stream);
        hipMemsetAsync(stats, 0, 768 * 4, stream);
        k_msg_scatter<<<2048, 256, 0, stream>>>(h, ei, ea, bt + (size_t)l * 3 * 8 * 128, aggu);
        k_gemm1<<<3125, 256, 0, stream>>>(h, aggu, eps, l, W1 + (size_t)l * 128 * 256,
                                          b1 + l * 256, t);
        k_bn_stats256<<<256, 256, 0, stream>>>(t, stats);
        k_bn_final<<<1, 256, 0, stream>>>(stats, 256, bn1g + l * 256, bn1b + l * 256,
                                          stats + 768, stats + 1024);
        k_gemm2<<<3125, 128, 0, stream>>>(t, stats + 768, stats + 1024,
                                          W2 + (size_t)l * 256 * 128, b2 + l * 128,
                                          aggu, stats + 512, stats + 640);
        k_bn_final<<<1, 128, 0, stream>>>(stats + 512, 128, obng + l * 128, obnb + l * 128,
                                          stats + 1280, stats + 1408);
        k_update_h<<<12500, 256, 0, stream>>>(h, aggu, stats + 1280, stats + 1408,
                                              (l < 2) ? 1 : 0);
    }

    k_init_seg<<<64, 256, 0, stream>>>(out);
    k_node_out<<<25000, 256, 0, stream>>>(h, batch, nW, nb, eW, out, p, q);
    k_edge_out<<<2344, 256, 0, stream>>>(ei, batch, p, q, eb, out);
}

// Round 2
// 2587.336 us; speedup vs baseline: 1.3413x; 1.3413x over previous
//
#include <hip/hip_runtime.h>
#include <math.h>

#define N_NODES 100000
#define N_EDGES 600000
#define N_GRAPHS 4096

// ---------------------------------------------------------------- atom encoder
__global__ void k_atom_encode(const int* __restrict__ x, const float* __restrict__ at,
                              float* __restrict__ h) {
    int n = blockIdx.x * 2 + (threadIdx.x >> 7);
    int d = threadIdx.x & 127;
    if (n >= N_NODES) return;
    const int* xr = x + n * 9;
    float s = 0.f;
#pragma unroll
    for (int f = 0; f < 9; ++f) {
        int v = xr[f];
        s += at[(f * 100 + v) * 128 + d];
    }
    h[(size_t)n * 128 + d] = s;
}

// ------------------------------------------------------------ CSR build (once)
__global__ void k_hist(const int* __restrict__ ei, int* __restrict__ cnt) {
    int e = blockIdx.x * 256 + threadIdx.x;
    if (e < N_EDGES) atomicAdd(&cnt[ei[N_EDGES + e]], 1);
}

// single-block exclusive scan of 100000 counts -> rowptr; also seeds cursor
__global__ void k_scan(int* __restrict__ cnt_cursor, int* __restrict__ rowptr) {
    __shared__ int ls[1024];
    int t = threadIdx.x;
    int c0 = t * 98;
    int c1 = min(c0 + 98, N_NODES);
    int s = 0;
    for (int i = c0; i < c1; ++i) s += cnt_cursor[i];
    ls[t] = s;
    __syncthreads();
    for (int off = 1; off < 1024; off <<= 1) {
        int v = (t >= off) ? ls[t - off] : 0;
        __syncthreads();
        ls[t] += v;
        __syncthreads();
    }
    int run = ls[t] - s;  // exclusive prefix
    for (int i = c0; i < c1; ++i) {
        int c = cnt_cursor[i];
        rowptr[i] = run;
        cnt_cursor[i] = run;
        run += c;
    }
    if (t == 1023) rowptr[N_NODES] = ls[1023];
}

__global__ void k_fill(const int* __restrict__ ei, int* __restrict__ cursor,
                       int* __restrict__ csr) {
    int e = blockIdx.x * 256 + threadIdx.x;
    if (e < N_EDGES) {
        int c = ei[N_EDGES + e];
        int pos = atomicAdd(&cursor[c], 1);
        csr[pos] = e;
    }
}

// ---------------------------- gather-aggregate: z = (1+eps)*h + sum relu(msg)
// one wave per destination node; bond tables (12 KB) staged in LDS
__global__ void k_gather(const float* __restrict__ h, const int* __restrict__ ei,
                         const int* __restrict__ ea, const float* __restrict__ bt_g,
                         const int* __restrict__ rowptr, const int* __restrict__ csr,
                         const float* __restrict__ eps, int l,
                         float* __restrict__ z) {
    __shared__ float bt[3 * 8 * 128];
    for (int i = threadIdx.x; i < 3 * 8 * 128; i += 256) bt[i] = bt_g[i];
    __syncthreads();
    int lane = threadIdx.x & 63;
    int n = blockIdx.x * 4 + (threadIdx.x >> 6);
    if (n >= N_NODES) return;
    int i0 = rowptr[n], i1 = rowptr[n + 1];
    float ax = 0.f, ay = 0.f;
    for (int i = i0; i < i1; ++i) {
        int e = csr[i];
        int r = ei[e];
        int a0 = ea[e * 3 + 0], a1 = ea[e * 3 + 1], a2 = ea[e * 3 + 2];
        float2 hv = ((const float2*)(h + (size_t)r * 128))[lane];
        float2 e0 = ((const float2*)(bt + a0 * 128))[lane];
        float2 e1 = ((const float2*)(bt + 1024 + a1 * 128))[lane];
        float2 e2 = ((const float2*)(bt + 2048 + a2 * 128))[lane];
        ax += fmaxf(hv.x + e0.x + e1.x + e2.x, 0.f);
        ay += fmaxf(hv.y + e0.y + e1.y + e2.y, 0.f);
    }
    float el = 1.0f + eps[l];
    float2 hn = ((const float2*)(h + (size_t)n * 128))[lane];
    float2 zv;
    zv.x = fmaf(el, hn.x, ax);
    zv.y = fmaf(el, hn.y, ay);
    ((float2*)(z + (size_t)n * 128))[lane] = zv;
}

// ------------------------------------------------------- GEMM1: t = z@W1 + b1
// 32 rows/block; 256 threads = 2 row-groups x 128 col-pairs (2 cols/thread)
__global__ __launch_bounds__(256) void k_gemm1(
    const float* __restrict__ z, const float* __restrict__ W,
    const float* __restrict__ bias, float* __restrict__ t) {
    __shared__ float zs[32 * 128];
    int n0 = blockIdx.x * 32;
    for (int i = threadIdx.x; i < 4096; i += 256)
        zs[i] = z[(size_t)n0 * 128 + i];
    __syncthreads();
    int jj = (threadIdx.x & 127) * 2;
    int rg = (threadIdx.x >> 7) * 16;
    float acc[16][2];
#pragma unroll
    for (int r = 0; r < 16; ++r) { acc[r][0] = 0.f; acc[r][1] = 0.f; }
    const float* Wp = W + jj;
    const float4* z4 = (const float4*)zs;
    for (int k4 = 0; k4 < 32; ++k4) {
        float2 w0 = *(const float2*)(Wp + (k4 * 4 + 0) * 256);
        float2 w1 = *(const float2*)(Wp + (k4 * 4 + 1) * 256);
        float2 w2 = *(const float2*)(Wp + (k4 * 4 + 2) * 256);
        float2 w3 = *(const float2*)(Wp + (k4 * 4 + 3) * 256);
#pragma unroll
        for (int r = 0; r < 16; ++r) {
            float4 zv = z4[(rg + r) * 32 + k4];
            acc[r][0] = fmaf(zv.w, w3.x, fmaf(zv.z, w2.x, fmaf(zv.y, w1.x, fmaf(zv.x, w0.x, acc[r][0]))));
            acc[r][1] = fmaf(zv.w, w3.y, fmaf(zv.z, w2.y, fmaf(zv.y, w1.y, fmaf(zv.x, w0.y, acc[r][1]))));
        }
    }
    float2 bb = *(const float2*)(bias + jj);
#pragma unroll
    for (int r = 0; r < 16; ++r) {
        float2 o;
        o.x = acc[r][0] + bb.x;
        o.y = acc[r][1] + bb.y;
        *(float2*)(t + (size_t)(n0 + rg + r) * 256 + jj) = o;
    }
}

// ------------------------------------------------- BN1 stats: column sum/sumsq
__global__ void k_bn_stats256(const float* __restrict__ t, float* __restrict__ stats) {
    int j = threadIdx.x;
    int r0 = blockIdx.x * 391;
    int r1 = min(r0 + 391, N_NODES);
    float s = 0.f, q = 0.f;
    for (int r = r0; r < r1; ++r) {
        float v = t[(size_t)r * 256 + j];
        s += v;
        q += v * v;
    }
    atomicAdd(&stats[j], s);
    atomicAdd(&stats[256 + j], q);
}

// ---------------------------------------------- BN finalize -> scale/shift
__global__ void k_bn_final(const float* __restrict__ sums, int C,
                           const float* __restrict__ g, const float* __restrict__ b,
                           float* __restrict__ scale, float* __restrict__ shift) {
    int j = threadIdx.x;
    if (j >= C) return;
    float m = sums[j] * (1.0f / N_NODES);
    float var = sums[C + j] * (1.0f / N_NODES) - m * m;
    float sc = g[j] / sqrtf(var + 1e-5f);
    scale[j] = sc;
    shift[j] = b[j] - m * sc;
}

// -------------------- GEMM2: u = relu(BN1(t))@W2 + b2, fused BN2 stat partials
__global__ __launch_bounds__(128) void k_gemm2(
    const float* __restrict__ t,
    const float* __restrict__ scale1, const float* __restrict__ shift1,
    const float* __restrict__ W, const float* __restrict__ bias,
    float* __restrict__ u, float* __restrict__ osum, float* __restrict__ osq) {
    __shared__ float ts[32 * 256];
    int n0 = blockIdx.x * 32;
    for (int i = threadIdx.x; i < 8192; i += 128) {
        int k = i & 255;
        float v = scale1[k] * t[(size_t)n0 * 256 + i] + shift1[k];
        ts[i] = fmaxf(v, 0.f);
    }
    __syncthreads();
    int j = threadIdx.x;
    float acc[32];
#pragma unroll
    for (int r = 0; r < 32; ++r) acc[r] = 0.f;
    const float* Wj = W + j;
    const float4* t4 = (const float4*)ts;
    for (int k4 = 0; k4 < 64; ++k4) {
        int k = k4 * 4;
        float w0 = Wj[(k + 0) * 128], w1 = Wj[(k + 1) * 128];
        float w2 = Wj[(k + 2) * 128], w3 = Wj[(k + 3) * 128];
#pragma unroll
        for (int r = 0; r < 32; ++r) {
            float4 zv = t4[r * 64 + k4];
            acc[r] = fmaf(zv.w, w3, fmaf(zv.z, w2, fmaf(zv.y, w1, fmaf(zv.x, w0, acc[r]))));
        }
    }
    float b = bias[j];
    float s = 0.f, q = 0.f;
    for (int r = 0; r < 32; ++r) {
        float v = acc[r] + b;
        u[(size_t)(n0 + r) * 128 + j] = v;
        s += v;
        q += v * v;
    }
    atomicAdd(&osum[j], s);
    atomicAdd(&osq[j], q);
}

// --------------------------------------- h += maybe_relu(BN2(u))  (elementwise)
__global__ void k_update_h(float* __restrict__ h, const float* __restrict__ u,
                           const float* __restrict__ scale2, const float* __restrict__ shift2,
                           int relu) {
    int i = blockIdx.x * 256 + threadIdx.x;  // float4 index, total N*128/4
    int d4 = i & 31;
    float4 uv = ((const float4*)u)[i];
    float4 sc = ((const float4*)scale2)[d4];
    float4 sh = ((const float4*)shift2)[d4];
    float4 hv = ((const float4*)h)[i];
    float vx = fmaf(sc.x, uv.x, sh.x);
    float vy = fmaf(sc.y, uv.y, sh.y);
    float vz = fmaf(sc.z, uv.z, sh.z);
    float vw = fmaf(sc.w, uv.w, sh.w);
    if (relu) {
        vx = fmaxf(vx, 0.f); vy = fmaxf(vy, 0.f);
        vz = fmaxf(vz, 0.f); vw = fmaxf(vw, 0.f);
    }
    hv.x += vx; hv.y += vy; hv.z += vz; hv.w += vw;
    ((float4*)h)[i] = hv;
}

// --------------------------------------- init the 4 G-sized segment-sum outputs
__global__ void k_init_seg(float* __restrict__ out) {
    int i = blockIdx.x * 256 + threadIdx.x;
    if (i < 4 * N_GRAPHS) out[N_NODES + N_EDGES + i] = 1e-8f;
}

// ------------- node head: node_key + per-node dots p,q + node segment sums
__global__ void k_node_out(const float* __restrict__ h, const int* __restrict__ batch,
                           const float* __restrict__ nW, const float* __restrict__ nb,
                           const float* __restrict__ eW,
                           float* __restrict__ out, float* __restrict__ p,
                           float* __restrict__ q) {
    int n = blockIdx.x * 4 + (threadIdx.x >> 6);
    int lane = threadIdx.x & 63;
    if (n >= N_NODES) return;
    float2 hv = ((const float2*)(h + (size_t)n * 128))[lane];
    float2 wn = ((const float2*)nW)[lane];
    float2 wa = ((const float2*)eW)[lane];
    float2 wb = ((const float2*)eW)[64 + lane];
    float dn = hv.x * wn.x + hv.y * wn.y;
    float da = hv.x * wa.x + hv.y * wa.y;
    float db = hv.x * wb.x + hv.y * wb.y;
#pragma unroll
    for (int off = 32; off; off >>= 1) {
        dn += __shfl_xor(dn, off);
        da += __shfl_xor(da, off);
        db += __shfl_xor(db, off);
    }
    if (lane == 0) {
        float nk = 1.f / (1.f + expf(-(dn + nb[0])));
        out[n] = nk;
        int g = batch[n];
        atomicAdd(&out[N_NODES + N_EDGES + g], nk);
        atomicAdd(&out[N_NODES + N_EDGES + N_GRAPHS + g], 1.0f - nk);
        p[n] = da;
        q[n] = db;
    }
}

// ------------- edge head: edge_key = sigmoid(p[row]+q[col]+b) + edge seg sums
__global__ void k_edge_out(const int* __restrict__ ei, const int* __restrict__ batch,
                           const float* __restrict__ p, const float* __restrict__ q,
                           const float* __restrict__ eb, float* __restrict__ out) {
    int e = blockIdx.x * 256 + threadIdx.x;
    if (e >= N_EDGES) return;
    int r = ei[e], c = ei[N_EDGES + e];
    float ek = 1.f / (1.f + expf(-(p[r] + q[c] + eb[0])));
    out[N_NODES + e] = ek;
    int g = batch[r];
    atomicAdd(&out[N_NODES + N_EDGES + 2 * N_GRAPHS + g], ek);
    atomicAdd(&out[N_NODES + N_EDGES + 3 * N_GRAPHS + g], 1.0f - ek);
}

extern "C" void kernel_launch(void* const* d_in, const int* in_sizes, int n_in,
                              void* d_out, int out_size, void* d_ws, size_t ws_size,
                              hipStream_t stream) {
    const int*   x     = (const int*)d_in[0];
    const int*   ei    = (const int*)d_in[1];
    const int*   ea    = (const int*)d_in[2];
    const int*   batch = (const int*)d_in[3];
    const float* at    = (const float*)d_in[4];
    const float* bt    = (const float*)d_in[5];
    const float* eps   = (const float*)d_in[6];
    const float* W1    = (const float*)d_in[7];
    const float* b1    = (const float*)d_in[8];
    const float* bn1g  = (const float*)d_in[9];
    const float* bn1b  = (const float*)d_in[10];
    const float* W2    = (const float*)d_in[11];
    const float* b2    = (const float*)d_in[12];
    const float* obng  = (const float*)d_in[13];
    const float* obnb  = (const float*)d_in[14];
    const float* nW    = (const float*)d_in[15];
    const float* nb    = (const float*)d_in[16];
    const float* eW    = (const float*)d_in[17];
    const float* eb    = (const float*)d_in[18];
    float* out = (float*)d_out;

    float* ws    = (float*)d_ws;
    float* h     = ws;                   // N*128 = 12,800,000
    float* t     = h + 12800000;         // N*256 = 25,600,000
    float* zu    = t + 25600000;         // N*128 (z for gemm1, then u from gemm2)
    float* stats = zu + 12800000;        // 1536 floats
    float* p     = stats + 1536;         // N
    float* q     = p + N_NODES;          // N
    int* rowptr  = (int*)(q + N_NODES);  // N+1
    int* cursor  = rowptr + N_NODES + 1; // N (counts, then running cursors)
    int* csr     = cursor + N_NODES;     // E
    // stats layout: [sum256][sq256][osum128][osq128][scale1 256][shift1 256][scale2 128][shift2 128]

    k_atom_encode<<<50000, 256, 0, stream>>>(x, at, h);

    // CSR of edges grouped by destination (col) — built once per call
    hipMemsetAsync(cursor, 0, N_NODES * sizeof(int), stream);
    k_hist<<<2344, 256, 0, stream>>>(ei, cursor);
    k_scan<<<1, 1024, 0, stream>>>(cursor, rowptr);
    k_fill<<<2344, 256, 0, stream>>>(ei, cursor, csr);

    for (int l = 0; l < 3; ++l) {
        hipMemsetAsync(stats, 0, 768 * 4, stream);
        k_gather<<<25000, 256, 0, stream>>>(h, ei, ea, bt + (size_t)l * 3 * 8 * 128,
                                            rowptr, csr, eps, l, zu);
        k_gemm1<<<3125, 256, 0, stream>>>(zu, W1 + (size_t)l * 128 * 256, b1 + l * 256, t);
        k_bn_stats256<<<256, 256, 0, stream>>>(t, stats);
        k_bn_final<<<1, 256, 0, stream>>>(stats, 256, bn1g + l * 256, bn1b + l * 256,
                                          stats + 768, stats + 1024);
        k_gemm2<<<3125, 128, 0, stream>>>(t, stats + 768, stats + 1024,
                                          W2 + (size_t)l * 256 * 128, b2 + l * 128,
                                          zu, stats + 512, stats + 640);
        k_bn_final<<<1, 128, 0, stream>>>(stats + 512, 128, obng + l * 128, obnb + l * 128,
                                          stats + 1280, stats + 1408);
        k_update_h<<<12500, 256, 0, stream>>>(h, zu, stats + 1280, stats + 1408,
                                              (l < 2) ? 1 : 0);
    }

    k_init_seg<<<64, 256, 0, stream>>>(out);
    k_node_out<<<25000, 256, 0, stream>>>(h, batch, nW, nb, eW, out, p, q);
    k_edge_out<<<2344, 256, 0, stream>>>(ei, batch, p, q, eb, out);
}

// Round 3
// 1364.230 us; speedup vs baseline: 2.5439x; 1.8966x over previous
//
#include <hip/hip_runtime.h>
#include <math.h>

#define N_NODES 100000
#define N_EDGES 600000
#define N_GRAPHS 4096

typedef __attribute__((ext_vector_type(8))) short short8v;   // 8 bf16 (4 VGPR)
typedef __attribute__((ext_vector_type(4))) float f32x4;

__device__ __forceinline__ unsigned short bf16_rne(float f) {
    unsigned int u = __float_as_uint(f);
    u += 0x7fffu + ((u >> 16) & 1u);
    return (unsigned short)(u >> 16);
}
__device__ __forceinline__ unsigned int pack2(float a, float b) {
    return (unsigned int)bf16_rne(a) | ((unsigned int)bf16_rne(b) << 16);
}

// ---------------------------------------------------------------- atom encoder
__global__ void k_atom_encode(const int* __restrict__ x, const float* __restrict__ at,
                              float* __restrict__ h) {
    int n = blockIdx.x * 2 + (threadIdx.x >> 7);
    int d = threadIdx.x & 127;
    if (n >= N_NODES) return;
    const int* xr = x + n * 9;
    float s = 0.f;
#pragma unroll
    for (int f = 0; f < 9; ++f) {
        int v = xr[f];
        s += at[(f * 100 + v) * 128 + d];
    }
    h[(size_t)n * 128 + d] = s;
}

// ------------------------------------------------------------ CSR build (once)
__global__ void k_hist(const int* __restrict__ ei, int* __restrict__ cnt) {
    int e = blockIdx.x * 256 + threadIdx.x;
    if (e < N_EDGES) atomicAdd(&cnt[ei[N_EDGES + e]], 1);
}

__global__ void k_scan(int* __restrict__ cnt_cursor, int* __restrict__ rowptr) {
    __shared__ int ls[1024];
    int t = threadIdx.x;
    int c0 = t * 98;
    int c1 = min(c0 + 98, N_NODES);
    int s = 0;
    for (int i = c0; i < c1; ++i) s += cnt_cursor[i];
    ls[t] = s;
    __syncthreads();
    for (int off = 1; off < 1024; off <<= 1) {
        int v = (t >= off) ? ls[t - off] : 0;
        __syncthreads();
        ls[t] += v;
        __syncthreads();
    }
    int run = ls[t] - s;  // exclusive prefix
    for (int i = c0; i < c1; ++i) {
        int c = cnt_cursor[i];
        rowptr[i] = run;
        cnt_cursor[i] = run;
        run += c;
    }
    if (t == 1023) rowptr[N_NODES] = ls[1023];
}

__global__ void k_fill(const int* __restrict__ ei, int* __restrict__ cursor,
                       int* __restrict__ csr) {
    int e = blockIdx.x * 256 + threadIdx.x;
    if (e < N_EDGES) {
        int c = ei[N_EDGES + e];
        int pos = atomicAdd(&cursor[c], 1);
        csr[pos] = e;
    }
}

// ---------------- weight pre-swizzle: fp32 -> bf16 in MFMA B-fragment layout
// b_frag[i] = B[k4*32 + kg*8 + i][col]  ->  Bp[(k4*4+kg)*COLS*8 + col*8 + i]
__global__ void k_convw(const float* __restrict__ W1, const float* __restrict__ W2,
                        unsigned short* __restrict__ Bp1, unsigned short* __restrict__ Bp2) {
    int idx = blockIdx.x * 256 + threadIdx.x;
    if (idx < 3 * 128 * 256) {
        int l = idx >> 15, r = idx & 32767;
        int k = r >> 8, j = r & 255;
        float v = W1[(size_t)l * 32768 + k * 256 + j];
        Bp1[(size_t)l * 32768 + (((k >> 5) * 4 + ((k >> 3) & 3)) * 256 + j) * 8 + (k & 7)] =
            bf16_rne(v);
    } else if (idx < 6 * 128 * 256) {
        int t = idx - 98304;
        int l = t >> 15, r = t & 32767;
        int k = r >> 7, j = r & 127;
        float v = W2[(size_t)l * 32768 + k * 128 + j];
        Bp2[(size_t)l * 32768 + (((k >> 5) * 4 + ((k >> 3) & 3)) * 128 + j) * 8 + (k & 7)] =
            bf16_rne(v);
    }
}

// ---------------------------- gather-aggregate: z = (1+eps)*h + sum relu(msg)
__global__ void k_gather(const float* __restrict__ h, const int* __restrict__ ei,
                         const int* __restrict__ ea, const float* __restrict__ bt_g,
                         const int* __restrict__ rowptr, const int* __restrict__ csr,
                         const float* __restrict__ eps, int l,
                         float* __restrict__ z) {
    __shared__ float bt[3 * 8 * 128];
    for (int i = threadIdx.x; i < 3 * 8 * 128; i += 256) bt[i] = bt_g[i];
    __syncthreads();
    int lane = threadIdx.x & 63;
    int n = blockIdx.x * 4 + (threadIdx.x >> 6);
    if (n >= N_NODES) return;
    int i0 = rowptr[n], i1 = rowptr[n + 1];
    float ax = 0.f, ay = 0.f;
    for (int i = i0; i < i1; ++i) {
        int e = csr[i];
        int r = ei[e];
        int a0 = ea[e * 3 + 0], a1 = ea[e * 3 + 1], a2 = ea[e * 3 + 2];
        float2 hv = ((const float2*)(h + (size_t)r * 128))[lane];
        float2 e0 = ((const float2*)(bt + a0 * 128))[lane];
        float2 e1 = ((const float2*)(bt + 1024 + a1 * 128))[lane];
        float2 e2 = ((const float2*)(bt + 2048 + a2 * 128))[lane];
        ax += fmaxf(hv.x + e0.x + e1.x + e2.x, 0.f);
        ay += fmaxf(hv.y + e0.y + e1.y + e2.y, 0.f);
    }
    float el = 1.0f + eps[l];
    float2 hn = ((const float2*)(h + (size_t)n * 128))[lane];
    float2 zv;
    zv.x = fmaf(el, hn.x, ax);
    zv.y = fmaf(el, hn.y, ay);
    ((float2*)(z + (size_t)n * 128))[lane] = zv;
}

// --------------------- GEMM1 (MFMA): t = z@W1 + b1, fused BN1 column stats
// BM=64, N=256, K=128. 4 waves; wave w -> cols [w*64, w*64+64)
__global__ __launch_bounds__(256) void k_gemm1(
    const float* __restrict__ z, const unsigned short* __restrict__ Bp,
    const float* __restrict__ bias, float* __restrict__ t,
    float* __restrict__ stats) {
    __shared__ unsigned short As[8192] __attribute__((aligned(16)));  // 16 KB
    int n0 = blockIdx.x * 64;
    // stage z[64x128] -> bf16 MFMA-A layout: frag=((r>>4)*4+k4)*4+kg
    for (int s = 0; s < 8; ++s) {
        int i = threadIdx.x + s * 256;            // float4 index
        int r = i >> 5, kq = i & 31;
        float4 zv;
        if (n0 + r < N_NODES) zv = ((const float4*)z)[(size_t)(n0 + r) * 32 + kq];
        else zv = make_float4(0.f, 0.f, 0.f, 0.f);
        int frag = (((r >> 4) * 4 + (kq >> 3)) * 4 + ((kq >> 1) & 3));
        int off = frag * 128 + (r & 15) * 8 + (kq & 1) * 4;   // ushort units
        uint2 w;
        w.x = pack2(zv.x, zv.y);
        w.y = pack2(zv.z, zv.w);
        *(uint2*)(&As[off]) = w;
    }
    __syncthreads();
    int lane = threadIdx.x & 63;
    int wid = threadIdx.x >> 6;
    int row = lane & 15, kg = lane >> 4;
    int colbase = wid * 64;
    f32x4 acc[4][4];
#pragma unroll
    for (int a = 0; a < 4; ++a)
#pragma unroll
        for (int b = 0; b < 4; ++b) acc[a][b] = (f32x4)(0.f);
#pragma unroll
    for (int k4 = 0; k4 < 4; ++k4) {
        short8v af[4], bf[4];
#pragma unroll
        for (int rb = 0; rb < 4; ++rb)
            af[rb] = *(const short8v*)(&As[((rb * 4 + k4) * 4 + kg) * 128 + row * 8]);
#pragma unroll
        for (int cf = 0; cf < 4; ++cf)
            bf[cf] = *(const short8v*)(Bp + ((k4 * 4 + kg) * 256 + colbase + cf * 16 + row) * 8);
#pragma unroll
        for (int rb = 0; rb < 4; ++rb)
#pragma unroll
            for (int cf = 0; cf < 4; ++cf)
                acc[rb][cf] = __builtin_amdgcn_mfma_f32_16x16x32_bf16(af[rb], bf[cf],
                                                                      acc[rb][cf], 0, 0, 0);
    }
    // epilogue: +bias, store t, per-column sum/sumsq partials
#pragma unroll
    for (int cf = 0; cf < 4; ++cf) {
        int j = colbase + cf * 16 + row;
        float bj = bias[j];
        float s = 0.f, q = 0.f;
#pragma unroll
        for (int rb = 0; rb < 4; ++rb) {
#pragma unroll
            for (int r = 0; r < 4; ++r) {
                int gr = n0 + rb * 16 + kg * 4 + r;
                if (gr < N_NODES) {
                    float v = acc[rb][cf][r] + bj;
                    t[(size_t)gr * 256 + j] = v;
                    s += v;
                    q += v * v;
                }
            }
        }
        s += __shfl_xor(s, 16); s += __shfl_xor(s, 32);
        q += __shfl_xor(q, 16); q += __shfl_xor(q, 32);
        if (lane < 16) {
            atomicAdd(&stats[j], s);
            atomicAdd(&stats[256 + j], q);
        }
    }
}

// ---------------------------------------------- BN finalize -> scale/shift
__global__ void k_bn_final(const float* __restrict__ sums, int C,
                           const float* __restrict__ g, const float* __restrict__ b,
                           float* __restrict__ scale, float* __restrict__ shift) {
    int j = threadIdx.x;
    if (j >= C) return;
    float m = sums[j] * (1.0f / N_NODES);
    float var = sums[C + j] * (1.0f / N_NODES) - m * m;
    float sc = g[j] / sqrtf(var + 1e-5f);
    scale[j] = sc;
    shift[j] = b[j] - m * sc;
}

// ------- GEMM2 (MFMA): u = relu(BN1(t))@W2 + b2, fused BN2 column stats
// BM=64, N=128, K=256. 4 waves; wave w -> cols [w*32, w*32+32)
__global__ __launch_bounds__(256) void k_gemm2(
    const float* __restrict__ t, const unsigned short* __restrict__ Bp,
    const float* __restrict__ scale1, const float* __restrict__ shift1,
    const float* __restrict__ bias, float* __restrict__ u,
    float* __restrict__ osum, float* __restrict__ osq) {
    __shared__ unsigned short As[16384] __attribute__((aligned(16)));  // 32 KB
    int n0 = blockIdx.x * 64;
    // stage relu(scale1*t+shift1)[64x256] -> bf16 MFMA-A layout (k4 0..7)
    for (int s = 0; s < 16; ++s) {
        int i = threadIdx.x + s * 256;            // float4 index
        int r = i >> 6, kq = i & 63;
        int k = kq * 4;
        float4 tv;
        if (n0 + r < N_NODES) tv = ((const float4*)t)[(size_t)(n0 + r) * 64 + kq];
        else tv = make_float4(0.f, 0.f, 0.f, 0.f);
        float4 sc = *(const float4*)(scale1 + k);
        float4 sh = *(const float4*)(shift1 + k);
        float vx = fmaxf(fmaf(sc.x, tv.x, sh.x), 0.f);
        float vy = fmaxf(fmaf(sc.y, tv.y, sh.y), 0.f);
        float vz = fmaxf(fmaf(sc.z, tv.z, sh.z), 0.f);
        float vw = fmaxf(fmaf(sc.w, tv.w, sh.w), 0.f);
        int frag = (((r >> 4) * 8 + (kq >> 3)) * 4 + ((kq >> 1) & 3));
        int off = frag * 128 + (r & 15) * 8 + (kq & 1) * 4;
        uint2 w;
        w.x = pack2(vx, vy);
        w.y = pack2(vz, vw);
        *(uint2*)(&As[off]) = w;
    }
    __syncthreads();
    int lane = threadIdx.x & 63;
    int wid = threadIdx.x >> 6;
    int row = lane & 15, kg = lane >> 4;
    int colbase = wid * 32;
    f32x4 acc[4][2];
#pragma unroll
    for (int a = 0; a < 4; ++a) {
        acc[a][0] = (f32x4)(0.f);
        acc[a][1] = (f32x4)(0.f);
    }
#pragma unroll
    for (int k4 = 0; k4 < 8; ++k4) {
        short8v af[4], bf[2];
#pragma unroll
        for (int rb = 0; rb < 4; ++rb)
            af[rb] = *(const short8v*)(&As[((rb * 8 + k4) * 4 + kg) * 128 + row * 8]);
#pragma unroll
        for (int cf = 0; cf < 2; ++cf)
            bf[cf] = *(const short8v*)(Bp + ((k4 * 4 + kg) * 128 + colbase + cf * 16 + row) * 8);
#pragma unroll
        for (int rb = 0; rb < 4; ++rb)
#pragma unroll
            for (int cf = 0; cf < 2; ++cf)
                acc[rb][cf] = __builtin_amdgcn_mfma_f32_16x16x32_bf16(af[rb], bf[cf],
                                                                      acc[rb][cf], 0, 0, 0);
    }
#pragma unroll
    for (int cf = 0; cf < 2; ++cf) {
        int j = colbase + cf * 16 + row;
        float bj = bias[j];
        float s = 0.f, q = 0.f;
#pragma unroll
        for (int rb = 0; rb < 4; ++rb) {
#pragma unroll
            for (int r = 0; r < 4; ++r) {
                int gr = n0 + rb * 16 + kg * 4 + r;
                if (gr < N_NODES) {
                    float v = acc[rb][cf][r] + bj;
                    u[(size_t)gr * 128 + j] = v;
                    s += v;
                    q += v * v;
                }
            }
        }
        s += __shfl_xor(s, 16); s += __shfl_xor(s, 32);
        q += __shfl_xor(q, 16); q += __shfl_xor(q, 32);
        if (lane < 16) {
            atomicAdd(&osum[j], s);
            atomicAdd(&osq[j], q);
        }
    }
}

// --------------------------------------- h += maybe_relu(BN2(u))  (elementwise)
__global__ void k_update_h(float* __restrict__ h, const float* __restrict__ u,
                           const float* __restrict__ scale2, const float* __restrict__ shift2,
                           int relu) {
    int i = blockIdx.x * 256 + threadIdx.x;  // float4 index, total N*128/4
    int d4 = i & 31;
    float4 uv = ((const float4*)u)[i];
    float4 sc = ((const float4*)scale2)[d4];
    float4 sh = ((const float4*)shift2)[d4];
    float4 hv = ((const float4*)h)[i];
    float vx = fmaf(sc.x, uv.x, sh.x);
    float vy = fmaf(sc.y, uv.y, sh.y);
    float vz = fmaf(sc.z, uv.z, sh.z);
    float vw = fmaf(sc.w, uv.w, sh.w);
    if (relu) {
        vx = fmaxf(vx, 0.f); vy = fmaxf(vy, 0.f);
        vz = fmaxf(vz, 0.f); vw = fmaxf(vw, 0.f);
    }
    hv.x += vx; hv.y += vy; hv.z += vz; hv.w += vw;
    ((float4*)h)[i] = hv;
}

// --------------------------------------- init the 4 G-sized segment-sum outputs
__global__ void k_init_seg(float* __restrict__ out) {
    int i = blockIdx.x * 256 + threadIdx.x;
    if (i < 4 * N_GRAPHS) out[N_NODES + N_EDGES + i] = 1e-8f;
}

// ------------- node head: node_key + per-node dots p,q + node segment sums
__global__ void k_node_out(const float* __restrict__ h, const int* __restrict__ batch,
                           const float* __restrict__ nW, const float* __restrict__ nb,
                           const float* __restrict__ eW,
                           float* __restrict__ out, float* __restrict__ p,
                           float* __restrict__ q) {
    int n = blockIdx.x * 4 + (threadIdx.x >> 6);
    int lane = threadIdx.x & 63;
    if (n >= N_NODES) return;
    float2 hv = ((const float2*)(h + (size_t)n * 128))[lane];
    float2 wn = ((const float2*)nW)[lane];
    float2 wa = ((const float2*)eW)[lane];
    float2 wb = ((const float2*)eW)[64 + lane];
    float dn = hv.x * wn.x + hv.y * wn.y;
    float da = hv.x * wa.x + hv.y * wa.y;
    float db = hv.x * wb.x + hv.y * wb.y;
#pragma unroll
    for (int off = 32; off; off >>= 1) {
        dn += __shfl_xor(dn, off);
        da += __shfl_xor(da, off);
        db += __shfl_xor(db, off);
    }
    if (lane == 0) {
        float nk = 1.f / (1.f + expf(-(dn + nb[0])));
        out[n] = nk;
        int g = batch[n];
        atomicAdd(&out[N_NODES + N_EDGES + g], nk);
        atomicAdd(&out[N_NODES + N_EDGES + N_GRAPHS + g], 1.0f - nk);
        p[n] = da;
        q[n] = db;
    }
}

// ------------- edge head: edge_key = sigmoid(p[row]+q[col]+b) + edge seg sums
__global__ void k_edge_out(const int* __restrict__ ei, const int* __restrict__ batch,
                           const float* __restrict__ p, const float* __restrict__ q,
                           const float* __restrict__ eb, float* __restrict__ out) {
    int e = blockIdx.x * 256 + threadIdx.x;
    if (e >= N_EDGES) return;
    int r = ei[e], c = ei[N_EDGES + e];
    float ek = 1.f / (1.f + expf(-(p[r] + q[c] + eb[0])));
    out[N_NODES + e] = ek;
    int g = batch[r];
    atomicAdd(&out[N_NODES + N_EDGES + 2 * N_GRAPHS + g], ek);
    atomicAdd(&out[N_NODES + N_EDGES + 3 * N_GRAPHS + g], 1.0f - ek);
}

extern "C" void kernel_launch(void* const* d_in, const int* in_sizes, int n_in,
                              void* d_out, int out_size, void* d_ws, size_t ws_size,
                              hipStream_t stream) {
    const int*   x     = (const int*)d_in[0];
    const int*   ei    = (const int*)d_in[1];
    const int*   ea    = (const int*)d_in[2];
    const int*   batch = (const int*)d_in[3];
    const float* at    = (const float*)d_in[4];
    const float* bt    = (const float*)d_in[5];
    const float* eps   = (const float*)d_in[6];
    const float* W1    = (const float*)d_in[7];
    const float* b1    = (const float*)d_in[8];
    const float* bn1g  = (const float*)d_in[9];
    const float* bn1b  = (const float*)d_in[10];
    const float* W2    = (const float*)d_in[11];
    const float* b2    = (const float*)d_in[12];
    const float* obng  = (const float*)d_in[13];
    const float* obnb  = (const float*)d_in[14];
    const float* nW    = (const float*)d_in[15];
    const float* nb    = (const float*)d_in[16];
    const float* eW    = (const float*)d_in[17];
    const float* eb    = (const float*)d_in[18];
    float* out = (float*)d_out;

    float* ws    = (float*)d_ws;
    float* h     = ws;                   // N*128
    float* t     = h + 12800000;         // N*256
    float* zu    = t + 25600000;         // N*128 (z for gemm1, then u from gemm2)
    float* stats = zu + 12800000;        // 1536
    float* p     = stats + 1536;         // N
    float* q     = p + N_NODES;          // N
    unsigned short* Bp1 = (unsigned short*)(q + N_NODES);  // 3*128*256 bf16 (16B-aligned)
    unsigned short* Bp2 = Bp1 + 3 * 32768;                 // 3*256*128 bf16
    int* rowptr  = (int*)(Bp2 + 3 * 32768);  // N+1
    int* cursor  = rowptr + N_NODES + 1;     // N
    int* csr     = cursor + N_NODES;         // E
    // stats layout: [sum256][sq256][osum128][osq128][scale1@768][shift1@1024][scale2@1280][shift2@1408]

    k_atom_encode<<<50000, 256, 0, stream>>>(x, at, h);
    k_convw<<<768, 256, 0, stream>>>(W1, W2, Bp1, Bp2);

    // CSR of edges grouped by destination (col)
    hipMemsetAsync(cursor, 0, N_NODES * sizeof(int), stream);
    k_hist<<<2344, 256, 0, stream>>>(ei, cursor);
    k_scan<<<1, 1024, 0, stream>>>(cursor, rowptr);
    k_fill<<<2344, 256, 0, stream>>>(ei, cursor, csr);

    for (int l = 0; l < 3; ++l) {
        hipMemsetAsync(stats, 0, 768 * 4, stream);
        k_gather<<<25000, 256, 0, stream>>>(h, ei, ea, bt + (size_t)l * 3 * 8 * 128,
                                            rowptr, csr, eps, l, zu);
        k_gemm1<<<1563, 256, 0, stream>>>(zu, Bp1 + (size_t)l * 32768, b1 + l * 256, t, stats);
        k_bn_final<<<1, 256, 0, stream>>>(stats, 256, bn1g + l * 256, bn1b + l * 256,
                                          stats + 768, stats + 1024);
        k_gemm2<<<1563, 256, 0, stream>>>(t, Bp2 + (size_t)l * 32768, stats + 768, stats + 1024,
                                          b2 + l * 128, zu, stats + 512, stats + 640);
        k_bn_final<<<1, 128, 0, stream>>>(stats + 512, 128, obng + l * 128, obnb + l * 128,
                                          stats + 1280, stats + 1408);
        k_update_h<<<12500, 256, 0, stream>>>(h, zu, stats + 1280, stats + 1408,
                                              (l < 2) ? 1 : 0);
    }

    k_init_seg<<<64, 256, 0, stream>>>(out);
    k_node_out<<<25000, 256, 0, stream>>>(h, batch, nW, nb, eW, out, p, q);
    k_edge_out<<<2344, 256, 0, stream>>>(ei, batch, p, q, eb, out);
}

// Round 4
// 1153.459 us; speedup vs baseline: 3.0087x; 1.1827x over previous
//
#include <hip/hip_runtime.h>
#include <math.h>

#define N_NODES 100000
#define N_EDGES 600000
#define N_GRAPHS 4096
#define SCAN_CHUNK 512
#define SCAN_NBLK 196   // ceil(100000/512)

typedef __attribute__((ext_vector_type(8))) short short8v;   // 8 bf16 (4 VGPR)
typedef __attribute__((ext_vector_type(4))) float f32x4;

__device__ __forceinline__ unsigned short bf16_rne(float f) {
    unsigned int u = __float_as_uint(f);
    u += 0x7fffu + ((u >> 16) & 1u);
    return (unsigned short)(u >> 16);
}
__device__ __forceinline__ unsigned int pack2(float a, float b) {
    return (unsigned int)bf16_rne(a) | ((unsigned int)bf16_rne(b) << 16);
}

// ---------------------------------------------------------------- atom encoder
__global__ void k_atom_encode(const int* __restrict__ x, const float* __restrict__ at,
                              float* __restrict__ h) {
    int n = blockIdx.x * 2 + (threadIdx.x >> 7);
    int d = threadIdx.x & 127;
    if (n >= N_NODES) return;
    const int* xr = x + n * 9;
    float s = 0.f;
#pragma unroll
    for (int f = 0; f < 9; ++f) {
        int v = xr[f];
        s += at[(f * 100 + v) * 128 + d];
    }
    h[(size_t)n * 128 + d] = s;
}

// ------------------------------------------------------------ CSR build (once)
__global__ void k_hist(const int* __restrict__ ei, int* __restrict__ cnt) {
    int e = blockIdx.x * 256 + threadIdx.x;
    if (e < N_EDGES) atomicAdd(&cnt[ei[N_EDGES + e]], 1);
}

// phase A: per-512-chunk sums
__global__ void k_scan_partial(const int* __restrict__ cnt, int* __restrict__ bsum) {
    __shared__ int ls[256];
    int base = blockIdx.x * SCAN_CHUNK;
    int t = threadIdx.x;
    int s = 0;
    for (int i = base + t; i < base + SCAN_CHUNK && i < N_NODES; i += 256) s += cnt[i];
    ls[t] = s;
    __syncthreads();
    for (int off = 128; off; off >>= 1) {
        if (t < off) ls[t] += ls[t + off];
        __syncthreads();
    }
    if (t == 0) bsum[blockIdx.x] = ls[0];
}

// phase B: exclusive scan of the 196 chunk sums (in place), total -> rowptr[N]
__global__ void k_scan_bsum(int* __restrict__ bsum, int* __restrict__ rowptr) {
    __shared__ int ls[256];
    int t = threadIdx.x;
    int v = (t < SCAN_NBLK) ? bsum[t] : 0;
    ls[t] = v;
    __syncthreads();
    for (int off = 1; off < 256; off <<= 1) {
        int x = (t >= off) ? ls[t - off] : 0;
        __syncthreads();
        ls[t] += x;
        __syncthreads();
    }
    if (t < SCAN_NBLK) bsum[t] = ls[t] - v;  // exclusive prefix
    if (t == 255) rowptr[N_NODES] = ls[255];
}

// phase C: local scan + chunk offset; counts buffer becomes cursor (in place)
__global__ __launch_bounds__(512) void k_scan_final(const int* __restrict__ bsum,
                                                    int* __restrict__ cnt_cursor,
                                                    int* __restrict__ rowptr) {
    __shared__ int ls[512];
    int base = blockIdx.x * SCAN_CHUNK;
    int t = threadIdx.x;
    int i = base + t;
    int v = (i < N_NODES) ? cnt_cursor[i] : 0;
    ls[t] = v;
    __syncthreads();
    for (int off = 1; off < 512; off <<= 1) {
        int x = (t >= off) ? ls[t - off] : 0;
        __syncthreads();
        ls[t] += x;
        __syncthreads();
    }
    if (i < N_NODES) {
        int excl = bsum[blockIdx.x] + ls[t] - v;
        rowptr[i] = excl;
        cnt_cursor[i] = excl;
    }
}

__global__ void k_fill(const int* __restrict__ ei, int* __restrict__ cursor,
                       int* __restrict__ csr) {
    int e = blockIdx.x * 256 + threadIdx.x;
    if (e < N_EDGES) {
        int c = ei[N_EDGES + e];
        int pos = atomicAdd(&cursor[c], 1);
        csr[pos] = e;
    }
}

// ---------------- weight pre-swizzle: fp32 -> bf16 in MFMA B-fragment layout
__global__ void k_convw(const float* __restrict__ W1, const float* __restrict__ W2,
                        unsigned short* __restrict__ Bp1, unsigned short* __restrict__ Bp2) {
    int idx = blockIdx.x * 256 + threadIdx.x;
    if (idx < 3 * 128 * 256) {
        int l = idx >> 15, r = idx & 32767;
        int k = r >> 8, j = r & 255;
        float v = W1[(size_t)l * 32768 + k * 256 + j];
        Bp1[(size_t)l * 32768 + (((k >> 5) * 4 + ((k >> 3) & 3)) * 256 + j) * 8 + (k & 7)] =
            bf16_rne(v);
    } else if (idx < 6 * 128 * 256) {
        int t = idx - 98304;
        int l = t >> 15, r = t & 32767;
        int k = r >> 7, j = r & 127;
        float v = W2[(size_t)l * 32768 + k * 128 + j];
        Bp2[(size_t)l * 32768 + (((k >> 5) * 4 + ((k >> 3) & 3)) * 128 + j) * 8 + (k & 7)] =
            bf16_rne(v);
    }
}

// ---------------------------- gather-aggregate: z = (1+eps)*h + sum relu(msg)
__global__ void k_gather(const float* __restrict__ h, const int* __restrict__ ei,
                         const int* __restrict__ ea, const float* __restrict__ bt_g,
                         const int* __restrict__ rowptr, const int* __restrict__ csr,
                         const float* __restrict__ eps, int l,
                         float* __restrict__ z) {
    __shared__ float bt[3 * 8 * 128];
    for (int i = threadIdx.x; i < 3 * 8 * 128; i += 256) bt[i] = bt_g[i];
    __syncthreads();
    int lane = threadIdx.x & 63;
    int n = blockIdx.x * 4 + (threadIdx.x >> 6);
    if (n >= N_NODES) return;
    int i0 = rowptr[n], i1 = rowptr[n + 1];
    float ax = 0.f, ay = 0.f;
    for (int i = i0; i < i1; ++i) {
        int e = csr[i];
        int r = ei[e];
        int a0 = ea[e * 3 + 0], a1 = ea[e * 3 + 1], a2 = ea[e * 3 + 2];
        float2 hv = ((const float2*)(h + (size_t)r * 128))[lane];
        float2 e0 = ((const float2*)(bt + a0 * 128))[lane];
        float2 e1 = ((const float2*)(bt + 1024 + a1 * 128))[lane];
        float2 e2 = ((const float2*)(bt + 2048 + a2 * 128))[lane];
        ax += fmaxf(hv.x + e0.x + e1.x + e2.x, 0.f);
        ay += fmaxf(hv.y + e0.y + e1.y + e2.y, 0.f);
    }
    float el = 1.0f + eps[l];
    float2 hn = ((const float2*)(h + (size_t)n * 128))[lane];
    float2 zv;
    zv.x = fmaf(el, hn.x, ax);
    zv.y = fmaf(el, hn.y, ay);
    ((float2*)(z + (size_t)n * 128))[lane] = zv;
}

// --------------------- GEMM1 (MFMA): t = z@W1 + b1, fused BN1 column stats
__global__ __launch_bounds__(256) void k_gemm1(
    const float* __restrict__ z, const unsigned short* __restrict__ Bp,
    const float* __restrict__ bias, float* __restrict__ t,
    float* __restrict__ stats) {
    __shared__ unsigned short As[8192] __attribute__((aligned(16)));  // 16 KB
    int n0 = blockIdx.x * 64;
    for (int s = 0; s < 8; ++s) {
        int i = threadIdx.x + s * 256;            // float4 index
        int r = i >> 5, kq = i & 31;
        float4 zv;
        if (n0 + r < N_NODES) zv = ((const float4*)z)[(size_t)(n0 + r) * 32 + kq];
        else zv = make_float4(0.f, 0.f, 0.f, 0.f);
        int frag = (((r >> 4) * 4 + (kq >> 3)) * 4 + ((kq >> 1) & 3));
        int off = frag * 128 + (r & 15) * 8 + (kq & 1) * 4;   // ushort units
        uint2 w;
        w.x = pack2(zv.x, zv.y);
        w.y = pack2(zv.z, zv.w);
        *(uint2*)(&As[off]) = w;
    }
    __syncthreads();
    int lane = threadIdx.x & 63;
    int wid = threadIdx.x >> 6;
    int row = lane & 15, kg = lane >> 4;
    int colbase = wid * 64;
    f32x4 acc[4][4];
#pragma unroll
    for (int a = 0; a < 4; ++a)
#pragma unroll
        for (int b = 0; b < 4; ++b) acc[a][b] = (f32x4)(0.f);
#pragma unroll
    for (int k4 = 0; k4 < 4; ++k4) {
        short8v af[4], bf[4];
#pragma unroll
        for (int rb = 0; rb < 4; ++rb)
            af[rb] = *(const short8v*)(&As[((rb * 4 + k4) * 4 + kg) * 128 + row * 8]);
#pragma unroll
        for (int cf = 0; cf < 4; ++cf)
            bf[cf] = *(const short8v*)(Bp + ((k4 * 4 + kg) * 256 + colbase + cf * 16 + row) * 8);
#pragma unroll
        for (int rb = 0; rb < 4; ++rb)
#pragma unroll
            for (int cf = 0; cf < 4; ++cf)
                acc[rb][cf] = __builtin_amdgcn_mfma_f32_16x16x32_bf16(af[rb], bf[cf],
                                                                      acc[rb][cf], 0, 0, 0);
    }
#pragma unroll
    for (int cf = 0; cf < 4; ++cf) {
        int j = colbase + cf * 16 + row;
        float bj = bias[j];
        float s = 0.f, q = 0.f;
#pragma unroll
        for (int rb = 0; rb < 4; ++rb) {
#pragma unroll
            for (int r = 0; r < 4; ++r) {
                int gr = n0 + rb * 16 + kg * 4 + r;
                if (gr < N_NODES) {
                    float v = acc[rb][cf][r] + bj;
                    t[(size_t)gr * 256 + j] = v;
                    s += v;
                    q += v * v;
                }
            }
        }
        s += __shfl_xor(s, 16); s += __shfl_xor(s, 32);
        q += __shfl_xor(q, 16); q += __shfl_xor(q, 32);
        if (lane < 16) {
            atomicAdd(&stats[j], s);
            atomicAdd(&stats[256 + j], q);
        }
    }
}

// ---------------------------------------------- BN finalize -> scale/shift
__global__ void k_bn_final(const float* __restrict__ sums, int C,
                           const float* __restrict__ g, const float* __restrict__ b,
                           float* __restrict__ scale, float* __restrict__ shift) {
    int j = threadIdx.x;
    if (j >= C) return;
    float m = sums[j] * (1.0f / N_NODES);
    float var = sums[C + j] * (1.0f / N_NODES) - m * m;
    float sc = g[j] / sqrtf(var + 1e-5f);
    scale[j] = sc;
    shift[j] = b[j] - m * sc;
}

// ------- GEMM2 (MFMA): u = relu(BN1(t))@W2 + b2, fused BN2 column stats
__global__ __launch_bounds__(256) void k_gemm2(
    const float* __restrict__ t, const unsigned short* __restrict__ Bp,
    const float* __restrict__ scale1, const float* __restrict__ shift1,
    const float* __restrict__ bias, float* __restrict__ u,
    float* __restrict__ osum, float* __restrict__ osq) {
    __shared__ unsigned short As[16384] __attribute__((aligned(16)));  // 32 KB
    int n0 = blockIdx.x * 64;
    for (int s = 0; s < 16; ++s) {
        int i = threadIdx.x + s * 256;            // float4 index
        int r = i >> 6, kq = i & 63;
        int k = kq * 4;
        float4 tv;
        if (n0 + r < N_NODES) tv = ((const float4*)t)[(size_t)(n0 + r) * 64 + kq];
        else tv = make_float4(0.f, 0.f, 0.f, 0.f);
        float4 sc = *(const float4*)(scale1 + k);
        float4 sh = *(const float4*)(shift1 + k);
        float vx = fmaxf(fmaf(sc.x, tv.x, sh.x), 0.f);
        float vy = fmaxf(fmaf(sc.y, tv.y, sh.y), 0.f);
        float vz = fmaxf(fmaf(sc.z, tv.z, sh.z), 0.f);
        float vw = fmaxf(fmaf(sc.w, tv.w, sh.w), 0.f);
        int frag = (((r >> 4) * 8 + (kq >> 3)) * 4 + ((kq >> 1) & 3));
        int off = frag * 128 + (r & 15) * 8 + (kq & 1) * 4;
        uint2 w;
        w.x = pack2(vx, vy);
        w.y = pack2(vz, vw);
        *(uint2*)(&As[off]) = w;
    }
    __syncthreads();
    int lane = threadIdx.x & 63;
    int wid = threadIdx.x >> 6;
    int row = lane & 15, kg = lane >> 4;
    int colbase = wid * 32;
    f32x4 acc[4][2];
#pragma unroll
    for (int a = 0; a < 4; ++a) {
        acc[a][0] = (f32x4)(0.f);
        acc[a][1] = (f32x4)(0.f);
    }
#pragma unroll
    for (int k4 = 0; k4 < 8; ++k4) {
        short8v af[4], bf[2];
#pragma unroll
        for (int rb = 0; rb < 4; ++rb)
            af[rb] = *(const short8v*)(&As[((rb * 8 + k4) * 4 + kg) * 128 + row * 8]);
#pragma unroll
        for (int cf = 0; cf < 2; ++cf)
            bf[cf] = *(const short8v*)(Bp + ((k4 * 4 + kg) * 128 + colbase + cf * 16 + row) * 8);
#pragma unroll
        for (int rb = 0; rb < 4; ++rb)
#pragma unroll
            for (int cf = 0; cf < 2; ++cf)
                acc[rb][cf] = __builtin_amdgcn_mfma_f32_16x16x32_bf16(af[rb], bf[cf],
                                                                      acc[rb][cf], 0, 0, 0);
    }
#pragma unroll
    for (int cf = 0; cf < 2; ++cf) {
        int j = colbase + cf * 16 + row;
        float bj = bias[j];
        float s = 0.f, q = 0.f;
#pragma unroll
        for (int rb = 0; rb < 4; ++rb) {
#pragma unroll
            for (int r = 0; r < 4; ++r) {
                int gr = n0 + rb * 16 + kg * 4 + r;
                if (gr < N_NODES) {
                    float v = acc[rb][cf][r] + bj;
                    u[(size_t)gr * 128 + j] = v;
                    s += v;
                    q += v * v;
                }
            }
        }
        s += __shfl_xor(s, 16); s += __shfl_xor(s, 32);
        q += __shfl_xor(q, 16); q += __shfl_xor(q, 32);
        if (lane < 16) {
            atomicAdd(&osum[j], s);
            atomicAdd(&osq[j], q);
        }
    }
}

// --------------------------------------- h += maybe_relu(BN2(u))  (elementwise)
__global__ void k_update_h(float* __restrict__ h, const float* __restrict__ u,
                           const float* __restrict__ scale2, const float* __restrict__ shift2,
                           int relu) {
    int i = blockIdx.x * 256 + threadIdx.x;  // float4 index, total N*128/4
    int d4 = i & 31;
    float4 uv = ((const float4*)u)[i];
    float4 sc = ((const float4*)scale2)[d4];
    float4 sh = ((const float4*)shift2)[d4];
    float4 hv = ((const float4*)h)[i];
    float vx = fmaf(sc.x, uv.x, sh.x);
    float vy = fmaf(sc.y, uv.y, sh.y);
    float vz = fmaf(sc.z, uv.z, sh.z);
    float vw = fmaf(sc.w, uv.w, sh.w);
    if (relu) {
        vx = fmaxf(vx, 0.f); vy = fmaxf(vy, 0.f);
        vz = fmaxf(vz, 0.f); vw = fmaxf(vw, 0.f);
    }
    hv.x += vx; hv.y += vy; hv.z += vz; hv.w += vw;
    ((float4*)h)[i] = hv;
}

// --------------------------------------- init the 4 G-sized segment-sum outputs
__global__ void k_init_seg(float* __restrict__ out) {
    int i = blockIdx.x * 256 + threadIdx.x;
    if (i < 4 * N_GRAPHS) out[N_NODES + N_EDGES + i] = 1e-8f;
}

// ------------- node head: node_key + per-node dots p,q + node segment sums
__global__ void k_node_out(const float* __restrict__ h, const int* __restrict__ batch,
                           const float* __restrict__ nW, const float* __restrict__ nb,
                           const float* __restrict__ eW,
                           float* __restrict__ out, float* __restrict__ p,
                           float* __restrict__ q) {
    int n = blockIdx.x * 4 + (threadIdx.x >> 6);
    int lane = threadIdx.x & 63;
    if (n >= N_NODES) return;
    float2 hv = ((const float2*)(h + (size_t)n * 128))[lane];
    float2 wn = ((const float2*)nW)[lane];
    float2 wa = ((const float2*)eW)[lane];
    float2 wb = ((const float2*)eW)[64 + lane];
    float dn = hv.x * wn.x + hv.y * wn.y;
    float da = hv.x * wa.x + hv.y * wa.y;
    float db = hv.x * wb.x + hv.y * wb.y;
#pragma unroll
    for (int off = 32; off; off >>= 1) {
        dn += __shfl_xor(dn, off);
        da += __shfl_xor(da, off);
        db += __shfl_xor(db, off);
    }
    if (lane == 0) {
        float nk = 1.f / (1.f + expf(-(dn + nb[0])));
        out[n] = nk;
        int g = batch[n];
        atomicAdd(&out[N_NODES + N_EDGES + g], nk);
        atomicAdd(&out[N_NODES + N_EDGES + N_GRAPHS + g], 1.0f - nk);
        p[n] = da;
        q[n] = db;
    }
}

// ------------- edge head: edge_key = sigmoid(p[row]+q[col]+b) + edge seg sums
__global__ void k_edge_out(const int* __restrict__ ei, const int* __restrict__ batch,
                           const float* __restrict__ p, const float* __restrict__ q,
                           const float* __restrict__ eb, float* __restrict__ out) {
    int e = blockIdx.x * 256 + threadIdx.x;
    if (e >= N_EDGES) return;
    int r = ei[e], c = ei[N_EDGES + e];
    float ek = 1.f / (1.f + expf(-(p[r] + q[c] + eb[0])));
    out[N_NODES + e] = ek;
    int g = batch[r];
    atomicAdd(&out[N_NODES + N_EDGES + 2 * N_GRAPHS + g], ek);
    atomicAdd(&out[N_NODES + N_EDGES + 3 * N_GRAPHS + g], 1.0f - ek);
}

extern "C" void kernel_launch(void* const* d_in, const int* in_sizes, int n_in,
                              void* d_out, int out_size, void* d_ws, size_t ws_size,
                              hipStream_t stream) {
    const int*   x     = (const int*)d_in[0];
    const int*   ei    = (const int*)d_in[1];
    const int*   ea    = (const int*)d_in[2];
    const int*   batch = (const int*)d_in[3];
    const float* at    = (const float*)d_in[4];
    const float* bt    = (const float*)d_in[5];
    const float* eps   = (const float*)d_in[6];
    const float* W1    = (const float*)d_in[7];
    const float* b1    = (const float*)d_in[8];
    const float* bn1g  = (const float*)d_in[9];
    const float* bn1b  = (const float*)d_in[10];
    const float* W2    = (const float*)d_in[11];
    const float* b2    = (const float*)d_in[12];
    const float* obng  = (const float*)d_in[13];
    const float* obnb  = (const float*)d_in[14];
    const float* nW    = (const float*)d_in[15];
    const float* nb    = (const float*)d_in[16];
    const float* eW    = (const float*)d_in[17];
    const float* eb    = (const float*)d_in[18];
    float* out = (float*)d_out;

    float* ws    = (float*)d_ws;
    float* h     = ws;                   // N*128
    float* t     = h + 12800000;         // N*256
    float* zu    = t + 25600000;         // N*128 (z for gemm1, then u from gemm2)
    float* stats = zu + 12800000;        // 1536
    float* p     = stats + 1536;         // N
    float* q     = p + N_NODES;          // N
    unsigned short* Bp1 = (unsigned short*)(q + N_NODES);  // 3*128*256 bf16
    unsigned short* Bp2 = Bp1 + 3 * 32768;                 // 3*256*128 bf16
    int* rowptr  = (int*)(Bp2 + 3 * 32768);  // N+1
    int* cursor  = rowptr + N_NODES + 1;     // N (counts, then cursors)
    int* csr     = cursor + N_NODES;         // E
    int* bsum    = csr + N_EDGES;            // SCAN_NBLK
    // stats layout: [sum256][sq256][osum128][osq128][scale1@768][shift1@1024][scale2@1280][shift2@1408]

    k_atom_encode<<<50000, 256, 0, stream>>>(x, at, h);
    k_convw<<<768, 256, 0, stream>>>(W1, W2, Bp1, Bp2);

    // CSR of edges grouped by destination (col) — parallel 3-phase scan
    hipMemsetAsync(cursor, 0, N_NODES * sizeof(int), stream);
    k_hist<<<2344, 256, 0, stream>>>(ei, cursor);
    k_scan_partial<<<SCAN_NBLK, 256, 0, stream>>>(cursor, bsum);
    k_scan_bsum<<<1, 256, 0, stream>>>(bsum, rowptr);
    k_scan_final<<<SCAN_NBLK, 512, 0, stream>>>(bsum, cursor, rowptr);
    k_fill<<<2344, 256, 0, stream>>>(ei, cursor, csr);

    for (int l = 0; l < 3; ++l) {
        hipMemsetAsync(stats, 0, 768 * 4, stream);
        k_gather<<<25000, 256, 0, stream>>>(h, ei, ea, bt + (size_t)l * 3 * 8 * 128,
                                            rowptr, csr, eps, l, zu);
        k_gemm1<<<1563, 256, 0, stream>>>(zu, Bp1 + (size_t)l * 32768, b1 + l * 256, t, stats);
        k_bn_final<<<1, 256, 0, stream>>>(stats, 256, bn1g + l * 256, bn1b + l * 256,
                                          stats + 768, stats + 1024);
        k_gemm2<<<1563, 256, 0, stream>>>(t, Bp2 + (size_t)l * 32768, stats + 768, stats + 1024,
                                          b2 + l * 128, zu, stats + 512, stats + 640);
        k_bn_final<<<1, 128, 0, stream>>>(stats + 512, 128, obng + l * 128, obnb + l * 128,
                                          stats + 1280, stats + 1408);
        k_update_h<<<12500, 256, 0, stream>>>(h, zu, stats + 1280, stats + 1408,
                                              (l < 2) ? 1 : 0);
    }

    k_init_seg<<<64, 256, 0, stream>>>(out);
    k_node_out<<<25000, 256, 0, stream>>>(h, batch, nW, nb, eW, out, p, q);
    k_edge_out<<<2344, 256, 0, stream>>>(ei, batch, p, q, eb, out);
}

// Round 5
// 934.262 us; speedup vs baseline: 3.7146x; 1.2346x over previous
//
#include <hip/hip_runtime.h>
#include <math.h>

#define N_NODES 100000
#define N_EDGES 600000
#define N_GRAPHS 4096
#define SCAN_CHUNK 512
#define SCAN_NBLK 196   // ceil(100000/512)

typedef __attribute__((ext_vector_type(8))) short short8v;   // 8 bf16 (4 VGPR)
typedef __attribute__((ext_vector_type(4))) float f32x4;

__device__ __forceinline__ unsigned short bf16_rne(float f) {
    unsigned int u = __float_as_uint(f);
    u += 0x7fffu + ((u >> 16) & 1u);
    return (unsigned short)(u >> 16);
}
__device__ __forceinline__ unsigned int pack2(float a, float b) {
    return (unsigned int)bf16_rne(a) | ((unsigned int)bf16_rne(b) << 16);
}
__device__ __forceinline__ float bf2f(unsigned short u) {
    return __uint_as_float(((unsigned int)u) << 16);
}

// ------------------------------------------- atom encoder (writes fp32 + bf16)
__global__ void k_atom_encode(const int* __restrict__ x, const float* __restrict__ at,
                              float* __restrict__ h, unsigned short* __restrict__ hb) {
    int n = blockIdx.x * 2 + (threadIdx.x >> 7);
    int d = threadIdx.x & 127;
    if (n >= N_NODES) return;
    const int* xr = x + n * 9;
    float s = 0.f;
#pragma unroll
    for (int f = 0; f < 9; ++f) {
        int v = xr[f];
        s += at[(f * 100 + v) * 128 + d];
    }
    h[(size_t)n * 128 + d] = s;
    hb[(size_t)n * 128 + d] = bf16_rne(s);
}

// ------------------------------------------------------------ CSR build (once)
__global__ void k_hist(const int* __restrict__ ei, int* __restrict__ cnt) {
    int e = blockIdx.x * 256 + threadIdx.x;
    if (e < N_EDGES) atomicAdd(&cnt[ei[N_EDGES + e]], 1);
}

__global__ void k_scan_partial(const int* __restrict__ cnt, int* __restrict__ bsum) {
    __shared__ int ls[256];
    int base = blockIdx.x * SCAN_CHUNK;
    int t = threadIdx.x;
    int s = 0;
    for (int i = base + t; i < base + SCAN_CHUNK && i < N_NODES; i += 256) s += cnt[i];
    ls[t] = s;
    __syncthreads();
    for (int off = 128; off; off >>= 1) {
        if (t < off) ls[t] += ls[t + off];
        __syncthreads();
    }
    if (t == 0) bsum[blockIdx.x] = ls[0];
}

__global__ void k_scan_bsum(int* __restrict__ bsum, int* __restrict__ rowptr) {
    __shared__ int ls[256];
    int t = threadIdx.x;
    int v = (t < SCAN_NBLK) ? bsum[t] : 0;
    ls[t] = v;
    __syncthreads();
    for (int off = 1; off < 256; off <<= 1) {
        int x = (t >= off) ? ls[t - off] : 0;
        __syncthreads();
        ls[t] += x;
        __syncthreads();
    }
    if (t < SCAN_NBLK) bsum[t] = ls[t] - v;  // exclusive prefix
    if (t == 255) rowptr[N_NODES] = ls[255];
}

__global__ __launch_bounds__(512) void k_scan_final(const int* __restrict__ bsum,
                                                    int* __restrict__ cnt_cursor,
                                                    int* __restrict__ rowptr) {
    __shared__ int ls[512];
    int base = blockIdx.x * SCAN_CHUNK;
    int t = threadIdx.x;
    int i = base + t;
    int v = (i < N_NODES) ? cnt_cursor[i] : 0;
    ls[t] = v;
    __syncthreads();
    for (int off = 1; off < 512; off <<= 1) {
        int x = (t >= off) ? ls[t - off] : 0;
        __syncthreads();
        ls[t] += x;
        __syncthreads();
    }
    if (i < N_NODES) {
        int excl = bsum[blockIdx.x] + ls[t] - v;
        rowptr[i] = excl;
        cnt_cursor[i] = excl;
    }
}

// fill CSR-ordered source-row + packed edge-attr arrays (kills 2 indirections)
__global__ void k_fill(const int* __restrict__ ei, const int* __restrict__ ea,
                       int* __restrict__ cursor,
                       int* __restrict__ csr_row, int* __restrict__ csr_attr) {
    int e = blockIdx.x * 256 + threadIdx.x;
    if (e < N_EDGES) {
        int c = ei[N_EDGES + e];
        int pos = atomicAdd(&cursor[c], 1);
        csr_row[pos] = ei[e];
        csr_attr[pos] = ea[e * 3] | (ea[e * 3 + 1] << 8) | (ea[e * 3 + 2] << 16);
    }
}

// ---------------- weight pre-swizzle: fp32 -> bf16 in MFMA B-fragment layout
__global__ void k_convw(const float* __restrict__ W1, const float* __restrict__ W2,
                        unsigned short* __restrict__ Bp1, unsigned short* __restrict__ Bp2) {
    int idx = blockIdx.x * 256 + threadIdx.x;
    if (idx < 3 * 128 * 256) {
        int l = idx >> 15, r = idx & 32767;
        int k = r >> 8, j = r & 255;
        float v = W1[(size_t)l * 32768 + k * 256 + j];
        Bp1[(size_t)l * 32768 + (((k >> 5) * 4 + ((k >> 3) & 3)) * 256 + j) * 8 + (k & 7)] =
            bf16_rne(v);
    } else if (idx < 6 * 128 * 256) {
        int t = idx - 98304;
        int l = t >> 15, r = t & 32767;
        int k = r >> 7, j = r & 127;
        float v = W2[(size_t)l * 32768 + k * 128 + j];
        Bp2[(size_t)l * 32768 + (((k >> 5) * 4 + ((k >> 3) & 3)) * 128 + j) * 8 + (k & 7)] =
            bf16_rne(v);
    }
}

// ---------------------------- gather-aggregate: z = (1+eps)*h + sum relu(msg)
// wave per node; bf16 h rows; 4-wide unroll for load-latency overlap
#define ACC_EDGE(u, qv)                                                       \
    {                                                                         \
        float hx = bf2f((unsigned short)((u) & 0xffffu));                     \
        float hy = bf2f((unsigned short)((u) >> 16));                         \
        float2 e0 = ((const float2*)(bt + ((qv) & 255) * 128))[lane];         \
        float2 e1 = ((const float2*)(bt + 1024 + (((qv) >> 8) & 255) * 128))[lane]; \
        float2 e2 = ((const float2*)(bt + 2048 + (((qv) >> 16) & 255) * 128))[lane]; \
        ax += fmaxf(hx + e0.x + e1.x + e2.x, 0.f);                            \
        ay += fmaxf(hy + e0.y + e1.y + e2.y, 0.f);                            \
    }

__global__ void k_gather(const unsigned short* __restrict__ hb, const float* __restrict__ h,
                         const int* __restrict__ csr_row, const int* __restrict__ csr_attr,
                         const int* __restrict__ rowptr, const float* __restrict__ bt_g,
                         const float* __restrict__ eps, int l,
                         unsigned short* __restrict__ zb) {
    __shared__ float bt[3 * 8 * 128];
    for (int i = threadIdx.x; i < 3 * 8 * 128; i += 256) bt[i] = bt_g[i];
    __syncthreads();
    int lane = threadIdx.x & 63;
    int n = blockIdx.x * 4 + (threadIdx.x >> 6);
    if (n >= N_NODES) return;
    int i0 = rowptr[n], i1 = rowptr[n + 1];
    float ax = 0.f, ay = 0.f;
    int i = i0;
    for (; i + 4 <= i1; i += 4) {
        int r0 = csr_row[i], r1 = csr_row[i + 1], r2 = csr_row[i + 2], r3 = csr_row[i + 3];
        int q0 = csr_attr[i], q1 = csr_attr[i + 1], q2 = csr_attr[i + 2], q3 = csr_attr[i + 3];
        unsigned int u0 = ((const unsigned int*)(hb + (size_t)r0 * 128))[lane];
        unsigned int u1 = ((const unsigned int*)(hb + (size_t)r1 * 128))[lane];
        unsigned int u2 = ((const unsigned int*)(hb + (size_t)r2 * 128))[lane];
        unsigned int u3 = ((const unsigned int*)(hb + (size_t)r3 * 128))[lane];
        ACC_EDGE(u0, q0); ACC_EDGE(u1, q1); ACC_EDGE(u2, q2); ACC_EDGE(u3, q3);
    }
    for (; i < i1; ++i) {
        int r0 = csr_row[i];
        int q0 = csr_attr[i];
        unsigned int u0 = ((const unsigned int*)(hb + (size_t)r0 * 128))[lane];
        ACC_EDGE(u0, q0);
    }
    float el = 1.0f + eps[l];
    float2 hn = ((const float2*)(h + (size_t)n * 128))[lane];
    ((unsigned int*)(zb + (size_t)n * 128))[lane] =
        pack2(fmaf(el, hn.x, ax), fmaf(el, hn.y, ay));
}

// --------------------- GEMM1 (MFMA): t = z@W1 + b1, fused BN1 column stats
// BM=64, N=256, K=128; 4 waves -> 64 cols each; bf16 in, bf16 out, fp32 stats
__global__ __launch_bounds__(256) void k_gemm1(
    const unsigned short* __restrict__ zb, const unsigned short* __restrict__ Bp,
    const float* __restrict__ bias, unsigned short* __restrict__ tb,
    float* __restrict__ stats) {
    __shared__ unsigned short As[8192] __attribute__((aligned(16)));  // 16 KB
    int n0 = blockIdx.x * 64;
#pragma unroll
    for (int s = 0; s < 4; ++s) {
        int i = threadIdx.x + s * 256;            // 16B unit; 64 rows x 16 units
        int r = i >> 4, k8 = i & 15;
        short8v v = (short8v)(short)0;
        if (n0 + r < N_NODES) v = ((const short8v*)(zb + (size_t)(n0 + r) * 128))[k8];
        int frag = (r >> 4) * 16 + k8;
        int off = (frag * 128 + (r & 15) * 8) ^ ((k8 & 7) << 3);
        *(short8v*)(&As[off]) = v;
    }
    __syncthreads();
    int lane = threadIdx.x & 63;
    int wid = threadIdx.x >> 6;
    int row = lane & 15, kg = lane >> 4;
    int colbase = wid * 64;
    f32x4 acc[4][4];
#pragma unroll
    for (int a = 0; a < 4; ++a)
#pragma unroll
        for (int b = 0; b < 4; ++b) acc[a][b] = (f32x4)(0.f);
#pragma unroll
    for (int k4 = 0; k4 < 4; ++k4) {
        short8v af[4], bf[4];
#pragma unroll
        for (int rb = 0; rb < 4; ++rb)
            af[rb] = *(const short8v*)(&As[((rb * 16 + k4 * 4 + kg) * 128 + row * 8) ^
                                           (((k4 * 4 + kg) & 7) << 3)]);
#pragma unroll
        for (int cf = 0; cf < 4; ++cf)
            bf[cf] = *(const short8v*)(Bp + ((k4 * 4 + kg) * 256 + colbase + cf * 16 + row) * 8);
#pragma unroll
        for (int rb = 0; rb < 4; ++rb)
#pragma unroll
            for (int cf = 0; cf < 4; ++cf)
                acc[rb][cf] = __builtin_amdgcn_mfma_f32_16x16x32_bf16(af[rb], bf[cf],
                                                                      acc[rb][cf], 0, 0, 0);
    }
#pragma unroll
    for (int cf = 0; cf < 4; ++cf) {
        int j = colbase + cf * 16 + row;
        float bj = bias[j];
        float s = 0.f, q = 0.f;
#pragma unroll
        for (int rb = 0; rb < 4; ++rb) {
#pragma unroll
            for (int r = 0; r < 4; ++r) {
                int gr = n0 + rb * 16 + kg * 4 + r;
                if (gr < N_NODES) {
                    float v = acc[rb][cf][r] + bj;
                    tb[(size_t)gr * 256 + j] = bf16_rne(v);
                    s += v;
                    q += v * v;
                }
            }
        }
        s += __shfl_xor(s, 16); s += __shfl_xor(s, 32);
        q += __shfl_xor(q, 16); q += __shfl_xor(q, 32);
        if (lane < 16) {
            atomicAdd(&stats[j], s);
            atomicAdd(&stats[256 + j], q);
        }
    }
}

// ---------------------------------------------- BN finalize -> scale/shift
__global__ void k_bn_final(const float* __restrict__ sums, int C,
                           const float* __restrict__ g, const float* __restrict__ b,
                           float* __restrict__ scale, float* __restrict__ shift) {
    int j = threadIdx.x;
    if (j >= C) return;
    float m = sums[j] * (1.0f / N_NODES);
    float var = sums[C + j] * (1.0f / N_NODES) - m * m;
    float sc = g[j] / sqrtf(var + 1e-5f);
    scale[j] = sc;
    shift[j] = b[j] - m * sc;
}

// ------- GEMM2 (MFMA): u = relu(BN1(t))@W2 + b2, fused BN2 column stats
// BM=64, N=128, K=256; bf16 in (affine+relu in staging), bf16 out
__global__ __launch_bounds__(256) void k_gemm2(
    const unsigned short* __restrict__ tb, const unsigned short* __restrict__ Bp,
    const float* __restrict__ scale1, const float* __restrict__ shift1,
    const float* __restrict__ bias, unsigned short* __restrict__ ub,
    float* __restrict__ osum, float* __restrict__ osq) {
    __shared__ unsigned short As[16384] __attribute__((aligned(16)));  // 32 KB
    int n0 = blockIdx.x * 64;
#pragma unroll
    for (int s = 0; s < 8; ++s) {
        int i = threadIdx.x + s * 256;            // 16B unit; 64 rows x 32 units
        int r = i >> 5, k8 = i & 31;
        short8v v = (short8v)(short)0;
        if (n0 + r < N_NODES) v = ((const short8v*)(tb + (size_t)(n0 + r) * 256))[k8];
        int kb = k8 * 8;
        float4 sc0 = *(const float4*)(scale1 + kb);
        float4 sc1 = *(const float4*)(scale1 + kb + 4);
        float4 sh0 = *(const float4*)(shift1 + kb);
        float4 sh1 = *(const float4*)(shift1 + kb + 4);
        short8v o;
        o[0] = (short)bf16_rne(fmaxf(fmaf(sc0.x, bf2f((unsigned short)v[0]), sh0.x), 0.f));
        o[1] = (short)bf16_rne(fmaxf(fmaf(sc0.y, bf2f((unsigned short)v[1]), sh0.y), 0.f));
        o[2] = (short)bf16_rne(fmaxf(fmaf(sc0.z, bf2f((unsigned short)v[2]), sh0.z), 0.f));
        o[3] = (short)bf16_rne(fmaxf(fmaf(sc0.w, bf2f((unsigned short)v[3]), sh0.w), 0.f));
        o[4] = (short)bf16_rne(fmaxf(fmaf(sc1.x, bf2f((unsigned short)v[4]), sh1.x), 0.f));
        o[5] = (short)bf16_rne(fmaxf(fmaf(sc1.y, bf2f((unsigned short)v[5]), sh1.y), 0.f));
        o[6] = (short)bf16_rne(fmaxf(fmaf(sc1.z, bf2f((unsigned short)v[6]), sh1.z), 0.f));
        o[7] = (short)bf16_rne(fmaxf(fmaf(sc1.w, bf2f((unsigned short)v[7]), sh1.w), 0.f));
        int frag = (r >> 4) * 32 + k8;
        int off = (frag * 128 + (r & 15) * 8) ^ ((k8 & 7) << 3);
        *(short8v*)(&As[off]) = o;
    }
    __syncthreads();
    int lane = threadIdx.x & 63;
    int wid = threadIdx.x >> 6;
    int row = lane & 15, kg = lane >> 4;
    int colbase = wid * 32;
    f32x4 acc[4][2];
#pragma unroll
    for (int a = 0; a < 4; ++a) {
        acc[a][0] = (f32x4)(0.f);
        acc[a][1] = (f32x4)(0.f);
    }
#pragma unroll
    for (int k4 = 0; k4 < 8; ++k4) {
        short8v af[4], bf[2];
#pragma unroll
        for (int rb = 0; rb < 4; ++rb)
            af[rb] = *(const short8v*)(&As[((rb * 32 + k4 * 4 + kg) * 128 + row * 8) ^
                                           (((k4 * 4 + kg) & 7) << 3)]);
#pragma unroll
        for (int cf = 0; cf < 2; ++cf)
            bf[cf] = *(const short8v*)(Bp + ((k4 * 4 + kg) * 128 + colbase + cf * 16 + row) * 8);
#pragma unroll
        for (int rb = 0; rb < 4; ++rb)
#pragma unroll
            for (int cf = 0; cf < 2; ++cf)
                acc[rb][cf] = __builtin_amdgcn_mfma_f32_16x16x32_bf16(af[rb], bf[cf],
                                                                      acc[rb][cf], 0, 0, 0);
    }
#pragma unroll
    for (int cf = 0; cf < 2; ++cf) {
        int j = colbase + cf * 16 + row;
        float bj = bias[j];
        float s = 0.f, q = 0.f;
#pragma unroll
        for (int rb = 0; rb < 4; ++rb) {
#pragma unroll
            for (int r = 0; r < 4; ++r) {
                int gr = n0 + rb * 16 + kg * 4 + r;
                if (gr < N_NODES) {
                    float v = acc[rb][cf][r] + bj;
                    ub[(size_t)gr * 128 + j] = bf16_rne(v);
                    s += v;
                    q += v * v;
                }
            }
        }
        s += __shfl_xor(s, 16); s += __shfl_xor(s, 32);
        q += __shfl_xor(q, 16); q += __shfl_xor(q, 32);
        if (lane < 16) {
            atomicAdd(&osum[j], s);
            atomicAdd(&osq[j], q);
        }
    }
}

// ------------------- h += maybe_relu(BN2(u)); refresh bf16 mirror hb
__global__ void k_update_h(float* __restrict__ h, unsigned short* __restrict__ hb,
                           const unsigned short* __restrict__ ub,
                           const float* __restrict__ scale2, const float* __restrict__ shift2,
                           int relu) {
    int i = blockIdx.x * 256 + threadIdx.x;  // 8-elem unit; total N*16 = 1.6M
    int d8 = i & 15;
    uint4 uv = ((const uint4*)ub)[i];
    float4 sc0 = ((const float4*)scale2)[d8 * 2];
    float4 sc1 = ((const float4*)scale2)[d8 * 2 + 1];
    float4 sh0 = ((const float4*)shift2)[d8 * 2];
    float4 sh1 = ((const float4*)shift2)[d8 * 2 + 1];
    float4 h0 = ((const float4*)h)[i * 2];
    float4 h1 = ((const float4*)h)[i * 2 + 1];
    float v0 = fmaf(sc0.x, bf2f((unsigned short)(uv.x & 0xffffu)), sh0.x);
    float v1 = fmaf(sc0.y, bf2f((unsigned short)(uv.x >> 16)), sh0.y);
    float v2 = fmaf(sc0.z, bf2f((unsigned short)(uv.y & 0xffffu)), sh0.z);
    float v3 = fmaf(sc0.w, bf2f((unsigned short)(uv.y >> 16)), sh0.w);
    float v4 = fmaf(sc1.x, bf2f((unsigned short)(uv.z & 0xffffu)), sh1.x);
    float v5 = fmaf(sc1.y, bf2f((unsigned short)(uv.z >> 16)), sh1.y);
    float v6 = fmaf(sc1.z, bf2f((unsigned short)(uv.w & 0xffffu)), sh1.z);
    float v7 = fmaf(sc1.w, bf2f((unsigned short)(uv.w >> 16)), sh1.w);
    if (relu) {
        v0 = fmaxf(v0, 0.f); v1 = fmaxf(v1, 0.f); v2 = fmaxf(v2, 0.f); v3 = fmaxf(v3, 0.f);
        v4 = fmaxf(v4, 0.f); v5 = fmaxf(v5, 0.f); v6 = fmaxf(v6, 0.f); v7 = fmaxf(v7, 0.f);
    }
    h0.x += v0; h0.y += v1; h0.z += v2; h0.w += v3;
    h1.x += v4; h1.y += v5; h1.z += v6; h1.w += v7;
    ((float4*)h)[i * 2] = h0;
    ((float4*)h)[i * 2 + 1] = h1;
    uint4 hp;
    hp.x = pack2(h0.x, h0.y); hp.y = pack2(h0.z, h0.w);
    hp.z = pack2(h1.x, h1.y); hp.w = pack2(h1.z, h1.w);
    ((uint4*)hb)[i] = hp;
}

// --------------------------------------- init the 4 G-sized segment-sum outputs
__global__ void k_init_seg(float* __restrict__ out) {
    int i = blockIdx.x * 256 + threadIdx.x;
    if (i < 4 * N_GRAPHS) out[N_NODES + N_EDGES + i] = 1e-8f;
}

// ------------- node head: node_key + per-node dots p,q + node segment sums
__global__ void k_node_out(const float* __restrict__ h, const int* __restrict__ batch,
                           const float* __restrict__ nW, const float* __restrict__ nb,
                           const float* __restrict__ eW,
                           float* __restrict__ out, float* __restrict__ p,
                           float* __restrict__ q) {
    int n = blockIdx.x * 4 + (threadIdx.x >> 6);
    int lane = threadIdx.x & 63;
    if (n >= N_NODES) return;
    float2 hv = ((const float2*)(h + (size_t)n * 128))[lane];
    float2 wn = ((const float2*)nW)[lane];
    float2 wa = ((const float2*)eW)[lane];
    float2 wb = ((const float2*)eW)[64 + lane];
    float dn = hv.x * wn.x + hv.y * wn.y;
    float da = hv.x * wa.x + hv.y * wa.y;
    float db = hv.x * wb.x + hv.y * wb.y;
#pragma unroll
    for (int off = 32; off; off >>= 1) {
        dn += __shfl_xor(dn, off);
        da += __shfl_xor(da, off);
        db += __shfl_xor(db, off);
    }
    if (lane == 0) {
        float nk = 1.f / (1.f + expf(-(dn + nb[0])));
        out[n] = nk;
        int g = batch[n];
        atomicAdd(&out[N_NODES + N_EDGES + g], nk);
        atomicAdd(&out[N_NODES + N_EDGES + N_GRAPHS + g], 1.0f - nk);
        p[n] = da;
        q[n] = db;
    }
}

// ------------- edge head: edge_key = sigmoid(p[row]+q[col]+b) + edge seg sums
__global__ void k_edge_out(const int* __restrict__ ei, const int* __restrict__ batch,
                           const float* __restrict__ p, const float* __restrict__ q,
                           const float* __restrict__ eb, float* __restrict__ out) {
    int e = blockIdx.x * 256 + threadIdx.x;
    if (e >= N_EDGES) return;
    int r = ei[e], c = ei[N_EDGES + e];
    float ek = 1.f / (1.f + expf(-(p[r] + q[c] + eb[0])));
    out[N_NODES + e] = ek;
    int g = batch[r];
    atomicAdd(&out[N_NODES + N_EDGES + 2 * N_GRAPHS + g], ek);
    atomicAdd(&out[N_NODES + N_EDGES + 3 * N_GRAPHS + g], 1.0f - ek);
}

extern "C" void kernel_launch(void* const* d_in, const int* in_sizes, int n_in,
                              void* d_out, int out_size, void* d_ws, size_t ws_size,
                              hipStream_t stream) {
    const int*   x     = (const int*)d_in[0];
    const int*   ei    = (const int*)d_in[1];
    const int*   ea    = (const int*)d_in[2];
    const int*   batch = (const int*)d_in[3];
    const float* at    = (const float*)d_in[4];
    const float* bt    = (const float*)d_in[5];
    const float* eps   = (const float*)d_in[6];
    const float* W1    = (const float*)d_in[7];
    const float* b1    = (const float*)d_in[8];
    const float* bn1g  = (const float*)d_in[9];
    const float* bn1b  = (const float*)d_in[10];
    const float* W2    = (const float*)d_in[11];
    const float* b2    = (const float*)d_in[12];
    const float* obng  = (const float*)d_in[13];
    const float* obnb  = (const float*)d_in[14];
    const float* nW    = (const float*)d_in[15];
    const float* nb    = (const float*)d_in[16];
    const float* eW    = (const float*)d_in[17];
    const float* eb    = (const float*)d_in[18];
    float* out = (float*)d_out;

    float* ws    = (float*)d_ws;
    float* h     = ws;                       // N*128 fp32
    float* stats = h + 12800000;             // 1536
    float* p     = stats + 1536;             // N
    float* q     = p + N_NODES;              // N
    unsigned short* hb  = (unsigned short*)(q + N_NODES);  // N*128 bf16 (16B aligned)
    unsigned short* zub = hb + 12800000;     // N*128 bf16: z (gemm1 in), then u (gemm2 out)
    unsigned short* tb  = zub + 12800000;    // N*256 bf16
    unsigned short* Bp1 = tb + 25600000;     // 3*128*256 bf16
    unsigned short* Bp2 = Bp1 + 3 * 32768;   // 3*256*128 bf16
    int* rowptr  = (int*)(Bp2 + 3 * 32768);  // N+1
    int* cursor  = rowptr + N_NODES + 1;     // N (counts, then cursors)
    int* csr_row = cursor + N_NODES;         // E
    int* csr_attr = csr_row + N_EDGES;       // E
    int* bsum    = csr_attr + N_EDGES;       // SCAN_NBLK
    // stats: [sum256][sq256][osum128][osq128][scale1@768][shift1@1024][scale2@1280][shift2@1408]

    k_atom_encode<<<50000, 256, 0, stream>>>(x, at, h, hb);
    k_convw<<<768, 256, 0, stream>>>(W1, W2, Bp1, Bp2);

    // CSR of edges grouped by destination (col) — parallel 3-phase scan
    hipMemsetAsync(cursor, 0, N_NODES * sizeof(int), stream);
    k_hist<<<2344, 256, 0, stream>>>(ei, cursor);
    k_scan_partial<<<SCAN_NBLK, 256, 0, stream>>>(cursor, bsum);
    k_scan_bsum<<<1, 256, 0, stream>>>(bsum, rowptr);
    k_scan_final<<<SCAN_NBLK, 512, 0, stream>>>(bsum, cursor, rowptr);
    k_fill<<<2344, 256, 0, stream>>>(ei, ea, cursor, csr_row, csr_attr);

    for (int l = 0; l < 3; ++l) {
        hipMemsetAsync(stats, 0, 768 * 4, stream);
        k_gather<<<25000, 256, 0, stream>>>(hb, h, csr_row, csr_attr, rowptr,
                                            bt + (size_t)l * 3 * 8 * 128, eps, l, zub);
        k_gemm1<<<1563, 256, 0, stream>>>(zub, Bp1 + (size_t)l * 32768, b1 + l * 256, tb, stats);
        k_bn_final<<<1, 256, 0, stream>>>(stats, 256, bn1g + l * 256, bn1b + l * 256,
                                          stats + 768, stats + 1024);
        k_gemm2<<<1563, 256, 0, stream>>>(tb, Bp2 + (size_t)l * 32768, stats + 768, stats + 1024,
                                          b2 + l * 128, zub, stats + 512, stats + 640);
        k_bn_final<<<1, 128, 0, stream>>>(stats + 512, 128, obng + l * 128, obnb + l * 128,
                                          stats + 1280, stats + 1408);
        k_update_h<<<6250, 256, 0, stream>>>(h, hb, zub, stats + 1280, stats + 1408,
                                             (l < 2) ? 1 : 0);
    }

    k_init_seg<<<64, 256, 0, stream>>>(out);
    k_node_out<<<25000, 256, 0, stream>>>(h, batch, nW, nb, eW, out, p, q);
    k_edge_out<<<2344, 256, 0, stream>>>(ei, batch, p, q, eb, out);
}

// Round 6
// 920.063 us; speedup vs baseline: 3.7720x; 1.0154x over previous
//
#include <hip/hip_runtime.h>
#include <math.h>

#define N_NODES 100000
#define N_EDGES 600000
#define N_GRAPHS 4096
#define SCAN_CHUNK 512
#define SCAN_NBLK 196   // ceil(100000/512)

typedef __attribute__((ext_vector_type(8))) short short8v;   // 8 bf16 (4 VGPR)
typedef __attribute__((ext_vector_type(4))) float f32x4;

// fp32 pair -> packed bf16 (RNE) via the HW instruction (manual bit-twiddle
// is ~4 VALU ops/elem and the compiler can't pattern-match it to cvt_pk)
__device__ __forceinline__ unsigned int pack2(float a, float b) {
    unsigned int r;
    asm("v_cvt_pk_bf16_f32 %0, %1, %2" : "=v"(r) : "v"(a), "v"(b));
    return r;
}
__device__ __forceinline__ unsigned short bf16_rne(float f) {
    unsigned int r;
    asm("v_cvt_pk_bf16_f32 %0, %1, %2" : "=v"(r) : "v"(f), "v"(f));
    return (unsigned short)r;
}
__device__ __forceinline__ float bf2f(unsigned short u) {
    return __uint_as_float(((unsigned int)u) << 16);
}

// ------------------------------------------- atom encoder (writes fp32 + bf16)
__global__ void k_atom_encode(const int* __restrict__ x, const float* __restrict__ at,
                              float* __restrict__ h, unsigned short* __restrict__ hb) {
    int n = blockIdx.x * 2 + (threadIdx.x >> 7);
    int d = threadIdx.x & 127;
    if (n >= N_NODES) return;
    const int* xr = x + n * 9;
    float s = 0.f;
#pragma unroll
    for (int f = 0; f < 9; ++f) {
        int v = xr[f];
        s += at[(f * 100 + v) * 128 + d];
    }
    h[(size_t)n * 128 + d] = s;
    hb[(size_t)n * 128 + d] = bf16_rne(s);
}

// ------------------------------------------------------------ CSR build (once)
__global__ void k_hist(const int* __restrict__ ei, int* __restrict__ cnt) {
    int e = blockIdx.x * 256 + threadIdx.x;
    if (e < N_EDGES) atomicAdd(&cnt[ei[N_EDGES + e]], 1);
}

__global__ void k_scan_partial(const int* __restrict__ cnt, int* __restrict__ bsum) {
    __shared__ int ls[256];
    int base = blockIdx.x * SCAN_CHUNK;
    int t = threadIdx.x;
    int s = 0;
    for (int i = base + t; i < base + SCAN_CHUNK && i < N_NODES; i += 256) s += cnt[i];
    ls[t] = s;
    __syncthreads();
    for (int off = 128; off; off >>= 1) {
        if (t < off) ls[t] += ls[t + off];
        __syncthreads();
    }
    if (t == 0) bsum[blockIdx.x] = ls[0];
}

__global__ void k_scan_bsum(int* __restrict__ bsum, int* __restrict__ rowptr) {
    __shared__ int ls[256];
    int t = threadIdx.x;
    int v = (t < SCAN_NBLK) ? bsum[t] : 0;
    ls[t] = v;
    __syncthreads();
    for (int off = 1; off < 256; off <<= 1) {
        int x = (t >= off) ? ls[t - off] : 0;
        __syncthreads();
        ls[t] += x;
        __syncthreads();
    }
    if (t < SCAN_NBLK) bsum[t] = ls[t] - v;  // exclusive prefix
    if (t == 255) rowptr[N_NODES] = ls[255];
}

__global__ __launch_bounds__(512) void k_scan_final(const int* __restrict__ bsum,
                                                    int* __restrict__ cnt_cursor,
                                                    int* __restrict__ rowptr) {
    __shared__ int ls[512];
    int base = blockIdx.x * SCAN_CHUNK;
    int t = threadIdx.x;
    int i = base + t;
    int v = (i < N_NODES) ? cnt_cursor[i] : 0;
    ls[t] = v;
    __syncthreads();
    for (int off = 1; off < 512; off <<= 1) {
        int x = (t >= off) ? ls[t - off] : 0;
        __syncthreads();
        ls[t] += x;
        __syncthreads();
    }
    if (i < N_NODES) {
        int excl = bsum[blockIdx.x] + ls[t] - v;
        rowptr[i] = excl;
        cnt_cursor[i] = excl;
    }
}

// fill CSR-ordered source-row + packed edge-attr arrays
__global__ void k_fill(const int* __restrict__ ei, const int* __restrict__ ea,
                       int* __restrict__ cursor,
                       int* __restrict__ csr_row, int* __restrict__ csr_attr) {
    int e = blockIdx.x * 256 + threadIdx.x;
    if (e < N_EDGES) {
        int c = ei[N_EDGES + e];
        int pos = atomicAdd(&cursor[c], 1);
        csr_row[pos] = ei[e];
        csr_attr[pos] = ea[e * 3] | (ea[e * 3 + 1] << 8) | (ea[e * 3 + 2] << 16);
    }
}

// ---------------- weight pre-swizzle: fp32 -> bf16 in MFMA B-fragment layout
__global__ void k_convw(const float* __restrict__ W1, const float* __restrict__ W2,
                        unsigned short* __restrict__ Bp1, unsigned short* __restrict__ Bp2) {
    int idx = blockIdx.x * 256 + threadIdx.x;
    if (idx < 3 * 128 * 256) {
        int l = idx >> 15, r = idx & 32767;
        int k = r >> 8, j = r & 255;
        float v = W1[(size_t)l * 32768 + k * 256 + j];
        Bp1[(size_t)l * 32768 + (((k >> 5) * 4 + ((k >> 3) & 3)) * 256 + j) * 8 + (k & 7)] =
            bf16_rne(v);
    } else if (idx < 6 * 128 * 256) {
        int t = idx - 98304;
        int l = t >> 15, r = t & 32767;
        int k = r >> 7, j = r & 127;
        float v = W2[(size_t)l * 32768 + k * 128 + j];
        Bp2[(size_t)l * 32768 + (((k >> 5) * 4 + ((k >> 3) & 3)) * 128 + j) * 8 + (k & 7)] =
            bf16_rne(v);
    }
}

// ---------------------------- gather-aggregate: z = (1+eps)*h + sum relu(msg)
// wave per node; bf16 h rows (incl. self term); 4-wide unroll for MLP
#define ACC_EDGE(u, qv)                                                       \
    {                                                                         \
        float hx = bf2f((unsigned short)((u) & 0xffffu));                     \
        float hy = bf2f((unsigned short)((u) >> 16));                         \
        float2 e0 = ((const float2*)(bt + ((qv) & 255) * 128))[lane];         \
        float2 e1 = ((const float2*)(bt + 1024 + (((qv) >> 8) & 255) * 128))[lane]; \
        float2 e2 = ((const float2*)(bt + 2048 + (((qv) >> 16) & 255) * 128))[lane]; \
        ax += fmaxf(hx + e0.x + e1.x + e2.x, 0.f);                            \
        ay += fmaxf(hy + e0.y + e1.y + e2.y, 0.f);                            \
    }

__global__ void k_gather(const unsigned short* __restrict__ hb,
                         const int* __restrict__ csr_row, const int* __restrict__ csr_attr,
                         const int* __restrict__ rowptr, const float* __restrict__ bt_g,
                         const float* __restrict__ eps, int l,
                         unsigned short* __restrict__ zb) {
    __shared__ float bt[3 * 8 * 128];
    for (int i = threadIdx.x; i < 3 * 8 * 128; i += 256) bt[i] = bt_g[i];
    __syncthreads();
    int lane = threadIdx.x & 63;
    int n = blockIdx.x * 4 + (threadIdx.x >> 6);
    if (n >= N_NODES) return;
    int i0 = rowptr[n], i1 = rowptr[n + 1];
    float ax = 0.f, ay = 0.f;
    int i = i0;
    for (; i + 4 <= i1; i += 4) {
        int r0 = csr_row[i], r1 = csr_row[i + 1], r2 = csr_row[i + 2], r3 = csr_row[i + 3];
        int q0 = csr_attr[i], q1 = csr_attr[i + 1], q2 = csr_attr[i + 2], q3 = csr_attr[i + 3];
        unsigned int u0 = ((const unsigned int*)(hb + (size_t)r0 * 128))[lane];
        unsigned int u1 = ((const unsigned int*)(hb + (size_t)r1 * 128))[lane];
        unsigned int u2 = ((const unsigned int*)(hb + (size_t)r2 * 128))[lane];
        unsigned int u3 = ((const unsigned int*)(hb + (size_t)r3 * 128))[lane];
        ACC_EDGE(u0, q0); ACC_EDGE(u1, q1); ACC_EDGE(u2, q2); ACC_EDGE(u3, q3);
    }
    for (; i < i1; ++i) {
        int r0 = csr_row[i];
        int q0 = csr_attr[i];
        unsigned int u0 = ((const unsigned int*)(hb + (size_t)r0 * 128))[lane];
        ACC_EDGE(u0, q0);
    }
    float el = 1.0f + eps[l];
    unsigned int un = ((const unsigned int*)(hb + (size_t)n * 128))[lane];
    float zx = fmaf(el, bf2f((unsigned short)(un & 0xffffu)), ax);
    float zy = fmaf(el, bf2f((unsigned short)(un >> 16)), ay);
    ((unsigned int*)(zb + (size_t)n * 128))[lane] = pack2(zx, zy);
}

// --------------------- GEMM1 (MFMA): t = z@W1 + b1, fused BN1 column stats
// BM=64, N=256, K=128; 4 waves -> 64 cols each
__global__ __launch_bounds__(256) void k_gemm1(
    const unsigned short* __restrict__ zb, const unsigned short* __restrict__ Bp,
    const float* __restrict__ bias, unsigned short* __restrict__ tb,
    float* __restrict__ stats) {
    __shared__ unsigned short As[8192] __attribute__((aligned(16)));  // 16 KB
    int n0 = blockIdx.x * 64;
#pragma unroll
    for (int s = 0; s < 4; ++s) {
        int i = threadIdx.x + s * 256;            // 16B unit; 64 rows x 16 units
        int r = i >> 4, k8 = i & 15;
        short8v v = (short8v)(short)0;
        if (n0 + r < N_NODES) v = ((const short8v*)(zb + (size_t)(n0 + r) * 128))[k8];
        int frag = (r >> 4) * 16 + k8;
        int off = (frag * 128 + (r & 15) * 8) ^ ((k8 & 7) << 3);
        *(short8v*)(&As[off]) = v;
    }
    __syncthreads();
    int lane = threadIdx.x & 63;
    int wid = threadIdx.x >> 6;
    int row = lane & 15, kg = lane >> 4;
    int colbase = wid * 64;
    f32x4 acc[4][4];
#pragma unroll
    for (int a = 0; a < 4; ++a)
#pragma unroll
        for (int b = 0; b < 4; ++b) acc[a][b] = (f32x4)(0.f);
#pragma unroll
    for (int k4 = 0; k4 < 4; ++k4) {
        short8v af[4], bf[4];
#pragma unroll
        for (int rb = 0; rb < 4; ++rb)
            af[rb] = *(const short8v*)(&As[((rb * 16 + k4 * 4 + kg) * 128 + row * 8) ^
                                           (((k4 * 4 + kg) & 7) << 3)]);
#pragma unroll
        for (int cf = 0; cf < 4; ++cf)
            bf[cf] = *(const short8v*)(Bp + ((k4 * 4 + kg) * 256 + colbase + cf * 16 + row) * 8);
#pragma unroll
        for (int rb = 0; rb < 4; ++rb)
#pragma unroll
            for (int cf = 0; cf < 4; ++cf)
                acc[rb][cf] = __builtin_amdgcn_mfma_f32_16x16x32_bf16(af[rb], bf[cf],
                                                                      acc[rb][cf], 0, 0, 0);
    }
#pragma unroll
    for (int cf = 0; cf < 4; ++cf) {
        int j = colbase + cf * 16 + row;
        float bj = bias[j];
        float s = 0.f, q = 0.f;
#pragma unroll
        for (int rb = 0; rb < 4; ++rb) {
#pragma unroll
            for (int r = 0; r < 4; ++r) {
                int gr = n0 + rb * 16 + kg * 4 + r;
                if (gr < N_NODES) {
                    float v = acc[rb][cf][r] + bj;
                    tb[(size_t)gr * 256 + j] = bf16_rne(v);
                    s += v;
                    q += v * v;
                }
            }
        }
        s += __shfl_xor(s, 16); s += __shfl_xor(s, 32);
        q += __shfl_xor(q, 16); q += __shfl_xor(q, 32);
        if (lane < 16) {
            atomicAdd(&stats[j], s);
            atomicAdd(&stats[256 + j], q);
        }
    }
}

// ------- GEMM2 (MFMA): u = relu(BN1(t))@W2 + b2, fused BN2 column stats
// BN1 scale/shift computed per-thread in registers ((tid+s*256)&31 == tid&31,
// so each staging thread owns a fixed 8-column group)
__global__ __launch_bounds__(256) void k_gemm2(
    const unsigned short* __restrict__ tb, const unsigned short* __restrict__ Bp,
    const float* __restrict__ stats, const float* __restrict__ g1,
    const float* __restrict__ b1g,
    const float* __restrict__ bias, unsigned short* __restrict__ ub,
    float* __restrict__ osum, float* __restrict__ osq) {
    __shared__ unsigned short As[16384] __attribute__((aligned(16)));  // 32 KB
    int n0 = blockIdx.x * 64;
    int tid = threadIdx.x;
    int kb = (tid & 31) * 8;
    float scr[8], shr[8];
#pragma unroll
    for (int j = 0; j < 8; ++j) {
        float m = stats[kb + j] * (1.0f / N_NODES);
        float var = stats[256 + kb + j] * (1.0f / N_NODES) - m * m;
        float sc = g1[kb + j] / sqrtf(var + 1e-5f);
        scr[j] = sc;
        shr[j] = b1g[kb + j] - m * sc;
    }
#pragma unroll
    for (int s = 0; s < 8; ++s) {
        int i = tid + s * 256;                    // 16B unit; 64 rows x 32 units
        int r = i >> 5, k8 = i & 31;
        short8v v = (short8v)(short)0;
        if (n0 + r < N_NODES) v = ((const short8v*)(tb + (size_t)(n0 + r) * 256))[k8];
        float f0 = fmaxf(fmaf(scr[0], bf2f((unsigned short)v[0]), shr[0]), 0.f);
        float f1 = fmaxf(fmaf(scr[1], bf2f((unsigned short)v[1]), shr[1]), 0.f);
        float f2 = fmaxf(fmaf(scr[2], bf2f((unsigned short)v[2]), shr[2]), 0.f);
        float f3 = fmaxf(fmaf(scr[3], bf2f((unsigned short)v[3]), shr[3]), 0.f);
        float f4 = fmaxf(fmaf(scr[4], bf2f((unsigned short)v[4]), shr[4]), 0.f);
        float f5 = fmaxf(fmaf(scr[5], bf2f((unsigned short)v[5]), shr[5]), 0.f);
        float f6 = fmaxf(fmaf(scr[6], bf2f((unsigned short)v[6]), shr[6]), 0.f);
        float f7 = fmaxf(fmaf(scr[7], bf2f((unsigned short)v[7]), shr[7]), 0.f);
        uint4 ov;
        ov.x = pack2(f0, f1); ov.y = pack2(f2, f3);
        ov.z = pack2(f4, f5); ov.w = pack2(f6, f7);
        int frag = (r >> 4) * 32 + k8;
        int off = (frag * 128 + (r & 15) * 8) ^ ((k8 & 7) << 3);
        *(uint4*)(&As[off]) = ov;
    }
    __syncthreads();
    int lane = threadIdx.x & 63;
    int wid = threadIdx.x >> 6;
    int row = lane & 15, kg = lane >> 4;
    int colbase = wid * 32;
    f32x4 acc[4][2];
#pragma unroll
    for (int a = 0; a < 4; ++a) {
        acc[a][0] = (f32x4)(0.f);
        acc[a][1] = (f32x4)(0.f);
    }
#pragma unroll
    for (int k4 = 0; k4 < 8; ++k4) {
        short8v af[4], bf[2];
#pragma unroll
        for (int rb = 0; rb < 4; ++rb)
            af[rb] = *(const short8v*)(&As[((rb * 32 + k4 * 4 + kg) * 128 + row * 8) ^
                                           (((k4 * 4 + kg) & 7) << 3)]);
#pragma unroll
        for (int cf = 0; cf < 2; ++cf)
            bf[cf] = *(const short8v*)(Bp + ((k4 * 4 + kg) * 128 + colbase + cf * 16 + row) * 8);
#pragma unroll
        for (int rb = 0; rb < 4; ++rb)
#pragma unroll
            for (int cf = 0; cf < 2; ++cf)
                acc[rb][cf] = __builtin_amdgcn_mfma_f32_16x16x32_bf16(af[rb], bf[cf],
                                                                      acc[rb][cf], 0, 0, 0);
    }
#pragma unroll
    for (int cf = 0; cf < 2; ++cf) {
        int j = colbase + cf * 16 + row;
        float bj = bias[j];
        float s = 0.f, q = 0.f;
#pragma unroll
        for (int rb = 0; rb < 4; ++rb) {
#pragma unroll
            for (int r = 0; r < 4; ++r) {
                int gr = n0 + rb * 16 + kg * 4 + r;
                if (gr < N_NODES) {
                    float v = acc[rb][cf][r] + bj;
                    ub[(size_t)gr * 128 + j] = bf16_rne(v);
                    s += v;
                    q += v * v;
                }
            }
        }
        s += __shfl_xor(s, 16); s += __shfl_xor(s, 32);
        q += __shfl_xor(q, 16); q += __shfl_xor(q, 32);
        if (lane < 16) {
            atomicAdd(&osum[j], s);
            atomicAdd(&osq[j], q);
        }
    }
}

// --------- h += maybe_relu(BN2(u)); refresh bf16 mirror. BN2 scale/shift
// computed per-thread in registers ((bid*256+tid)&15 == tid&15)
__global__ void k_update_h(float* __restrict__ h, unsigned short* __restrict__ hb,
                           const unsigned short* __restrict__ ub,
                           const float* __restrict__ osum, const float* __restrict__ osq,
                           const float* __restrict__ g2, const float* __restrict__ b2g,
                           int relu) {
    int kb = (threadIdx.x & 15) * 8;
    float scr[8], shr[8];
#pragma unroll
    for (int j = 0; j < 8; ++j) {
        float m = osum[kb + j] * (1.0f / N_NODES);
        float var = osq[kb + j] * (1.0f / N_NODES) - m * m;
        float sc = g2[kb + j] / sqrtf(var + 1e-5f);
        scr[j] = sc;
        shr[j] = b2g[kb + j] - m * sc;
    }
    int i = blockIdx.x * 256 + threadIdx.x;  // 8-elem unit; total N*16 = 1.6M
    uint4 uv = ((const uint4*)ub)[i];
    float4 h0 = ((const float4*)h)[i * 2];
    float4 h1 = ((const float4*)h)[i * 2 + 1];
    float v0 = fmaf(scr[0], bf2f((unsigned short)(uv.x & 0xffffu)), shr[0]);
    float v1 = fmaf(scr[1], bf2f((unsigned short)(uv.x >> 16)), shr[1]);
    float v2 = fmaf(scr[2], bf2f((unsigned short)(uv.y & 0xffffu)), shr[2]);
    float v3 = fmaf(scr[3], bf2f((unsigned short)(uv.y >> 16)), shr[3]);
    float v4 = fmaf(scr[4], bf2f((unsigned short)(uv.z & 0xffffu)), shr[4]);
    float v5 = fmaf(scr[5], bf2f((unsigned short)(uv.z >> 16)), shr[5]);
    float v6 = fmaf(scr[6], bf2f((unsigned short)(uv.w & 0xffffu)), shr[6]);
    float v7 = fmaf(scr[7], bf2f((unsigned short)(uv.w >> 16)), shr[7]);
    if (relu) {
        v0 = fmaxf(v0, 0.f); v1 = fmaxf(v1, 0.f); v2 = fmaxf(v2, 0.f); v3 = fmaxf(v3, 0.f);
        v4 = fmaxf(v4, 0.f); v5 = fmaxf(v5, 0.f); v6 = fmaxf(v6, 0.f); v7 = fmaxf(v7, 0.f);
    }
    h0.x += v0; h0.y += v1; h0.z += v2; h0.w += v3;
    h1.x += v4; h1.y += v5; h1.z += v6; h1.w += v7;
    ((float4*)h)[i * 2] = h0;
    ((float4*)h)[i * 2 + 1] = h1;
    uint4 hp;
    hp.x = pack2(h0.x, h0.y); hp.y = pack2(h0.z, h0.w);
    hp.z = pack2(h1.x, h1.y); hp.w = pack2(h1.z, h1.w);
    ((uint4*)hb)[i] = hp;
}

// --------------------------------------- init the 4 G-sized segment-sum outputs
__global__ void k_init_seg(float* __restrict__ out) {
    int i = blockIdx.x * 256 + threadIdx.x;
    if (i < 4 * N_GRAPHS) out[N_NODES + N_EDGES + i] = 1e-8f;
}

// ------------- node head: node_key + per-node dots p,q + node segment sums
__global__ void k_node_out(const float* __restrict__ h, const int* __restrict__ batch,
                           const float* __restrict__ nW, const float* __restrict__ nb,
                           const float* __restrict__ eW,
                           float* __restrict__ out, float* __restrict__ p,
                           float* __restrict__ q) {
    int n = blockIdx.x * 4 + (threadIdx.x >> 6);
    int lane = threadIdx.x & 63;
    if (n >= N_NODES) return;
    float2 hv = ((const float2*)(h + (size_t)n * 128))[lane];
    float2 wn = ((const float2*)nW)[lane];
    float2 wa = ((const float2*)eW)[lane];
    float2 wb = ((const float2*)eW)[64 + lane];
    float dn = hv.x * wn.x + hv.y * wn.y;
    float da = hv.x * wa.x + hv.y * wa.y;
    float db = hv.x * wb.x + hv.y * wb.y;
#pragma unroll
    for (int off = 32; off; off >>= 1) {
        dn += __shfl_xor(dn, off);
        da += __shfl_xor(da, off);
        db += __shfl_xor(db, off);
    }
    if (lane == 0) {
        float nk = 1.f / (1.f + expf(-(dn + nb[0])));
        out[n] = nk;
        int g = batch[n];
        atomicAdd(&out[N_NODES + N_EDGES + g], nk);
        atomicAdd(&out[N_NODES + N_EDGES + N_GRAPHS + g], 1.0f - nk);
        p[n] = da;
        q[n] = db;
    }
}

// ------------- edge head: edge_key = sigmoid(p[row]+q[col]+b) + edge seg sums
__global__ void k_edge_out(const int* __restrict__ ei, const int* __restrict__ batch,
                           const float* __restrict__ p, const float* __restrict__ q,
                           const float* __restrict__ eb, float* __restrict__ out) {
    int e = blockIdx.x * 256 + threadIdx.x;
    if (e >= N_EDGES) return;
    int r = ei[e], c = ei[N_EDGES + e];
    float ek = 1.f / (1.f + expf(-(p[r] + q[c] + eb[0])));
    out[N_NODES + e] = ek;
    int g = batch[r];
    atomicAdd(&out[N_NODES + N_EDGES + 2 * N_GRAPHS + g], ek);
    atomicAdd(&out[N_NODES + N_EDGES + 3 * N_GRAPHS + g], 1.0f - ek);
}

extern "C" void kernel_launch(void* const* d_in, const int* in_sizes, int n_in,
                              void* d_out, int out_size, void* d_ws, size_t ws_size,
                              hipStream_t stream) {
    const int*   x     = (const int*)d_in[0];
    const int*   ei    = (const int*)d_in[1];
    const int*   ea    = (const int*)d_in[2];
    const int*   batch = (const int*)d_in[3];
    const float* at    = (const float*)d_in[4];
    const float* bt    = (const float*)d_in[5];
    const float* eps   = (const float*)d_in[6];
    const float* W1    = (const float*)d_in[7];
    const float* b1    = (const float*)d_in[8];
    const float* bn1g  = (const float*)d_in[9];
    const float* bn1b  = (const float*)d_in[10];
    const float* W2    = (const float*)d_in[11];
    const float* b2    = (const float*)d_in[12];
    const float* obng  = (const float*)d_in[13];
    const float* obnb  = (const float*)d_in[14];
    const float* nW    = (const float*)d_in[15];
    const float* nb    = (const float*)d_in[16];
    const float* eW    = (const float*)d_in[17];
    const float* eb    = (const float*)d_in[18];
    float* out = (float*)d_out;

    float* ws    = (float*)d_ws;
    float* h     = ws;                       // N*128 fp32
    float* stats = h + 12800000;             // 3*768 per-layer accumulators
    float* p     = stats + 2304;             // N
    float* q     = p + N_NODES;              // N
    unsigned short* hb  = (unsigned short*)(q + N_NODES);  // N*128 bf16
    unsigned short* zub = hb + 12800000;     // N*128 bf16: z (gemm1 in), then u
    unsigned short* tb  = zub + 12800000;    // N*256 bf16
    unsigned short* Bp1 = tb + 25600000;     // 3*128*256 bf16
    unsigned short* Bp2 = Bp1 + 3 * 32768;   // 3*256*128 bf16
    int* rowptr  = (int*)(Bp2 + 3 * 32768);  // N+1
    int* cursor  = rowptr + N_NODES + 1;     // N (counts, then cursors)
    int* csr_row = cursor + N_NODES;         // E
    int* csr_attr = csr_row + N_EDGES;       // E
    int* bsum    = csr_attr + N_EDGES;       // SCAN_NBLK
    // per-layer stats l at stats + l*768: [sum256][sq256][osum128][osq128]

    hipMemsetAsync(stats, 0, 3 * 768 * sizeof(float), stream);
    hipMemsetAsync(cursor, 0, N_NODES * sizeof(int), stream);
    k_atom_encode<<<50000, 256, 0, stream>>>(x, at, h, hb);
    k_convw<<<768, 256, 0, stream>>>(W1, W2, Bp1, Bp2);

    // CSR of edges grouped by destination (col) — parallel 3-phase scan
    k_hist<<<2344, 256, 0, stream>>>(ei, cursor);
    k_scan_partial<<<SCAN_NBLK, 256, 0, stream>>>(cursor, bsum);
    k_scan_bsum<<<1, 256, 0, stream>>>(bsum, rowptr);
    k_scan_final<<<SCAN_NBLK, 512, 0, stream>>>(bsum, cursor, rowptr);
    k_fill<<<2344, 256, 0, stream>>>(ei, ea, cursor, csr_row, csr_attr);

    for (int l = 0; l < 3; ++l) {
        float* sl = stats + l * 768;
        k_gather<<<25000, 256, 0, stream>>>(hb, csr_row, csr_attr, rowptr,
                                            bt + (size_t)l * 3 * 8 * 128, eps, l, zub);
        k_gemm1<<<1563, 256, 0, stream>>>(zub, Bp1 + (size_t)l * 32768, b1 + l * 256, tb, sl);
        k_gemm2<<<1563, 256, 0, stream>>>(tb, Bp2 + (size_t)l * 32768, sl,
                                          bn1g + l * 256, bn1b + l * 256,
                                          b2 + l * 128, zub, sl + 512, sl + 640);
        k_update_h<<<6250, 256, 0, stream>>>(h, hb, zub, sl + 512, sl + 640,
                                             obng + l * 128, obnb + l * 128,
                                             (l < 2) ? 1 : 0);
    }

    k_init_seg<<<64, 256, 0, stream>>>(out);
    k_node_out<<<25000, 256, 0, stream>>>(h, batch, nW, nb, eW, out, p, q);
    k_edge_out<<<2344, 256, 0, stream>>>(ei, batch, p, q, eb, out);
}

// Round 7
// 802.544 us; speedup vs baseline: 4.3243x; 1.1464x over previous
//
#include <hip/hip_runtime.h>
#include <math.h>

#define N_NODES 100000
#define N_EDGES 600000
#define N_GRAPHS 4096
#define SCAN_CHUNK 512
#define SCAN_NBLK 196   // ceil(100000/512)

typedef __attribute__((ext_vector_type(8))) short short8v;   // 8 bf16 (4 VGPR)
typedef __attribute__((ext_vector_type(4))) float f32x4;

// fp32 pair -> packed bf16 (RNE) via the HW instruction
__device__ __forceinline__ unsigned int pack2(float a, float b) {
    unsigned int r;
    asm("v_cvt_pk_bf16_f32 %0, %1, %2" : "=v"(r) : "v"(a), "v"(b));
    return r;
}
__device__ __forceinline__ unsigned short bf16_rne(float f) {
    unsigned int r;
    asm("v_cvt_pk_bf16_f32 %0, %1, %2" : "=v"(r) : "v"(f), "v"(f));
    return (unsigned short)r;
}
__device__ __forceinline__ float bf2f(unsigned short u) {
    return __uint_as_float(((unsigned int)u) << 16);
}

// ------------------------------------------- atom encoder (writes fp32 + bf16)
__global__ void k_atom_encode(const int* __restrict__ x, const float* __restrict__ at,
                              float* __restrict__ h, unsigned short* __restrict__ hb) {
    int n = blockIdx.x * 2 + (threadIdx.x >> 7);
    int d = threadIdx.x & 127;
    if (n >= N_NODES) return;
    const int* xr = x + n * 9;
    float s = 0.f;
#pragma unroll
    for (int f = 0; f < 9; ++f) {
        int v = xr[f];
        s += at[(f * 100 + v) * 128 + d];
    }
    h[(size_t)n * 128 + d] = s;
    hb[(size_t)n * 128 + d] = bf16_rne(s);
}

// --------- combined bond table: ct[l][idx][d] = bf16(sum of 3 table rows)
__global__ void k_bondc(const float* __restrict__ bt, unsigned short* __restrict__ ct) {
    int idx = blockIdx.x * 256 + threadIdx.x;
    if (idx >= 3 * 512 * 128) return;
    int d = idx & 127;
    int c = (idx >> 7) & 511;
    int l = idx >> 16;
    const float* base = bt + (size_t)l * 3072;
    float v = base[(c >> 6) * 128 + d] + base[1024 + ((c >> 3) & 7) * 128 + d] +
              base[2048 + (c & 7) * 128 + d];
    ct[idx] = bf16_rne(v);
}

// --------------------------- CSR build (once); init_seg fused into hist
__global__ void k_hist(const int* __restrict__ ei, int* __restrict__ cnt,
                       float* __restrict__ out) {
    int e = blockIdx.x * 256 + threadIdx.x;
    if (e < 4 * N_GRAPHS) out[N_NODES + N_EDGES + e] = 1e-8f;
    if (e < N_EDGES) atomicAdd(&cnt[ei[N_EDGES + e]], 1);
}

__global__ void k_scan_partial(const int* __restrict__ cnt, int* __restrict__ bsum) {
    __shared__ int ls[256];
    int base = blockIdx.x * SCAN_CHUNK;
    int t = threadIdx.x;
    int s = 0;
    for (int i = base + t; i < base + SCAN_CHUNK && i < N_NODES; i += 256) s += cnt[i];
    ls[t] = s;
    __syncthreads();
    for (int off = 128; off; off >>= 1) {
        if (t < off) ls[t] += ls[t + off];
        __syncthreads();
    }
    if (t == 0) bsum[blockIdx.x] = ls[0];
}

__global__ void k_scan_bsum(int* __restrict__ bsum, int* __restrict__ rowptr) {
    __shared__ int ls[256];
    int t = threadIdx.x;
    int v = (t < SCAN_NBLK) ? bsum[t] : 0;
    ls[t] = v;
    __syncthreads();
    for (int off = 1; off < 256; off <<= 1) {
        int x = (t >= off) ? ls[t - off] : 0;
        __syncthreads();
        ls[t] += x;
        __syncthreads();
    }
    if (t < SCAN_NBLK) bsum[t] = ls[t] - v;  // exclusive prefix
    if (t == 255) rowptr[N_NODES] = ls[255];
}

__global__ __launch_bounds__(512) void k_scan_final(const int* __restrict__ bsum,
                                                    int* __restrict__ cnt_cursor,
                                                    int* __restrict__ rowptr) {
    __shared__ int ls[512];
    int base = blockIdx.x * SCAN_CHUNK;
    int t = threadIdx.x;
    int i = base + t;
    int v = (i < N_NODES) ? cnt_cursor[i] : 0;
    ls[t] = v;
    __syncthreads();
    for (int off = 1; off < 512; off <<= 1) {
        int x = (t >= off) ? ls[t - off] : 0;
        __syncthreads();
        ls[t] += x;
        __syncthreads();
    }
    if (i < N_NODES) {
        int excl = bsum[blockIdx.x] + ls[t] - v;
        rowptr[i] = excl;
        cnt_cursor[i] = excl;
    }
}

// fill CSR-ordered source-row + combined-attr-index arrays
__global__ void k_fill(const int* __restrict__ ei, const int* __restrict__ ea,
                       int* __restrict__ cursor,
                       int* __restrict__ csr_row, int* __restrict__ csr_attr) {
    int e = blockIdx.x * 256 + threadIdx.x;
    if (e < N_EDGES) {
        int c = ei[N_EDGES + e];
        int pos = atomicAdd(&cursor[c], 1);
        csr_row[pos] = ei[e];
        csr_attr[pos] = ea[e * 3] * 64 + ea[e * 3 + 1] * 8 + ea[e * 3 + 2];
    }
}

// ---------------- weight pre-swizzle: fp32 -> bf16 in MFMA B-fragment layout
__global__ void k_convw(const float* __restrict__ W1, const float* __restrict__ W2,
                        unsigned short* __restrict__ Bp1, unsigned short* __restrict__ Bp2) {
    int idx = blockIdx.x * 256 + threadIdx.x;
    if (idx < 3 * 128 * 256) {
        int l = idx >> 15, r = idx & 32767;
        int k = r >> 8, j = r & 255;
        float v = W1[(size_t)l * 32768 + k * 256 + j];
        Bp1[(size_t)l * 32768 + (((k >> 5) * 4 + ((k >> 3) & 3)) * 256 + j) * 8 + (k & 7)] =
            bf16_rne(v);
    } else if (idx < 6 * 128 * 256) {
        int t = idx - 98304;
        int l = t >> 15, r = t & 32767;
        int k = r >> 7, j = r & 127;
        float v = W2[(size_t)l * 32768 + k * 128 + j];
        Bp2[(size_t)l * 32768 + (((k >> 5) * 4 + ((k >> 3) & 3)) * 128 + j) * 8 + (k & 7)] =
            bf16_rne(v);
    }
}

// ---------------------------- gather-aggregate: z = (1+eps)*h + sum relu(msg)
// wave per node; per edge: 2 independent 4B loads (hb row, ct row) + ~8 VALU
#define EDGE2(uu, cc)                                                          \
    {                                                                          \
        ax += fmaxf(bf2f((unsigned short)((uu) & 0xffffu)) +                   \
                    bf2f((unsigned short)((cc) & 0xffffu)), 0.f);              \
        ay += fmaxf(bf2f((unsigned short)((uu) >> 16)) +                       \
                    bf2f((unsigned short)((cc) >> 16)), 0.f);                  \
    }

__global__ void k_gather(const unsigned short* __restrict__ hb,
                         const int* __restrict__ csr_row, const int* __restrict__ csr_attr,
                         const int* __restrict__ rowptr, const unsigned short* __restrict__ ct,
                         const float* __restrict__ eps, int l,
                         unsigned short* __restrict__ zb) {
    int lane = threadIdx.x & 63;
    int n = blockIdx.x * 4 + (threadIdx.x >> 6);
    if (n >= N_NODES) return;
    int i0 = rowptr[n], i1 = rowptr[n + 1];
    float ax = 0.f, ay = 0.f;
    int i = i0;
    for (; i + 4 <= i1; i += 4) {
        int r0 = csr_row[i], r1 = csr_row[i + 1], r2 = csr_row[i + 2], r3 = csr_row[i + 3];
        int q0 = csr_attr[i], q1 = csr_attr[i + 1], q2 = csr_attr[i + 2], q3 = csr_attr[i + 3];
        unsigned int u0 = ((const unsigned int*)(hb + (size_t)r0 * 128))[lane];
        unsigned int u1 = ((const unsigned int*)(hb + (size_t)r1 * 128))[lane];
        unsigned int u2 = ((const unsigned int*)(hb + (size_t)r2 * 128))[lane];
        unsigned int u3 = ((const unsigned int*)(hb + (size_t)r3 * 128))[lane];
        unsigned int c0 = ((const unsigned int*)(ct + q0 * 128))[lane];
        unsigned int c1 = ((const unsigned int*)(ct + q1 * 128))[lane];
        unsigned int c2 = ((const unsigned int*)(ct + q2 * 128))[lane];
        unsigned int c3 = ((const unsigned int*)(ct + q3 * 128))[lane];
        EDGE2(u0, c0); EDGE2(u1, c1); EDGE2(u2, c2); EDGE2(u3, c3);
    }
    for (; i < i1; ++i) {
        int r0 = csr_row[i];
        int q0 = csr_attr[i];
        unsigned int u0 = ((const unsigned int*)(hb + (size_t)r0 * 128))[lane];
        unsigned int c0 = ((const unsigned int*)(ct + q0 * 128))[lane];
        EDGE2(u0, c0);
    }
    float el = 1.0f + eps[l];
    unsigned int un = ((const unsigned int*)(hb + (size_t)n * 128))[lane];
    float zx = fmaf(el, bf2f((unsigned short)(un & 0xffffu)), ax);
    float zy = fmaf(el, bf2f((unsigned short)(un >> 16)), ay);
    ((unsigned int*)(zb + (size_t)n * 128))[lane] = pack2(zx, zy);
}

// --------------------- GEMM1 (MFMA, swapped operands -> (z@W1)^T fragments):
// t = z@W1 + b1, fused BN1 column stats. Each thread's 4 acc values are 4
// CONSECUTIVE COLUMNS of one row -> uint2 stores. Stats via LDS transpose.
__global__ __launch_bounds__(256) void k_gemm1(
    const unsigned short* __restrict__ zb, const unsigned short* __restrict__ Bp,
    const float* __restrict__ bias, unsigned short* __restrict__ tb,
    float* __restrict__ stats) {
    __shared__ unsigned short As[8192] __attribute__((aligned(16)));  // 16 KB
    int n0 = blockIdx.x * 64;
#pragma unroll
    for (int s = 0; s < 4; ++s) {
        int i = threadIdx.x + s * 256;            // 16B unit; 64 rows x 16 units
        int r = i >> 4, k8 = i & 15;
        short8v v = (short8v)(short)0;
        if (n0 + r < N_NODES) v = ((const short8v*)(zb + (size_t)(n0 + r) * 128))[k8];
        int frag = (r >> 4) * 16 + k8;
        int off = (frag * 128 + (r & 15) * 8) ^ ((k8 & 7) << 3);
        *(short8v*)(&As[off]) = v;
    }
    __syncthreads();
    int lane = threadIdx.x & 63;
    int wid = threadIdx.x >> 6;
    int l15 = lane & 15, kg = lane >> 4;
    int colbase = wid * 64;
    f32x4 acc[4][4];  // [rb][cf]
#pragma unroll
    for (int a = 0; a < 4; ++a)
#pragma unroll
        for (int b = 0; b < 4; ++b) acc[a][b] = (f32x4)(0.f);
#pragma unroll
    for (int k4 = 0; k4 < 4; ++k4) {
        short8v af[4], bf[4];
#pragma unroll
        for (int rb = 0; rb < 4; ++rb)
            af[rb] = *(const short8v*)(&As[((rb * 16 + k4 * 4 + kg) * 128 + l15 * 8) ^
                                           (((k4 * 4 + kg) & 7) << 3)]);
#pragma unroll
        for (int cf = 0; cf < 4; ++cf)
            bf[cf] = *(const short8v*)(Bp + ((k4 * 4 + kg) * 256 + colbase + cf * 16 + l15) * 8);
#pragma unroll
        for (int rb = 0; rb < 4; ++rb)
#pragma unroll
            for (int cf = 0; cf < 4; ++cf)
                acc[rb][cf] = __builtin_amdgcn_mfma_f32_16x16x32_bf16(bf[cf], af[rb],
                                                                      acc[rb][cf], 0, 0, 0);
    }
    // epilogue: D^T layout -> thread holds rows gr=n0+rb*16+l15, cols j0..j0+3
    float s4[4][4], q4[4][4];
#pragma unroll
    for (int cf = 0; cf < 4; ++cf)
#pragma unroll
        for (int r = 0; r < 4; ++r) { s4[cf][r] = 0.f; q4[cf][r] = 0.f; }
#pragma unroll
    for (int cf = 0; cf < 4; ++cf) {
        int j0 = colbase + cf * 16 + kg * 4;
        float4 b4 = *(const float4*)(bias + j0);
#pragma unroll
        for (int rb = 0; rb < 4; ++rb) {
            int gr = n0 + rb * 16 + l15;
            if (gr < N_NODES) {
                float v0 = acc[rb][cf][0] + b4.x;
                float v1 = acc[rb][cf][1] + b4.y;
                float v2 = acc[rb][cf][2] + b4.z;
                float v3 = acc[rb][cf][3] + b4.w;
                uint2 st;
                st.x = pack2(v0, v1);
                st.y = pack2(v2, v3);
                *(uint2*)(tb + (size_t)gr * 256 + j0) = st;
                s4[cf][0] += v0; q4[cf][0] += v0 * v0;
                s4[cf][1] += v1; q4[cf][1] += v1 * v1;
                s4[cf][2] += v2; q4[cf][2] += v2 * v2;
                s4[cf][3] += v3; q4[cf][3] += v3 * v3;
            }
        }
    }
    // stats reduce via LDS (reuse As after barrier): part[j][16]
    float* part = (float*)As;
    __syncthreads();
#pragma unroll
    for (int cf = 0; cf < 4; ++cf)
#pragma unroll
        for (int r = 0; r < 4; ++r)
            part[(colbase + cf * 16 + kg * 4 + r) * 16 + l15] = s4[cf][r];
    __syncthreads();
    {
        int j = threadIdx.x;
        const float4* pr = (const float4*)(part + j * 16);
        float4 a0 = pr[0], a1 = pr[1], a2 = pr[2], a3 = pr[3];
        float s = a0.x + a0.y + a0.z + a0.w + a1.x + a1.y + a1.z + a1.w +
                  a2.x + a2.y + a2.z + a2.w + a3.x + a3.y + a3.z + a3.w;
        atomicAdd(&stats[j], s);
    }
    __syncthreads();
#pragma unroll
    for (int cf = 0; cf < 4; ++cf)
#pragma unroll
        for (int r = 0; r < 4; ++r)
            part[(colbase + cf * 16 + kg * 4 + r) * 16 + l15] = q4[cf][r];
    __syncthreads();
    {
        int j = threadIdx.x;
        const float4* pr = (const float4*)(part + j * 16);
        float4 a0 = pr[0], a1 = pr[1], a2 = pr[2], a3 = pr[3];
        float s = a0.x + a0.y + a0.z + a0.w + a1.x + a1.y + a1.z + a1.w +
                  a2.x + a2.y + a2.z + a2.w + a3.x + a3.y + a3.z + a3.w;
        atomicAdd(&stats[256 + j], s);
    }
}

// ------- GEMM2 (MFMA, swapped): u = relu(BN1(t))@W2 + b2, fused BN2 stats
__global__ __launch_bounds__(256) void k_gemm2(
    const unsigned short* __restrict__ tb, const unsigned short* __restrict__ Bp,
    const float* __restrict__ stats, const float* __restrict__ g1,
    const float* __restrict__ b1g,
    const float* __restrict__ bias, unsigned short* __restrict__ ub,
    float* __restrict__ osum, float* __restrict__ osq) {
    __shared__ unsigned short As[16384] __attribute__((aligned(16)));  // 32 KB
    int n0 = blockIdx.x * 64;
    int tid = threadIdx.x;
    int kb = (tid & 31) * 8;
    float scr[8], shr[8];
#pragma unroll
    for (int j = 0; j < 8; ++j) {
        float m = stats[kb + j] * (1.0f / N_NODES);
        float var = stats[256 + kb + j] * (1.0f / N_NODES) - m * m;
        float sc = g1[kb + j] / sqrtf(var + 1e-5f);
        scr[j] = sc;
        shr[j] = b1g[kb + j] - m * sc;
    }
#pragma unroll
    for (int s = 0; s < 8; ++s) {
        int i = tid + s * 256;                    // 16B unit; 64 rows x 32 units
        int r = i >> 5, k8 = i & 31;
        short8v v = (short8v)(short)0;
        if (n0 + r < N_NODES) v = ((const short8v*)(tb + (size_t)(n0 + r) * 256))[k8];
        float f0 = fmaxf(fmaf(scr[0], bf2f((unsigned short)v[0]), shr[0]), 0.f);
        float f1 = fmaxf(fmaf(scr[1], bf2f((unsigned short)v[1]), shr[1]), 0.f);
        float f2 = fmaxf(fmaf(scr[2], bf2f((unsigned short)v[2]), shr[2]), 0.f);
        float f3 = fmaxf(fmaf(scr[3], bf2f((unsigned short)v[3]), shr[3]), 0.f);
        float f4 = fmaxf(fmaf(scr[4], bf2f((unsigned short)v[4]), shr[4]), 0.f);
        float f5 = fmaxf(fmaf(scr[5], bf2f((unsigned short)v[5]), shr[5]), 0.f);
        float f6 = fmaxf(fmaf(scr[6], bf2f((unsigned short)v[6]), shr[6]), 0.f);
        float f7 = fmaxf(fmaf(scr[7], bf2f((unsigned short)v[7]), shr[7]), 0.f);
        uint4 ov;
        ov.x = pack2(f0, f1); ov.y = pack2(f2, f3);
        ov.z = pack2(f4, f5); ov.w = pack2(f6, f7);
        int frag = (r >> 4) * 32 + k8;
        int off = (frag * 128 + (r & 15) * 8) ^ ((k8 & 7) << 3);
        *(uint4*)(&As[off]) = ov;
    }
    __syncthreads();
    int lane = threadIdx.x & 63;
    int wid = threadIdx.x >> 6;
    int l15 = lane & 15, kg = lane >> 4;
    int colbase = wid * 32;
    f32x4 acc[4][2];  // [rb][cf]
#pragma unroll
    for (int a = 0; a < 4; ++a) {
        acc[a][0] = (f32x4)(0.f);
        acc[a][1] = (f32x4)(0.f);
    }
#pragma unroll
    for (int k4 = 0; k4 < 8; ++k4) {
        short8v af[4], bf[2];
#pragma unroll
        for (int rb = 0; rb < 4; ++rb)
            af[rb] = *(const short8v*)(&As[((rb * 32 + k4 * 4 + kg) * 128 + l15 * 8) ^
                                           (((k4 * 4 + kg) & 7) << 3)]);
#pragma unroll
        for (int cf = 0; cf < 2; ++cf)
            bf[cf] = *(const short8v*)(Bp + ((k4 * 4 + kg) * 128 + colbase + cf * 16 + l15) * 8);
#pragma unroll
        for (int rb = 0; rb < 4; ++rb)
#pragma unroll
            for (int cf = 0; cf < 2; ++cf)
                acc[rb][cf] = __builtin_amdgcn_mfma_f32_16x16x32_bf16(bf[cf], af[rb],
                                                                      acc[rb][cf], 0, 0, 0);
    }
    float s4[2][4], q4[2][4];
#pragma unroll
    for (int cf = 0; cf < 2; ++cf)
#pragma unroll
        for (int r = 0; r < 4; ++r) { s4[cf][r] = 0.f; q4[cf][r] = 0.f; }
#pragma unroll
    for (int cf = 0; cf < 2; ++cf) {
        int j0 = colbase + cf * 16 + kg * 4;
        float4 b4 = *(const float4*)(bias + j0);
#pragma unroll
        for (int rb = 0; rb < 4; ++rb) {
            int gr = n0 + rb * 16 + l15;
            if (gr < N_NODES) {
                float v0 = acc[rb][cf][0] + b4.x;
                float v1 = acc[rb][cf][1] + b4.y;
                float v2 = acc[rb][cf][2] + b4.z;
                float v3 = acc[rb][cf][3] + b4.w;
                uint2 st;
                st.x = pack2(v0, v1);
                st.y = pack2(v2, v3);
                *(uint2*)(ub + (size_t)gr * 128 + j0) = st;
                s4[cf][0] += v0; q4[cf][0] += v0 * v0;
                s4[cf][1] += v1; q4[cf][1] += v1 * v1;
                s4[cf][2] += v2; q4[cf][2] += v2 * v2;
                s4[cf][3] += v3; q4[cf][3] += v3 * v3;
            }
        }
    }
    float* part = (float*)As;  // need 128*16 floats = 8 KB
    __syncthreads();
#pragma unroll
    for (int cf = 0; cf < 2; ++cf)
#pragma unroll
        for (int r = 0; r < 4; ++r)
            part[(colbase + cf * 16 + kg * 4 + r) * 16 + l15] = s4[cf][r];
    __syncthreads();
    if (tid < 128) {
        const float4* pr = (const float4*)(part + tid * 16);
        float4 a0 = pr[0], a1 = pr[1], a2 = pr[2], a3 = pr[3];
        float s = a0.x + a0.y + a0.z + a0.w + a1.x + a1.y + a1.z + a1.w +
                  a2.x + a2.y + a2.z + a2.w + a3.x + a3.y + a3.z + a3.w;
        atomicAdd(&osum[tid], s);
    }
    __syncthreads();
#pragma unroll
    for (int cf = 0; cf < 2; ++cf)
#pragma unroll
        for (int r = 0; r < 4; ++r)
            part[(colbase + cf * 16 + kg * 4 + r) * 16 + l15] = q4[cf][r];
    __syncthreads();
    if (tid < 128) {
        const float4* pr = (const float4*)(part + tid * 16);
        float4 a0 = pr[0], a1 = pr[1], a2 = pr[2], a3 = pr[3];
        float s = a0.x + a0.y + a0.z + a0.w + a1.x + a1.y + a1.z + a1.w +
                  a2.x + a2.y + a2.z + a2.w + a3.x + a3.y + a3.z + a3.w;
        atomicAdd(&osq[tid], s);
    }
}

// --------- h += maybe_relu(BN2(u)); refresh bf16 mirror; per-thread BN finalize
__global__ void k_update_h(float* __restrict__ h, unsigned short* __restrict__ hb,
                           const unsigned short* __restrict__ ub,
                           const float* __restrict__ osum, const float* __restrict__ osq,
                           const float* __restrict__ g2, const float* __restrict__ b2g,
                           int relu) {
    int kb = (threadIdx.x & 15) * 8;
    float scr[8], shr[8];
#pragma unroll
    for (int j = 0; j < 8; ++j) {
        float m = osum[kb + j] * (1.0f / N_NODES);
        float var = osq[kb + j] * (1.0f / N_NODES) - m * m;
        float sc = g2[kb + j] / sqrtf(var + 1e-5f);
        scr[j] = sc;
        shr[j] = b2g[kb + j] - m * sc;
    }
    int i = blockIdx.x * 256 + threadIdx.x;  // 8-elem unit; total N*16 = 1.6M
    uint4 uv = ((const uint4*)ub)[i];
    float4 h0 = ((const float4*)h)[i * 2];
    float4 h1 = ((const float4*)h)[i * 2 + 1];
    float v0 = fmaf(scr[0], bf2f((unsigned short)(uv.x & 0xffffu)), shr[0]);
    float v1 = fmaf(scr[1], bf2f((unsigned short)(uv.x >> 16)), shr[1]);
    float v2 = fmaf(scr[2], bf2f((unsigned short)(uv.y & 0xffffu)), shr[2]);
    float v3 = fmaf(scr[3], bf2f((unsigned short)(uv.y >> 16)), shr[3]);
    float v4 = fmaf(scr[4], bf2f((unsigned short)(uv.z & 0xffffu)), shr[4]);
    float v5 = fmaf(scr[5], bf2f((unsigned short)(uv.z >> 16)), shr[5]);
    float v6 = fmaf(scr[6], bf2f((unsigned short)(uv.w & 0xffffu)), shr[6]);
    float v7 = fmaf(scr[7], bf2f((unsigned short)(uv.w >> 16)), shr[7]);
    if (relu) {
        v0 = fmaxf(v0, 0.f); v1 = fmaxf(v1, 0.f); v2 = fmaxf(v2, 0.f); v3 = fmaxf(v3, 0.f);
        v4 = fmaxf(v4, 0.f); v5 = fmaxf(v5, 0.f); v6 = fmaxf(v6, 0.f); v7 = fmaxf(v7, 0.f);
    }
    h0.x += v0; h0.y += v1; h0.z += v2; h0.w += v3;
    h1.x += v4; h1.y += v5; h1.z += v6; h1.w += v7;
    ((float4*)h)[i * 2] = h0;
    ((float4*)h)[i * 2 + 1] = h1;
    uint4 hp;
    hp.x = pack2(h0.x, h0.y); hp.y = pack2(h0.z, h0.w);
    hp.z = pack2(h1.x, h1.y); hp.w = pack2(h1.z, h1.w);
    ((uint4*)hb)[i] = hp;
}

// ------------- node head: node_key + per-node dots p,q + node segment sums
__global__ void k_node_out(const float* __restrict__ h, const int* __restrict__ batch,
                           const float* __restrict__ nW, const float* __restrict__ nb,
                           const float* __restrict__ eW,
                           float* __restrict__ out, float* __restrict__ p,
                           float* __restrict__ q) {
    int n = blockIdx.x * 4 + (threadIdx.x >> 6);
    int lane = threadIdx.x & 63;
    if (n >= N_NODES) return;
    float2 hv = ((const float2*)(h + (size_t)n * 128))[lane];
    float2 wn = ((const float2*)nW)[lane];
    float2 wa = ((const float2*)eW)[lane];
    float2 wb = ((const float2*)eW)[64 + lane];
    float dn = hv.x * wn.x + hv.y * wn.y;
    float da = hv.x * wa.x + hv.y * wa.y;
    float db = hv.x * wb.x + hv.y * wb.y;
#pragma unroll
    for (int off = 32; off; off >>= 1) {
        dn += __shfl_xor(dn, off);
        da += __shfl_xor(da, off);
        db += __shfl_xor(db, off);
    }
    if (lane == 0) {
        float nk = 1.f / (1.f + expf(-(dn + nb[0])));
        out[n] = nk;
        int g = batch[n];
        atomicAdd(&out[N_NODES + N_EDGES + g], nk);
        atomicAdd(&out[N_NODES + N_EDGES + N_GRAPHS + g], 1.0f - nk);
        p[n] = da;
        q[n] = db;
    }
}

// ------------- edge head: edge_key = sigmoid(p[row]+q[col]+b) + edge seg sums
__global__ void k_edge_out(const int* __restrict__ ei, const int* __restrict__ batch,
                           const float* __restrict__ p, const float* __restrict__ q,
                           const float* __restrict__ eb, float* __restrict__ out) {
    int e = blockIdx.x * 256 + threadIdx.x;
    if (e >= N_EDGES) return;
    int r = ei[e], c = ei[N_EDGES + e];
    float ek = 1.f / (1.f + expf(-(p[r] + q[c] + eb[0])));
    out[N_NODES + e] = ek;
    int g = batch[r];
    atomicAdd(&out[N_NODES + N_EDGES + 2 * N_GRAPHS + g], ek);
    atomicAdd(&out[N_NODES + N_EDGES + 3 * N_GRAPHS + g], 1.0f - ek);
}

extern "C" void kernel_launch(void* const* d_in, const int* in_sizes, int n_in,
                              void* d_out, int out_size, void* d_ws, size_t ws_size,
                              hipStream_t stream) {
    const int*   x     = (const int*)d_in[0];
    const int*   ei    = (const int*)d_in[1];
    const int*   ea    = (const int*)d_in[2];
    const int*   batch = (const int*)d_in[3];
    const float* at    = (const float*)d_in[4];
    const float* bt    = (const float*)d_in[5];
    const float* eps   = (const float*)d_in[6];
    const float* W1    = (const float*)d_in[7];
    const float* b1    = (const float*)d_in[8];
    const float* bn1g  = (const float*)d_in[9];
    const float* bn1b  = (const float*)d_in[10];
    const float* W2    = (const float*)d_in[11];
    const float* b2    = (const float*)d_in[12];
    const float* obng  = (const float*)d_in[13];
    const float* obnb  = (const float*)d_in[14];
    const float* nW    = (const float*)d_in[15];
    const float* nb    = (const float*)d_in[16];
    const float* eW    = (const float*)d_in[17];
    const float* eb    = (const float*)d_in[18];
    float* out = (float*)d_out;

    float* ws    = (float*)d_ws;
    float* h     = ws;                       // N*128 fp32
    float* stats = h + 12800000;             // 3*768 per-layer accumulators
    float* p     = stats + 2304;             // N
    float* q     = p + N_NODES;              // N
    unsigned short* hb  = (unsigned short*)(q + N_NODES);  // N*128 bf16
    unsigned short* zub = hb + 12800000;     // N*128 bf16: z (gemm1 in), then u
    unsigned short* tb  = zub + 12800000;    // N*256 bf16
    unsigned short* Bp1 = tb + 25600000;     // 3*128*256 bf16
    unsigned short* Bp2 = Bp1 + 3 * 32768;   // 3*256*128 bf16
    unsigned short* ct  = Bp2 + 3 * 32768;   // 3*512*128 bf16 combined bond
    int* rowptr  = (int*)(ct + 3 * 65536);   // N+1
    int* cursor  = rowptr + N_NODES + 1;     // N (counts, then cursors)
    int* csr_row = cursor + N_NODES;         // E
    int* csr_attr = csr_row + N_EDGES;       // E
    int* bsum    = csr_attr + N_EDGES;       // SCAN_NBLK
    // per-layer stats l at stats + l*768: [sum256][sq256][osum128][osq128]

    hipMemsetAsync(stats, 0, 3 * 768 * sizeof(float), stream);
    hipMemsetAsync(cursor, 0, N_NODES * sizeof(int), stream);
    k_atom_encode<<<50000, 256, 0, stream>>>(x, at, h, hb);
    k_convw<<<768, 256, 0, stream>>>(W1, W2, Bp1, Bp2);
    k_bondc<<<768, 256, 0, stream>>>(bt, ct);

    // CSR of edges grouped by destination (col) — parallel 3-phase scan
    k_hist<<<2344, 256, 0, stream>>>(ei, cursor, out);
    k_scan_partial<<<SCAN_NBLK, 256, 0, stream>>>(cursor, bsum);
    k_scan_bsum<<<1, 256, 0, stream>>>(bsum, rowptr);
    k_scan_final<<<SCAN_NBLK, 512, 0, stream>>>(bsum, cursor, rowptr);
    k_fill<<<2344, 256, 0, stream>>>(ei, ea, cursor, csr_row, csr_attr);

    for (int l = 0; l < 3; ++l) {
        float* sl = stats + l * 768;
        k_gather<<<25000, 256, 0, stream>>>(hb, csr_row, csr_attr, rowptr,
                                            ct + (size_t)l * 65536, eps, l, zub);
        k_gemm1<<<1563, 256, 0, stream>>>(zub, Bp1 + (size_t)l * 32768, b1 + l * 256, tb, sl);
        k_gemm2<<<1563, 256, 0, stream>>>(tb, Bp2 + (size_t)l * 32768, sl,
                                          bn1g + l * 256, bn1b + l * 256,
                                          b2 + l * 128, zub, sl + 512, sl + 640);
        k_update_h<<<6250, 256, 0, stream>>>(h, hb, zub, sl + 512, sl + 640,
                                             obng + l * 128, obnb + l * 128,
                                             (l < 2) ? 1 : 0);
    }

    k_node_out<<<25000, 256, 0, stream>>>(h, batch, nW, nb, eW, out, p, q);
    k_edge_out<<<2344, 256, 0, stream>>>(ei, batch, p, q, eb, out);
}

// Round 8
// 798.684 us; speedup vs baseline: 4.3452x; 1.0048x over previous
//
#include <hip/hip_runtime.h>
#include <math.h>

#define N_NODES 100000
#define N_EDGES 600000
#define N_GRAPHS 4096
#define SCAN_CHUNK 512
#define SCAN_NBLK 196   // ceil(100000/512)

typedef __attribute__((ext_vector_type(8))) short short8v;   // 8 bf16 (4 VGPR)
typedef __attribute__((ext_vector_type(4))) float f32x4;

// fp32 pair -> packed bf16 (RNE) via the HW instruction
__device__ __forceinline__ unsigned int pack2(float a, float b) {
    unsigned int r;
    asm("v_cvt_pk_bf16_f32 %0, %1, %2" : "=v"(r) : "v"(a), "v"(b));
    return r;
}
__device__ __forceinline__ unsigned short bf16_rne(float f) {
    unsigned int r;
    asm("v_cvt_pk_bf16_f32 %0, %1, %2" : "=v"(r) : "v"(f), "v"(f));
    return (unsigned short)r;
}
__device__ __forceinline__ float bf2f(unsigned short u) {
    return __uint_as_float(((unsigned int)u) << 16);
}

// ------------------------------------------- atom encoder (writes fp32 + bf16)
__global__ void k_atom_encode(const int* __restrict__ x, const float* __restrict__ at,
                              float* __restrict__ h, unsigned short* __restrict__ hb) {
    int n = blockIdx.x * 2 + (threadIdx.x >> 7);
    int d = threadIdx.x & 127;
    if (n >= N_NODES) return;
    const int* xr = x + n * 9;
    float s = 0.f;
#pragma unroll
    for (int f = 0; f < 9; ++f) {
        int v = xr[f];
        s += at[(f * 100 + v) * 128 + d];
    }
    h[(size_t)n * 128 + d] = s;
    hb[(size_t)n * 128 + d] = bf16_rne(s);
}

// --------- combined bond table: ct[l][idx][d] = bf16(sum of 3 table rows)
__global__ void k_bondc(const float* __restrict__ bt, unsigned short* __restrict__ ct) {
    int idx = blockIdx.x * 256 + threadIdx.x;
    if (idx >= 3 * 512 * 128) return;
    int d = idx & 127;
    int c = (idx >> 7) & 511;
    int l = idx >> 16;
    const float* base = bt + (size_t)l * 3072;
    float v = base[(c >> 6) * 128 + d] + base[1024 + ((c >> 3) & 7) * 128 + d] +
              base[2048 + (c & 7) * 128 + d];
    ct[idx] = bf16_rne(v);
}

// --------------------------- CSR build (once)
__global__ void k_hist(const int* __restrict__ ei, int* __restrict__ cnt) {
    int e = blockIdx.x * 256 + threadIdx.x;
    if (e < N_EDGES) atomicAdd(&cnt[ei[N_EDGES + e]], 1);
}

__global__ void k_scan_partial(const int* __restrict__ cnt, int* __restrict__ bsum) {
    __shared__ int ls[256];
    int base = blockIdx.x * SCAN_CHUNK;
    int t = threadIdx.x;
    int s = 0;
    for (int i = base + t; i < base + SCAN_CHUNK && i < N_NODES; i += 256) s += cnt[i];
    ls[t] = s;
    __syncthreads();
    for (int off = 128; off; off >>= 1) {
        if (t < off) ls[t] += ls[t + off];
        __syncthreads();
    }
    if (t == 0) bsum[blockIdx.x] = ls[0];
}

__global__ void k_scan_bsum(int* __restrict__ bsum, int* __restrict__ rowptr) {
    __shared__ int ls[256];
    int t = threadIdx.x;
    int v = (t < SCAN_NBLK) ? bsum[t] : 0;
    ls[t] = v;
    __syncthreads();
    for (int off = 1; off < 256; off <<= 1) {
        int x = (t >= off) ? ls[t - off] : 0;
        __syncthreads();
        ls[t] += x;
        __syncthreads();
    }
    if (t < SCAN_NBLK) bsum[t] = ls[t] - v;  // exclusive prefix
    if (t == 255) rowptr[N_NODES] = ls[255];
}

__global__ __launch_bounds__(512) void k_scan_final(const int* __restrict__ bsum,
                                                    int* __restrict__ cnt_cursor,
                                                    int* __restrict__ rowptr) {
    __shared__ int ls[512];
    int base = blockIdx.x * SCAN_CHUNK;
    int t = threadIdx.x;
    int i = base + t;
    int v = (i < N_NODES) ? cnt_cursor[i] : 0;
    ls[t] = v;
    __syncthreads();
    for (int off = 1; off < 512; off <<= 1) {
        int x = (t >= off) ? ls[t - off] : 0;
        __syncthreads();
        ls[t] += x;
        __syncthreads();
    }
    if (i < N_NODES) {
        int excl = bsum[blockIdx.x] + ls[t] - v;
        rowptr[i] = excl;
        cnt_cursor[i] = excl;
    }
}

// fill CSR-ordered source-row + combined-attr-index arrays
__global__ void k_fill(const int* __restrict__ ei, const int* __restrict__ ea,
                       int* __restrict__ cursor,
                       int* __restrict__ csr_row, int* __restrict__ csr_attr) {
    int e = blockIdx.x * 256 + threadIdx.x;
    if (e < N_EDGES) {
        int c = ei[N_EDGES + e];
        int pos = atomicAdd(&cursor[c], 1);
        csr_row[pos] = ei[e];
        csr_attr[pos] = ea[e * 3] * 64 + ea[e * 3 + 1] * 8 + ea[e * 3 + 2];
    }
}

// ---------------- weight pre-swizzle: fp32 -> bf16 in MFMA B-fragment layout
__global__ void k_convw(const float* __restrict__ W1, const float* __restrict__ W2,
                        unsigned short* __restrict__ Bp1, unsigned short* __restrict__ Bp2) {
    int idx = blockIdx.x * 256 + threadIdx.x;
    if (idx < 3 * 128 * 256) {
        int l = idx >> 15, r = idx & 32767;
        int k = r >> 8, j = r & 255;
        float v = W1[(size_t)l * 32768 + k * 256 + j];
        Bp1[(size_t)l * 32768 + (((k >> 5) * 4 + ((k >> 3) & 3)) * 256 + j) * 8 + (k & 7)] =
            bf16_rne(v);
    } else if (idx < 6 * 128 * 256) {
        int t = idx - 98304;
        int l = t >> 15, r = t & 32767;
        int k = r >> 7, j = r & 127;
        float v = W2[(size_t)l * 32768 + k * 128 + j];
        Bp2[(size_t)l * 32768 + (((k >> 5) * 4 + ((k >> 3) & 3)) * 128 + j) * 8 + (k & 7)] =
            bf16_rne(v);
    }
}

// ---------------------------- gather-aggregate: z = (1+eps)*h + sum relu(msg)
#define EDGE2(uu, cc)                                                          \
    {                                                                          \
        ax += fmaxf(bf2f((unsigned short)((uu) & 0xffffu)) +                   \
                    bf2f((unsigned short)((cc) & 0xffffu)), 0.f);              \
        ay += fmaxf(bf2f((unsigned short)((uu) >> 16)) +                       \
                    bf2f((unsigned short)((cc) >> 16)), 0.f);                  \
    }

__global__ void k_gather(const unsigned short* __restrict__ hb,
                         const int* __restrict__ csr_row, const int* __restrict__ csr_attr,
                         const int* __restrict__ rowptr, const unsigned short* __restrict__ ct,
                         const float* __restrict__ eps, int l,
                         unsigned short* __restrict__ zb) {
    int lane = threadIdx.x & 63;
    int n = blockIdx.x * 4 + (threadIdx.x >> 6);
    if (n >= N_NODES) return;
    int i0 = rowptr[n], i1 = rowptr[n + 1];
    float ax = 0.f, ay = 0.f;
    int i = i0;
    for (; i + 4 <= i1; i += 4) {
        int r0 = csr_row[i], r1 = csr_row[i + 1], r2 = csr_row[i + 2], r3 = csr_row[i + 3];
        int q0 = csr_attr[i], q1 = csr_attr[i + 1], q2 = csr_attr[i + 2], q3 = csr_attr[i + 3];
        unsigned int u0 = ((const unsigned int*)(hb + (size_t)r0 * 128))[lane];
        unsigned int u1 = ((const unsigned int*)(hb + (size_t)r1 * 128))[lane];
        unsigned int u2 = ((const unsigned int*)(hb + (size_t)r2 * 128))[lane];
        unsigned int u3 = ((const unsigned int*)(hb + (size_t)r3 * 128))[lane];
        unsigned int c0 = ((const unsigned int*)(ct + q0 * 128))[lane];
        unsigned int c1 = ((const unsigned int*)(ct + q1 * 128))[lane];
        unsigned int c2 = ((const unsigned int*)(ct + q2 * 128))[lane];
        unsigned int c3 = ((const unsigned int*)(ct + q3 * 128))[lane];
        EDGE2(u0, c0); EDGE2(u1, c1); EDGE2(u2, c2); EDGE2(u3, c3);
    }
    for (; i < i1; ++i) {
        int r0 = csr_row[i];
        int q0 = csr_attr[i];
        unsigned int u0 = ((const unsigned int*)(hb + (size_t)r0 * 128))[lane];
        unsigned int c0 = ((const unsigned int*)(ct + q0 * 128))[lane];
        EDGE2(u0, c0);
    }
    float el = 1.0f + eps[l];
    unsigned int un = ((const unsigned int*)(hb + (size_t)n * 128))[lane];
    float zx = fmaf(el, bf2f((unsigned short)(un & 0xffffu)), ax);
    float zy = fmaf(el, bf2f((unsigned short)(un >> 16)), ay);
    ((unsigned int*)(zb + (size_t)n * 128))[lane] = pack2(zx, zy);
}

// --------------------- GEMM1 (MFMA, swapped operands -> (z@W1)^T fragments)
__global__ __launch_bounds__(256) void k_gemm1(
    const unsigned short* __restrict__ zb, const unsigned short* __restrict__ Bp,
    const float* __restrict__ bias, unsigned short* __restrict__ tb,
    float* __restrict__ stats) {
    __shared__ unsigned short As[8192] __attribute__((aligned(16)));  // 16 KB
    int n0 = blockIdx.x * 64;
#pragma unroll
    for (int s = 0; s < 4; ++s) {
        int i = threadIdx.x + s * 256;            // 16B unit; 64 rows x 16 units
        int r = i >> 4, k8 = i & 15;
        short8v v = (short8v)(short)0;
        if (n0 + r < N_NODES) v = ((const short8v*)(zb + (size_t)(n0 + r) * 128))[k8];
        int frag = (r >> 4) * 16 + k8;
        int off = (frag * 128 + (r & 15) * 8) ^ ((k8 & 7) << 3);
        *(short8v*)(&As[off]) = v;
    }
    __syncthreads();
    int lane = threadIdx.x & 63;
    int wid = threadIdx.x >> 6;
    int l15 = lane & 15, kg = lane >> 4;
    int colbase = wid * 64;
    f32x4 acc[4][4];  // [rb][cf]
#pragma unroll
    for (int a = 0; a < 4; ++a)
#pragma unroll
        for (int b = 0; b < 4; ++b) acc[a][b] = (f32x4)(0.f);
#pragma unroll
    for (int k4 = 0; k4 < 4; ++k4) {
        short8v af[4], bf[4];
#pragma unroll
        for (int rb = 0; rb < 4; ++rb)
            af[rb] = *(const short8v*)(&As[((rb * 16 + k4 * 4 + kg) * 128 + l15 * 8) ^
                                           (((k4 * 4 + kg) & 7) << 3)]);
#pragma unroll
        for (int cf = 0; cf < 4; ++cf)
            bf[cf] = *(const short8v*)(Bp + ((k4 * 4 + kg) * 256 + colbase + cf * 16 + l15) * 8);
#pragma unroll
        for (int rb = 0; rb < 4; ++rb)
#pragma unroll
            for (int cf = 0; cf < 4; ++cf)
                acc[rb][cf] = __builtin_amdgcn_mfma_f32_16x16x32_bf16(bf[cf], af[rb],
                                                                      acc[rb][cf], 0, 0, 0);
    }
    float s4[4][4], q4[4][4];
#pragma unroll
    for (int cf = 0; cf < 4; ++cf)
#pragma unroll
        for (int r = 0; r < 4; ++r) { s4[cf][r] = 0.f; q4[cf][r] = 0.f; }
#pragma unroll
    for (int cf = 0; cf < 4; ++cf) {
        int j0 = colbase + cf * 16 + kg * 4;
        float4 b4 = *(const float4*)(bias + j0);
#pragma unroll
        for (int rb = 0; rb < 4; ++rb) {
            int gr = n0 + rb * 16 + l15;
            if (gr < N_NODES) {
                float v0 = acc[rb][cf][0] + b4.x;
                float v1 = acc[rb][cf][1] + b4.y;
                float v2 = acc[rb][cf][2] + b4.z;
                float v3 = acc[rb][cf][3] + b4.w;
                uint2 st;
                st.x = pack2(v0, v1);
                st.y = pack2(v2, v3);
                *(uint2*)(tb + (size_t)gr * 256 + j0) = st;
                s4[cf][0] += v0; q4[cf][0] += v0 * v0;
                s4[cf][1] += v1; q4[cf][1] += v1 * v1;
                s4[cf][2] += v2; q4[cf][2] += v2 * v2;
                s4[cf][3] += v3; q4[cf][3] += v3 * v3;
            }
        }
    }
    float* part = (float*)As;
    __syncthreads();
#pragma unroll
    for (int cf = 0; cf < 4; ++cf)
#pragma unroll
        for (int r = 0; r < 4; ++r)
            part[(colbase + cf * 16 + kg * 4 + r) * 16 + l15] = s4[cf][r];
    __syncthreads();
    {
        int j = threadIdx.x;
        const float4* pr = (const float4*)(part + j * 16);
        float4 a0 = pr[0], a1 = pr[1], a2 = pr[2], a3 = pr[3];
        float s = a0.x + a0.y + a0.z + a0.w + a1.x + a1.y + a1.z + a1.w +
                  a2.x + a2.y + a2.z + a2.w + a3.x + a3.y + a3.z + a3.w;
        atomicAdd(&stats[j], s);
    }
    __syncthreads();
#pragma unroll
    for (int cf = 0; cf < 4; ++cf)
#pragma unroll
        for (int r = 0; r < 4; ++r)
            part[(colbase + cf * 16 + kg * 4 + r) * 16 + l15] = q4[cf][r];
    __syncthreads();
    {
        int j = threadIdx.x;
        const float4* pr = (const float4*)(part + j * 16);
        float4 a0 = pr[0], a1 = pr[1], a2 = pr[2], a3 = pr[3];
        float s = a0.x + a0.y + a0.z + a0.w + a1.x + a1.y + a1.z + a1.w +
                  a2.x + a2.y + a2.z + a2.w + a3.x + a3.y + a3.z + a3.w;
        atomicAdd(&stats[256 + j], s);
    }
}

// ------- GEMM2 (MFMA, swapped): u = relu(BN1(t))@W2 + b2, fused BN2 stats
__global__ __launch_bounds__(256) void k_gemm2(
    const unsigned short* __restrict__ tb, const unsigned short* __restrict__ Bp,
    const float* __restrict__ stats, const float* __restrict__ g1,
    const float* __restrict__ b1g,
    const float* __restrict__ bias, unsigned short* __restrict__ ub,
    float* __restrict__ osum, float* __restrict__ osq) {
    __shared__ unsigned short As[16384] __attribute__((aligned(16)));  // 32 KB
    int n0 = blockIdx.x * 64;
    int tid = threadIdx.x;
    int kb = (tid & 31) * 8;
    float scr[8], shr[8];
#pragma unroll
    for (int j = 0; j < 8; ++j) {
        float m = stats[kb + j] * (1.0f / N_NODES);
        float var = stats[256 + kb + j] * (1.0f / N_NODES) - m * m;
        float sc = g1[kb + j] / sqrtf(var + 1e-5f);
        scr[j] = sc;
        shr[j] = b1g[kb + j] - m * sc;
    }
#pragma unroll
    for (int s = 0; s < 8; ++s) {
        int i = tid + s * 256;                    // 16B unit; 64 rows x 32 units
        int r = i >> 5, k8 = i & 31;
        short8v v = (short8v)(short)0;
        if (n0 + r < N_NODES) v = ((const short8v*)(tb + (size_t)(n0 + r) * 256))[k8];
        float f0 = fmaxf(fmaf(scr[0], bf2f((unsigned short)v[0]), shr[0]), 0.f);
        float f1 = fmaxf(fmaf(scr[1], bf2f((unsigned short)v[1]), shr[1]), 0.f);
        float f2 = fmaxf(fmaf(scr[2], bf2f((unsigned short)v[2]), shr[2]), 0.f);
        float f3 = fmaxf(fmaf(scr[3], bf2f((unsigned short)v[3]), shr[3]), 0.f);
        float f4 = fmaxf(fmaf(scr[4], bf2f((unsigned short)v[4]), shr[4]), 0.f);
        float f5 = fmaxf(fmaf(scr[5], bf2f((unsigned short)v[5]), shr[5]), 0.f);
        float f6 = fmaxf(fmaf(scr[6], bf2f((unsigned short)v[6]), shr[6]), 0.f);
        float f7 = fmaxf(fmaf(scr[7], bf2f((unsigned short)v[7]), shr[7]), 0.f);
        uint4 ov;
        ov.x = pack2(f0, f1); ov.y = pack2(f2, f3);
        ov.z = pack2(f4, f5); ov.w = pack2(f6, f7);
        int frag = (r >> 4) * 32 + k8;
        int off = (frag * 128 + (r & 15) * 8) ^ ((k8 & 7) << 3);
        *(uint4*)(&As[off]) = ov;
    }
    __syncthreads();
    int lane = threadIdx.x & 63;
    int wid = threadIdx.x >> 6;
    int l15 = lane & 15, kg = lane >> 4;
    int colbase = wid * 32;
    f32x4 acc[4][2];  // [rb][cf]
#pragma unroll
    for (int a = 0; a < 4; ++a) {
        acc[a][0] = (f32x4)(0.f);
        acc[a][1] = (f32x4)(0.f);
    }
#pragma unroll
    for (int k4 = 0; k4 < 8; ++k4) {
        short8v af[4], bf[2];
#pragma unroll
        for (int rb = 0; rb < 4; ++rb)
            af[rb] = *(const short8v*)(&As[((rb * 32 + k4 * 4 + kg) * 128 + l15 * 8) ^
                                           (((k4 * 4 + kg) & 7) << 3)]);
#pragma unroll
        for (int cf = 0; cf < 2; ++cf)
            bf[cf] = *(const short8v*)(Bp + ((k4 * 4 + kg) * 128 + colbase + cf * 16 + l15) * 8);
#pragma unroll
        for (int rb = 0; rb < 4; ++rb)
#pragma unroll
            for (int cf = 0; cf < 2; ++cf)
                acc[rb][cf] = __builtin_amdgcn_mfma_f32_16x16x32_bf16(bf[cf], af[rb],
                                                                      acc[rb][cf], 0, 0, 0);
    }
    float s4[2][4], q4[2][4];
#pragma unroll
    for (int cf = 0; cf < 2; ++cf)
#pragma unroll
        for (int r = 0; r < 4; ++r) { s4[cf][r] = 0.f; q4[cf][r] = 0.f; }
#pragma unroll
    for (int cf = 0; cf < 2; ++cf) {
        int j0 = colbase + cf * 16 + kg * 4;
        float4 b4 = *(const float4*)(bias + j0);
#pragma unroll
        for (int rb = 0; rb < 4; ++rb) {
            int gr = n0 + rb * 16 + l15;
            if (gr < N_NODES) {
                float v0 = acc[rb][cf][0] + b4.x;
                float v1 = acc[rb][cf][1] + b4.y;
                float v2 = acc[rb][cf][2] + b4.z;
                float v3 = acc[rb][cf][3] + b4.w;
                uint2 st;
                st.x = pack2(v0, v1);
                st.y = pack2(v2, v3);
                *(uint2*)(ub + (size_t)gr * 128 + j0) = st;
                s4[cf][0] += v0; q4[cf][0] += v0 * v0;
                s4[cf][1] += v1; q4[cf][1] += v1 * v1;
                s4[cf][2] += v2; q4[cf][2] += v2 * v2;
                s4[cf][3] += v3; q4[cf][3] += v3 * v3;
            }
        }
    }
    float* part = (float*)As;  // need 128*16 floats = 8 KB
    __syncthreads();
#pragma unroll
    for (int cf = 0; cf < 2; ++cf)
#pragma unroll
        for (int r = 0; r < 4; ++r)
            part[(colbase + cf * 16 + kg * 4 + r) * 16 + l15] = s4[cf][r];
    __syncthreads();
    if (tid < 128) {
        const float4* pr = (const float4*)(part + tid * 16);
        float4 a0 = pr[0], a1 = pr[1], a2 = pr[2], a3 = pr[3];
        float s = a0.x + a0.y + a0.z + a0.w + a1.x + a1.y + a1.z + a1.w +
                  a2.x + a2.y + a2.z + a2.w + a3.x + a3.y + a3.z + a3.w;
        atomicAdd(&osum[tid], s);
    }
    __syncthreads();
#pragma unroll
    for (int cf = 0; cf < 2; ++cf)
#pragma unroll
        for (int r = 0; r < 4; ++r)
            part[(colbase + cf * 16 + kg * 4 + r) * 16 + l15] = q4[cf][r];
    __syncthreads();
    if (tid < 128) {
        const float4* pr = (const float4*)(part + tid * 16);
        float4 a0 = pr[0], a1 = pr[1], a2 = pr[2], a3 = pr[3];
        float s = a0.x + a0.y + a0.z + a0.w + a1.x + a1.y + a1.z + a1.w +
                  a2.x + a2.y + a2.z + a2.w + a3.x + a3.y + a3.z + a3.w;
        atomicAdd(&osq[tid], s);
    }
}

// --------- h += maybe_relu(BN2(u)); refresh bf16 mirror; per-thread BN finalize
__global__ void k_update_h(float* __restrict__ h, unsigned short* __restrict__ hb,
                           const unsigned short* __restrict__ ub,
                           const float* __restrict__ osum, const float* __restrict__ osq,
                           const float* __restrict__ g2, const float* __restrict__ b2g,
                           int relu) {
    int kb = (threadIdx.x & 15) * 8;
    float scr[8], shr[8];
#pragma unroll
    for (int j = 0; j < 8; ++j) {
        float m = osum[kb + j] * (1.0f / N_NODES);
        float var = osq[kb + j] * (1.0f / N_NODES) - m * m;
        float sc = g2[kb + j] / sqrtf(var + 1e-5f);
        scr[j] = sc;
        shr[j] = b2g[kb + j] - m * sc;
    }
    int i = blockIdx.x * 256 + threadIdx.x;  // 8-elem unit; total N*16 = 1.6M
    uint4 uv = ((const uint4*)ub)[i];
    float4 h0 = ((const float4*)h)[i * 2];
    float4 h1 = ((const float4*)h)[i * 2 + 1];
    float v0 = fmaf(scr[0], bf2f((unsigned short)(uv.x & 0xffffu)), shr[0]);
    float v1 = fmaf(scr[1], bf2f((unsigned short)(uv.x >> 16)), shr[1]);
    float v2 = fmaf(scr[2], bf2f((unsigned short)(uv.y & 0xffffu)), shr[2]);
    float v3 = fmaf(scr[3], bf2f((unsigned short)(uv.y >> 16)), shr[3]);
    float v4 = fmaf(scr[4], bf2f((unsigned short)(uv.z & 0xffffu)), shr[4]);
    float v5 = fmaf(scr[5], bf2f((unsigned short)(uv.z >> 16)), shr[5]);
    float v6 = fmaf(scr[6], bf2f((unsigned short)(uv.w & 0xffffu)), shr[6]);
    float v7 = fmaf(scr[7], bf2f((unsigned short)(uv.w >> 16)), shr[7]);
    if (relu) {
        v0 = fmaxf(v0, 0.f); v1 = fmaxf(v1, 0.f); v2 = fmaxf(v2, 0.f); v3 = fmaxf(v3, 0.f);
        v4 = fmaxf(v4, 0.f); v5 = fmaxf(v5, 0.f); v6 = fmaxf(v6, 0.f); v7 = fmaxf(v7, 0.f);
    }
    h0.x += v0; h0.y += v1; h0.z += v2; h0.w += v3;
    h1.x += v4; h1.y += v5; h1.z += v6; h1.w += v7;
    ((float4*)h)[i * 2] = h0;
    ((float4*)h)[i * 2 + 1] = h1;
    uint4 hp;
    hp.x = pack2(h0.x, h0.y); hp.y = pack2(h0.z, h0.w);
    hp.z = pack2(h1.x, h1.y); hp.w = pack2(h1.z, h1.w);
    ((uint4*)hb)[i] = hp;
}

// ------------- node head: node_key + per-node dots p,q; seg sums into spread
// scratch copies (nsc[blockIdx&7][2][4096]) to avoid per-line atomic pileup
__global__ void k_node_out(const float* __restrict__ h, const int* __restrict__ batch,
                           const float* __restrict__ nW, const float* __restrict__ nb,
                           const float* __restrict__ eW,
                           float* __restrict__ out, float* __restrict__ p,
                           float* __restrict__ q, float* __restrict__ nsc) {
    int n = blockIdx.x * 4 + (threadIdx.x >> 6);
    int lane = threadIdx.x & 63;
    if (n >= N_NODES) return;
    float2 hv = ((const float2*)(h + (size_t)n * 128))[lane];
    float2 wn = ((const float2*)nW)[lane];
    float2 wa = ((const float2*)eW)[lane];
    float2 wb = ((const float2*)eW)[64 + lane];
    float dn = hv.x * wn.x + hv.y * wn.y;
    float da = hv.x * wa.x + hv.y * wa.y;
    float db = hv.x * wb.x + hv.y * wb.y;
#pragma unroll
    for (int off = 32; off; off >>= 1) {
        dn += __shfl_xor(dn, off);
        da += __shfl_xor(da, off);
        db += __shfl_xor(db, off);
    }
    if (lane == 0) {
        float nk = 1.f / (1.f + expf(-(dn + nb[0])));
        out[n] = nk;
        int g = batch[n];
        float* base = nsc + (size_t)(blockIdx.x & 7) * 8192;
        atomicAdd(&base[g], nk);
        atomicAdd(&base[4096 + g], 1.0f - nk);
        p[n] = da;
        q[n] = db;
    }
}

// ------------- edge head: edge_key + seg sums into esc[blockIdx&15][2][4096]
__global__ void k_edge_out(const int* __restrict__ ei, const int* __restrict__ batch,
                           const float* __restrict__ p, const float* __restrict__ q,
                           const float* __restrict__ eb, float* __restrict__ out,
                           float* __restrict__ esc) {
    int e = blockIdx.x * 256 + threadIdx.x;
    if (e >= N_EDGES) return;
    int r = ei[e], c = ei[N_EDGES + e];
    float ek = 1.f / (1.f + expf(-(p[r] + q[c] + eb[0])));
    out[N_NODES + e] = ek;
    int g = batch[r];
    float* base = esc + (size_t)(blockIdx.x & 15) * 8192;
    atomicAdd(&base[g], ek);
    atomicAdd(&base[4096 + g], 1.0f - ek);
}

// ------------- reduce the spread scratch copies into the 4 output segments
__global__ void k_seg_reduce(const float* __restrict__ nsc, const float* __restrict__ esc,
                             float* __restrict__ out) {
    int i = blockIdx.x * 256 + threadIdx.x;   // 0..16383
    if (i >= 16384) return;
    float s = 1e-8f;
    if (i < 8192) {
#pragma unroll
        for (int c = 0; c < 8; ++c) s += nsc[c * 8192 + i];
    } else {
        int j = i - 8192;
#pragma unroll
        for (int c = 0; c < 16; ++c) s += esc[c * 8192 + j];
    }
    out[N_NODES + N_EDGES + i] = s;
}

extern "C" void kernel_launch(void* const* d_in, const int* in_sizes, int n_in,
                              void* d_out, int out_size, void* d_ws, size_t ws_size,
                              hipStream_t stream) {
    const int*   x     = (const int*)d_in[0];
    const int*   ei    = (const int*)d_in[1];
    const int*   ea    = (const int*)d_in[2];
    const int*   batch = (const int*)d_in[3];
    const float* at    = (const float*)d_in[4];
    const float* bt    = (const float*)d_in[5];
    const float* eps   = (const float*)d_in[6];
    const float* W1    = (const float*)d_in[7];
    const float* b1    = (const float*)d_in[8];
    const float* bn1g  = (const float*)d_in[9];
    const float* bn1b  = (const float*)d_in[10];
    const float* W2    = (const float*)d_in[11];
    const float* b2    = (const float*)d_in[12];
    const float* obng  = (const float*)d_in[13];
    const float* obnb  = (const float*)d_in[14];
    const float* nW    = (const float*)d_in[15];
    const float* nb    = (const float*)d_in[16];
    const float* eW    = (const float*)d_in[17];
    const float* eb    = (const float*)d_in[18];
    float* out = (float*)d_out;

    float* ws    = (float*)d_ws;
    float* h     = ws;                       // N*128 fp32
    float* stats = h + 12800000;             // 3*768 per-layer accumulators
    float* p     = stats + 2304;             // N
    float* q     = p + N_NODES;              // N
    float* nsc   = q + N_NODES;              // 8*8192 node seg scratch
    float* esc   = nsc + 8 * 8192;           // 16*8192 edge seg scratch
    unsigned short* hb  = (unsigned short*)(esc + 16 * 8192);  // N*128 bf16
    unsigned short* zub = hb + 12800000;     // N*128 bf16: z (gemm1 in), then u
    unsigned short* tb  = zub + 12800000;    // N*256 bf16
    unsigned short* Bp1 = tb + 25600000;     // 3*128*256 bf16
    unsigned short* Bp2 = Bp1 + 3 * 32768;   // 3*256*128 bf16
    unsigned short* ct  = Bp2 + 3 * 32768;   // 3*512*128 bf16 combined bond
    int* rowptr  = (int*)(ct + 3 * 65536);   // N+1
    int* cursor  = rowptr + N_NODES + 1;     // N (counts, then cursors)
    int* csr_row = cursor + N_NODES;         // E
    int* csr_attr = csr_row + N_EDGES;       // E
    int* bsum    = csr_attr + N_EDGES;       // SCAN_NBLK
    // per-layer stats l at stats + l*768: [sum256][sq256][osum128][osq128]

    hipMemsetAsync(stats, 0, 3 * 768 * sizeof(float), stream);
    hipMemsetAsync(nsc, 0, 24 * 8192 * sizeof(float), stream);
    hipMemsetAsync(cursor, 0, N_NODES * sizeof(int), stream);
    k_atom_encode<<<50000, 256, 0, stream>>>(x, at, h, hb);
    k_convw<<<768, 256, 0, stream>>>(W1, W2, Bp1, Bp2);
    k_bondc<<<768, 256, 0, stream>>>(bt, ct);

    // CSR of edges grouped by destination (col) — parallel 3-phase scan
    k_hist<<<2344, 256, 0, stream>>>(ei, cursor);
    k_scan_partial<<<SCAN_NBLK, 256, 0, stream>>>(cursor, bsum);
    k_scan_bsum<<<1, 256, 0, stream>>>(bsum, rowptr);
    k_scan_final<<<SCAN_NBLK, 512, 0, stream>>>(bsum, cursor, rowptr);
    k_fill<<<2344, 256, 0, stream>>>(ei, ea, cursor, csr_row, csr_attr);

    for (int l = 0; l < 3; ++l) {
        float* sl = stats + l * 768;
        k_gather<<<25000, 256, 0, stream>>>(hb, csr_row, csr_attr, rowptr,
                                            ct + (size_t)l * 65536, eps, l, zub);
        k_gemm1<<<1563, 256, 0, stream>>>(zub, Bp1 + (size_t)l * 32768, b1 + l * 256, tb, sl);
        k_gemm2<<<1563, 256, 0, stream>>>(tb, Bp2 + (size_t)l * 32768, sl,
                                          bn1g + l * 256, bn1b + l * 256,
                                          b2 + l * 128, zub, sl + 512, sl + 640);
        k_update_h<<<6250, 256, 0, stream>>>(h, hb, zub, sl + 512, sl + 640,
                                             obng + l * 128, obnb + l * 128,
                                             (l < 2) ? 1 : 0);
    }

    k_node_out<<<25000, 256, 0, stream>>>(h, batch, nW, nb, eW, out, p, q, nsc);
    k_edge_out<<<2344, 256, 0, stream>>>(ei, batch, p, q, eb, out, esc);
    k_seg_reduce<<<64, 256, 0, stream>>>(nsc, esc, out);
}

// Round 9
// 622.434 us; speedup vs baseline: 5.5756x; 1.2832x over previous
//
#include <hip/hip_runtime.h>
#include <math.h>

#define N_NODES 100000
#define N_EDGES 600000
#define N_GRAPHS 4096
#define SCAN_CHUNK 512
#define SCAN_NBLK 196   // ceil(100000/512)
#define EOUT_BLK 512    // edge_out grid (LDS-binned, scratch copies)

typedef __attribute__((ext_vector_type(8))) short short8v;   // 8 bf16 (4 VGPR)
typedef __attribute__((ext_vector_type(4))) float f32x4;

// fp32 pair -> packed bf16 (RNE) via the HW instruction
__device__ __forceinline__ unsigned int pack2(float a, float b) {
    unsigned int r;
    asm("v_cvt_pk_bf16_f32 %0, %1, %2" : "=v"(r) : "v"(a), "v"(b));
    return r;
}
__device__ __forceinline__ unsigned short bf16_rne(float f) {
    unsigned int r;
    asm("v_cvt_pk_bf16_f32 %0, %1, %2" : "=v"(r) : "v"(f), "v"(f));
    return (unsigned short)r;
}
__device__ __forceinline__ float bf2f(unsigned short u) {
    return __uint_as_float(((unsigned int)u) << 16);
}

// ------------------------------------------- atom encoder (writes fp32 + bf16)
__global__ void k_atom_encode(const int* __restrict__ x, const float* __restrict__ at,
                              float* __restrict__ h, unsigned short* __restrict__ hb) {
    int n = blockIdx.x * 2 + (threadIdx.x >> 7);
    int d = threadIdx.x & 127;
    if (n >= N_NODES) return;
    const int* xr = x + n * 9;
    float s = 0.f;
#pragma unroll
    for (int f = 0; f < 9; ++f) {
        int v = xr[f];
        s += at[(f * 100 + v) * 128 + d];
    }
    h[(size_t)n * 128 + d] = s;
    hb[(size_t)n * 128 + d] = bf16_rne(s);
}

// --------- combined bond table: ct[l][idx][d] = bf16(sum of 3 table rows)
__global__ void k_bondc(const float* __restrict__ bt, unsigned short* __restrict__ ct) {
    int idx = blockIdx.x * 256 + threadIdx.x;
    if (idx >= 3 * 512 * 128) return;
    int d = idx & 127;
    int c = (idx >> 7) & 511;
    int l = idx >> 16;
    const float* base = bt + (size_t)l * 3072;
    float v = base[(c >> 6) * 128 + d] + base[1024 + ((c >> 3) & 7) * 128 + d] +
              base[2048 + (c & 7) * 128 + d];
    ct[idx] = bf16_rne(v);
}

// --------------------------- CSR build (once)
__global__ void k_hist(const int* __restrict__ ei, int* __restrict__ cnt) {
    int e = blockIdx.x * 256 + threadIdx.x;
    if (e < N_EDGES) atomicAdd(&cnt[ei[N_EDGES + e]], 1);
}

__global__ void k_scan_partial(const int* __restrict__ cnt, int* __restrict__ bsum) {
    __shared__ int ls[256];
    int base = blockIdx.x * SCAN_CHUNK;
    int t = threadIdx.x;
    int s = 0;
    for (int i = base + t; i < base + SCAN_CHUNK && i < N_NODES; i += 256) s += cnt[i];
    ls[t] = s;
    __syncthreads();
    for (int off = 128; off; off >>= 1) {
        if (t < off) ls[t] += ls[t + off];
        __syncthreads();
    }
    if (t == 0) bsum[blockIdx.x] = ls[0];
}

__global__ void k_scan_bsum(int* __restrict__ bsum, int* __restrict__ rowptr) {
    __shared__ int ls[256];
    int t = threadIdx.x;
    int v = (t < SCAN_NBLK) ? bsum[t] : 0;
    ls[t] = v;
    __syncthreads();
    for (int off = 1; off < 256; off <<= 1) {
        int x = (t >= off) ? ls[t - off] : 0;
        __syncthreads();
        ls[t] += x;
        __syncthreads();
    }
    if (t < SCAN_NBLK) bsum[t] = ls[t] - v;  // exclusive prefix
    if (t == 255) rowptr[N_NODES] = ls[255];
}

__global__ __launch_bounds__(512) void k_scan_final(const int* __restrict__ bsum,
                                                    int* __restrict__ cnt_cursor,
                                                    int* __restrict__ rowptr) {
    __shared__ int ls[512];
    int base = blockIdx.x * SCAN_CHUNK;
    int t = threadIdx.x;
    int i = base + t;
    int v = (i < N_NODES) ? cnt_cursor[i] : 0;
    ls[t] = v;
    __syncthreads();
    for (int off = 1; off < 512; off <<= 1) {
        int x = (t >= off) ? ls[t - off] : 0;
        __syncthreads();
        ls[t] += x;
        __syncthreads();
    }
    if (i < N_NODES) {
        int excl = bsum[blockIdx.x] + ls[t] - v;
        rowptr[i] = excl;
        cnt_cursor[i] = excl;
    }
}

// fill CSR-ordered source-row + combined-attr-index arrays
__global__ void k_fill(const int* __restrict__ ei, const int* __restrict__ ea,
                       int* __restrict__ cursor,
                       int* __restrict__ csr_row, int* __restrict__ csr_attr) {
    int e = blockIdx.x * 256 + threadIdx.x;
    if (e < N_EDGES) {
        int c = ei[N_EDGES + e];
        int pos = atomicAdd(&cursor[c], 1);
        csr_row[pos] = ei[e];
        csr_attr[pos] = ea[e * 3] * 64 + ea[e * 3 + 1] * 8 + ea[e * 3 + 2];
    }
}

// ---------------- weight pre-swizzle: fp32 -> bf16 in MFMA B-fragment layout
__global__ void k_convw(const float* __restrict__ W1, const float* __restrict__ W2,
                        unsigned short* __restrict__ Bp1, unsigned short* __restrict__ Bp2) {
    int idx = blockIdx.x * 256 + threadIdx.x;
    if (idx < 3 * 128 * 256) {
        int l = idx >> 15, r = idx & 32767;
        int k = r >> 8, j = r & 255;
        float v = W1[(size_t)l * 32768 + k * 256 + j];
        Bp1[(size_t)l * 32768 + (((k >> 5) * 4 + ((k >> 3) & 3)) * 256 + j) * 8 + (k & 7)] =
            bf16_rne(v);
    } else if (idx < 6 * 128 * 256) {
        int t = idx - 98304;
        int l = t >> 15, r = t & 32767;
        int k = r >> 7, j = r & 127;
        float v = W2[(size_t)l * 32768 + k * 128 + j];
        Bp2[(size_t)l * 32768 + (((k >> 5) * 4 + ((k >> 3) & 3)) * 128 + j) * 8 + (k & 7)] =
            bf16_rne(v);
    }
}

// ---------------------------- gather-aggregate: z = (1+eps)*h + sum relu(msg)
#define EDGE2(uu, cc)                                                          \
    {                                                                          \
        ax += fmaxf(bf2f((unsigned short)((uu) & 0xffffu)) +                   \
                    bf2f((unsigned short)((cc) & 0xffffu)), 0.f);              \
        ay += fmaxf(bf2f((unsigned short)((uu) >> 16)) +                       \
                    bf2f((unsigned short)((cc) >> 16)), 0.f);                  \
    }

__global__ void k_gather(const unsigned short* __restrict__ hb,
                         const int* __restrict__ csr_row, const int* __restrict__ csr_attr,
                         const int* __restrict__ rowptr, const unsigned short* __restrict__ ct,
                         const float* __restrict__ eps, int l,
                         unsigned short* __restrict__ zb) {
    int lane = threadIdx.x & 63;
    int n = blockIdx.x * 4 + (threadIdx.x >> 6);
    if (n >= N_NODES) return;
    int i0 = rowptr[n], i1 = rowptr[n + 1];
    float ax = 0.f, ay = 0.f;
    int i = i0;
    for (; i + 4 <= i1; i += 4) {
        int r0 = csr_row[i], r1 = csr_row[i + 1], r2 = csr_row[i + 2], r3 = csr_row[i + 3];
        int q0 = csr_attr[i], q1 = csr_attr[i + 1], q2 = csr_attr[i + 2], q3 = csr_attr[i + 3];
        unsigned int u0 = ((const unsigned int*)(hb + (size_t)r0 * 128))[lane];
        unsigned int u1 = ((const unsigned int*)(hb + (size_t)r1 * 128))[lane];
        unsigned int u2 = ((const unsigned int*)(hb + (size_t)r2 * 128))[lane];
        unsigned int u3 = ((const unsigned int*)(hb + (size_t)r3 * 128))[lane];
        unsigned int c0 = ((const unsigned int*)(ct + q0 * 128))[lane];
        unsigned int c1 = ((const unsigned int*)(ct + q1 * 128))[lane];
        unsigned int c2 = ((const unsigned int*)(ct + q2 * 128))[lane];
        unsigned int c3 = ((const unsigned int*)(ct + q3 * 128))[lane];
        EDGE2(u0, c0); EDGE2(u1, c1); EDGE2(u2, c2); EDGE2(u3, c3);
    }
    for (; i < i1; ++i) {
        int r0 = csr_row[i];
        int q0 = csr_attr[i];
        unsigned int u0 = ((const unsigned int*)(hb + (size_t)r0 * 128))[lane];
        unsigned int c0 = ((const unsigned int*)(ct + q0 * 128))[lane];
        EDGE2(u0, c0);
    }
    float el = 1.0f + eps[l];
    unsigned int un = ((const unsigned int*)(hb + (size_t)n * 128))[lane];
    float zx = fmaf(el, bf2f((unsigned short)(un & 0xffffu)), ax);
    float zy = fmaf(el, bf2f((unsigned short)(un >> 16)), ay);
    ((unsigned int*)(zb + (size_t)n * 128))[lane] = pack2(zx, zy);
}

// --------------------- GEMM1 (MFMA, swapped operands -> (z@W1)^T fragments)
// stats partials go to 16 spread copies (sl[(bid&15)*768 + ...])
__global__ __launch_bounds__(256) void k_gemm1(
    const unsigned short* __restrict__ zb, const unsigned short* __restrict__ Bp,
    const float* __restrict__ bias, unsigned short* __restrict__ tb,
    float* __restrict__ sl) {
    __shared__ unsigned short As[8192] __attribute__((aligned(16)));  // 16 KB
    int n0 = blockIdx.x * 64;
#pragma unroll
    for (int s = 0; s < 4; ++s) {
        int i = threadIdx.x + s * 256;            // 16B unit; 64 rows x 16 units
        int r = i >> 4, k8 = i & 15;
        short8v v = (short8v)(short)0;
        if (n0 + r < N_NODES) v = ((const short8v*)(zb + (size_t)(n0 + r) * 128))[k8];
        int frag = (r >> 4) * 16 + k8;
        int off = (frag * 128 + (r & 15) * 8) ^ ((k8 & 7) << 3);
        *(short8v*)(&As[off]) = v;
    }
    __syncthreads();
    int lane = threadIdx.x & 63;
    int wid = threadIdx.x >> 6;
    int l15 = lane & 15, kg = lane >> 4;
    int colbase = wid * 64;
    f32x4 acc[4][4];  // [rb][cf]
#pragma unroll
    for (int a = 0; a < 4; ++a)
#pragma unroll
        for (int b = 0; b < 4; ++b) acc[a][b] = (f32x4)(0.f);
#pragma unroll
    for (int k4 = 0; k4 < 4; ++k4) {
        short8v af[4], bf[4];
#pragma unroll
        for (int rb = 0; rb < 4; ++rb)
            af[rb] = *(const short8v*)(&As[((rb * 16 + k4 * 4 + kg) * 128 + l15 * 8) ^
                                           (((k4 * 4 + kg) & 7) << 3)]);
#pragma unroll
        for (int cf = 0; cf < 4; ++cf)
            bf[cf] = *(const short8v*)(Bp + ((k4 * 4 + kg) * 256 + colbase + cf * 16 + l15) * 8);
#pragma unroll
        for (int rb = 0; rb < 4; ++rb)
#pragma unroll
            for (int cf = 0; cf < 4; ++cf)
                acc[rb][cf] = __builtin_amdgcn_mfma_f32_16x16x32_bf16(bf[cf], af[rb],
                                                                      acc[rb][cf], 0, 0, 0);
    }
    float s4[4][4], q4[4][4];
#pragma unroll
    for (int cf = 0; cf < 4; ++cf)
#pragma unroll
        for (int r = 0; r < 4; ++r) { s4[cf][r] = 0.f; q4[cf][r] = 0.f; }
#pragma unroll
    for (int cf = 0; cf < 4; ++cf) {
        int j0 = colbase + cf * 16 + kg * 4;
        float4 b4 = *(const float4*)(bias + j0);
#pragma unroll
        for (int rb = 0; rb < 4; ++rb) {
            int gr = n0 + rb * 16 + l15;
            if (gr < N_NODES) {
                float v0 = acc[rb][cf][0] + b4.x;
                float v1 = acc[rb][cf][1] + b4.y;
                float v2 = acc[rb][cf][2] + b4.z;
                float v3 = acc[rb][cf][3] + b4.w;
                uint2 st;
                st.x = pack2(v0, v1);
                st.y = pack2(v2, v3);
                *(uint2*)(tb + (size_t)gr * 256 + j0) = st;
                s4[cf][0] += v0; q4[cf][0] += v0 * v0;
                s4[cf][1] += v1; q4[cf][1] += v1 * v1;
                s4[cf][2] += v2; q4[cf][2] += v2 * v2;
                s4[cf][3] += v3; q4[cf][3] += v3 * v3;
            }
        }
    }
    float* stats = sl + (size_t)(blockIdx.x & 15) * 768;
    float* part = (float*)As;
    __syncthreads();
#pragma unroll
    for (int cf = 0; cf < 4; ++cf)
#pragma unroll
        for (int r = 0; r < 4; ++r)
            part[(colbase + cf * 16 + kg * 4 + r) * 16 + l15] = s4[cf][r];
    __syncthreads();
    {
        int j = threadIdx.x;
        const float4* pr = (const float4*)(part + j * 16);
        float4 a0 = pr[0], a1 = pr[1], a2 = pr[2], a3 = pr[3];
        float s = a0.x + a0.y + a0.z + a0.w + a1.x + a1.y + a1.z + a1.w +
                  a2.x + a2.y + a2.z + a2.w + a3.x + a3.y + a3.z + a3.w;
        atomicAdd(&stats[j], s);
    }
    __syncthreads();
#pragma unroll
    for (int cf = 0; cf < 4; ++cf)
#pragma unroll
        for (int r = 0; r < 4; ++r)
            part[(colbase + cf * 16 + kg * 4 + r) * 16 + l15] = q4[cf][r];
    __syncthreads();
    {
        int j = threadIdx.x;
        const float4* pr = (const float4*)(part + j * 16);
        float4 a0 = pr[0], a1 = pr[1], a2 = pr[2], a3 = pr[3];
        float s = a0.x + a0.y + a0.z + a0.w + a1.x + a1.y + a1.z + a1.w +
                  a2.x + a2.y + a2.z + a2.w + a3.x + a3.y + a3.z + a3.w;
        atomicAdd(&stats[256 + j], s);
    }
}

// ----- BN finalize: sum 16 spread copies -> scale/shift (tiny kernel)
__global__ void k_bnfin(const float* __restrict__ sl, int off, int C,
                        const float* __restrict__ g, const float* __restrict__ b,
                        float* __restrict__ scale, float* __restrict__ shift) {
    int j = threadIdx.x;
    if (j >= C) return;
    float s = 0.f, q = 0.f;
#pragma unroll
    for (int c = 0; c < 16; ++c) {
        s += sl[c * 768 + off + j];
        q += sl[c * 768 + off + C + j];
    }
    float m = s * (1.0f / N_NODES);
    float var = q * (1.0f / N_NODES) - m * m;
    float sc = g[j] / sqrtf(var + 1e-5f);
    scale[j] = sc;
    shift[j] = b[j] - m * sc;
}

// ------- GEMM2 (MFMA, swapped): u = relu(BN1(t))@W2 + b2, fused BN2 stats
// scale1/shift1 precomputed; BN2 partials to 16 spread copies at sl+512/640
__global__ __launch_bounds__(256) void k_gemm2(
    const unsigned short* __restrict__ tb, const unsigned short* __restrict__ Bp,
    const float* __restrict__ scale1, const float* __restrict__ shift1,
    const float* __restrict__ bias, unsigned short* __restrict__ ub,
    float* __restrict__ sl) {
    __shared__ unsigned short As[16384] __attribute__((aligned(16)));  // 32 KB
    int n0 = blockIdx.x * 64;
    int tid = threadIdx.x;
    int kb = (tid & 31) * 8;
    float scr[8], shr[8];
    {
        float4 sa = *(const float4*)(scale1 + kb);
        float4 sb = *(const float4*)(scale1 + kb + 4);
        float4 ha = *(const float4*)(shift1 + kb);
        float4 hbv = *(const float4*)(shift1 + kb + 4);
        scr[0] = sa.x; scr[1] = sa.y; scr[2] = sa.z; scr[3] = sa.w;
        scr[4] = sb.x; scr[5] = sb.y; scr[6] = sb.z; scr[7] = sb.w;
        shr[0] = ha.x; shr[1] = ha.y; shr[2] = ha.z; shr[3] = ha.w;
        shr[4] = hbv.x; shr[5] = hbv.y; shr[6] = hbv.z; shr[7] = hbv.w;
    }
#pragma unroll
    for (int s = 0; s < 8; ++s) {
        int i = tid + s * 256;                    // 16B unit; 64 rows x 32 units
        int r = i >> 5, k8 = i & 31;
        short8v v = (short8v)(short)0;
        if (n0 + r < N_NODES) v = ((const short8v*)(tb + (size_t)(n0 + r) * 256))[k8];
        float f0 = fmaxf(fmaf(scr[0], bf2f((unsigned short)v[0]), shr[0]), 0.f);
        float f1 = fmaxf(fmaf(scr[1], bf2f((unsigned short)v[1]), shr[1]), 0.f);
        float f2 = fmaxf(fmaf(scr[2], bf2f((unsigned short)v[2]), shr[2]), 0.f);
        float f3 = fmaxf(fmaf(scr[3], bf2f((unsigned short)v[3]), shr[3]), 0.f);
        float f4 = fmaxf(fmaf(scr[4], bf2f((unsigned short)v[4]), shr[4]), 0.f);
        float f5 = fmaxf(fmaf(scr[5], bf2f((unsigned short)v[5]), shr[5]), 0.f);
        float f6 = fmaxf(fmaf(scr[6], bf2f((unsigned short)v[6]), shr[6]), 0.f);
        float f7 = fmaxf(fmaf(scr[7], bf2f((unsigned short)v[7]), shr[7]), 0.f);
        uint4 ov;
        ov.x = pack2(f0, f1); ov.y = pack2(f2, f3);
        ov.z = pack2(f4, f5); ov.w = pack2(f6, f7);
        int frag = (r >> 4) * 32 + k8;
        int off = (frag * 128 + (r & 15) * 8) ^ ((k8 & 7) << 3);
        *(uint4*)(&As[off]) = ov;
    }
    __syncthreads();
    int lane = threadIdx.x & 63;
    int wid = threadIdx.x >> 6;
    int l15 = lane & 15, kg = lane >> 4;
    int colbase = wid * 32;
    f32x4 acc[4][2];  // [rb][cf]
#pragma unroll
    for (int a = 0; a < 4; ++a) {
        acc[a][0] = (f32x4)(0.f);
        acc[a][1] = (f32x4)(0.f);
    }
#pragma unroll
    for (int k4 = 0; k4 < 8; ++k4) {
        short8v af[4], bf[2];
#pragma unroll
        for (int rb = 0; rb < 4; ++rb)
            af[rb] = *(const short8v*)(&As[((rb * 32 + k4 * 4 + kg) * 128 + l15 * 8) ^
                                           (((k4 * 4 + kg) & 7) << 3)]);
#pragma unroll
        for (int cf = 0; cf < 2; ++cf)
            bf[cf] = *(const short8v*)(Bp + ((k4 * 4 + kg) * 128 + colbase + cf * 16 + l15) * 8);
#pragma unroll
        for (int rb = 0; rb < 4; ++rb)
#pragma unroll
            for (int cf = 0; cf < 2; ++cf)
                acc[rb][cf] = __builtin_amdgcn_mfma_f32_16x16x32_bf16(bf[cf], af[rb],
                                                                      acc[rb][cf], 0, 0, 0);
    }
    float s4[2][4], q4[2][4];
#pragma unroll
    for (int cf = 0; cf < 2; ++cf)
#pragma unroll
        for (int r = 0; r < 4; ++r) { s4[cf][r] = 0.f; q4[cf][r] = 0.f; }
#pragma unroll
    for (int cf = 0; cf < 2; ++cf) {
        int j0 = colbase + cf * 16 + kg * 4;
        float4 b4 = *(const float4*)(bias + j0);
#pragma unroll
        for (int rb = 0; rb < 4; ++rb) {
            int gr = n0 + rb * 16 + l15;
            if (gr < N_NODES) {
                float v0 = acc[rb][cf][0] + b4.x;
                float v1 = acc[rb][cf][1] + b4.y;
                float v2 = acc[rb][cf][2] + b4.z;
                float v3 = acc[rb][cf][3] + b4.w;
                uint2 st;
                st.x = pack2(v0, v1);
                st.y = pack2(v2, v3);
                *(uint2*)(ub + (size_t)gr * 128 + j0) = st;
                s4[cf][0] += v0; q4[cf][0] += v0 * v0;
                s4[cf][1] += v1; q4[cf][1] += v1 * v1;
                s4[cf][2] += v2; q4[cf][2] += v2 * v2;
                s4[cf][3] += v3; q4[cf][3] += v3 * v3;
            }
        }
    }
    float* stats = sl + (size_t)(blockIdx.x & 15) * 768;
    float* part = (float*)As;  // need 128*16 floats = 8 KB
    __syncthreads();
#pragma unroll
    for (int cf = 0; cf < 2; ++cf)
#pragma unroll
        for (int r = 0; r < 4; ++r)
            part[(colbase + cf * 16 + kg * 4 + r) * 16 + l15] = s4[cf][r];
    __syncthreads();
    if (tid < 128) {
        const float4* pr = (const float4*)(part + tid * 16);
        float4 a0 = pr[0], a1 = pr[1], a2 = pr[2], a3 = pr[3];
        float s = a0.x + a0.y + a0.z + a0.w + a1.x + a1.y + a1.z + a1.w +
                  a2.x + a2.y + a2.z + a2.w + a3.x + a3.y + a3.z + a3.w;
        atomicAdd(&stats[512 + tid], s);
    }
    __syncthreads();
#pragma unroll
    for (int cf = 0; cf < 2; ++cf)
#pragma unroll
        for (int r = 0; r < 4; ++r)
            part[(colbase + cf * 16 + kg * 4 + r) * 16 + l15] = q4[cf][r];
    __syncthreads();
    if (tid < 128) {
        const float4* pr = (const float4*)(part + tid * 16);
        float4 a0 = pr[0], a1 = pr[1], a2 = pr[2], a3 = pr[3];
        float s = a0.x + a0.y + a0.z + a0.w + a1.x + a1.y + a1.z + a1.w +
                  a2.x + a2.y + a2.z + a2.w + a3.x + a3.y + a3.z + a3.w;
        atomicAdd(&stats[640 + tid], s);
    }
}

// --------- h += maybe_relu(BN2(u)); refresh bf16 mirror (scale/shift precomputed)
__global__ void k_update_h(float* __restrict__ h, unsigned short* __restrict__ hb,
                           const unsigned short* __restrict__ ub,
                           const float* __restrict__ scale2, const float* __restrict__ shift2,
                           int relu) {
    int kb = (threadIdx.x & 15) * 8;
    float scr[8], shr[8];
    {
        float4 sa = *(const float4*)(scale2 + kb);
        float4 sb = *(const float4*)(scale2 + kb + 4);
        float4 ha = *(const float4*)(shift2 + kb);
        float4 hbv = *(const float4*)(shift2 + kb + 4);
        scr[0] = sa.x; scr[1] = sa.y; scr[2] = sa.z; scr[3] = sa.w;
        scr[4] = sb.x; scr[5] = sb.y; scr[6] = sb.z; scr[7] = sb.w;
        shr[0] = ha.x; shr[1] = ha.y; shr[2] = ha.z; shr[3] = ha.w;
        shr[4] = hbv.x; shr[5] = hbv.y; shr[6] = hbv.z; shr[7] = hbv.w;
    }
    int i = blockIdx.x * 256 + threadIdx.x;  // 8-elem unit; total N*16 = 1.6M
    uint4 uv = ((const uint4*)ub)[i];
    float4 h0 = ((const float4*)h)[i * 2];
    float4 h1 = ((const float4*)h)[i * 2 + 1];
    float v0 = fmaf(scr[0], bf2f((unsigned short)(uv.x & 0xffffu)), shr[0]);
    float v1 = fmaf(scr[1], bf2f((unsigned short)(uv.x >> 16)), shr[1]);
    float v2 = fmaf(scr[2], bf2f((unsigned short)(uv.y & 0xffffu)), shr[2]);
    float v3 = fmaf(scr[3], bf2f((unsigned short)(uv.y >> 16)), shr[3]);
    float v4 = fmaf(scr[4], bf2f((unsigned short)(uv.z & 0xffffu)), shr[4]);
    float v5 = fmaf(scr[5], bf2f((unsigned short)(uv.z >> 16)), shr[5]);
    float v6 = fmaf(scr[6], bf2f((unsigned short)(uv.w & 0xffffu)), shr[6]);
    float v7 = fmaf(scr[7], bf2f((unsigned short)(uv.w >> 16)), shr[7]);
    if (relu) {
        v0 = fmaxf(v0, 0.f); v1 = fmaxf(v1, 0.f); v2 = fmaxf(v2, 0.f); v3 = fmaxf(v3, 0.f);
        v4 = fmaxf(v4, 0.f); v5 = fmaxf(v5, 0.f); v6 = fmaxf(v6, 0.f); v7 = fmaxf(v7, 0.f);
    }
    h0.x += v0; h0.y += v1; h0.z += v2; h0.w += v3;
    h1.x += v4; h1.y += v5; h1.z += v6; h1.w += v7;
    ((float4*)h)[i * 2] = h0;
    ((float4*)h)[i * 2 + 1] = h1;
    uint4 hp;
    hp.x = pack2(h0.x, h0.y); hp.y = pack2(h0.z, h0.w);
    hp.z = pack2(h1.x, h1.y); hp.w = pack2(h1.z, h1.w);
    ((uint4*)hb)[i] = hp;
}

// ------------- node head: node_key + per-node dots p,q; seg sums into spread
// scratch copies (nsc[blockIdx&7][2][4096])
__global__ void k_node_out(const float* __restrict__ h, const int* __restrict__ batch,
                           const float* __restrict__ nW, const float* __restrict__ nb,
                           const float* __restrict__ eW,
                           float* __restrict__ out, float* __restrict__ p,
                           float* __restrict__ q, float* __restrict__ nsc) {
    int n = blockIdx.x * 4 + (threadIdx.x >> 6);
    int lane = threadIdx.x & 63;
    if (n >= N_NODES) return;
    float2 hv = ((const float2*)(h + (size_t)n * 128))[lane];
    float2 wn = ((const float2*)nW)[lane];
    float2 wa = ((const float2*)eW)[lane];
    float2 wb = ((const float2*)eW)[64 + lane];
    float dn = hv.x * wn.x + hv.y * wn.y;
    float da = hv.x * wa.x + hv.y * wa.y;
    float db = hv.x * wb.x + hv.y * wb.y;
#pragma unroll
    for (int off = 32; off; off >>= 1) {
        dn += __shfl_xor(dn, off);
        da += __shfl_xor(da, off);
        db += __shfl_xor(db, off);
    }
    if (lane == 0) {
        float nk = 1.f / (1.f + expf(-(dn + nb[0])));
        out[n] = nk;
        int g = batch[n];
        float* base = nsc + (size_t)(blockIdx.x & 7) * 8192;
        atomicAdd(&base[g], nk);
        atomicAdd(&base[4096 + g], 1.0f - nk);
        p[n] = da;
        q[n] = db;
    }
}

// ------------- edge head: LDS-binned seg sums, zero global atomics.
// 512 grid-stride blocks; per-block bins flushed to esc[bid][8192]
__global__ __launch_bounds__(256) void k_edge_out(
    const int* __restrict__ ei, const int* __restrict__ batch,
    const float* __restrict__ p, const float* __restrict__ q,
    const float* __restrict__ eb, float* __restrict__ out,
    float* __restrict__ esc) {
    __shared__ float bins[8192];  // [2][4096] = 32 KB
    for (int i = threadIdx.x; i < 8192; i += 256) bins[i] = 0.f;
    __syncthreads();
    float ebv = eb[0];
    for (int e = blockIdx.x * 256 + threadIdx.x; e < N_EDGES; e += EOUT_BLK * 256) {
        int r = ei[e], c = ei[N_EDGES + e];
        float ek = 1.f / (1.f + expf(-(p[r] + q[c] + ebv)));
        out[N_NODES + e] = ek;
        int g = batch[r];
        atomicAdd(&bins[g], ek);
        atomicAdd(&bins[4096 + g], 1.0f - ek);
    }
    __syncthreads();
    float* dst = esc + (size_t)blockIdx.x * 8192;
    for (int i = threadIdx.x; i < 8192; i += 256) dst[i] = bins[i];
}

// ------------- reduce the scratch copies into the 4 output segments
__global__ void k_seg_reduce(const float* __restrict__ nsc, const float* __restrict__ esc,
                             float* __restrict__ out) {
    int i = blockIdx.x * 256 + threadIdx.x;   // 0..16383
    if (i >= 16384) return;
    float s = 1e-8f;
    if (i < 8192) {
#pragma unroll
        for (int c = 0; c < 8; ++c) s += nsc[c * 8192 + i];
    } else {
        int j = i - 8192;
        for (int c = 0; c < EOUT_BLK; ++c) s += esc[(size_t)c * 8192 + j];
    }
    out[N_NODES + N_EDGES + i] = s;
}

extern "C" void kernel_launch(void* const* d_in, const int* in_sizes, int n_in,
                              void* d_out, int out_size, void* d_ws, size_t ws_size,
                              hipStream_t stream) {
    const int*   x     = (const int*)d_in[0];
    const int*   ei    = (const int*)d_in[1];
    const int*   ea    = (const int*)d_in[2];
    const int*   batch = (const int*)d_in[3];
    const float* at    = (const float*)d_in[4];
    const float* bt    = (const float*)d_in[5];
    const float* eps   = (const float*)d_in[6];
    const float* W1    = (const float*)d_in[7];
    const float* b1    = (const float*)d_in[8];
    const float* bn1g  = (const float*)d_in[9];
    const float* bn1b  = (const float*)d_in[10];
    const float* W2    = (const float*)d_in[11];
    const float* b2    = (const float*)d_in[12];
    const float* obng  = (const float*)d_in[13];
    const float* obnb  = (const float*)d_in[14];
    const float* nW    = (const float*)d_in[15];
    const float* nb    = (const float*)d_in[16];
    const float* eW    = (const float*)d_in[17];
    const float* eb    = (const float*)d_in[18];
    float* out = (float*)d_out;

    float* ws    = (float*)d_ws;
    float* h     = ws;                       // N*128 fp32
    float* stats = h + 12800000;             // 3 layers x 16 copies x 768
    float* sf    = stats + 3 * 16 * 768;     // scale1/shift1/scale2/shift2 (768)
    float* p     = sf + 768;                 // N
    float* q     = p + N_NODES;              // N
    float* nsc   = q + N_NODES;              // 8*8192 node seg scratch
    float* esc   = nsc + 8 * 8192;           // EOUT_BLK*8192 edge seg scratch (16 MB)
    unsigned short* hb  = (unsigned short*)(esc + (size_t)EOUT_BLK * 8192);  // N*128 bf16
    unsigned short* zub = hb + 12800000;     // N*128 bf16: z (gemm1 in), then u
    unsigned short* tb  = zub + 12800000;    // N*256 bf16
    unsigned short* Bp1 = tb + 25600000;     // 3*128*256 bf16
    unsigned short* Bp2 = Bp1 + 3 * 32768;   // 3*256*128 bf16
    unsigned short* ct  = Bp2 + 3 * 32768;   // 3*512*128 bf16 combined bond
    int* rowptr  = (int*)(ct + 3 * 65536);   // N+1
    int* cursor  = rowptr + N_NODES + 1;     // N (counts, then cursors)
    int* csr_row = cursor + N_NODES;         // E
    int* csr_attr = csr_row + N_EDGES;       // E
    int* bsum    = csr_attr + N_EDGES;       // SCAN_NBLK
    // per-layer stats: sl = stats + l*16*768; copy c at sl + c*768:
    //   [sum256][sq256][osum128@512][osq128@640]

    hipMemsetAsync(stats, 0, 3 * 16 * 768 * sizeof(float), stream);
    hipMemsetAsync(nsc, 0, 8 * 8192 * sizeof(float), stream);
    hipMemsetAsync(cursor, 0, N_NODES * sizeof(int), stream);
    k_atom_encode<<<50000, 256, 0, stream>>>(x, at, h, hb);
    k_convw<<<768, 256, 0, stream>>>(W1, W2, Bp1, Bp2);
    k_bondc<<<768, 256, 0, stream>>>(bt, ct);

    // CSR of edges grouped by destination (col) — parallel 3-phase scan
    k_hist<<<2344, 256, 0, stream>>>(ei, cursor);
    k_scan_partial<<<SCAN_NBLK, 256, 0, stream>>>(cursor, bsum);
    k_scan_bsum<<<1, 256, 0, stream>>>(bsum, rowptr);
    k_scan_final<<<SCAN_NBLK, 512, 0, stream>>>(bsum, cursor, rowptr);
    k_fill<<<2344, 256, 0, stream>>>(ei, ea, cursor, csr_row, csr_attr);

    for (int l = 0; l < 3; ++l) {
        float* sl = stats + (size_t)l * 16 * 768;
        k_gather<<<25000, 256, 0, stream>>>(hb, csr_row, csr_attr, rowptr,
                                            ct + (size_t)l * 65536, eps, l, zub);
        k_gemm1<<<1563, 256, 0, stream>>>(zub, Bp1 + (size_t)l * 32768, b1 + l * 256, tb, sl);
        k_bnfin<<<1, 256, 0, stream>>>(sl, 0, 256, bn1g + l * 256, bn1b + l * 256,
                                       sf, sf + 256);
        k_gemm2<<<1563, 256, 0, stream>>>(tb, Bp2 + (size_t)l * 32768, sf, sf + 256,
                                          b2 + l * 128, zub, sl);
        k_bnfin<<<1, 128, 0, stream>>>(sl, 512, 128, obng + l * 128, obnb + l * 128,
                                       sf + 512, sf + 640);
        k_update_h<<<6250, 256, 0, stream>>>(h, hb, zub, sf + 512, sf + 640,
                                             (l < 2) ? 1 : 0);
    }

    k_node_out<<<25000, 256, 0, stream>>>(h, batch, nW, nb, eW, out, p, q, nsc);
    k_edge_out<<<EOUT_BLK, 256, 0, stream>>>(ei, batch, p, q, eb, out, esc);
    k_seg_reduce<<<64, 256, 0, stream>>>(nsc, esc, out);
}

// Round 10
// 582.902 us; speedup vs baseline: 5.9538x; 1.0678x over previous
//
#include <hip/hip_runtime.h>
#include <math.h>

#define N_NODES 100000
#define N_EDGES 600000
#define N_GRAPHS 4096
#define SCAN_CHUNK 512
#define SCAN_NBLK 196   // ceil(100000/512)
#define EOUT_BLK 512    // edge_out grid (LDS-binned, scratch copies)

typedef __attribute__((ext_vector_type(8))) short short8v;   // 8 bf16 (4 VGPR)
typedef __attribute__((ext_vector_type(4))) float f32x4;

// fp32 pair -> packed bf16 (RNE) via the HW instruction
__device__ __forceinline__ unsigned int pack2(float a, float b) {
    unsigned int r;
    asm("v_cvt_pk_bf16_f32 %0, %1, %2" : "=v"(r) : "v"(a), "v"(b));
    return r;
}
__device__ __forceinline__ unsigned short bf16_rne(float f) {
    unsigned int r;
    asm("v_cvt_pk_bf16_f32 %0, %1, %2" : "=v"(r) : "v"(f), "v"(f));
    return (unsigned short)r;
}
__device__ __forceinline__ float bf2f(unsigned short u) {
    return __uint_as_float(((unsigned int)u) << 16);
}

// ------------------------------------------- atom encoder (writes fp32 + bf16)
__global__ void k_atom_encode(const int* __restrict__ x, const float* __restrict__ at,
                              float* __restrict__ h, unsigned short* __restrict__ hb) {
    int n = blockIdx.x * 2 + (threadIdx.x >> 7);
    int d = threadIdx.x & 127;
    if (n >= N_NODES) return;
    const int* xr = x + n * 9;
    float s = 0.f;
#pragma unroll
    for (int f = 0; f < 9; ++f) {
        int v = xr[f];
        s += at[(f * 100 + v) * 128 + d];
    }
    h[(size_t)n * 128 + d] = s;
    hb[(size_t)n * 128 + d] = bf16_rne(s);
}

// --------- combined bond table: ct[l][idx][d] = bf16(sum of 3 table rows)
__global__ void k_bondc(const float* __restrict__ bt, unsigned short* __restrict__ ct) {
    int idx = blockIdx.x * 256 + threadIdx.x;
    if (idx >= 3 * 512 * 128) return;
    int d = idx & 127;
    int c = (idx >> 7) & 511;
    int l = idx >> 16;
    const float* base = bt + (size_t)l * 3072;
    float v = base[(c >> 6) * 128 + d] + base[1024 + ((c >> 3) & 7) * 128 + d] +
              base[2048 + (c & 7) * 128 + d];
    ct[idx] = bf16_rne(v);
}

// --------------------------- CSR build (once)
__global__ void k_hist(const int* __restrict__ ei, int* __restrict__ cnt) {
    int e = blockIdx.x * 256 + threadIdx.x;
    if (e < N_EDGES) atomicAdd(&cnt[ei[N_EDGES + e]], 1);
}

__global__ void k_scan_partial(const int* __restrict__ cnt, int* __restrict__ bsum) {
    __shared__ int ls[256];
    int base = blockIdx.x * SCAN_CHUNK;
    int t = threadIdx.x;
    int s = 0;
    for (int i = base + t; i < base + SCAN_CHUNK && i < N_NODES; i += 256) s += cnt[i];
    ls[t] = s;
    __syncthreads();
    for (int off = 128; off; off >>= 1) {
        if (t < off) ls[t] += ls[t + off];
        __syncthreads();
    }
    if (t == 0) bsum[blockIdx.x] = ls[0];
}

__global__ void k_scan_bsum(int* __restrict__ bsum, int* __restrict__ rowptr) {
    __shared__ int ls[256];
    int t = threadIdx.x;
    int v = (t < SCAN_NBLK) ? bsum[t] : 0;
    ls[t] = v;
    __syncthreads();
    for (int off = 1; off < 256; off <<= 1) {
        int x = (t >= off) ? ls[t - off] : 0;
        __syncthreads();
        ls[t] += x;
        __syncthreads();
    }
    if (t < SCAN_NBLK) bsum[t] = ls[t] - v;  // exclusive prefix
    if (t == 255) rowptr[N_NODES] = ls[255];
}

__global__ __launch_bounds__(512) void k_scan_final(const int* __restrict__ bsum,
                                                    int* __restrict__ cnt_cursor,
                                                    int* __restrict__ rowptr) {
    __shared__ int ls[512];
    int base = blockIdx.x * SCAN_CHUNK;
    int t = threadIdx.x;
    int i = base + t;
    int v = (i < N_NODES) ? cnt_cursor[i] : 0;
    ls[t] = v;
    __syncthreads();
    for (int off = 1; off < 512; off <<= 1) {
        int x = (t >= off) ? ls[t - off] : 0;
        __syncthreads();
        ls[t] += x;
        __syncthreads();
    }
    if (i < N_NODES) {
        int excl = bsum[blockIdx.x] + ls[t] - v;
        rowptr[i] = excl;
        cnt_cursor[i] = excl;
    }
}

// fill CSR-ordered source-row + combined-attr-index arrays
__global__ void k_fill(const int* __restrict__ ei, const int* __restrict__ ea,
                       int* __restrict__ cursor,
                       int* __restrict__ csr_row, int* __restrict__ csr_attr) {
    int e = blockIdx.x * 256 + threadIdx.x;
    if (e < N_EDGES) {
        int c = ei[N_EDGES + e];
        int pos = atomicAdd(&cursor[c], 1);
        csr_row[pos] = ei[e];
        csr_attr[pos] = ea[e * 3] * 64 + ea[e * 3 + 1] * 8 + ea[e * 3 + 2];
    }
}

// ---------------- weight pre-swizzle: fp32 -> bf16 in MFMA B-fragment layout
__global__ void k_convw(const float* __restrict__ W1, const float* __restrict__ W2,
                        unsigned short* __restrict__ Bp1, unsigned short* __restrict__ Bp2) {
    int idx = blockIdx.x * 256 + threadIdx.x;
    if (idx < 3 * 128 * 256) {
        int l = idx >> 15, r = idx & 32767;
        int k = r >> 8, j = r & 255;
        float v = W1[(size_t)l * 32768 + k * 256 + j];
        Bp1[(size_t)l * 32768 + (((k >> 5) * 4 + ((k >> 3) & 3)) * 256 + j) * 8 + (k & 7)] =
            bf16_rne(v);
    } else if (idx < 6 * 128 * 256) {
        int t = idx - 98304;
        int l = t >> 15, r = t & 32767;
        int k = r >> 7, j = r & 127;
        float v = W2[(size_t)l * 32768 + k * 128 + j];
        Bp2[(size_t)l * 32768 + (((k >> 5) * 4 + ((k >> 3) & 3)) * 128 + j) * 8 + (k & 7)] =
            bf16_rne(v);
    }
}

// ---------------------------- gather-aggregate: z = (1+eps)*h + sum relu(msg)
#define EDGE2(uu, cc)                                                          \
    {                                                                          \
        ax += fmaxf(bf2f((unsigned short)((uu) & 0xffffu)) +                   \
                    bf2f((unsigned short)((cc) & 0xffffu)), 0.f);              \
        ay += fmaxf(bf2f((unsigned short)((uu) >> 16)) +                       \
                    bf2f((unsigned short)((cc) >> 16)), 0.f);                  \
    }

__global__ void k_gather(const unsigned short* __restrict__ hb,
                         const int* __restrict__ csr_row, const int* __restrict__ csr_attr,
                         const int* __restrict__ rowptr, const unsigned short* __restrict__ ct,
                         const float* __restrict__ eps, int l,
                         unsigned short* __restrict__ zb) {
    int lane = threadIdx.x & 63;
    int n = blockIdx.x * 4 + (threadIdx.x >> 6);
    if (n >= N_NODES) return;
    int i0 = rowptr[n], i1 = rowptr[n + 1];
    float ax = 0.f, ay = 0.f;
    int i = i0;
    for (; i + 4 <= i1; i += 4) {
        int r0 = csr_row[i], r1 = csr_row[i + 1], r2 = csr_row[i + 2], r3 = csr_row[i + 3];
        int q0 = csr_attr[i], q1 = csr_attr[i + 1], q2 = csr_attr[i + 2], q3 = csr_attr[i + 3];
        unsigned int u0 = ((const unsigned int*)(hb + (size_t)r0 * 128))[lane];
        unsigned int u1 = ((const unsigned int*)(hb + (size_t)r1 * 128))[lane];
        unsigned int u2 = ((const unsigned int*)(hb + (size_t)r2 * 128))[lane];
        unsigned int u3 = ((const unsigned int*)(hb + (size_t)r3 * 128))[lane];
        unsigned int c0 = ((const unsigned int*)(ct + q0 * 128))[lane];
        unsigned int c1 = ((const unsigned int*)(ct + q1 * 128))[lane];
        unsigned int c2 = ((const unsigned int*)(ct + q2 * 128))[lane];
        unsigned int c3 = ((const unsigned int*)(ct + q3 * 128))[lane];
        EDGE2(u0, c0); EDGE2(u1, c1); EDGE2(u2, c2); EDGE2(u3, c3);
    }
    for (; i < i1; ++i) {
        int r0 = csr_row[i];
        int q0 = csr_attr[i];
        unsigned int u0 = ((const unsigned int*)(hb + (size_t)r0 * 128))[lane];
        unsigned int c0 = ((const unsigned int*)(ct + q0 * 128))[lane];
        EDGE2(u0, c0);
    }
    float el = 1.0f + eps[l];
    unsigned int un = ((const unsigned int*)(hb + (size_t)n * 128))[lane];
    float zx = fmaf(el, bf2f((unsigned short)(un & 0xffffu)), ax);
    float zy = fmaf(el, bf2f((unsigned short)(un >> 16)), ay);
    ((unsigned int*)(zb + (size_t)n * 128))[lane] = pack2(zx, zy);
}

// --------------------- GEMM1 (MFMA, swapped operands -> (z@W1)^T fragments)
// stats partials go to 16 spread copies (sl[(bid&15)*768 + ...])
__global__ __launch_bounds__(256) void k_gemm1(
    const unsigned short* __restrict__ zb, const unsigned short* __restrict__ Bp,
    const float* __restrict__ bias, unsigned short* __restrict__ tb,
    float* __restrict__ sl) {
    __shared__ unsigned short As[8192] __attribute__((aligned(16)));  // 16 KB
    int n0 = blockIdx.x * 64;
#pragma unroll
    for (int s = 0; s < 4; ++s) {
        int i = threadIdx.x + s * 256;            // 16B unit; 64 rows x 16 units
        int r = i >> 4, k8 = i & 15;
        short8v v = (short8v)(short)0;
        if (n0 + r < N_NODES) v = ((const short8v*)(zb + (size_t)(n0 + r) * 128))[k8];
        int frag = (r >> 4) * 16 + k8;
        int off = (frag * 128 + (r & 15) * 8) ^ ((k8 & 7) << 3);
        *(short8v*)(&As[off]) = v;
    }
    __syncthreads();
    int lane = threadIdx.x & 63;
    int wid = threadIdx.x >> 6;
    int l15 = lane & 15, kg = lane >> 4;
    int colbase = wid * 64;
    f32x4 acc[4][4];  // [rb][cf]
#pragma unroll
    for (int a = 0; a < 4; ++a)
#pragma unroll
        for (int b = 0; b < 4; ++b) acc[a][b] = (f32x4)(0.f);
#pragma unroll
    for (int k4 = 0; k4 < 4; ++k4) {
        short8v af[4], bf[4];
#pragma unroll
        for (int rb = 0; rb < 4; ++rb)
            af[rb] = *(const short8v*)(&As[((rb * 16 + k4 * 4 + kg) * 128 + l15 * 8) ^
                                           (((k4 * 4 + kg) & 7) << 3)]);
#pragma unroll
        for (int cf = 0; cf < 4; ++cf)
            bf[cf] = *(const short8v*)(Bp + ((k4 * 4 + kg) * 256 + colbase + cf * 16 + l15) * 8);
#pragma unroll
        for (int rb = 0; rb < 4; ++rb)
#pragma unroll
            for (int cf = 0; cf < 4; ++cf)
                acc[rb][cf] = __builtin_amdgcn_mfma_f32_16x16x32_bf16(bf[cf], af[rb],
                                                                      acc[rb][cf], 0, 0, 0);
    }
    float s4[4][4], q4[4][4];
#pragma unroll
    for (int cf = 0; cf < 4; ++cf)
#pragma unroll
        for (int r = 0; r < 4; ++r) { s4[cf][r] = 0.f; q4[cf][r] = 0.f; }
#pragma unroll
    for (int cf = 0; cf < 4; ++cf) {
        int j0 = colbase + cf * 16 + kg * 4;
        float4 b4 = *(const float4*)(bias + j0);
#pragma unroll
        for (int rb = 0; rb < 4; ++rb) {
            int gr = n0 + rb * 16 + l15;
            if (gr < N_NODES) {
                float v0 = acc[rb][cf][0] + b4.x;
                float v1 = acc[rb][cf][1] + b4.y;
                float v2 = acc[rb][cf][2] + b4.z;
                float v3 = acc[rb][cf][3] + b4.w;
                uint2 st;
                st.x = pack2(v0, v1);
                st.y = pack2(v2, v3);
                *(uint2*)(tb + (size_t)gr * 256 + j0) = st;
                s4[cf][0] += v0; q4[cf][0] += v0 * v0;
                s4[cf][1] += v1; q4[cf][1] += v1 * v1;
                s4[cf][2] += v2; q4[cf][2] += v2 * v2;
                s4[cf][3] += v3; q4[cf][3] += v3 * v3;
            }
        }
    }
    float* stats = sl + (size_t)(blockIdx.x & 15) * 768;
    float* part = (float*)As;
    __syncthreads();
#pragma unroll
    for (int cf = 0; cf < 4; ++cf)
#pragma unroll
        for (int r = 0; r < 4; ++r)
            part[(colbase + cf * 16 + kg * 4 + r) * 16 + l15] = s4[cf][r];
    __syncthreads();
    {
        int j = threadIdx.x;
        const float4* pr = (const float4*)(part + j * 16);
        float4 a0 = pr[0], a1 = pr[1], a2 = pr[2], a3 = pr[3];
        float s = a0.x + a0.y + a0.z + a0.w + a1.x + a1.y + a1.z + a1.w +
                  a2.x + a2.y + a2.z + a2.w + a3.x + a3.y + a3.z + a3.w;
        atomicAdd(&stats[j], s);
    }
    __syncthreads();
#pragma unroll
    for (int cf = 0; cf < 4; ++cf)
#pragma unroll
        for (int r = 0; r < 4; ++r)
            part[(colbase + cf * 16 + kg * 4 + r) * 16 + l15] = q4[cf][r];
    __syncthreads();
    {
        int j = threadIdx.x;
        const float4* pr = (const float4*)(part + j * 16);
        float4 a0 = pr[0], a1 = pr[1], a2 = pr[2], a3 = pr[3];
        float s = a0.x + a0.y + a0.z + a0.w + a1.x + a1.y + a1.z + a1.w +
                  a2.x + a2.y + a2.z + a2.w + a3.x + a3.y + a3.z + a3.w;
        atomicAdd(&stats[256 + j], s);
    }
}

// ----- BN finalize: sum 16 spread copies -> scale/shift (tiny kernel)
__global__ void k_bnfin(const float* __restrict__ sl, int off, int C,
                        const float* __restrict__ g, const float* __restrict__ b,
                        float* __restrict__ scale, float* __restrict__ shift) {
    int j = threadIdx.x;
    if (j >= C) return;
    float s = 0.f, q = 0.f;
#pragma unroll
    for (int c = 0; c < 16; ++c) {
        s += sl[c * 768 + off + j];
        q += sl[c * 768 + off + C + j];
    }
    float m = s * (1.0f / N_NODES);
    float var = q * (1.0f / N_NODES) - m * m;
    float sc = g[j] / sqrtf(var + 1e-5f);
    scale[j] = sc;
    shift[j] = b[j] - m * sc;
}

// ------- GEMM2 (MFMA, swapped): u = relu(BN1(t))@W2 + b2, fused BN2 stats
// scale1/shift1 precomputed; BN2 partials to 16 spread copies at sl+512/640
__global__ __launch_bounds__(256) void k_gemm2(
    const unsigned short* __restrict__ tb, const unsigned short* __restrict__ Bp,
    const float* __restrict__ scale1, const float* __restrict__ shift1,
    const float* __restrict__ bias, unsigned short* __restrict__ ub,
    float* __restrict__ sl) {
    __shared__ unsigned short As[16384] __attribute__((aligned(16)));  // 32 KB
    int n0 = blockIdx.x * 64;
    int tid = threadIdx.x;
    int kb = (tid & 31) * 8;
    float scr[8], shr[8];
    {
        float4 sa = *(const float4*)(scale1 + kb);
        float4 sb = *(const float4*)(scale1 + kb + 4);
        float4 ha = *(const float4*)(shift1 + kb);
        float4 hbv = *(const float4*)(shift1 + kb + 4);
        scr[0] = sa.x; scr[1] = sa.y; scr[2] = sa.z; scr[3] = sa.w;
        scr[4] = sb.x; scr[5] = sb.y; scr[6] = sb.z; scr[7] = sb.w;
        shr[0] = ha.x; shr[1] = ha.y; shr[2] = ha.z; shr[3] = ha.w;
        shr[4] = hbv.x; shr[5] = hbv.y; shr[6] = hbv.z; shr[7] = hbv.w;
    }
#pragma unroll
    for (int s = 0; s < 8; ++s) {
        int i = tid + s * 256;                    // 16B unit; 64 rows x 32 units
        int r = i >> 5, k8 = i & 31;
        short8v v = (short8v)(short)0;
        if (n0 + r < N_NODES) v = ((const short8v*)(tb + (size_t)(n0 + r) * 256))[k8];
        float f0 = fmaxf(fmaf(scr[0], bf2f((unsigned short)v[0]), shr[0]), 0.f);
        float f1 = fmaxf(fmaf(scr[1], bf2f((unsigned short)v[1]), shr[1]), 0.f);
        float f2 = fmaxf(fmaf(scr[2], bf2f((unsigned short)v[2]), shr[2]), 0.f);
        float f3 = fmaxf(fmaf(scr[3], bf2f((unsigned short)v[3]), shr[3]), 0.f);
        float f4 = fmaxf(fmaf(scr[4], bf2f((unsigned short)v[4]), shr[4]), 0.f);
        float f5 = fmaxf(fmaf(scr[5], bf2f((unsigned short)v[5]), shr[5]), 0.f);
        float f6 = fmaxf(fmaf(scr[6], bf2f((unsigned short)v[6]), shr[6]), 0.f);
        float f7 = fmaxf(fmaf(scr[7], bf2f((unsigned short)v[7]), shr[7]), 0.f);
        uint4 ov;
        ov.x = pack2(f0, f1); ov.y = pack2(f2, f3);
        ov.z = pack2(f4, f5); ov.w = pack2(f6, f7);
        int frag = (r >> 4) * 32 + k8;
        int off = (frag * 128 + (r & 15) * 8) ^ ((k8 & 7) << 3);
        *(uint4*)(&As[off]) = ov;
    }
    __syncthreads();
    int lane = threadIdx.x & 63;
    int wid = threadIdx.x >> 6;
    int l15 = lane & 15, kg = lane >> 4;
    int colbase = wid * 32;
    f32x4 acc[4][2];  // [rb][cf]
#pragma unroll
    for (int a = 0; a < 4; ++a) {
        acc[a][0] = (f32x4)(0.f);
        acc[a][1] = (f32x4)(0.f);
    }
#pragma unroll
    for (int k4 = 0; k4 < 8; ++k4) {
        short8v af[4], bf[2];
#pragma unroll
        for (int rb = 0; rb < 4; ++rb)
            af[rb] = *(const short8v*)(&As[((rb * 32 + k4 * 4 + kg) * 128 + l15 * 8) ^
                                           (((k4 * 4 + kg) & 7) << 3)]);
#pragma unroll
        for (int cf = 0; cf < 2; ++cf)
            bf[cf] = *(const short8v*)(Bp + ((k4 * 4 + kg) * 128 + colbase + cf * 16 + l15) * 8);
#pragma unroll
        for (int rb = 0; rb < 4; ++rb)
#pragma unroll
            for (int cf = 0; cf < 2; ++cf)
                acc[rb][cf] = __builtin_amdgcn_mfma_f32_16x16x32_bf16(bf[cf], af[rb],
                                                                      acc[rb][cf], 0, 0, 0);
    }
    float s4[2][4], q4[2][4];
#pragma unroll
    for (int cf = 0; cf < 2; ++cf)
#pragma unroll
        for (int r = 0; r < 4; ++r) { s4[cf][r] = 0.f; q4[cf][r] = 0.f; }
#pragma unroll
    for (int cf = 0; cf < 2; ++cf) {
        int j0 = colbase + cf * 16 + kg * 4;
        float4 b4 = *(const float4*)(bias + j0);
#pragma unroll
        for (int rb = 0; rb < 4; ++rb) {
            int gr = n0 + rb * 16 + l15;
            if (gr < N_NODES) {
                float v0 = acc[rb][cf][0] + b4.x;
                float v1 = acc[rb][cf][1] + b4.y;
                float v2 = acc[rb][cf][2] + b4.z;
                float v3 = acc[rb][cf][3] + b4.w;
                uint2 st;
                st.x = pack2(v0, v1);
                st.y = pack2(v2, v3);
                *(uint2*)(ub + (size_t)gr * 128 + j0) = st;
                s4[cf][0] += v0; q4[cf][0] += v0 * v0;
                s4[cf][1] += v1; q4[cf][1] += v1 * v1;
                s4[cf][2] += v2; q4[cf][2] += v2 * v2;
                s4[cf][3] += v3; q4[cf][3] += v3 * v3;
            }
        }
    }
    float* stats = sl + (size_t)(blockIdx.x & 15) * 768;
    float* part = (float*)As;  // need 128*16 floats = 8 KB
    __syncthreads();
#pragma unroll
    for (int cf = 0; cf < 2; ++cf)
#pragma unroll
        for (int r = 0; r < 4; ++r)
            part[(colbase + cf * 16 + kg * 4 + r) * 16 + l15] = s4[cf][r];
    __syncthreads();
    if (tid < 128) {
        const float4* pr = (const float4*)(part + tid * 16);
        float4 a0 = pr[0], a1 = pr[1], a2 = pr[2], a3 = pr[3];
        float s = a0.x + a0.y + a0.z + a0.w + a1.x + a1.y + a1.z + a1.w +
                  a2.x + a2.y + a2.z + a2.w + a3.x + a3.y + a3.z + a3.w;
        atomicAdd(&stats[512 + tid], s);
    }
    __syncthreads();
#pragma unroll
    for (int cf = 0; cf < 2; ++cf)
#pragma unroll
        for (int r = 0; r < 4; ++r)
            part[(colbase + cf * 16 + kg * 4 + r) * 16 + l15] = q4[cf][r];
    __syncthreads();
    if (tid < 128) {
        const float4* pr = (const float4*)(part + tid * 16);
        float4 a0 = pr[0], a1 = pr[1], a2 = pr[2], a3 = pr[3];
        float s = a0.x + a0.y + a0.z + a0.w + a1.x + a1.y + a1.z + a1.w +
                  a2.x + a2.y + a2.z + a2.w + a3.x + a3.y + a3.z + a3.w;
        atomicAdd(&stats[640 + tid], s);
    }
}

// --------- h += maybe_relu(BN2(u)); refresh bf16 mirror; on the last layer,
// fuse the node head: dots with nW/eW from the in-register final h, 16-lane
// shuffle reduce, node_key + p/q + node seg sums (spread scratch)
__global__ void k_update_h(float* __restrict__ h, unsigned short* __restrict__ hb,
                           const unsigned short* __restrict__ ub,
                           const float* __restrict__ scale2, const float* __restrict__ shift2,
                           int relu, int head,
                           const int* __restrict__ batch, const float* __restrict__ nW,
                           const float* __restrict__ nb, const float* __restrict__ eW,
                           float* __restrict__ out, float* __restrict__ p,
                           float* __restrict__ q, float* __restrict__ nsc) {
    int kb = (threadIdx.x & 15) * 8;
    float scr[8], shr[8];
    {
        float4 sa = *(const float4*)(scale2 + kb);
        float4 sb = *(const float4*)(scale2 + kb + 4);
        float4 ha = *(const float4*)(shift2 + kb);
        float4 hbv = *(const float4*)(shift2 + kb + 4);
        scr[0] = sa.x; scr[1] = sa.y; scr[2] = sa.z; scr[3] = sa.w;
        scr[4] = sb.x; scr[5] = sb.y; scr[6] = sb.z; scr[7] = sb.w;
        shr[0] = ha.x; shr[1] = ha.y; shr[2] = ha.z; shr[3] = ha.w;
        shr[4] = hbv.x; shr[5] = hbv.y; shr[6] = hbv.z; shr[7] = hbv.w;
    }
    int i = blockIdx.x * 256 + threadIdx.x;  // 8-elem unit; total N*16 = 1.6M
    uint4 uv = ((const uint4*)ub)[i];
    float4 h0 = ((const float4*)h)[i * 2];
    float4 h1 = ((const float4*)h)[i * 2 + 1];
    float v0 = fmaf(scr[0], bf2f((unsigned short)(uv.x & 0xffffu)), shr[0]);
    float v1 = fmaf(scr[1], bf2f((unsigned short)(uv.x >> 16)), shr[1]);
    float v2 = fmaf(scr[2], bf2f((unsigned short)(uv.y & 0xffffu)), shr[2]);
    float v3 = fmaf(scr[3], bf2f((unsigned short)(uv.y >> 16)), shr[3]);
    float v4 = fmaf(scr[4], bf2f((unsigned short)(uv.z & 0xffffu)), shr[4]);
    float v5 = fmaf(scr[5], bf2f((unsigned short)(uv.z >> 16)), shr[5]);
    float v6 = fmaf(scr[6], bf2f((unsigned short)(uv.w & 0xffffu)), shr[6]);
    float v7 = fmaf(scr[7], bf2f((unsigned short)(uv.w >> 16)), shr[7]);
    if (relu) {
        v0 = fmaxf(v0, 0.f); v1 = fmaxf(v1, 0.f); v2 = fmaxf(v2, 0.f); v3 = fmaxf(v3, 0.f);
        v4 = fmaxf(v4, 0.f); v5 = fmaxf(v5, 0.f); v6 = fmaxf(v6, 0.f); v7 = fmaxf(v7, 0.f);
    }
    h0.x += v0; h0.y += v1; h0.z += v2; h0.w += v3;
    h1.x += v4; h1.y += v5; h1.z += v6; h1.w += v7;
    ((float4*)h)[i * 2] = h0;
    ((float4*)h)[i * 2 + 1] = h1;
    uint4 hp;
    hp.x = pack2(h0.x, h0.y); hp.y = pack2(h0.z, h0.w);
    hp.z = pack2(h1.x, h1.y); hp.w = pack2(h1.z, h1.w);
    ((uint4*)hb)[i] = hp;
    if (head) {
        float4 wn0 = *(const float4*)(nW + kb);
        float4 wn1 = *(const float4*)(nW + kb + 4);
        float4 wa0 = *(const float4*)(eW + kb);
        float4 wa1 = *(const float4*)(eW + kb + 4);
        float4 wb0 = *(const float4*)(eW + 128 + kb);
        float4 wb1 = *(const float4*)(eW + 128 + kb + 4);
        float pn = h0.x * wn0.x + h0.y * wn0.y + h0.z * wn0.z + h0.w * wn0.w +
                   h1.x * wn1.x + h1.y * wn1.y + h1.z * wn1.z + h1.w * wn1.w;
        float pa = h0.x * wa0.x + h0.y * wa0.y + h0.z * wa0.z + h0.w * wa0.w +
                   h1.x * wa1.x + h1.y * wa1.y + h1.z * wa1.z + h1.w * wa1.w;
        float pb = h0.x * wb0.x + h0.y * wb0.y + h0.z * wb0.z + h0.w * wb0.w +
                   h1.x * wb1.x + h1.y * wb1.y + h1.z * wb1.z + h1.w * wb1.w;
#pragma unroll
        for (int off = 1; off < 16; off <<= 1) {
            pn += __shfl_xor(pn, off);
            pa += __shfl_xor(pa, off);
            pb += __shfl_xor(pb, off);
        }
        if ((threadIdx.x & 15) == 0) {
            int gr = i >> 4;
            float nk = 1.f / (1.f + expf(-(pn + nb[0])));
            out[gr] = nk;
            int g = batch[gr];
            float* base = nsc + (size_t)(blockIdx.x & 7) * 8192;
            atomicAdd(&base[g], nk);
            atomicAdd(&base[4096 + g], 1.0f - nk);
            p[gr] = pa;
            q[gr] = pb;
        }
    }
}

// ------------- edge head: LDS-binned seg sums, zero global atomics.
// 512 grid-stride blocks; per-block bins flushed to esc[bid][8192]
__global__ __launch_bounds__(256) void k_edge_out(
    const int* __restrict__ ei, const int* __restrict__ batch,
    const float* __restrict__ p, const float* __restrict__ q,
    const float* __restrict__ eb, float* __restrict__ out,
    float* __restrict__ esc) {
    __shared__ float bins[8192];  // [2][4096] = 32 KB
    for (int i = threadIdx.x; i < 8192; i += 256) bins[i] = 0.f;
    __syncthreads();
    float ebv = eb[0];
    for (int e = blockIdx.x * 256 + threadIdx.x; e < N_EDGES; e += EOUT_BLK * 256) {
        int r = ei[e], c = ei[N_EDGES + e];
        float ek = 1.f / (1.f + expf(-(p[r] + q[c] + ebv)));
        out[N_NODES + e] = ek;
        int g = batch[r];
        atomicAdd(&bins[g], ek);
        atomicAdd(&bins[4096 + g], 1.0f - ek);
    }
    __syncthreads();
    float* dst = esc + (size_t)blockIdx.x * 8192;
    for (int i = threadIdx.x; i < 8192; i += 256) dst[i] = bins[i];
}

// ------------- reduce the scratch copies into the 4 output segments
__global__ void k_seg_reduce(const float* __restrict__ nsc, const float* __restrict__ esc,
                             float* __restrict__ out) {
    int i = blockIdx.x * 256 + threadIdx.x;   // 0..16383
    if (i >= 16384) return;
    float s = 1e-8f;
    if (i < 8192) {
#pragma unroll
        for (int c = 0; c < 8; ++c) s += nsc[c * 8192 + i];
    } else {
        int j = i - 8192;
        for (int c = 0; c < EOUT_BLK; ++c) s += esc[(size_t)c * 8192 + j];
    }
    out[N_NODES + N_EDGES + i] = s;
}

extern "C" void kernel_launch(void* const* d_in, const int* in_sizes, int n_in,
                              void* d_out, int out_size, void* d_ws, size_t ws_size,
                              hipStream_t stream) {
    const int*   x     = (const int*)d_in[0];
    const int*   ei    = (const int*)d_in[1];
    const int*   ea    = (const int*)d_in[2];
    const int*   batch = (const int*)d_in[3];
    const float* at    = (const float*)d_in[4];
    const float* bt    = (const float*)d_in[5];
    const float* eps   = (const float*)d_in[6];
    const float* W1    = (const float*)d_in[7];
    const float* b1    = (const float*)d_in[8];
    const float* bn1g  = (const float*)d_in[9];
    const float* bn1b  = (const float*)d_in[10];
    const float* W2    = (const float*)d_in[11];
    const float* b2    = (const float*)d_in[12];
    const float* obng  = (const float*)d_in[13];
    const float* obnb  = (const float*)d_in[14];
    const float* nW    = (const float*)d_in[15];
    const float* nb    = (const float*)d_in[16];
    const float* eW    = (const float*)d_in[17];
    const float* eb    = (const float*)d_in[18];
    float* out = (float*)d_out;

    float* ws    = (float*)d_ws;
    float* h     = ws;                       // N*128 fp32
    float* stats = h + 12800000;             // 3 layers x 16 copies x 768
    float* sf    = stats + 3 * 16 * 768;     // scale1/shift1/scale2/shift2 (768)
    float* p     = sf + 768;                 // N
    float* q     = p + N_NODES;              // N
    float* nsc   = q + N_NODES;              // 8*8192 node seg scratch
    float* esc   = nsc + 8 * 8192;           // EOUT_BLK*8192 edge seg scratch (16 MB)
    unsigned short* hb  = (unsigned short*)(esc + (size_t)EOUT_BLK * 8192);  // N*128 bf16
    unsigned short* zub = hb + 12800000;     // N*128 bf16: z (gemm1 in), then u
    unsigned short* tb  = zub + 12800000;    // N*256 bf16
    unsigned short* Bp1 = tb + 25600000;     // 3*128*256 bf16
    unsigned short* Bp2 = Bp1 + 3 * 32768;   // 3*256*128 bf16
    unsigned short* ct  = Bp2 + 3 * 32768;   // 3*512*128 bf16 combined bond
    int* rowptr  = (int*)(ct + 3 * 65536);   // N+1
    int* cursor  = rowptr + N_NODES + 1;     // N (counts, then cursors)
    int* csr_row = cursor + N_NODES;         // E
    int* csr_attr = csr_row + N_EDGES;       // E
    int* bsum    = csr_attr + N_EDGES;       // SCAN_NBLK
    // per-layer stats: sl = stats + l*16*768; copy c at sl + c*768:
    //   [sum256][sq256][osum128@512][osq128@640]

    hipMemsetAsync(stats, 0, 3 * 16 * 768 * sizeof(float), stream);
    hipMemsetAsync(nsc, 0, 8 * 8192 * sizeof(float), stream);
    hipMemsetAsync(cursor, 0, N_NODES * sizeof(int), stream);
    k_atom_encode<<<50000, 256, 0, stream>>>(x, at, h, hb);
    k_convw<<<768, 256, 0, stream>>>(W1, W2, Bp1, Bp2);
    k_bondc<<<768, 256, 0, stream>>>(bt, ct);

    // CSR of edges grouped by destination (col) — parallel 3-phase scan
    k_hist<<<2344, 256, 0, stream>>>(ei, cursor);
    k_scan_partial<<<SCAN_NBLK, 256, 0, stream>>>(cursor, bsum);
    k_scan_bsum<<<1, 256, 0, stream>>>(bsum, rowptr);
    k_scan_final<<<SCAN_NBLK, 512, 0, stream>>>(bsum, cursor, rowptr);
    k_fill<<<2344, 256, 0, stream>>>(ei, ea, cursor, csr_row, csr_attr);

    for (int l = 0; l < 3; ++l) {
        float* sl = stats + (size_t)l * 16 * 768;
        k_gather<<<25000, 256, 0, stream>>>(hb, csr_row, csr_attr, rowptr,
                                            ct + (size_t)l * 65536, eps, l, zub);
        k_gemm1<<<1563, 256, 0, stream>>>(zub, Bp1 + (size_t)l * 32768, b1 + l * 256, tb, sl);
        k_bnfin<<<1, 256, 0, stream>>>(sl, 0, 256, bn1g + l * 256, bn1b + l * 256,
                                       sf, sf + 256);
        k_gemm2<<<1563, 256, 0, stream>>>(tb, Bp2 + (size_t)l * 32768, sf, sf + 256,
                                          b2 + l * 128, zub, sl);
        k_bnfin<<<1, 128, 0, stream>>>(sl, 512, 128, obng + l * 128, obnb + l * 128,
                                       sf + 512, sf + 640);
        k_update_h<<<6250, 256, 0, stream>>>(h, hb, zub, sf + 512, sf + 640,
                                             (l < 2) ? 1 : 0, (l == 2) ? 1 : 0,
                                             batch, nW, nb, eW, out, p, q, nsc);
    }

    k_edge_out<<<EOUT_BLK, 256, 0, stream>>>(ei, batch, p, q, eb, out, esc);
    k_seg_reduce<<<64, 256, 0, stream>>>(nsc, esc, out);
}

// Round 11
// 551.711 us; speedup vs baseline: 6.2903x; 1.0565x over previous
//
#include <hip/hip_runtime.h>
#include <math.h>

#define N_NODES 100000
#define N_EDGES 600000
#define N_GRAPHS 4096
#define SCAN_CHUNK 512
#define SCAN_NBLK 196   // ceil(100000/512)
#define EOUT_BLK 512    // edge_out grid (LDS-binned, scratch copies)

typedef __attribute__((ext_vector_type(8))) short short8v;   // 8 bf16 (4 VGPR)
typedef __attribute__((ext_vector_type(4))) float f32x4;

// fp32 pair -> packed bf16 (RNE) via the HW instruction
__device__ __forceinline__ unsigned int pack2(float a, float b) {
    unsigned int r;
    asm("v_cvt_pk_bf16_f32 %0, %1, %2" : "=v"(r) : "v"(a), "v"(b));
    return r;
}
__device__ __forceinline__ unsigned short bf16_rne(float f) {
    unsigned int r;
    asm("v_cvt_pk_bf16_f32 %0, %1, %2" : "=v"(r) : "v"(f), "v"(f));
    return (unsigned short)r;
}
__device__ __forceinline__ float bf2f(unsigned short u) {
    return __uint_as_float(((unsigned int)u) << 16);
}

// ------------------------------------------- atom encoder (bf16 h only)
__global__ void k_atom_encode(const int* __restrict__ x, const float* __restrict__ at,
                              unsigned short* __restrict__ hb) {
    int n = blockIdx.x * 2 + (threadIdx.x >> 7);
    int d = threadIdx.x & 127;
    if (n >= N_NODES) return;
    const int* xr = x + n * 9;
    float s = 0.f;
#pragma unroll
    for (int f = 0; f < 9; ++f) {
        int v = xr[f];
        s += at[(f * 100 + v) * 128 + d];
    }
    hb[(size_t)n * 128 + d] = bf16_rne(s);
}

// --------- combined bond table: ct[l][idx][d] = bf16(sum of 3 table rows)
__global__ void k_bondc(const float* __restrict__ bt, unsigned short* __restrict__ ct) {
    int idx = blockIdx.x * 256 + threadIdx.x;
    if (idx >= 3 * 512 * 128) return;
    int d = idx & 127;
    int c = (idx >> 7) & 511;
    int l = idx >> 16;
    const float* base = bt + (size_t)l * 3072;
    float v = base[(c >> 6) * 128 + d] + base[1024 + ((c >> 3) & 7) * 128 + d] +
              base[2048 + (c & 7) * 128 + d];
    ct[idx] = bf16_rne(v);
}

// --------------------------- CSR build (once)
__global__ void k_hist(const int* __restrict__ ei, int* __restrict__ cnt) {
    int e = blockIdx.x * 256 + threadIdx.x;
    if (e < N_EDGES) atomicAdd(&cnt[ei[N_EDGES + e]], 1);
}

__global__ void k_scan_partial(const int* __restrict__ cnt, int* __restrict__ bsum) {
    __shared__ int ls[256];
    int base = blockIdx.x * SCAN_CHUNK;
    int t = threadIdx.x;
    int s = 0;
    for (int i = base + t; i < base + SCAN_CHUNK && i < N_NODES; i += 256) s += cnt[i];
    ls[t] = s;
    __syncthreads();
    for (int off = 128; off; off >>= 1) {
        if (t < off) ls[t] += ls[t + off];
        __syncthreads();
    }
    if (t == 0) bsum[blockIdx.x] = ls[0];
}

__global__ void k_scan_bsum(int* __restrict__ bsum, int* __restrict__ rowptr) {
    __shared__ int ls[256];
    int t = threadIdx.x;
    int v = (t < SCAN_NBLK) ? bsum[t] : 0;
    ls[t] = v;
    __syncthreads();
    for (int off = 1; off < 256; off <<= 1) {
        int x = (t >= off) ? ls[t - off] : 0;
        __syncthreads();
        ls[t] += x;
        __syncthreads();
    }
    if (t < SCAN_NBLK) bsum[t] = ls[t] - v;  // exclusive prefix
    if (t == 255) rowptr[N_NODES] = ls[255];
}

__global__ __launch_bounds__(512) void k_scan_final(const int* __restrict__ bsum,
                                                    int* __restrict__ cnt_cursor,
                                                    int* __restrict__ rowptr) {
    __shared__ int ls[512];
    int base = blockIdx.x * SCAN_CHUNK;
    int t = threadIdx.x;
    int i = base + t;
    int v = (i < N_NODES) ? cnt_cursor[i] : 0;
    ls[t] = v;
    __syncthreads();
    for (int off = 1; off < 512; off <<= 1) {
        int x = (t >= off) ? ls[t - off] : 0;
        __syncthreads();
        ls[t] += x;
        __syncthreads();
    }
    if (i < N_NODES) {
        int excl = bsum[blockIdx.x] + ls[t] - v;
        rowptr[i] = excl;
        cnt_cursor[i] = excl;
    }
}

// fill CSR-ordered source-row + combined-attr-index arrays
__global__ void k_fill(const int* __restrict__ ei, const int* __restrict__ ea,
                       int* __restrict__ cursor,
                       int* __restrict__ csr_row, int* __restrict__ csr_attr) {
    int e = blockIdx.x * 256 + threadIdx.x;
    if (e < N_EDGES) {
        int c = ei[N_EDGES + e];
        int pos = atomicAdd(&cursor[c], 1);
        csr_row[pos] = ei[e];
        csr_attr[pos] = ea[e * 3] * 64 + ea[e * 3 + 1] * 8 + ea[e * 3 + 2];
    }
}

// ---------------- weight pre-swizzle: fp32 -> bf16 in MFMA B-fragment layout
__global__ void k_convw(const float* __restrict__ W1, const float* __restrict__ W2,
                        unsigned short* __restrict__ Bp1, unsigned short* __restrict__ Bp2) {
    int idx = blockIdx.x * 256 + threadIdx.x;
    if (idx < 3 * 128 * 256) {
        int l = idx >> 15, r = idx & 32767;
        int k = r >> 8, j = r & 255;
        float v = W1[(size_t)l * 32768 + k * 256 + j];
        Bp1[(size_t)l * 32768 + (((k >> 5) * 4 + ((k >> 3) & 3)) * 256 + j) * 8 + (k & 7)] =
            bf16_rne(v);
    } else if (idx < 6 * 128 * 256) {
        int t = idx - 98304;
        int l = t >> 15, r = t & 32767;
        int k = r >> 7, j = r & 127;
        float v = W2[(size_t)l * 32768 + k * 128 + j];
        Bp2[(size_t)l * 32768 + (((k >> 5) * 4 + ((k >> 3) & 3)) * 128 + j) * 8 + (k & 7)] =
            bf16_rne(v);
    }
}

// ---------------------------- gather-aggregate: z = (1+eps)*h + sum relu(msg)
#define EDGE2(uu, cc)                                                          \
    {                                                                          \
        ax += fmaxf(bf2f((unsigned short)((uu) & 0xffffu)) +                   \
                    bf2f((unsigned short)((cc) & 0xffffu)), 0.f);              \
        ay += fmaxf(bf2f((unsigned short)((uu) >> 16)) +                       \
                    bf2f((unsigned short)((cc) >> 16)), 0.f);                  \
    }

__global__ void k_gather(const unsigned short* __restrict__ hb,
                         const int* __restrict__ csr_row, const int* __restrict__ csr_attr,
                         const int* __restrict__ rowptr, const unsigned short* __restrict__ ct,
                         const float* __restrict__ eps, int l,
                         unsigned short* __restrict__ zb) {
    int lane = threadIdx.x & 63;
    int n = blockIdx.x * 4 + (threadIdx.x >> 6);
    if (n >= N_NODES) return;
    int i0 = rowptr[n], i1 = rowptr[n + 1];
    float ax = 0.f, ay = 0.f;
    int i = i0;
    for (; i + 4 <= i1; i += 4) {
        int r0 = csr_row[i], r1 = csr_row[i + 1], r2 = csr_row[i + 2], r3 = csr_row[i + 3];
        int q0 = csr_attr[i], q1 = csr_attr[i + 1], q2 = csr_attr[i + 2], q3 = csr_attr[i + 3];
        unsigned int u0 = ((const unsigned int*)(hb + (size_t)r0 * 128))[lane];
        unsigned int u1 = ((const unsigned int*)(hb + (size_t)r1 * 128))[lane];
        unsigned int u2 = ((const unsigned int*)(hb + (size_t)r2 * 128))[lane];
        unsigned int u3 = ((const unsigned int*)(hb + (size_t)r3 * 128))[lane];
        unsigned int c0 = ((const unsigned int*)(ct + q0 * 128))[lane];
        unsigned int c1 = ((const unsigned int*)(ct + q1 * 128))[lane];
        unsigned int c2 = ((const unsigned int*)(ct + q2 * 128))[lane];
        unsigned int c3 = ((const unsigned int*)(ct + q3 * 128))[lane];
        EDGE2(u0, c0); EDGE2(u1, c1); EDGE2(u2, c2); EDGE2(u3, c3);
    }
    for (; i < i1; ++i) {
        int r0 = csr_row[i];
        int q0 = csr_attr[i];
        unsigned int u0 = ((const unsigned int*)(hb + (size_t)r0 * 128))[lane];
        unsigned int c0 = ((const unsigned int*)(ct + q0 * 128))[lane];
        EDGE2(u0, c0);
    }
    float el = 1.0f + eps[l];
    unsigned int un = ((const unsigned int*)(hb + (size_t)n * 128))[lane];
    float zx = fmaf(el, bf2f((unsigned short)(un & 0xffffu)), ax);
    float zy = fmaf(el, bf2f((unsigned short)(un >> 16)), ay);
    ((unsigned int*)(zb + (size_t)n * 128))[lane] = pack2(zx, zy);
}

// --------------------- GEMM1 (MFMA, swapped operands -> (z@W1)^T fragments)
// stats partials go to 16 spread copies (sl[(bid&15)*768 + ...])
__global__ __launch_bounds__(256) void k_gemm1(
    const unsigned short* __restrict__ zb, const unsigned short* __restrict__ Bp,
    const float* __restrict__ bias, unsigned short* __restrict__ tb,
    float* __restrict__ sl) {
    __shared__ unsigned short As[8192] __attribute__((aligned(16)));  // 16 KB
    int n0 = blockIdx.x * 64;
#pragma unroll
    for (int s = 0; s < 4; ++s) {
        int i = threadIdx.x + s * 256;            // 16B unit; 64 rows x 16 units
        int r = i >> 4, k8 = i & 15;
        short8v v = (short8v)(short)0;
        if (n0 + r < N_NODES) v = ((const short8v*)(zb + (size_t)(n0 + r) * 128))[k8];
        int frag = (r >> 4) * 16 + k8;
        int off = (frag * 128 + (r & 15) * 8) ^ ((k8 & 7) << 3);
        *(short8v*)(&As[off]) = v;
    }
    __syncthreads();
    int lane = threadIdx.x & 63;
    int wid = threadIdx.x >> 6;
    int l15 = lane & 15, kg = lane >> 4;
    int colbase = wid * 64;
    f32x4 acc[4][4];  // [rb][cf]
#pragma unroll
    for (int a = 0; a < 4; ++a)
#pragma unroll
        for (int b = 0; b < 4; ++b) acc[a][b] = (f32x4)(0.f);
#pragma unroll
    for (int k4 = 0; k4 < 4; ++k4) {
        short8v af[4], bf[4];
#pragma unroll
        for (int rb = 0; rb < 4; ++rb)
            af[rb] = *(const short8v*)(&As[((rb * 16 + k4 * 4 + kg) * 128 + l15 * 8) ^
                                           (((k4 * 4 + kg) & 7) << 3)]);
#pragma unroll
        for (int cf = 0; cf < 4; ++cf)
            bf[cf] = *(const short8v*)(Bp + ((k4 * 4 + kg) * 256 + colbase + cf * 16 + l15) * 8);
#pragma unroll
        for (int rb = 0; rb < 4; ++rb)
#pragma unroll
            for (int cf = 0; cf < 4; ++cf)
                acc[rb][cf] = __builtin_amdgcn_mfma_f32_16x16x32_bf16(bf[cf], af[rb],
                                                                      acc[rb][cf], 0, 0, 0);
    }
    float s4[4][4], q4[4][4];
#pragma unroll
    for (int cf = 0; cf < 4; ++cf)
#pragma unroll
        for (int r = 0; r < 4; ++r) { s4[cf][r] = 0.f; q4[cf][r] = 0.f; }
#pragma unroll
    for (int cf = 0; cf < 4; ++cf) {
        int j0 = colbase + cf * 16 + kg * 4;
        float4 b4 = *(const float4*)(bias + j0);
#pragma unroll
        for (int rb = 0; rb < 4; ++rb) {
            int gr = n0 + rb * 16 + l15;
            if (gr < N_NODES) {
                float v0 = acc[rb][cf][0] + b4.x;
                float v1 = acc[rb][cf][1] + b4.y;
                float v2 = acc[rb][cf][2] + b4.z;
                float v3 = acc[rb][cf][3] + b4.w;
                uint2 st;
                st.x = pack2(v0, v1);
                st.y = pack2(v2, v3);
                *(uint2*)(tb + (size_t)gr * 256 + j0) = st;
                s4[cf][0] += v0; q4[cf][0] += v0 * v0;
                s4[cf][1] += v1; q4[cf][1] += v1 * v1;
                s4[cf][2] += v2; q4[cf][2] += v2 * v2;
                s4[cf][3] += v3; q4[cf][3] += v3 * v3;
            }
        }
    }
    float* stats = sl + (size_t)(blockIdx.x & 15) * 768;
    float* part = (float*)As;
    __syncthreads();
#pragma unroll
    for (int cf = 0; cf < 4; ++cf)
#pragma unroll
        for (int r = 0; r < 4; ++r)
            part[(colbase + cf * 16 + kg * 4 + r) * 16 + l15] = s4[cf][r];
    __syncthreads();
    {
        int j = threadIdx.x;
        const float4* pr = (const float4*)(part + j * 16);
        float4 a0 = pr[0], a1 = pr[1], a2 = pr[2], a3 = pr[3];
        float s = a0.x + a0.y + a0.z + a0.w + a1.x + a1.y + a1.z + a1.w +
                  a2.x + a2.y + a2.z + a2.w + a3.x + a3.y + a3.z + a3.w;
        atomicAdd(&stats[j], s);
    }
    __syncthreads();
#pragma unroll
    for (int cf = 0; cf < 4; ++cf)
#pragma unroll
        for (int r = 0; r < 4; ++r)
            part[(colbase + cf * 16 + kg * 4 + r) * 16 + l15] = q4[cf][r];
    __syncthreads();
    {
        int j = threadIdx.x;
        const float4* pr = (const float4*)(part + j * 16);
        float4 a0 = pr[0], a1 = pr[1], a2 = pr[2], a3 = pr[3];
        float s = a0.x + a0.y + a0.z + a0.w + a1.x + a1.y + a1.z + a1.w +
                  a2.x + a2.y + a2.z + a2.w + a3.x + a3.y + a3.z + a3.w;
        atomicAdd(&stats[256 + j], s);
    }
}

// ----- BN finalize: sum 16 spread copies -> scale/shift (tiny kernel)
__global__ void k_bnfin(const float* __restrict__ sl, int off, int C,
                        const float* __restrict__ g, const float* __restrict__ b,
                        float* __restrict__ scale, float* __restrict__ shift) {
    int j = threadIdx.x;
    if (j >= C) return;
    float s = 0.f, q = 0.f;
#pragma unroll
    for (int c = 0; c < 16; ++c) {
        s += sl[c * 768 + off + j];
        q += sl[c * 768 + off + C + j];
    }
    float m = s * (1.0f / N_NODES);
    float var = q * (1.0f / N_NODES) - m * m;
    float sc = g[j] / sqrtf(var + 1e-5f);
    scale[j] = sc;
    shift[j] = b[j] - m * sc;
}

// ------- GEMM2 (MFMA, swapped): u = relu(BN1(t))@W2 + b2, fused BN2 stats
// scale1/shift1 precomputed; BN2 partials to 16 spread copies at sl+512/640
__global__ __launch_bounds__(256) void k_gemm2(
    const unsigned short* __restrict__ tb, const unsigned short* __restrict__ Bp,
    const float* __restrict__ scale1, const float* __restrict__ shift1,
    const float* __restrict__ bias, unsigned short* __restrict__ ub,
    float* __restrict__ sl) {
    __shared__ unsigned short As[16384] __attribute__((aligned(16)));  // 32 KB
    int n0 = blockIdx.x * 64;
    int tid = threadIdx.x;
    int kb = (tid & 31) * 8;
    float scr[8], shr[8];
    {
        float4 sa = *(const float4*)(scale1 + kb);
        float4 sb = *(const float4*)(scale1 + kb + 4);
        float4 ha = *(const float4*)(shift1 + kb);
        float4 hbv = *(const float4*)(shift1 + kb + 4);
        scr[0] = sa.x; scr[1] = sa.y; scr[2] = sa.z; scr[3] = sa.w;
        scr[4] = sb.x; scr[5] = sb.y; scr[6] = sb.z; scr[7] = sb.w;
        shr[0] = ha.x; shr[1] = ha.y; shr[2] = ha.z; shr[3] = ha.w;
        shr[4] = hbv.x; shr[5] = hbv.y; shr[6] = hbv.z; shr[7] = hbv.w;
    }
#pragma unroll
    for (int s = 0; s < 8; ++s) {
        int i = tid + s * 256;                    // 16B unit; 64 rows x 32 units
        int r = i >> 5, k8 = i & 31;
        short8v v = (short8v)(short)0;
        if (n0 + r < N_NODES) v = ((const short8v*)(tb + (size_t)(n0 + r) * 256))[k8];
        float f0 = fmaxf(fmaf(scr[0], bf2f((unsigned short)v[0]), shr[0]), 0.f);
        float f1 = fmaxf(fmaf(scr[1], bf2f((unsigned short)v[1]), shr[1]), 0.f);
        float f2 = fmaxf(fmaf(scr[2], bf2f((unsigned short)v[2]), shr[2]), 0.f);
        float f3 = fmaxf(fmaf(scr[3], bf2f((unsigned short)v[3]), shr[3]), 0.f);
        float f4 = fmaxf(fmaf(scr[4], bf2f((unsigned short)v[4]), shr[4]), 0.f);
        float f5 = fmaxf(fmaf(scr[5], bf2f((unsigned short)v[5]), shr[5]), 0.f);
        float f6 = fmaxf(fmaf(scr[6], bf2f((unsigned short)v[6]), shr[6]), 0.f);
        float f7 = fmaxf(fmaf(scr[7], bf2f((unsigned short)v[7]), shr[7]), 0.f);
        uint4 ov;
        ov.x = pack2(f0, f1); ov.y = pack2(f2, f3);
        ov.z = pack2(f4, f5); ov.w = pack2(f6, f7);
        int frag = (r >> 4) * 32 + k8;
        int off = (frag * 128 + (r & 15) * 8) ^ ((k8 & 7) << 3);
        *(uint4*)(&As[off]) = ov;
    }
    __syncthreads();
    int lane = threadIdx.x & 63;
    int wid = threadIdx.x >> 6;
    int l15 = lane & 15, kg = lane >> 4;
    int colbase = wid * 32;
    f32x4 acc[4][2];  // [rb][cf]
#pragma unroll
    for (int a = 0; a < 4; ++a) {
        acc[a][0] = (f32x4)(0.f);
        acc[a][1] = (f32x4)(0.f);
    }
#pragma unroll
    for (int k4 = 0; k4 < 8; ++k4) {
        short8v af[4], bf[2];
#pragma unroll
        for (int rb = 0; rb < 4; ++rb)
            af[rb] = *(const short8v*)(&As[((rb * 32 + k4 * 4 + kg) * 128 + l15 * 8) ^
                                           (((k4 * 4 + kg) & 7) << 3)]);
#pragma unroll
        for (int cf = 0; cf < 2; ++cf)
            bf[cf] = *(const short8v*)(Bp + ((k4 * 4 + kg) * 128 + colbase + cf * 16 + l15) * 8);
#pragma unroll
        for (int rb = 0; rb < 4; ++rb)
#pragma unroll
            for (int cf = 0; cf < 2; ++cf)
                acc[rb][cf] = __builtin_amdgcn_mfma_f32_16x16x32_bf16(bf[cf], af[rb],
                                                                      acc[rb][cf], 0, 0, 0);
    }
    float s4[2][4], q4[2][4];
#pragma unroll
    for (int cf = 0; cf < 2; ++cf)
#pragma unroll
        for (int r = 0; r < 4; ++r) { s4[cf][r] = 0.f; q4[cf][r] = 0.f; }
#pragma unroll
    for (int cf = 0; cf < 2; ++cf) {
        int j0 = colbase + cf * 16 + kg * 4;
        float4 b4 = *(const float4*)(bias + j0);
#pragma unroll
        for (int rb = 0; rb < 4; ++rb) {
            int gr = n0 + rb * 16 + l15;
            if (gr < N_NODES) {
                float v0 = acc[rb][cf][0] + b4.x;
                float v1 = acc[rb][cf][1] + b4.y;
                float v2 = acc[rb][cf][2] + b4.z;
                float v3 = acc[rb][cf][3] + b4.w;
                uint2 st;
                st.x = pack2(v0, v1);
                st.y = pack2(v2, v3);
                *(uint2*)(ub + (size_t)gr * 128 + j0) = st;
                s4[cf][0] += v0; q4[cf][0] += v0 * v0;
                s4[cf][1] += v1; q4[cf][1] += v1 * v1;
                s4[cf][2] += v2; q4[cf][2] += v2 * v2;
                s4[cf][3] += v3; q4[cf][3] += v3 * v3;
            }
        }
    }
    float* stats = sl + (size_t)(blockIdx.x & 15) * 768;
    float* part = (float*)As;  // need 128*16 floats = 8 KB
    __syncthreads();
#pragma unroll
    for (int cf = 0; cf < 2; ++cf)
#pragma unroll
        for (int r = 0; r < 4; ++r)
            part[(colbase + cf * 16 + kg * 4 + r) * 16 + l15] = s4[cf][r];
    __syncthreads();
    if (tid < 128) {
        const float4* pr = (const float4*)(part + tid * 16);
        float4 a0 = pr[0], a1 = pr[1], a2 = pr[2], a3 = pr[3];
        float s = a0.x + a0.y + a0.z + a0.w + a1.x + a1.y + a1.z + a1.w +
                  a2.x + a2.y + a2.z + a2.w + a3.x + a3.y + a3.z + a3.w;
        atomicAdd(&stats[512 + tid], s);
    }
    __syncthreads();
#pragma unroll
    for (int cf = 0; cf < 2; ++cf)
#pragma unroll
        for (int r = 0; r < 4; ++r)
            part[(colbase + cf * 16 + kg * 4 + r) * 16 + l15] = q4[cf][r];
    __syncthreads();
    if (tid < 128) {
        const float4* pr = (const float4*)(part + tid * 16);
        float4 a0 = pr[0], a1 = pr[1], a2 = pr[2], a3 = pr[3];
        float s = a0.x + a0.y + a0.z + a0.w + a1.x + a1.y + a1.z + a1.w +
                  a2.x + a2.y + a2.z + a2.w + a3.x + a3.y + a3.z + a3.w;
        atomicAdd(&stats[640 + tid], s);
    }
}

// --------- hb += maybe_relu(BN2(u)) in fp32, repack to bf16 (sole residual
// state). Last layer: fused node head from the pre-rounding fp32 values.
__global__ void k_update_h(unsigned short* __restrict__ hb,
                           const unsigned short* __restrict__ ub,
                           const float* __restrict__ scale2, const float* __restrict__ shift2,
                           int relu, int head,
                           const int* __restrict__ batch, const float* __restrict__ nW,
                           const float* __restrict__ nb, const float* __restrict__ eW,
                           float* __restrict__ out, float* __restrict__ p,
                           float* __restrict__ q, float* __restrict__ nsc) {
    int kb = (threadIdx.x & 15) * 8;
    float scr[8], shr[8];
    {
        float4 sa = *(const float4*)(scale2 + kb);
        float4 sb = *(const float4*)(scale2 + kb + 4);
        float4 ha = *(const float4*)(shift2 + kb);
        float4 hbv = *(const float4*)(shift2 + kb + 4);
        scr[0] = sa.x; scr[1] = sa.y; scr[2] = sa.z; scr[3] = sa.w;
        scr[4] = sb.x; scr[5] = sb.y; scr[6] = sb.z; scr[7] = sb.w;
        shr[0] = ha.x; shr[1] = ha.y; shr[2] = ha.z; shr[3] = ha.w;
        shr[4] = hbv.x; shr[5] = hbv.y; shr[6] = hbv.z; shr[7] = hbv.w;
    }
    int i = blockIdx.x * 256 + threadIdx.x;  // 8-elem unit; total N*16 = 1.6M
    uint4 uv = ((const uint4*)ub)[i];
    uint4 hv = ((const uint4*)hb)[i];
    float v0 = fmaf(scr[0], bf2f((unsigned short)(uv.x & 0xffffu)), shr[0]);
    float v1 = fmaf(scr[1], bf2f((unsigned short)(uv.x >> 16)), shr[1]);
    float v2 = fmaf(scr[2], bf2f((unsigned short)(uv.y & 0xffffu)), shr[2]);
    float v3 = fmaf(scr[3], bf2f((unsigned short)(uv.y >> 16)), shr[3]);
    float v4 = fmaf(scr[4], bf2f((unsigned short)(uv.z & 0xffffu)), shr[4]);
    float v5 = fmaf(scr[5], bf2f((unsigned short)(uv.z >> 16)), shr[5]);
    float v6 = fmaf(scr[6], bf2f((unsigned short)(uv.w & 0xffffu)), shr[6]);
    float v7 = fmaf(scr[7], bf2f((unsigned short)(uv.w >> 16)), shr[7]);
    if (relu) {
        v0 = fmaxf(v0, 0.f); v1 = fmaxf(v1, 0.f); v2 = fmaxf(v2, 0.f); v3 = fmaxf(v3, 0.f);
        v4 = fmaxf(v4, 0.f); v5 = fmaxf(v5, 0.f); v6 = fmaxf(v6, 0.f); v7 = fmaxf(v7, 0.f);
    }
    float h0 = bf2f((unsigned short)(hv.x & 0xffffu)) + v0;
    float h1 = bf2f((unsigned short)(hv.x >> 16)) + v1;
    float h2 = bf2f((unsigned short)(hv.y & 0xffffu)) + v2;
    float h3 = bf2f((unsigned short)(hv.y >> 16)) + v3;
    float h4 = bf2f((unsigned short)(hv.z & 0xffffu)) + v4;
    float h5 = bf2f((unsigned short)(hv.z >> 16)) + v5;
    float h6 = bf2f((unsigned short)(hv.w & 0xffffu)) + v6;
    float h7 = bf2f((unsigned short)(hv.w >> 16)) + v7;
    uint4 hp;
    hp.x = pack2(h0, h1); hp.y = pack2(h2, h3);
    hp.z = pack2(h4, h5); hp.w = pack2(h6, h7);
    ((uint4*)hb)[i] = hp;
    if (head) {
        float4 wn0 = *(const float4*)(nW + kb);
        float4 wn1 = *(const float4*)(nW + kb + 4);
        float4 wa0 = *(const float4*)(eW + kb);
        float4 wa1 = *(const float4*)(eW + kb + 4);
        float4 wb0 = *(const float4*)(eW + 128 + kb);
        float4 wb1 = *(const float4*)(eW + 128 + kb + 4);
        float pn = h0 * wn0.x + h1 * wn0.y + h2 * wn0.z + h3 * wn0.w +
                   h4 * wn1.x + h5 * wn1.y + h6 * wn1.z + h7 * wn1.w;
        float pa = h0 * wa0.x + h1 * wa0.y + h2 * wa0.z + h3 * wa0.w +
                   h4 * wa1.x + h5 * wa1.y + h6 * wa1.z + h7 * wa1.w;
        float pb = h0 * wb0.x + h1 * wb0.y + h2 * wb0.z + h3 * wb0.w +
                   h4 * wb1.x + h5 * wb1.y + h6 * wb1.z + h7 * wb1.w;
#pragma unroll
        for (int off = 1; off < 16; off <<= 1) {
            pn += __shfl_xor(pn, off);
            pa += __shfl_xor(pa, off);
            pb += __shfl_xor(pb, off);
        }
        if ((threadIdx.x & 15) == 0) {
            int gr = i >> 4;
            float nk = 1.f / (1.f + expf(-(pn + nb[0])));
            out[gr] = nk;
            int g = batch[gr];
            float* base = nsc + (size_t)(blockIdx.x & 7) * 8192;
            atomicAdd(&base[g], nk);
            atomicAdd(&base[4096 + g], 1.0f - nk);
            p[gr] = pa;
            q[gr] = pb;
        }
    }
}

// ------------- edge head: LDS-binned seg sums, zero global atomics.
// 512 grid-stride blocks; per-block bins flushed to esc[bid][8192]
__global__ __launch_bounds__(256) void k_edge_out(
    const int* __restrict__ ei, const int* __restrict__ batch,
    const float* __restrict__ p, const float* __restrict__ q,
    const float* __restrict__ eb, float* __restrict__ out,
    float* __restrict__ esc) {
    __shared__ float bins[8192];  // [2][4096] = 32 KB
    for (int i = threadIdx.x; i < 8192; i += 256) bins[i] = 0.f;
    __syncthreads();
    float ebv = eb[0];
    for (int e = blockIdx.x * 256 + threadIdx.x; e < N_EDGES; e += EOUT_BLK * 256) {
        int r = ei[e], c = ei[N_EDGES + e];
        float ek = 1.f / (1.f + expf(-(p[r] + q[c] + ebv)));
        out[N_NODES + e] = ek;
        int g = batch[r];
        atomicAdd(&bins[g], ek);
        atomicAdd(&bins[4096 + g], 1.0f - ek);
    }
    __syncthreads();
    float* dst = esc + (size_t)blockIdx.x * 8192;
    for (int i = threadIdx.x; i < 8192; i += 256) dst[i] = bins[i];
}

// ------------- reduce the scratch copies into the 4 output segments
__global__ void k_seg_reduce(const float* __restrict__ nsc, const float* __restrict__ esc,
                             float* __restrict__ out) {
    int i = blockIdx.x * 256 + threadIdx.x;   // 0..16383
    if (i >= 16384) return;
    float s = 1e-8f;
    if (i < 8192) {
#pragma unroll
        for (int c = 0; c < 8; ++c) s += nsc[c * 8192 + i];
    } else {
        int j = i - 8192;
        for (int c = 0; c < EOUT_BLK; ++c) s += esc[(size_t)c * 8192 + j];
    }
    out[N_NODES + N_EDGES + i] = s;
}

extern "C" void kernel_launch(void* const* d_in, const int* in_sizes, int n_in,
                              void* d_out, int out_size, void* d_ws, size_t ws_size,
                              hipStream_t stream) {
    const int*   x     = (const int*)d_in[0];
    const int*   ei    = (const int*)d_in[1];
    const int*   ea    = (const int*)d_in[2];
    const int*   batch = (const int*)d_in[3];
    const float* at    = (const float*)d_in[4];
    const float* bt    = (const float*)d_in[5];
    const float* eps   = (const float*)d_in[6];
    const float* W1    = (const float*)d_in[7];
    const float* b1    = (const float*)d_in[8];
    const float* bn1g  = (const float*)d_in[9];
    const float* bn1b  = (const float*)d_in[10];
    const float* W2    = (const float*)d_in[11];
    const float* b2    = (const float*)d_in[12];
    const float* obng  = (const float*)d_in[13];
    const float* obnb  = (const float*)d_in[14];
    const float* nW    = (const float*)d_in[15];
    const float* nb    = (const float*)d_in[16];
    const float* eW    = (const float*)d_in[17];
    const float* eb    = (const float*)d_in[18];
    float* out = (float*)d_out;

    float* ws    = (float*)d_ws;
    float* stats = ws;                       // 3 layers x 16 copies x 768
    float* sf    = stats + 3 * 16 * 768;     // scale1/shift1/scale2/shift2 (768)
    float* p     = sf + 768;                 // N
    float* q     = p + N_NODES;              // N
    float* nsc   = q + N_NODES;              // 8*8192 node seg scratch
    float* esc   = nsc + 8 * 8192;           // EOUT_BLK*8192 edge seg scratch (16 MB)
    unsigned short* hb  = (unsigned short*)(esc + (size_t)EOUT_BLK * 8192);  // N*128 bf16
    unsigned short* zub = hb + 12800000;     // N*128 bf16: z (gemm1 in), then u
    unsigned short* tb  = zub + 12800000;    // N*256 bf16
    unsigned short* Bp1 = tb + 25600000;     // 3*128*256 bf16
    unsigned short* Bp2 = Bp1 + 3 * 32768;   // 3*256*128 bf16
    unsigned short* ct  = Bp2 + 3 * 32768;   // 3*512*128 bf16 combined bond
    int* rowptr  = (int*)(ct + 3 * 65536);   // N+1
    int* cursor  = rowptr + N_NODES + 1;     // N (counts, then cursors)
    int* csr_row = cursor + N_NODES;         // E
    int* csr_attr = csr_row + N_EDGES;       // E
    int* bsum    = csr_attr + N_EDGES;       // SCAN_NBLK
    // per-layer stats: sl = stats + l*16*768; copy c at sl + c*768:
    //   [sum256][sq256][osum128@512][osq128@640]

    hipMemsetAsync(stats, 0, 3 * 16 * 768 * sizeof(float), stream);
    hipMemsetAsync(nsc, 0, 8 * 8192 * sizeof(float), stream);
    hipMemsetAsync(cursor, 0, N_NODES * sizeof(int), stream);
    k_atom_encode<<<50000, 256, 0, stream>>>(x, at, hb);
    k_convw<<<768, 256, 0, stream>>>(W1, W2, Bp1, Bp2);
    k_bondc<<<768, 256, 0, stream>>>(bt, ct);

    // CSR of edges grouped by destination (col) — parallel 3-phase scan
    k_hist<<<2344, 256, 0, stream>>>(ei, cursor);
    k_scan_partial<<<SCAN_NBLK, 256, 0, stream>>>(cursor, bsum);
    k_scan_bsum<<<1, 256, 0, stream>>>(bsum, rowptr);
    k_scan_final<<<SCAN_NBLK, 512, 0, stream>>>(bsum, cursor, rowptr);
    k_fill<<<2344, 256, 0, stream>>>(ei, ea, cursor, csr_row, csr_attr);

    for (int l = 0; l < 3; ++l) {
        float* sl = stats + (size_t)l * 16 * 768;
        k_gather<<<25000, 256, 0, stream>>>(hb, csr_row, csr_attr, rowptr,
                                            ct + (size_t)l * 65536, eps, l, zub);
        k_gemm1<<<1563, 256, 0, stream>>>(zub, Bp1 + (size_t)l * 32768, b1 + l * 256, tb, sl);
        k_bnfin<<<1, 256, 0, stream>>>(sl, 0, 256, bn1g + l * 256, bn1b + l * 256,
                                       sf, sf + 256);
        k_gemm2<<<1563, 256, 0, stream>>>(tb, Bp2 + (size_t)l * 32768, sf, sf + 256,
                                          b2 + l * 128, zub, sl);
        k_bnfin<<<1, 128, 0, stream>>>(sl, 512, 128, obng + l * 128, obnb + l * 128,
                                       sf + 512, sf + 640);
        k_update_h<<<6250, 256, 0, stream>>>(hb, zub, sf + 512, sf + 640,
                                             (l < 2) ? 1 : 0, (l == 2) ? 1 : 0,
                                             batch, nW, nb, eW, out, p, q, nsc);
    }

    k_edge_out<<<EOUT_BLK, 256, 0, stream>>>(ei, batch, p, q, eb, out, esc);
    k_seg_reduce<<<64, 256, 0, stream>>>(nsc, esc, out);
}

// Round 12
// 543.243 us; speedup vs baseline: 6.3884x; 1.0156x over previous
//
#include <hip/hip_runtime.h>
#include <math.h>

#define N_NODES 100000
#define N_EDGES 600000
#define N_GRAPHS 4096
#define SCAN_CHUNK 512
#define SCAN_NBLK 196   // ceil(100000/512)
#define EOUT_BLK 512    // edge_out grid (LDS-binned, scratch copies)

typedef __attribute__((ext_vector_type(8))) short short8v;   // 8 bf16 (4 VGPR)
typedef __attribute__((ext_vector_type(4))) float f32x4;

// fp32 pair -> packed bf16 (RNE) via the HW instruction
__device__ __forceinline__ unsigned int pack2(float a, float b) {
    unsigned int r;
    asm("v_cvt_pk_bf16_f32 %0, %1, %2" : "=v"(r) : "v"(a), "v"(b));
    return r;
}
__device__ __forceinline__ unsigned short bf16_rne(float f) {
    unsigned int r;
    asm("v_cvt_pk_bf16_f32 %0, %1, %2" : "=v"(r) : "v"(f), "v"(f));
    return (unsigned short)r;
}
__device__ __forceinline__ float bf2f(unsigned short u) {
    return __uint_as_float(((unsigned int)u) << 16);
}

// ------------------------------------------- atom encoder (bf16 h only)
__global__ void k_atom_encode(const int* __restrict__ x, const float* __restrict__ at,
                              unsigned short* __restrict__ hb) {
    int n = blockIdx.x * 2 + (threadIdx.x >> 7);
    int d = threadIdx.x & 127;
    if (n >= N_NODES) return;
    const int* xr = x + n * 9;
    float s = 0.f;
#pragma unroll
    for (int f = 0; f < 9; ++f) {
        int v = xr[f];
        s += at[(f * 100 + v) * 128 + d];
    }
    hb[(size_t)n * 128 + d] = bf16_rne(s);
}

// --------- combined bond table: ct[l][idx][d] = bf16(sum of 3 table rows)
__global__ void k_bondc(const float* __restrict__ bt, unsigned short* __restrict__ ct) {
    int idx = blockIdx.x * 256 + threadIdx.x;
    if (idx >= 3 * 512 * 128) return;
    int d = idx & 127;
    int c = (idx >> 7) & 511;
    int l = idx >> 16;
    const float* base = bt + (size_t)l * 3072;
    float v = base[(c >> 6) * 128 + d] + base[1024 + ((c >> 3) & 7) * 128 + d] +
              base[2048 + (c & 7) * 128 + d];
    ct[idx] = bf16_rne(v);
}

// --------------------------- CSR build (once)
__global__ void k_hist(const int* __restrict__ ei, int* __restrict__ cnt) {
    int e = blockIdx.x * 256 + threadIdx.x;
    if (e < N_EDGES) atomicAdd(&cnt[ei[N_EDGES + e]], 1);
}

__global__ void k_scan_partial(const int* __restrict__ cnt, int* __restrict__ bsum) {
    __shared__ int ls[256];
    int base = blockIdx.x * SCAN_CHUNK;
    int t = threadIdx.x;
    int s = 0;
    for (int i = base + t; i < base + SCAN_CHUNK && i < N_NODES; i += 256) s += cnt[i];
    ls[t] = s;
    __syncthreads();
    for (int off = 128; off; off >>= 1) {
        if (t < off) ls[t] += ls[t + off];
        __syncthreads();
    }
    if (t == 0) bsum[blockIdx.x] = ls[0];
}

__global__ void k_scan_bsum(int* __restrict__ bsum, int* __restrict__ rowptr) {
    __shared__ int ls[256];
    int t = threadIdx.x;
    int v = (t < SCAN_NBLK) ? bsum[t] : 0;
    ls[t] = v;
    __syncthreads();
    for (int off = 1; off < 256; off <<= 1) {
        int x = (t >= off) ? ls[t - off] : 0;
        __syncthreads();
        ls[t] += x;
        __syncthreads();
    }
    if (t < SCAN_NBLK) bsum[t] = ls[t] - v;  // exclusive prefix
    if (t == 255) rowptr[N_NODES] = ls[255];
}

__global__ __launch_bounds__(512) void k_scan_final(const int* __restrict__ bsum,
                                                    int* __restrict__ cnt_cursor,
                                                    int* __restrict__ rowptr) {
    __shared__ int ls[512];
    int base = blockIdx.x * SCAN_CHUNK;
    int t = threadIdx.x;
    int i = base + t;
    int v = (i < N_NODES) ? cnt_cursor[i] : 0;
    ls[t] = v;
    __syncthreads();
    for (int off = 1; off < 512; off <<= 1) {
        int x = (t >= off) ? ls[t - off] : 0;
        __syncthreads();
        ls[t] += x;
        __syncthreads();
    }
    if (i < N_NODES) {
        int excl = bsum[blockIdx.x] + ls[t] - v;
        rowptr[i] = excl;
        cnt_cursor[i] = excl;
    }
}

// fill CSR-ordered source-row + combined-attr-index arrays
__global__ void k_fill(const int* __restrict__ ei, const int* __restrict__ ea,
                       int* __restrict__ cursor,
                       int* __restrict__ csr_row, int* __restrict__ csr_attr) {
    int e = blockIdx.x * 256 + threadIdx.x;
    if (e < N_EDGES) {
        int c = ei[N_EDGES + e];
        int pos = atomicAdd(&cursor[c], 1);
        csr_row[pos] = ei[e];
        csr_attr[pos] = ea[e * 3] * 64 + ea[e * 3 + 1] * 8 + ea[e * 3 + 2];
    }
}

// ---------------- weight pre-swizzle: fp32 -> bf16 in MFMA B-fragment layout
__global__ void k_convw(const float* __restrict__ W1, const float* __restrict__ W2,
                        unsigned short* __restrict__ Bp1, unsigned short* __restrict__ Bp2) {
    int idx = blockIdx.x * 256 + threadIdx.x;
    if (idx < 3 * 128 * 256) {
        int l = idx >> 15, r = idx & 32767;
        int k = r >> 8, j = r & 255;
        float v = W1[(size_t)l * 32768 + k * 256 + j];
        Bp1[(size_t)l * 32768 + (((k >> 5) * 4 + ((k >> 3) & 3)) * 256 + j) * 8 + (k & 7)] =
            bf16_rne(v);
    } else if (idx < 6 * 128 * 256) {
        int t = idx - 98304;
        int l = t >> 15, r = t & 32767;
        int k = r >> 7, j = r & 127;
        float v = W2[(size_t)l * 32768 + k * 128 + j];
        Bp2[(size_t)l * 32768 + (((k >> 5) * 4 + ((k >> 3) & 3)) * 128 + j) * 8 + (k & 7)] =
            bf16_rne(v);
    }
}

// ---------------------------- gather-aggregate: z = (1+eps)*h + sum relu(msg)
// wave per node; predicated 8-deep rounds: 16 loads in flight, no serial tail
__global__ void k_gather(const unsigned short* __restrict__ hb,
                         const int* __restrict__ csr_row, const int* __restrict__ csr_attr,
                         const int* __restrict__ rowptr, const unsigned short* __restrict__ ct,
                         const float* __restrict__ eps, int l,
                         unsigned short* __restrict__ zb) {
    int lane = threadIdx.x & 63;
    int n = blockIdx.x * 4 + (threadIdx.x >> 6);
    if (n >= N_NODES) return;
    int i0 = rowptr[n], i1 = rowptr[n + 1];
    float ax = 0.f, ay = 0.f;
    for (int base = i0; base < i1; base += 8) {
        int rr[8], qq[8];
#pragma unroll
        for (int k = 0; k < 8; ++k) {
            int idx = min(base + k, i1 - 1);
            rr[k] = csr_row[idx];
            qq[k] = csr_attr[idx];
        }
        unsigned int u[8], c[8];
#pragma unroll
        for (int k = 0; k < 8; ++k) {
            u[k] = ((const unsigned int*)(hb + (size_t)rr[k] * 128))[lane];
            c[k] = ((const unsigned int*)(ct + qq[k] * 128))[lane];
        }
#pragma unroll
        for (int k = 0; k < 8; ++k) {
            float mk = (base + k < i1) ? 1.f : 0.f;
            float vx = fmaxf(bf2f((unsigned short)(u[k] & 0xffffu)) +
                             bf2f((unsigned short)(c[k] & 0xffffu)), 0.f);
            float vy = fmaxf(bf2f((unsigned short)(u[k] >> 16)) +
                             bf2f((unsigned short)(c[k] >> 16)), 0.f);
            ax = fmaf(mk, vx, ax);
            ay = fmaf(mk, vy, ay);
        }
    }
    float el = 1.0f + eps[l];
    unsigned int un = ((const unsigned int*)(hb + (size_t)n * 128))[lane];
    float zx = fmaf(el, bf2f((unsigned short)(un & 0xffffu)), ax);
    float zy = fmaf(el, bf2f((unsigned short)(un >> 16)), ay);
    ((unsigned int*)(zb + (size_t)n * 128))[lane] = pack2(zx, zy);
}

// --------------------- GEMM1 (MFMA, swapped operands -> (z@W1)^T fragments)
// stats partials go to 16 spread copies (sl[(bid&15)*768 + ...])
__global__ __launch_bounds__(256) void k_gemm1(
    const unsigned short* __restrict__ zb, const unsigned short* __restrict__ Bp,
    const float* __restrict__ bias, unsigned short* __restrict__ tb,
    float* __restrict__ sl) {
    __shared__ unsigned short As[8192] __attribute__((aligned(16)));  // 16 KB
    int n0 = blockIdx.x * 64;
#pragma unroll
    for (int s = 0; s < 4; ++s) {
        int i = threadIdx.x + s * 256;            // 16B unit; 64 rows x 16 units
        int r = i >> 4, k8 = i & 15;
        short8v v = (short8v)(short)0;
        if (n0 + r < N_NODES) v = ((const short8v*)(zb + (size_t)(n0 + r) * 128))[k8];
        int frag = (r >> 4) * 16 + k8;
        int off = (frag * 128 + (r & 15) * 8) ^ ((k8 & 7) << 3);
        *(short8v*)(&As[off]) = v;
    }
    __syncthreads();
    int lane = threadIdx.x & 63;
    int wid = threadIdx.x >> 6;
    int l15 = lane & 15, kg = lane >> 4;
    int colbase = wid * 64;
    f32x4 acc[4][4];  // [rb][cf]
#pragma unroll
    for (int a = 0; a < 4; ++a)
#pragma unroll
        for (int b = 0; b < 4; ++b) acc[a][b] = (f32x4)(0.f);
#pragma unroll
    for (int k4 = 0; k4 < 4; ++k4) {
        short8v af[4], bf[4];
#pragma unroll
        for (int rb = 0; rb < 4; ++rb)
            af[rb] = *(const short8v*)(&As[((rb * 16 + k4 * 4 + kg) * 128 + l15 * 8) ^
                                           (((k4 * 4 + kg) & 7) << 3)]);
#pragma unroll
        for (int cf = 0; cf < 4; ++cf)
            bf[cf] = *(const short8v*)(Bp + ((k4 * 4 + kg) * 256 + colbase + cf * 16 + l15) * 8);
#pragma unroll
        for (int rb = 0; rb < 4; ++rb)
#pragma unroll
            for (int cf = 0; cf < 4; ++cf)
                acc[rb][cf] = __builtin_amdgcn_mfma_f32_16x16x32_bf16(bf[cf], af[rb],
                                                                      acc[rb][cf], 0, 0, 0);
    }
    float s4[4][4], q4[4][4];
#pragma unroll
    for (int cf = 0; cf < 4; ++cf)
#pragma unroll
        for (int r = 0; r < 4; ++r) { s4[cf][r] = 0.f; q4[cf][r] = 0.f; }
#pragma unroll
    for (int cf = 0; cf < 4; ++cf) {
        int j0 = colbase + cf * 16 + kg * 4;
        float4 b4 = *(const float4*)(bias + j0);
#pragma unroll
        for (int rb = 0; rb < 4; ++rb) {
            int gr = n0 + rb * 16 + l15;
            if (gr < N_NODES) {
                float v0 = acc[rb][cf][0] + b4.x;
                float v1 = acc[rb][cf][1] + b4.y;
                float v2 = acc[rb][cf][2] + b4.z;
                float v3 = acc[rb][cf][3] + b4.w;
                uint2 st;
                st.x = pack2(v0, v1);
                st.y = pack2(v2, v3);
                *(uint2*)(tb + (size_t)gr * 256 + j0) = st;
                s4[cf][0] += v0; q4[cf][0] += v0 * v0;
                s4[cf][1] += v1; q4[cf][1] += v1 * v1;
                s4[cf][2] += v2; q4[cf][2] += v2 * v2;
                s4[cf][3] += v3; q4[cf][3] += v3 * v3;
            }
        }
    }
    float* stats = sl + (size_t)(blockIdx.x & 15) * 768;
    float* part = (float*)As;
    __syncthreads();
#pragma unroll
    for (int cf = 0; cf < 4; ++cf)
#pragma unroll
        for (int r = 0; r < 4; ++r)
            part[(colbase + cf * 16 + kg * 4 + r) * 16 + l15] = s4[cf][r];
    __syncthreads();
    {
        int j = threadIdx.x;
        const float4* pr = (const float4*)(part + j * 16);
        float4 a0 = pr[0], a1 = pr[1], a2 = pr[2], a3 = pr[3];
        float s = a0.x + a0.y + a0.z + a0.w + a1.x + a1.y + a1.z + a1.w +
                  a2.x + a2.y + a2.z + a2.w + a3.x + a3.y + a3.z + a3.w;
        atomicAdd(&stats[j], s);
    }
    __syncthreads();
#pragma unroll
    for (int cf = 0; cf < 4; ++cf)
#pragma unroll
        for (int r = 0; r < 4; ++r)
            part[(colbase + cf * 16 + kg * 4 + r) * 16 + l15] = q4[cf][r];
    __syncthreads();
    {
        int j = threadIdx.x;
        const float4* pr = (const float4*)(part + j * 16);
        float4 a0 = pr[0], a1 = pr[1], a2 = pr[2], a3 = pr[3];
        float s = a0.x + a0.y + a0.z + a0.w + a1.x + a1.y + a1.z + a1.w +
                  a2.x + a2.y + a2.z + a2.w + a3.x + a3.y + a3.z + a3.w;
        atomicAdd(&stats[256 + j], s);
    }
}

// ------- GEMM2 (MFMA, swapped): u = relu(BN1(t))@W2 + b2, fused BN2 stats
// BN1 finalize done in-block: sum 16 spread copies -> LDS -> regs (no k_bnfin)
__global__ __launch_bounds__(256) void k_gemm2(
    const unsigned short* __restrict__ tb, const unsigned short* __restrict__ Bp,
    const float* __restrict__ sl, const float* __restrict__ g1,
    const float* __restrict__ b1g,
    const float* __restrict__ bias, unsigned short* __restrict__ ub,
    float* __restrict__ slw) {
    __shared__ unsigned short As[16384] __attribute__((aligned(16)));  // 32 KB
    int n0 = blockIdx.x * 64;
    int tid = threadIdx.x;
    // ---- BN1 finalize into As-as-float[512], then to regs
    {
        float* sfin = (float*)As;
        float s = 0.f, q = 0.f;
#pragma unroll
        for (int cc = 0; cc < 16; ++cc) {
            s += sl[cc * 768 + tid];
            q += sl[cc * 768 + 256 + tid];
        }
        float m = s * (1.0f / N_NODES);
        float var = q * (1.0f / N_NODES) - m * m;
        float sc = g1[tid] / sqrtf(var + 1e-5f);
        sfin[tid] = sc;
        sfin[256 + tid] = b1g[tid] - m * sc;
    }
    __syncthreads();
    int kb = (tid & 31) * 8;
    float scr[8], shr[8];
    {
        const float* sfin = (const float*)As;
#pragma unroll
        for (int j = 0; j < 8; ++j) {
            scr[j] = sfin[kb + j];
            shr[j] = sfin[256 + kb + j];
        }
    }
    __syncthreads();
#pragma unroll
    for (int s = 0; s < 8; ++s) {
        int i = tid + s * 256;                    // 16B unit; 64 rows x 32 units
        int r = i >> 5, k8 = i & 31;
        short8v v = (short8v)(short)0;
        if (n0 + r < N_NODES) v = ((const short8v*)(tb + (size_t)(n0 + r) * 256))[k8];
        float f0 = fmaxf(fmaf(scr[0], bf2f((unsigned short)v[0]), shr[0]), 0.f);
        float f1 = fmaxf(fmaf(scr[1], bf2f((unsigned short)v[1]), shr[1]), 0.f);
        float f2 = fmaxf(fmaf(scr[2], bf2f((unsigned short)v[2]), shr[2]), 0.f);
        float f3 = fmaxf(fmaf(scr[3], bf2f((unsigned short)v[3]), shr[3]), 0.f);
        float f4 = fmaxf(fmaf(scr[4], bf2f((unsigned short)v[4]), shr[4]), 0.f);
        float f5 = fmaxf(fmaf(scr[5], bf2f((unsigned short)v[5]), shr[5]), 0.f);
        float f6 = fmaxf(fmaf(scr[6], bf2f((unsigned short)v[6]), shr[6]), 0.f);
        float f7 = fmaxf(fmaf(scr[7], bf2f((unsigned short)v[7]), shr[7]), 0.f);
        uint4 ov;
        ov.x = pack2(f0, f1); ov.y = pack2(f2, f3);
        ov.z = pack2(f4, f5); ov.w = pack2(f6, f7);
        int frag = (r >> 4) * 32 + k8;
        int off = (frag * 128 + (r & 15) * 8) ^ ((k8 & 7) << 3);
        *(uint4*)(&As[off]) = ov;
    }
    __syncthreads();
    int lane = threadIdx.x & 63;
    int wid = threadIdx.x >> 6;
    int l15 = lane & 15, kg = lane >> 4;
    int colbase = wid * 32;
    f32x4 acc[4][2];  // [rb][cf]
#pragma unroll
    for (int a = 0; a < 4; ++a) {
        acc[a][0] = (f32x4)(0.f);
        acc[a][1] = (f32x4)(0.f);
    }
#pragma unroll
    for (int k4 = 0; k4 < 8; ++k4) {
        short8v af[4], bf[2];
#pragma unroll
        for (int rb = 0; rb < 4; ++rb)
            af[rb] = *(const short8v*)(&As[((rb * 32 + k4 * 4 + kg) * 128 + l15 * 8) ^
                                           (((k4 * 4 + kg) & 7) << 3)]);
#pragma unroll
        for (int cf = 0; cf < 2; ++cf)
            bf[cf] = *(const short8v*)(Bp + ((k4 * 4 + kg) * 128 + colbase + cf * 16 + l15) * 8);
#pragma unroll
        for (int rb = 0; rb < 4; ++rb)
#pragma unroll
            for (int cf = 0; cf < 2; ++cf)
                acc[rb][cf] = __builtin_amdgcn_mfma_f32_16x16x32_bf16(bf[cf], af[rb],
                                                                      acc[rb][cf], 0, 0, 0);
    }
    float s4[2][4], q4[2][4];
#pragma unroll
    for (int cf = 0; cf < 2; ++cf)
#pragma unroll
        for (int r = 0; r < 4; ++r) { s4[cf][r] = 0.f; q4[cf][r] = 0.f; }
#pragma unroll
    for (int cf = 0; cf < 2; ++cf) {
        int j0 = colbase + cf * 16 + kg * 4;
        float4 b4 = *(const float4*)(bias + j0);
#pragma unroll
        for (int rb = 0; rb < 4; ++rb) {
            int gr = n0 + rb * 16 + l15;
            if (gr < N_NODES) {
                float v0 = acc[rb][cf][0] + b4.x;
                float v1 = acc[rb][cf][1] + b4.y;
                float v2 = acc[rb][cf][2] + b4.z;
                float v3 = acc[rb][cf][3] + b4.w;
                uint2 st;
                st.x = pack2(v0, v1);
                st.y = pack2(v2, v3);
                *(uint2*)(ub + (size_t)gr * 128 + j0) = st;
                s4[cf][0] += v0; q4[cf][0] += v0 * v0;
                s4[cf][1] += v1; q4[cf][1] += v1 * v1;
                s4[cf][2] += v2; q4[cf][2] += v2 * v2;
                s4[cf][3] += v3; q4[cf][3] += v3 * v3;
            }
        }
    }
    float* stats = slw + (size_t)(blockIdx.x & 15) * 768;
    float* part = (float*)As;  // need 128*16 floats = 8 KB
    __syncthreads();
#pragma unroll
    for (int cf = 0; cf < 2; ++cf)
#pragma unroll
        for (int r = 0; r < 4; ++r)
            part[(colbase + cf * 16 + kg * 4 + r) * 16 + l15] = s4[cf][r];
    __syncthreads();
    if (tid < 128) {
        const float4* pr = (const float4*)(part + tid * 16);
        float4 a0 = pr[0], a1 = pr[1], a2 = pr[2], a3 = pr[3];
        float s = a0.x + a0.y + a0.z + a0.w + a1.x + a1.y + a1.z + a1.w +
                  a2.x + a2.y + a2.z + a2.w + a3.x + a3.y + a3.z + a3.w;
        atomicAdd(&stats[512 + tid], s);
    }
    __syncthreads();
#pragma unroll
    for (int cf = 0; cf < 2; ++cf)
#pragma unroll
        for (int r = 0; r < 4; ++r)
            part[(colbase + cf * 16 + kg * 4 + r) * 16 + l15] = q4[cf][r];
    __syncthreads();
    if (tid < 128) {
        const float4* pr = (const float4*)(part + tid * 16);
        float4 a0 = pr[0], a1 = pr[1], a2 = pr[2], a3 = pr[3];
        float s = a0.x + a0.y + a0.z + a0.w + a1.x + a1.y + a1.z + a1.w +
                  a2.x + a2.y + a2.z + a2.w + a3.x + a3.y + a3.z + a3.w;
        atomicAdd(&stats[640 + tid], s);
    }
}

// --------- hb += maybe_relu(BN2(u)); BN2 finalize in-block (16 spread copies
// -> LDS). Last layer: fused node head from pre-rounding fp32 values.
__global__ void k_update_h(unsigned short* __restrict__ hb,
                           const unsigned short* __restrict__ ub,
                           const float* __restrict__ sl,
                           const float* __restrict__ g2, const float* __restrict__ b2g,
                           int relu, int head,
                           const int* __restrict__ batch, const float* __restrict__ nW,
                           const float* __restrict__ nb, const float* __restrict__ eW,
                           float* __restrict__ out, float* __restrict__ p,
                           float* __restrict__ q, float* __restrict__ nsc) {
    __shared__ float sfin[256];
    if (threadIdx.x < 128) {
        int j = threadIdx.x;
        float s = 0.f, qq = 0.f;
#pragma unroll
        for (int cc = 0; cc < 16; ++cc) {
            s += sl[cc * 768 + 512 + j];
            qq += sl[cc * 768 + 640 + j];
        }
        float m = s * (1.0f / N_NODES);
        float var = qq * (1.0f / N_NODES) - m * m;
        float sc = g2[j] / sqrtf(var + 1e-5f);
        sfin[j] = sc;
        sfin[128 + j] = b2g[j] - m * sc;
    }
    __syncthreads();
    int kb = (threadIdx.x & 15) * 8;
    float scr[8], shr[8];
#pragma unroll
    for (int j = 0; j < 8; ++j) {
        scr[j] = sfin[kb + j];
        shr[j] = sfin[128 + kb + j];
    }
    int i = blockIdx.x * 256 + threadIdx.x;  // 8-elem unit; total N*16 = 1.6M
    uint4 uv = ((const uint4*)ub)[i];
    uint4 hv = ((const uint4*)hb)[i];
    float v0 = fmaf(scr[0], bf2f((unsigned short)(uv.x & 0xffffu)), shr[0]);
    float v1 = fmaf(scr[1], bf2f((unsigned short)(uv.x >> 16)), shr[1]);
    float v2 = fmaf(scr[2], bf2f((unsigned short)(uv.y & 0xffffu)), shr[2]);
    float v3 = fmaf(scr[3], bf2f((unsigned short)(uv.y >> 16)), shr[3]);
    float v4 = fmaf(scr[4], bf2f((unsigned short)(uv.z & 0xffffu)), shr[4]);
    float v5 = fmaf(scr[5], bf2f((unsigned short)(uv.z >> 16)), shr[5]);
    float v6 = fmaf(scr[6], bf2f((unsigned short)(uv.w & 0xffffu)), shr[6]);
    float v7 = fmaf(scr[7], bf2f((unsigned short)(uv.w >> 16)), shr[7]);
    if (relu) {
        v0 = fmaxf(v0, 0.f); v1 = fmaxf(v1, 0.f); v2 = fmaxf(v2, 0.f); v3 = fmaxf(v3, 0.f);
        v4 = fmaxf(v4, 0.f); v5 = fmaxf(v5, 0.f); v6 = fmaxf(v6, 0.f); v7 = fmaxf(v7, 0.f);
    }
    float h0 = bf2f((unsigned short)(hv.x & 0xffffu)) + v0;
    float h1 = bf2f((unsigned short)(hv.x >> 16)) + v1;
    float h2 = bf2f((unsigned short)(hv.y & 0xffffu)) + v2;
    float h3 = bf2f((unsigned short)(hv.y >> 16)) + v3;
    float h4 = bf2f((unsigned short)(hv.z & 0xffffu)) + v4;
    float h5 = bf2f((unsigned short)(hv.z >> 16)) + v5;
    float h6 = bf2f((unsigned short)(hv.w & 0xffffu)) + v6;
    float h7 = bf2f((unsigned short)(hv.w >> 16)) + v7;
    uint4 hp;
    hp.x = pack2(h0, h1); hp.y = pack2(h2, h3);
    hp.z = pack2(h4, h5); hp.w = pack2(h6, h7);
    ((uint4*)hb)[i] = hp;
    if (head) {
        float4 wn0 = *(const float4*)(nW + kb);
        float4 wn1 = *(const float4*)(nW + kb + 4);
        float4 wa0 = *(const float4*)(eW + kb);
        float4 wa1 = *(const float4*)(eW + kb + 4);
        float4 wb0 = *(const float4*)(eW + 128 + kb);
        float4 wb1 = *(const float4*)(eW + 128 + kb + 4);
        float pn = h0 * wn0.x + h1 * wn0.y + h2 * wn0.z + h3 * wn0.w +
                   h4 * wn1.x + h5 * wn1.y + h6 * wn1.z + h7 * wn1.w;
        float pa = h0 * wa0.x + h1 * wa0.y + h2 * wa0.z + h3 * wa0.w +
                   h4 * wa1.x + h5 * wa1.y + h6 * wa1.z + h7 * wa1.w;
        float pb = h0 * wb0.x + h1 * wb0.y + h2 * wb0.z + h3 * wb0.w +
                   h4 * wb1.x + h5 * wb1.y + h6 * wb1.z + h7 * wb1.w;
#pragma unroll
        for (int off = 1; off < 16; off <<= 1) {
            pn += __shfl_xor(pn, off);
            pa += __shfl_xor(pa, off);
            pb += __shfl_xor(pb, off);
        }
        if ((threadIdx.x & 15) == 0) {
            int gr = i >> 4;
            float nk = 1.f / (1.f + expf(-(pn + nb[0])));
            out[gr] = nk;
            int g = batch[gr];
            float* base = nsc + (size_t)(blockIdx.x & 7) * 8192;
            atomicAdd(&base[g], nk);
            atomicAdd(&base[4096 + g], 1.0f - nk);
            p[gr] = pa;
            q[gr] = pb;
        }
    }
}

// ------------- edge head: LDS-binned seg sums, zero global atomics.
// 512 grid-stride blocks; per-block bins flushed to esc[bid][8192]
__global__ __launch_bounds__(256) void k_edge_out(
    const int* __restrict__ ei, const int* __restrict__ batch,
    const float* __restrict__ p, const float* __restrict__ q,
    const float* __restrict__ eb, float* __restrict__ out,
    float* __restrict__ esc) {
    __shared__ float bins[8192];  // [2][4096] = 32 KB
    for (int i = threadIdx.x; i < 8192; i += 256) bins[i] = 0.f;
    __syncthreads();
    float ebv = eb[0];
    for (int e = blockIdx.x * 256 + threadIdx.x; e < N_EDGES; e += EOUT_BLK * 256) {
        int r = ei[e], c = ei[N_EDGES + e];
        float ek = 1.f / (1.f + expf(-(p[r] + q[c] + ebv)));
        out[N_NODES + e] = ek;
        int g = batch[r];
        atomicAdd(&bins[g], ek);
        atomicAdd(&bins[4096 + g], 1.0f - ek);
    }
    __syncthreads();
    float* dst = esc + (size_t)blockIdx.x * 8192;
    for (int i = threadIdx.x; i < 8192; i += 256) dst[i] = bins[i];
}

// ------------- reduce the scratch copies into the 4 output segments
__global__ void k_seg_reduce(const float* __restrict__ nsc, const float* __restrict__ esc,
                             float* __restrict__ out) {
    int i = blockIdx.x * 256 + threadIdx.x;   // 0..16383
    if (i >= 16384) return;
    float s = 1e-8f;
    if (i < 8192) {
#pragma unroll
        for (int c = 0; c < 8; ++c) s += nsc[c * 8192 + i];
    } else {
        int j = i - 8192;
        for (int c = 0; c < EOUT_BLK; ++c) s += esc[(size_t)c * 8192 + j];
    }
    out[N_NODES + N_EDGES + i] = s;
}

extern "C" void kernel_launch(void* const* d_in, const int* in_sizes, int n_in,
                              void* d_out, int out_size, void* d_ws, size_t ws_size,
                              hipStream_t stream) {
    const int*   x     = (const int*)d_in[0];
    const int*   ei    = (const int*)d_in[1];
    const int*   ea    = (const int*)d_in[2];
    const int*   batch = (const int*)d_in[3];
    const float* at    = (const float*)d_in[4];
    const float* bt    = (const float*)d_in[5];
    const float* eps   = (const float*)d_in[6];
    const float* W1    = (const float*)d_in[7];
    const float* b1    = (const float*)d_in[8];
    const float* bn1g  = (const float*)d_in[9];
    const float* bn1b  = (const float*)d_in[10];
    const float* W2    = (const float*)d_in[11];
    const float* b2    = (const float*)d_in[12];
    const float* obng  = (const float*)d_in[13];
    const float* obnb  = (const float*)d_in[14];
    const float* nW    = (const float*)d_in[15];
    const float* nb    = (const float*)d_in[16];
    const float* eW    = (const float*)d_in[17];
    const float* eb    = (const float*)d_in[18];
    float* out = (float*)d_out;

    float* ws    = (float*)d_ws;
    float* stats = ws;                       // 3 layers x 16 copies x 768
    float* p     = stats + 3 * 16 * 768;     // N
    float* q     = p + N_NODES;              // N
    float* nsc   = q + N_NODES;              // 8*8192 node seg scratch
    float* esc   = nsc + 8 * 8192;           // EOUT_BLK*8192 edge seg scratch (16 MB)
    unsigned short* hb  = (unsigned short*)(esc + (size_t)EOUT_BLK * 8192);  // N*128 bf16
    unsigned short* zub = hb + 12800000;     // N*128 bf16: z (gemm1 in), then u
    unsigned short* tb  = zub + 12800000;    // N*256 bf16
    unsigned short* Bp1 = tb + 25600000;     // 3*128*256 bf16
    unsigned short* Bp2 = Bp1 + 3 * 32768;   // 3*256*128 bf16
    unsigned short* ct  = Bp2 + 3 * 32768;   // 3*512*128 bf16 combined bond
    int* rowptr  = (int*)(ct + 3 * 65536);   // N+1
    int* cursor  = rowptr + N_NODES + 1;     // N (counts, then cursors)
    int* csr_row = cursor + N_NODES;         // E
    int* csr_attr = csr_row + N_EDGES;       // E
    int* bsum    = csr_attr + N_EDGES;       // SCAN_NBLK
    // per-layer stats: sl = stats + l*16*768; copy c at sl + c*768:
    //   [sum256][sq256][osum128@512][osq128@640]

    hipMemsetAsync(stats, 0, 3 * 16 * 768 * sizeof(float), stream);
    hipMemsetAsync(nsc, 0, 8 * 8192 * sizeof(float), stream);
    hipMemsetAsync(cursor, 0, N_NODES * sizeof(int), stream);
    k_atom_encode<<<50000, 256, 0, stream>>>(x, at, hb);
    k_convw<<<768, 256, 0, stream>>>(W1, W2, Bp1, Bp2);
    k_bondc<<<768, 256, 0, stream>>>(bt, ct);

    // CSR of edges grouped by destination (col) — parallel 3-phase scan
    k_hist<<<2344, 256, 0, stream>>>(ei, cursor);
    k_scan_partial<<<SCAN_NBLK, 256, 0, stream>>>(cursor, bsum);
    k_scan_bsum<<<1, 256, 0, stream>>>(bsum, rowptr);
    k_scan_final<<<SCAN_NBLK, 512, 0, stream>>>(bsum, cursor, rowptr);
    k_fill<<<2344, 256, 0, stream>>>(ei, ea, cursor, csr_row, csr_attr);

    for (int l = 0; l < 3; ++l) {
        float* sl = stats + (size_t)l * 16 * 768;
        k_gather<<<25000, 256, 0, stream>>>(hb, csr_row, csr_attr, rowptr,
                                            ct + (size_t)l * 65536, eps, l, zub);
        k_gemm1<<<1563, 256, 0, stream>>>(zub, Bp1 + (size_t)l * 32768, b1 + l * 256, tb, sl);
        k_gemm2<<<1563, 256, 0, stream>>>(tb, Bp2 + (size_t)l * 32768, sl,
                                          bn1g + l * 256, bn1b + l * 256,
                                          b2 + l * 128, zub, sl);
        k_update_h<<<6250, 256, 0, stream>>>(hb, zub, sl, obng + l * 128, obnb + l * 128,
                                             (l < 2) ? 1 : 0, (l == 2) ? 1 : 0,
                                             batch, nW, nb, eW, out, p, q, nsc);
    }

    k_edge_out<<<EOUT_BLK, 256, 0, stream>>>(ei, batch, p, q, eb, out, esc);
    k_seg_reduce<<<64, 256, 0, stream>>>(nsc, esc, out);
}

// Round 13
// 513.689 us; speedup vs baseline: 6.7559x; 1.0575x over previous
//
#include <hip/hip_runtime.h>
#include <math.h>

#define N_NODES 100000
#define N_EDGES 600000
#define N_GRAPHS 4096
#define SCAN_CHUNK 512
#define SCAN_NBLK 196   // ceil(100000/512)
#define EOUT_BLK 512    // edge_out grid (LDS-binned, scratch copies)

typedef __attribute__((ext_vector_type(8))) short short8v;   // 8 bf16 (4 VGPR)
typedef __attribute__((ext_vector_type(4))) float f32x4;

// fp32 pair -> packed bf16 (RNE) via the HW instruction
__device__ __forceinline__ unsigned int pack2(float a, float b) {
    unsigned int r;
    asm("v_cvt_pk_bf16_f32 %0, %1, %2" : "=v"(r) : "v"(a), "v"(b));
    return r;
}
__device__ __forceinline__ unsigned short bf16_rne(float f) {
    unsigned int r;
    asm("v_cvt_pk_bf16_f32 %0, %1, %2" : "=v"(r) : "v"(f), "v"(f));
    return (unsigned short)r;
}
__device__ __forceinline__ float bf2f(unsigned short u) {
    return __uint_as_float(((unsigned int)u) << 16);
}

// ------------------------------------------- atom encoder (bf16 h only)
__global__ void k_atom_encode(const int* __restrict__ x, const float* __restrict__ at,
                              unsigned short* __restrict__ hb) {
    int n = blockIdx.x * 2 + (threadIdx.x >> 7);
    int d = threadIdx.x & 127;
    if (n >= N_NODES) return;
    const int* xr = x + n * 9;
    float s = 0.f;
#pragma unroll
    for (int f = 0; f < 9; ++f) {
        int v = xr[f];
        s += at[(f * 100 + v) * 128 + d];
    }
    hb[(size_t)n * 128 + d] = bf16_rne(s);
}

// --------- combined bond table: ct[l][idx][d] = bf16(sum of 3 table rows)
__global__ void k_bondc(const float* __restrict__ bt, unsigned short* __restrict__ ct) {
    int idx = blockIdx.x * 256 + threadIdx.x;
    if (idx >= 3 * 512 * 128) return;
    int d = idx & 127;
    int c = (idx >> 7) & 511;
    int l = idx >> 16;
    const float* base = bt + (size_t)l * 3072;
    float v = base[(c >> 6) * 128 + d] + base[1024 + ((c >> 3) & 7) * 128 + d] +
              base[2048 + (c & 7) * 128 + d];
    ct[idx] = bf16_rne(v);
}

// --------------------------- CSR build (once)
__global__ void k_hist(const int* __restrict__ ei, int* __restrict__ cnt) {
    int e = blockIdx.x * 256 + threadIdx.x;
    if (e < N_EDGES) atomicAdd(&cnt[ei[N_EDGES + e]], 1);
}

__global__ void k_scan_partial(const int* __restrict__ cnt, int* __restrict__ bsum) {
    __shared__ int ls[256];
    int base = blockIdx.x * SCAN_CHUNK;
    int t = threadIdx.x;
    int s = 0;
    for (int i = base + t; i < base + SCAN_CHUNK && i < N_NODES; i += 256) s += cnt[i];
    ls[t] = s;
    __syncthreads();
    for (int off = 128; off; off >>= 1) {
        if (t < off) ls[t] += ls[t + off];
        __syncthreads();
    }
    if (t == 0) bsum[blockIdx.x] = ls[0];
}

__global__ void k_scan_bsum(int* __restrict__ bsum, int* __restrict__ rowptr) {
    __shared__ int ls[256];
    int t = threadIdx.x;
    int v = (t < SCAN_NBLK) ? bsum[t] : 0;
    ls[t] = v;
    __syncthreads();
    for (int off = 1; off < 256; off <<= 1) {
        int x = (t >= off) ? ls[t - off] : 0;
        __syncthreads();
        ls[t] += x;
        __syncthreads();
    }
    if (t < SCAN_NBLK) bsum[t] = ls[t] - v;  // exclusive prefix
    if (t == 255) rowptr[N_NODES] = ls[255];
}

__global__ __launch_bounds__(512) void k_scan_final(const int* __restrict__ bsum,
                                                    int* __restrict__ cnt_cursor,
                                                    int* __restrict__ rowptr) {
    __shared__ int ls[512];
    int base = blockIdx.x * SCAN_CHUNK;
    int t = threadIdx.x;
    int i = base + t;
    int v = (i < N_NODES) ? cnt_cursor[i] : 0;
    ls[t] = v;
    __syncthreads();
    for (int off = 1; off < 512; off <<= 1) {
        int x = (t >= off) ? ls[t - off] : 0;
        __syncthreads();
        ls[t] += x;
        __syncthreads();
    }
    if (i < N_NODES) {
        int excl = bsum[blockIdx.x] + ls[t] - v;
        rowptr[i] = excl;
        cnt_cursor[i] = excl;
    }
}

// fill CSR-ordered packed (row<<9)|attr array — single index stream
__global__ void k_fill(const int* __restrict__ ei, const int* __restrict__ ea,
                       int* __restrict__ cursor, int* __restrict__ csr_pack) {
    int e = blockIdx.x * 256 + threadIdx.x;
    if (e < N_EDGES) {
        int c = ei[N_EDGES + e];
        int pos = atomicAdd(&cursor[c], 1);
        int attr = ea[e * 3] * 64 + ea[e * 3 + 1] * 8 + ea[e * 3 + 2];
        csr_pack[pos] = (ei[e] << 9) | attr;
    }
}

// ---------------- weight pre-swizzle: fp32 -> bf16 in MFMA B-fragment layout
__global__ void k_convw(const float* __restrict__ W1, const float* __restrict__ W2,
                        unsigned short* __restrict__ Bp1, unsigned short* __restrict__ Bp2) {
    int idx = blockIdx.x * 256 + threadIdx.x;
    if (idx < 3 * 128 * 256) {
        int l = idx >> 15, r = idx & 32767;
        int k = r >> 8, j = r & 255;
        float v = W1[(size_t)l * 32768 + k * 256 + j];
        Bp1[(size_t)l * 32768 + (((k >> 5) * 4 + ((k >> 3) & 3)) * 256 + j) * 8 + (k & 7)] =
            bf16_rne(v);
    } else if (idx < 6 * 128 * 256) {
        int t = idx - 98304;
        int l = t >> 15, r = t & 32767;
        int k = r >> 7, j = r & 127;
        float v = W2[(size_t)l * 32768 + k * 128 + j];
        Bp2[(size_t)l * 32768 + (((k >> 5) * 4 + ((k >> 3) & 3)) * 128 + j) * 8 + (k & 7)] =
            bf16_rne(v);
    }
}

// ---------------------------- gather-aggregate: z = (1+eps)*h + sum relu(msg)
// wave per node; SCALARIZED index stream: n/i0/i1/csr_pack[i]/row-bases all in
// SGPRs (readfirstlane), vector loads = SGPR base + lane voffset. Per-edge
// VALU = unpack+max+acc only (~10 ops).
#define EDGE2(uu, cc)                                                          \
    {                                                                          \
        ax += fmaxf(bf2f((unsigned short)((uu) & 0xffffu)) +                   \
                    bf2f((unsigned short)((cc) & 0xffffu)), 0.f);              \
        ay += fmaxf(bf2f((unsigned short)((uu) >> 16)) +                       \
                    bf2f((unsigned short)((cc) >> 16)), 0.f);                  \
    }

__global__ void k_gather(const unsigned short* __restrict__ hb,
                         const int* __restrict__ csr_pack,
                         const int* __restrict__ rowptr, const unsigned short* __restrict__ ct,
                         const float* __restrict__ eps, int l,
                         unsigned short* __restrict__ zb) {
    int lane = threadIdx.x & 63;
    int n = blockIdx.x * 4 + (threadIdx.x >> 6);
    if (n >= N_NODES) return;
    n = __builtin_amdgcn_readfirstlane(n);
    int i0 = __builtin_amdgcn_readfirstlane(rowptr[n]);
    int i1 = __builtin_amdgcn_readfirstlane(rowptr[n + 1]);
    float ax = 0.f, ay = 0.f;
    int i = i0;
    for (; i + 4 <= i1; i += 4) {
        int rc0 = __builtin_amdgcn_readfirstlane(csr_pack[i]);
        int rc1 = __builtin_amdgcn_readfirstlane(csr_pack[i + 1]);
        int rc2 = __builtin_amdgcn_readfirstlane(csr_pack[i + 2]);
        int rc3 = __builtin_amdgcn_readfirstlane(csr_pack[i + 3]);
        unsigned int u0 = ((const unsigned int*)(hb + ((size_t)(rc0 >> 9) << 7)))[lane];
        unsigned int u1 = ((const unsigned int*)(hb + ((size_t)(rc1 >> 9) << 7)))[lane];
        unsigned int u2 = ((const unsigned int*)(hb + ((size_t)(rc2 >> 9) << 7)))[lane];
        unsigned int u3 = ((const unsigned int*)(hb + ((size_t)(rc3 >> 9) << 7)))[lane];
        unsigned int c0 = ((const unsigned int*)(ct + ((rc0 & 511) << 7)))[lane];
        unsigned int c1 = ((const unsigned int*)(ct + ((rc1 & 511) << 7)))[lane];
        unsigned int c2 = ((const unsigned int*)(ct + ((rc2 & 511) << 7)))[lane];
        unsigned int c3 = ((const unsigned int*)(ct + ((rc3 & 511) << 7)))[lane];
        EDGE2(u0, c0); EDGE2(u1, c1); EDGE2(u2, c2); EDGE2(u3, c3);
    }
    for (; i < i1; ++i) {
        int rc0 = __builtin_amdgcn_readfirstlane(csr_pack[i]);
        unsigned int u0 = ((const unsigned int*)(hb + ((size_t)(rc0 >> 9) << 7)))[lane];
        unsigned int c0 = ((const unsigned int*)(ct + ((rc0 & 511) << 7)))[lane];
        EDGE2(u0, c0);
    }
    float el = 1.0f + eps[l];
    unsigned int un = ((const unsigned int*)(hb + ((size_t)n << 7)))[lane];
    float zx = fmaf(el, bf2f((unsigned short)(un & 0xffffu)), ax);
    float zy = fmaf(el, bf2f((unsigned short)(un >> 16)), ay);
    ((unsigned int*)(zb + ((size_t)n << 7)))[lane] = pack2(zx, zy);
}

// --------------------- GEMM1 (MFMA, swapped operands -> (z@W1)^T fragments)
// stats partials go to 16 spread copies (sl[(bid&15)*768 + ...])
__global__ __launch_bounds__(256) void k_gemm1(
    const unsigned short* __restrict__ zb, const unsigned short* __restrict__ Bp,
    const float* __restrict__ bias, unsigned short* __restrict__ tb,
    float* __restrict__ sl) {
    __shared__ unsigned short As[8192] __attribute__((aligned(16)));  // 16 KB
    int n0 = blockIdx.x * 64;
#pragma unroll
    for (int s = 0; s < 4; ++s) {
        int i = threadIdx.x + s * 256;            // 16B unit; 64 rows x 16 units
        int r = i >> 4, k8 = i & 15;
        short8v v = (short8v)(short)0;
        if (n0 + r < N_NODES) v = ((const short8v*)(zb + (size_t)(n0 + r) * 128))[k8];
        int frag = (r >> 4) * 16 + k8;
        int off = (frag * 128 + (r & 15) * 8) ^ ((k8 & 7) << 3);
        *(short8v*)(&As[off]) = v;
    }
    __syncthreads();
    int lane = threadIdx.x & 63;
    int wid = threadIdx.x >> 6;
    int l15 = lane & 15, kg = lane >> 4;
    int colbase = wid * 64;
    f32x4 acc[4][4];  // [rb][cf]
#pragma unroll
    for (int a = 0; a < 4; ++a)
#pragma unroll
        for (int b = 0; b < 4; ++b) acc[a][b] = (f32x4)(0.f);
#pragma unroll
    for (int k4 = 0; k4 < 4; ++k4) {
        short8v af[4], bf[4];
#pragma unroll
        for (int rb = 0; rb < 4; ++rb)
            af[rb] = *(const short8v*)(&As[((rb * 16 + k4 * 4 + kg) * 128 + l15 * 8) ^
                                           (((k4 * 4 + kg) & 7) << 3)]);
#pragma unroll
        for (int cf = 0; cf < 4; ++cf)
            bf[cf] = *(const short8v*)(Bp + ((k4 * 4 + kg) * 256 + colbase + cf * 16 + l15) * 8);
#pragma unroll
        for (int rb = 0; rb < 4; ++rb)
#pragma unroll
            for (int cf = 0; cf < 4; ++cf)
                acc[rb][cf] = __builtin_amdgcn_mfma_f32_16x16x32_bf16(bf[cf], af[rb],
                                                                      acc[rb][cf], 0, 0, 0);
    }
    float s4[4][4], q4[4][4];
#pragma unroll
    for (int cf = 0; cf < 4; ++cf)
#pragma unroll
        for (int r = 0; r < 4; ++r) { s4[cf][r] = 0.f; q4[cf][r] = 0.f; }
#pragma unroll
    for (int cf = 0; cf < 4; ++cf) {
        int j0 = colbase + cf * 16 + kg * 4;
        float4 b4 = *(const float4*)(bias + j0);
#pragma unroll
        for (int rb = 0; rb < 4; ++rb) {
            int gr = n0 + rb * 16 + l15;
            if (gr < N_NODES) {
                float v0 = acc[rb][cf][0] + b4.x;
                float v1 = acc[rb][cf][1] + b4.y;
                float v2 = acc[rb][cf][2] + b4.z;
                float v3 = acc[rb][cf][3] + b4.w;
                uint2 st;
                st.x = pack2(v0, v1);
                st.y = pack2(v2, v3);
                *(uint2*)(tb + (size_t)gr * 256 + j0) = st;
                s4[cf][0] += v0; q4[cf][0] += v0 * v0;
                s4[cf][1] += v1; q4[cf][1] += v1 * v1;
                s4[cf][2] += v2; q4[cf][2] += v2 * v2;
                s4[cf][3] += v3; q4[cf][3] += v3 * v3;
            }
        }
    }
    float* stats = sl + (size_t)(blockIdx.x & 15) * 768;
    float* part = (float*)As;
    __syncthreads();
#pragma unroll
    for (int cf = 0; cf < 4; ++cf)
#pragma unroll
        for (int r = 0; r < 4; ++r)
            part[(colbase + cf * 16 + kg * 4 + r) * 16 + l15] = s4[cf][r];
    __syncthreads();
    {
        int j = threadIdx.x;
        const float4* pr = (const float4*)(part + j * 16);
        float4 a0 = pr[0], a1 = pr[1], a2 = pr[2], a3 = pr[3];
        float s = a0.x + a0.y + a0.z + a0.w + a1.x + a1.y + a1.z + a1.w +
                  a2.x + a2.y + a2.z + a2.w + a3.x + a3.y + a3.z + a3.w;
        atomicAdd(&stats[j], s);
    }
    __syncthreads();
#pragma unroll
    for (int cf = 0; cf < 4; ++cf)
#pragma unroll
        for (int r = 0; r < 4; ++r)
            part[(colbase + cf * 16 + kg * 4 + r) * 16 + l15] = q4[cf][r];
    __syncthreads();
    {
        int j = threadIdx.x;
        const float4* pr = (const float4*)(part + j * 16);
        float4 a0 = pr[0], a1 = pr[1], a2 = pr[2], a3 = pr[3];
        float s = a0.x + a0.y + a0.z + a0.w + a1.x + a1.y + a1.z + a1.w +
                  a2.x + a2.y + a2.z + a2.w + a3.x + a3.y + a3.z + a3.w;
        atomicAdd(&stats[256 + j], s);
    }
}

// ------- GEMM2 (MFMA, swapped): u = relu(BN1(t))@W2 + b2, fused BN2 stats
// BN1 finalize done in-block: sum 16 spread copies -> LDS -> regs (no k_bnfin)
__global__ __launch_bounds__(256) void k_gemm2(
    const unsigned short* __restrict__ tb, const unsigned short* __restrict__ Bp,
    const float* __restrict__ sl, const float* __restrict__ g1,
    const float* __restrict__ b1g,
    const float* __restrict__ bias, unsigned short* __restrict__ ub,
    float* __restrict__ slw) {
    __shared__ unsigned short As[16384] __attribute__((aligned(16)));  // 32 KB
    int n0 = blockIdx.x * 64;
    int tid = threadIdx.x;
    // ---- BN1 finalize into As-as-float[512], then to regs
    {
        float* sfin = (float*)As;
        float s = 0.f, q = 0.f;
#pragma unroll
        for (int cc = 0; cc < 16; ++cc) {
            s += sl[cc * 768 + tid];
            q += sl[cc * 768 + 256 + tid];
        }
        float m = s * (1.0f / N_NODES);
        float var = q * (1.0f / N_NODES) - m * m;
        float sc = g1[tid] / sqrtf(var + 1e-5f);
        sfin[tid] = sc;
        sfin[256 + tid] = b1g[tid] - m * sc;
    }
    __syncthreads();
    int kb = (tid & 31) * 8;
    float scr[8], shr[8];
    {
        const float* sfin = (const float*)As;
#pragma unroll
        for (int j = 0; j < 8; ++j) {
            scr[j] = sfin[kb + j];
            shr[j] = sfin[256 + kb + j];
        }
    }
    __syncthreads();
#pragma unroll
    for (int s = 0; s < 8; ++s) {
        int i = tid + s * 256;                    // 16B unit; 64 rows x 32 units
        int r = i >> 5, k8 = i & 31;
        short8v v = (short8v)(short)0;
        if (n0 + r < N_NODES) v = ((const short8v*)(tb + (size_t)(n0 + r) * 256))[k8];
        float f0 = fmaxf(fmaf(scr[0], bf2f((unsigned short)v[0]), shr[0]), 0.f);
        float f1 = fmaxf(fmaf(scr[1], bf2f((unsigned short)v[1]), shr[1]), 0.f);
        float f2 = fmaxf(fmaf(scr[2], bf2f((unsigned short)v[2]), shr[2]), 0.f);
        float f3 = fmaxf(fmaf(scr[3], bf2f((unsigned short)v[3]), shr[3]), 0.f);
        float f4 = fmaxf(fmaf(scr[4], bf2f((unsigned short)v[4]), shr[4]), 0.f);
        float f5 = fmaxf(fmaf(scr[5], bf2f((unsigned short)v[5]), shr[5]), 0.f);
        float f6 = fmaxf(fmaf(scr[6], bf2f((unsigned short)v[6]), shr[6]), 0.f);
        float f7 = fmaxf(fmaf(scr[7], bf2f((unsigned short)v[7]), shr[7]), 0.f);
        uint4 ov;
        ov.x = pack2(f0, f1); ov.y = pack2(f2, f3);
        ov.z = pack2(f4, f5); ov.w = pack2(f6, f7);
        int frag = (r >> 4) * 32 + k8;
        int off = (frag * 128 + (r & 15) * 8) ^ ((k8 & 7) << 3);
        *(uint4*)(&As[off]) = ov;
    }
    __syncthreads();
    int lane = threadIdx.x & 63;
    int wid = threadIdx.x >> 6;
    int l15 = lane & 15, kg = lane >> 4;
    int colbase = wid * 32;
    f32x4 acc[4][2];  // [rb][cf]
#pragma unroll
    for (int a = 0; a < 4; ++a) {
        acc[a][0] = (f32x4)(0.f);
        acc[a][1] = (f32x4)(0.f);
    }
#pragma unroll
    for (int k4 = 0; k4 < 8; ++k4) {
        short8v af[4], bf[2];
#pragma unroll
        for (int rb = 0; rb < 4; ++rb)
            af[rb] = *(const short8v*)(&As[((rb * 32 + k4 * 4 + kg) * 128 + l15 * 8) ^
                                           (((k4 * 4 + kg) & 7) << 3)]);
#pragma unroll
        for (int cf = 0; cf < 2; ++cf)
            bf[cf] = *(const short8v*)(Bp + ((k4 * 4 + kg) * 128 + colbase + cf * 16 + l15) * 8);
#pragma unroll
        for (int rb = 0; rb < 4; ++rb)
#pragma unroll
            for (int cf = 0; cf < 2; ++cf)
                acc[rb][cf] = __builtin_amdgcn_mfma_f32_16x16x32_bf16(bf[cf], af[rb],
                                                                      acc[rb][cf], 0, 0, 0);
    }
    float s4[2][4], q4[2][4];
#pragma unroll
    for (int cf = 0; cf < 2; ++cf)
#pragma unroll
        for (int r = 0; r < 4; ++r) { s4[cf][r] = 0.f; q4[cf][r] = 0.f; }
#pragma unroll
    for (int cf = 0; cf < 2; ++cf) {
        int j0 = colbase + cf * 16 + kg * 4;
        float4 b4 = *(const float4*)(bias + j0);
#pragma unroll
        for (int rb = 0; rb < 4; ++rb) {
            int gr = n0 + rb * 16 + l15;
            if (gr < N_NODES) {
                float v0 = acc[rb][cf][0] + b4.x;
                float v1 = acc[rb][cf][1] + b4.y;
                float v2 = acc[rb][cf][2] + b4.z;
                float v3 = acc[rb][cf][3] + b4.w;
                uint2 st;
                st.x = pack2(v0, v1);
                st.y = pack2(v2, v3);
                *(uint2*)(ub + (size_t)gr * 128 + j0) = st;
                s4[cf][0] += v0; q4[cf][0] += v0 * v0;
                s4[cf][1] += v1; q4[cf][1] += v1 * v1;
                s4[cf][2] += v2; q4[cf][2] += v2 * v2;
                s4[cf][3] += v3; q4[cf][3] += v3 * v3;
            }
        }
    }
    float* stats = slw + (size_t)(blockIdx.x & 15) * 768;
    float* part = (float*)As;  // need 128*16 floats = 8 KB
    __syncthreads();
#pragma unroll
    for (int cf = 0; cf < 2; ++cf)
#pragma unroll
        for (int r = 0; r < 4; ++r)
            part[(colbase + cf * 16 + kg * 4 + r) * 16 + l15] = s4[cf][r];
    __syncthreads();
    if (tid < 128) {
        const float4* pr = (const float4*)(part + tid * 16);
        float4 a0 = pr[0], a1 = pr[1], a2 = pr[2], a3 = pr[3];
        float s = a0.x + a0.y + a0.z + a0.w + a1.x + a1.y + a1.z + a1.w +
                  a2.x + a2.y + a2.z + a2.w + a3.x + a3.y + a3.z + a3.w;
        atomicAdd(&stats[512 + tid], s);
    }
    __syncthreads();
#pragma unroll
    for (int cf = 0; cf < 2; ++cf)
#pragma unroll
        for (int r = 0; r < 4; ++r)
            part[(colbase + cf * 16 + kg * 4 + r) * 16 + l15] = q4[cf][r];
    __syncthreads();
    if (tid < 128) {
        const float4* pr = (const float4*)(part + tid * 16);
        float4 a0 = pr[0], a1 = pr[1], a2 = pr[2], a3 = pr[3];
        float s = a0.x + a0.y + a0.z + a0.w + a1.x + a1.y + a1.z + a1.w +
                  a2.x + a2.y + a2.z + a2.w + a3.x + a3.y + a3.z + a3.w;
        atomicAdd(&stats[640 + tid], s);
    }
}

// --------- hb += maybe_relu(BN2(u)); BN2 finalize in-block (16 spread copies
// -> LDS). Last layer: fused node head from pre-rounding fp32 values.
__global__ void k_update_h(unsigned short* __restrict__ hb,
                           const unsigned short* __restrict__ ub,
                           const float* __restrict__ sl,
                           const float* __restrict__ g2, const float* __restrict__ b2g,
                           int relu, int head,
                           const int* __restrict__ batch, const float* __restrict__ nW,
                           const float* __restrict__ nb, const float* __restrict__ eW,
                           float* __restrict__ out, float* __restrict__ p,
                           float* __restrict__ q, float* __restrict__ nsc) {
    __shared__ float sfin[256];
    if (threadIdx.x < 128) {
        int j = threadIdx.x;
        float s = 0.f, qq = 0.f;
#pragma unroll
        for (int cc = 0; cc < 16; ++cc) {
            s += sl[cc * 768 + 512 + j];
            qq += sl[cc * 768 + 640 + j];
        }
        float m = s * (1.0f / N_NODES);
        float var = qq * (1.0f / N_NODES) - m * m;
        float sc = g2[j] / sqrtf(var + 1e-5f);
        sfin[j] = sc;
        sfin[128 + j] = b2g[j] - m * sc;
    }
    __syncthreads();
    int kb = (threadIdx.x & 15) * 8;
    float scr[8], shr[8];
#pragma unroll
    for (int j = 0; j < 8; ++j) {
        scr[j] = sfin[kb + j];
        shr[j] = sfin[128 + kb + j];
    }
    int i = blockIdx.x * 256 + threadIdx.x;  // 8-elem unit; total N*16 = 1.6M
    uint4 uv = ((const uint4*)ub)[i];
    uint4 hv = ((const uint4*)hb)[i];
    float v0 = fmaf(scr[0], bf2f((unsigned short)(uv.x & 0xffffu)), shr[0]);
    float v1 = fmaf(scr[1], bf2f((unsigned short)(uv.x >> 16)), shr[1]);
    float v2 = fmaf(scr[2], bf2f((unsigned short)(uv.y & 0xffffu)), shr[2]);
    float v3 = fmaf(scr[3], bf2f((unsigned short)(uv.y >> 16)), shr[3]);
    float v4 = fmaf(scr[4], bf2f((unsigned short)(uv.z & 0xffffu)), shr[4]);
    float v5 = fmaf(scr[5], bf2f((unsigned short)(uv.z >> 16)), shr[5]);
    float v6 = fmaf(scr[6], bf2f((unsigned short)(uv.w & 0xffffu)), shr[6]);
    float v7 = fmaf(scr[7], bf2f((unsigned short)(uv.w >> 16)), shr[7]);
    if (relu) {
        v0 = fmaxf(v0, 0.f); v1 = fmaxf(v1, 0.f); v2 = fmaxf(v2, 0.f); v3 = fmaxf(v3, 0.f);
        v4 = fmaxf(v4, 0.f); v5 = fmaxf(v5, 0.f); v6 = fmaxf(v6, 0.f); v7 = fmaxf(v7, 0.f);
    }
    float h0 = bf2f((unsigned short)(hv.x & 0xffffu)) + v0;
    float h1 = bf2f((unsigned short)(hv.x >> 16)) + v1;
    float h2 = bf2f((unsigned short)(hv.y & 0xffffu)) + v2;
    float h3 = bf2f((unsigned short)(hv.y >> 16)) + v3;
    float h4 = bf2f((unsigned short)(hv.z & 0xffffu)) + v4;
    float h5 = bf2f((unsigned short)(hv.z >> 16)) + v5;
    float h6 = bf2f((unsigned short)(hv.w & 0xffffu)) + v6;
    float h7 = bf2f((unsigned short)(hv.w >> 16)) + v7;
    uint4 hp;
    hp.x = pack2(h0, h1); hp.y = pack2(h2, h3);
    hp.z = pack2(h4, h5); hp.w = pack2(h6, h7);
    ((uint4*)hb)[i] = hp;
    if (head) {
        float4 wn0 = *(const float4*)(nW + kb);
        float4 wn1 = *(const float4*)(nW + kb + 4);
        float4 wa0 = *(const float4*)(eW + kb);
        float4 wa1 = *(const float4*)(eW + kb + 4);
        float4 wb0 = *(const float4*)(eW + 128 + kb);
        float4 wb1 = *(const float4*)(eW + 128 + kb + 4);
        float pn = h0 * wn0.x + h1 * wn0.y + h2 * wn0.z + h3 * wn0.w +
                   h4 * wn1.x + h5 * wn1.y + h6 * wn1.z + h7 * wn1.w;
        float pa = h0 * wa0.x + h1 * wa0.y + h2 * wa0.z + h3 * wa0.w +
                   h4 * wa1.x + h5 * wa1.y + h6 * wa1.z + h7 * wa1.w;
        float pb = h0 * wb0.x + h1 * wb0.y + h2 * wb0.z + h3 * wb0.w +
                   h4 * wb1.x + h5 * wb1.y + h6 * wb1.z + h7 * wb1.w;
#pragma unroll
        for (int off = 1; off < 16; off <<= 1) {
            pn += __shfl_xor(pn, off);
            pa += __shfl_xor(pa, off);
            pb += __shfl_xor(pb, off);
        }
        if ((threadIdx.x & 15) == 0) {
            int gr = i >> 4;
            float nk = 1.f / (1.f + expf(-(pn + nb[0])));
            out[gr] = nk;
            int g = batch[gr];
            float* base = nsc + (size_t)(blockIdx.x & 7) * 8192;
            atomicAdd(&base[g], nk);
            atomicAdd(&base[4096 + g], 1.0f - nk);
            p[gr] = pa;
            q[gr] = pb;
        }
    }
}

// ------------- edge head: LDS-binned seg sums, zero global atomics.
// 512 grid-stride blocks; per-block bins flushed to esc[bid][8192]
__global__ __launch_bounds__(256) void k_edge_out(
    const int* __restrict__ ei, const int* __restrict__ batch,
    const float* __restrict__ p, const float* __restrict__ q,
    const float* __restrict__ eb, float* __restrict__ out,
    float* __restrict__ esc) {
    __shared__ float bins[8192];  // [2][4096] = 32 KB
    for (int i = threadIdx.x; i < 8192; i += 256) bins[i] = 0.f;
    __syncthreads();
    float ebv = eb[0];
    for (int e = blockIdx.x * 256 + threadIdx.x; e < N_EDGES; e += EOUT_BLK * 256) {
        int r = ei[e], c = ei[N_EDGES + e];
        float ek = 1.f / (1.f + expf(-(p[r] + q[c] + ebv)));
        out[N_NODES + e] = ek;
        int g = batch[r];
        atomicAdd(&bins[g], ek);
        atomicAdd(&bins[4096 + g], 1.0f - ek);
    }
    __syncthreads();
    float* dst = esc + (size_t)blockIdx.x * 8192;
    for (int i = threadIdx.x; i < 8192; i += 256) dst[i] = bins[i];
}

// ------------- reduce the scratch copies into the 4 output segments
__global__ void k_seg_reduce(const float* __restrict__ nsc, const float* __restrict__ esc,
                             float* __restrict__ out) {
    int i = blockIdx.x * 256 + threadIdx.x;   // 0..16383
    if (i >= 16384) return;
    float s = 1e-8f;
    if (i < 8192) {
#pragma unroll
        for (int c = 0; c < 8; ++c) s += nsc[c * 8192 + i];
    } else {
        int j = i - 8192;
        for (int c = 0; c < EOUT_BLK; ++c) s += esc[(size_t)c * 8192 + j];
    }
    out[N_NODES + N_EDGES + i] = s;
}

extern "C" void kernel_launch(void* const* d_in, const int* in_sizes, int n_in,
                              void* d_out, int out_size, void* d_ws, size_t ws_size,
                              hipStream_t stream) {
    const int*   x     = (const int*)d_in[0];
    const int*   ei    = (const int*)d_in[1];
    const int*   ea    = (const int*)d_in[2];
    const int*   batch = (const int*)d_in[3];
    const float* at    = (const float*)d_in[4];
    const float* bt    = (const float*)d_in[5];
    const float* eps   = (const float*)d_in[6];
    const float* W1    = (const float*)d_in[7];
    const float* b1    = (const float*)d_in[8];
    const float* bn1g  = (const float*)d_in[9];
    const float* bn1b  = (const float*)d_in[10];
    const float* W2    = (const float*)d_in[11];
    const float* b2    = (const float*)d_in[12];
    const float* obng  = (const float*)d_in[13];
    const float* obnb  = (const float*)d_in[14];
    const float* nW    = (const float*)d_in[15];
    const float* nb    = (const float*)d_in[16];
    const float* eW    = (const float*)d_in[17];
    const float* eb    = (const float*)d_in[18];
    float* out = (float*)d_out;

    float* ws    = (float*)d_ws;
    float* stats = ws;                       // 3 layers x 16 copies x 768
    float* p     = stats + 3 * 16 * 768;     // N
    float* q     = p + N_NODES;              // N
    float* nsc   = q + N_NODES;              // 8*8192 node seg scratch
    float* esc   = nsc + 8 * 8192;           // EOUT_BLK*8192 edge seg scratch (16 MB)
    unsigned short* hb  = (unsigned short*)(esc + (size_t)EOUT_BLK * 8192);  // N*128 bf16
    unsigned short* zub = hb + 12800000;     // N*128 bf16: z (gemm1 in), then u
    unsigned short* tb  = zub + 12800000;    // N*256 bf16
    unsigned short* Bp1 = tb + 25600000;     // 3*128*256 bf16
    unsigned short* Bp2 = Bp1 + 3 * 32768;   // 3*256*128 bf16
    unsigned short* ct  = Bp2 + 3 * 32768;   // 3*512*128 bf16 combined bond
    int* rowptr  = (int*)(ct + 3 * 65536);   // N+1
    int* cursor  = rowptr + N_NODES + 1;     // N (counts, then cursors)
    int* csr_pack = cursor + N_NODES;        // E  (row<<9 | attr)
    int* bsum    = csr_pack + N_EDGES;       // SCAN_NBLK
    // per-layer stats: sl = stats + l*16*768; copy c at sl + c*768:
    //   [sum256][sq256][osum128@512][osq128@640]

    hipMemsetAsync(stats, 0, 3 * 16 * 768 * sizeof(float), stream);
    hipMemsetAsync(nsc, 0, 8 * 8192 * sizeof(float), stream);
    hipMemsetAsync(cursor, 0, N_NODES * sizeof(int), stream);
    k_atom_encode<<<50000, 256, 0, stream>>>(x, at, hb);
    k_convw<<<768, 256, 0, stream>>>(W1, W2, Bp1, Bp2);
    k_bondc<<<768, 256, 0, stream>>>(bt, ct);

    // CSR of edges grouped by destination (col) — parallel 3-phase scan
    k_hist<<<2344, 256, 0, stream>>>(ei, cursor);
    k_scan_partial<<<SCAN_NBLK, 256, 0, stream>>>(cursor, bsum);
    k_scan_bsum<<<1, 256, 0, stream>>>(bsum, rowptr);
    k_scan_final<<<SCAN_NBLK, 512, 0, stream>>>(bsum, cursor, rowptr);
    k_fill<<<2344, 256, 0, stream>>>(ei, ea, cursor, csr_pack);

    for (int l = 0; l < 3; ++l) {
        float* sl = stats + (size_t)l * 16 * 768;
        k_gather<<<25000, 256, 0, stream>>>(hb, csr_pack, rowptr,
                                            ct + (size_t)l * 65536, eps, l, zub);
        k_gemm1<<<1563, 256, 0, stream>>>(zub, Bp1 + (size_t)l * 32768, b1 + l * 256, tb, sl);
        k_gemm2<<<1563, 256, 0, stream>>>(tb, Bp2 + (size_t)l * 32768, sl,
                                          bn1g + l * 256, bn1b + l * 256,
                                          b2 + l * 128, zub, sl);
        k_update_h<<<6250, 256, 0, stream>>>(hb, zub, sl, obng + l * 128, obnb + l * 128,
                                             (l < 2) ? 1 : 0, (l == 2) ? 1 : 0,
                                             batch, nW, nb, eW, out, p, q, nsc);
    }

    k_edge_out<<<EOUT_BLK, 256, 0, stream>>>(ei, batch, p, q, eb, out, esc);
    k_seg_reduce<<<64, 256, 0, stream>>>(nsc, esc, out);
}

// Round 14
// 497.639 us; speedup vs baseline: 6.9738x; 1.0323x over previous
//
#include <hip/hip_runtime.h>
#include <math.h>

#define N_NODES 100000
#define N_EDGES 600000
#define N_GRAPHS 4096
#define SCAN_CHUNK 512
#define SCAN_NBLK 196   // ceil(100000/512)
#define EOUT_BLK 512    // edge_out grid (LDS-binned, scratch copies)
#define UPD_BLK 1024    // update_h grid (grid-stride, amortized BN2 finalize)

typedef __attribute__((ext_vector_type(8))) short short8v;   // 8 bf16 (4 VGPR)
typedef __attribute__((ext_vector_type(4))) float f32x4;

// fp32 pair -> packed bf16 (RNE) via the HW instruction
__device__ __forceinline__ unsigned int pack2(float a, float b) {
    unsigned int r;
    asm("v_cvt_pk_bf16_f32 %0, %1, %2" : "=v"(r) : "v"(a), "v"(b));
    return r;
}
__device__ __forceinline__ unsigned short bf16_rne(float f) {
    unsigned int r;
    asm("v_cvt_pk_bf16_f32 %0, %1, %2" : "=v"(r) : "v"(f), "v"(f));
    return (unsigned short)r;
}
__device__ __forceinline__ float bf2f(unsigned short u) {
    return __uint_as_float(((unsigned int)u) << 16);
}

// ------- atom encoder: wave per node, scalarized x-row, float2 table gathers
__global__ void k_atom_encode(const int* __restrict__ x, const float* __restrict__ at,
                              unsigned short* __restrict__ hb) {
    int lane = threadIdx.x & 63;
    int n = blockIdx.x * 4 + (threadIdx.x >> 6);
    if (n >= N_NODES) return;
    n = __builtin_amdgcn_readfirstlane(n);
    const int* xr = x + n * 9;
    float sx = 0.f, sy = 0.f;
#pragma unroll
    for (int f = 0; f < 9; ++f) {
        int v = __builtin_amdgcn_readfirstlane(xr[f]);
        float2 t = ((const float2*)(at + (f * 100 + v) * 128))[lane];
        sx += t.x;
        sy += t.y;
    }
    ((unsigned int*)(hb + ((size_t)n << 7)))[lane] = pack2(sx, sy);
}

// --------- combined bond table: ct[l][idx][d] = bf16(sum of 3 table rows)
__global__ void k_bondc(const float* __restrict__ bt, unsigned short* __restrict__ ct) {
    int idx = blockIdx.x * 256 + threadIdx.x;
    if (idx >= 3 * 512 * 128) return;
    int d = idx & 127;
    int c = (idx >> 7) & 511;
    int l = idx >> 16;
    const float* base = bt + (size_t)l * 3072;
    float v = base[(c >> 6) * 128 + d] + base[1024 + ((c >> 3) & 7) * 128 + d] +
              base[2048 + (c & 7) * 128 + d];
    ct[idx] = bf16_rne(v);
}

// --------------------------- CSR build (once)
__global__ void k_hist(const int* __restrict__ ei, int* __restrict__ cnt) {
    int e = blockIdx.x * 256 + threadIdx.x;
    if (e < N_EDGES) atomicAdd(&cnt[ei[N_EDGES + e]], 1);
}

__global__ void k_scan_partial(const int* __restrict__ cnt, int* __restrict__ bsum) {
    __shared__ int ls[256];
    int base = blockIdx.x * SCAN_CHUNK;
    int t = threadIdx.x;
    int s = 0;
    for (int i = base + t; i < base + SCAN_CHUNK && i < N_NODES; i += 256) s += cnt[i];
    ls[t] = s;
    __syncthreads();
    for (int off = 128; off; off >>= 1) {
        if (t < off) ls[t] += ls[t + off];
        __syncthreads();
    }
    if (t == 0) bsum[blockIdx.x] = ls[0];
}

__global__ void k_scan_bsum(int* __restrict__ bsum, int* __restrict__ rowptr) {
    __shared__ int ls[256];
    int t = threadIdx.x;
    int v = (t < SCAN_NBLK) ? bsum[t] : 0;
    ls[t] = v;
    __syncthreads();
    for (int off = 1; off < 256; off <<= 1) {
        int x = (t >= off) ? ls[t - off] : 0;
        __syncthreads();
        ls[t] += x;
        __syncthreads();
    }
    if (t < SCAN_NBLK) bsum[t] = ls[t] - v;  // exclusive prefix
    if (t == 255) rowptr[N_NODES] = ls[255];
}

__global__ __launch_bounds__(512) void k_scan_final(const int* __restrict__ bsum,
                                                    int* __restrict__ cnt_cursor,
                                                    int* __restrict__ rowptr) {
    __shared__ int ls[512];
    int base = blockIdx.x * SCAN_CHUNK;
    int t = threadIdx.x;
    int i = base + t;
    int v = (i < N_NODES) ? cnt_cursor[i] : 0;
    ls[t] = v;
    __syncthreads();
    for (int off = 1; off < 512; off <<= 1) {
        int x = (t >= off) ? ls[t - off] : 0;
        __syncthreads();
        ls[t] += x;
        __syncthreads();
    }
    if (i < N_NODES) {
        int excl = bsum[blockIdx.x] + ls[t] - v;
        rowptr[i] = excl;
        cnt_cursor[i] = excl;
    }
}

// fill CSR-ordered packed (row<<9)|attr array — single index stream
__global__ void k_fill(const int* __restrict__ ei, const int* __restrict__ ea,
                       int* __restrict__ cursor, int* __restrict__ csr_pack) {
    int e = blockIdx.x * 256 + threadIdx.x;
    if (e < N_EDGES) {
        int c = ei[N_EDGES + e];
        int pos = atomicAdd(&cursor[c], 1);
        int attr = ea[e * 3] * 64 + ea[e * 3 + 1] * 8 + ea[e * 3 + 2];
        csr_pack[pos] = (ei[e] << 9) | attr;
    }
}

// ---------------- weight pre-swizzle: fp32 -> bf16 in MFMA B-fragment layout
__global__ void k_convw(const float* __restrict__ W1, const float* __restrict__ W2,
                        unsigned short* __restrict__ Bp1, unsigned short* __restrict__ Bp2) {
    int idx = blockIdx.x * 256 + threadIdx.x;
    if (idx < 3 * 128 * 256) {
        int l = idx >> 15, r = idx & 32767;
        int k = r >> 8, j = r & 255;
        float v = W1[(size_t)l * 32768 + k * 256 + j];
        Bp1[(size_t)l * 32768 + (((k >> 5) * 4 + ((k >> 3) & 3)) * 256 + j) * 8 + (k & 7)] =
            bf16_rne(v);
    } else if (idx < 6 * 128 * 256) {
        int t = idx - 98304;
        int l = t >> 15, r = t & 32767;
        int k = r >> 7, j = r & 127;
        float v = W2[(size_t)l * 32768 + k * 128 + j];
        Bp2[(size_t)l * 32768 + (((k >> 5) * 4 + ((k >> 3) & 3)) * 128 + j) * 8 + (k & 7)] =
            bf16_rne(v);
    }
}

// ---------------------------- gather-aggregate: z = (1+eps)*h + sum relu(msg)
// wave per node; scalarized index stream (SGPR base + lane voffset loads)
#define EDGE2(uu, cc)                                                          \
    {                                                                          \
        ax += fmaxf(bf2f((unsigned short)((uu) & 0xffffu)) +                   \
                    bf2f((unsigned short)((cc) & 0xffffu)), 0.f);              \
        ay += fmaxf(bf2f((unsigned short)((uu) >> 16)) +                       \
                    bf2f((unsigned short)((cc) >> 16)), 0.f);                  \
    }

__global__ void k_gather(const unsigned short* __restrict__ hb,
                         const int* __restrict__ csr_pack,
                         const int* __restrict__ rowptr, const unsigned short* __restrict__ ct,
                         const float* __restrict__ eps, int l,
                         unsigned short* __restrict__ zb) {
    int lane = threadIdx.x & 63;
    int n = blockIdx.x * 4 + (threadIdx.x >> 6);
    if (n >= N_NODES) return;
    n = __builtin_amdgcn_readfirstlane(n);
    int i0 = __builtin_amdgcn_readfirstlane(rowptr[n]);
    int i1 = __builtin_amdgcn_readfirstlane(rowptr[n + 1]);
    float ax = 0.f, ay = 0.f;
    int i = i0;
    for (; i + 4 <= i1; i += 4) {
        int rc0 = __builtin_amdgcn_readfirstlane(csr_pack[i]);
        int rc1 = __builtin_amdgcn_readfirstlane(csr_pack[i + 1]);
        int rc2 = __builtin_amdgcn_readfirstlane(csr_pack[i + 2]);
        int rc3 = __builtin_amdgcn_readfirstlane(csr_pack[i + 3]);
        unsigned int u0 = ((const unsigned int*)(hb + ((size_t)(rc0 >> 9) << 7)))[lane];
        unsigned int u1 = ((const unsigned int*)(hb + ((size_t)(rc1 >> 9) << 7)))[lane];
        unsigned int u2 = ((const unsigned int*)(hb + ((size_t)(rc2 >> 9) << 7)))[lane];
        unsigned int u3 = ((const unsigned int*)(hb + ((size_t)(rc3 >> 9) << 7)))[lane];
        unsigned int c0 = ((const unsigned int*)(ct + ((rc0 & 511) << 7)))[lane];
        unsigned int c1 = ((const unsigned int*)(ct + ((rc1 & 511) << 7)))[lane];
        unsigned int c2 = ((const unsigned int*)(ct + ((rc2 & 511) << 7)))[lane];
        unsigned int c3 = ((const unsigned int*)(ct + ((rc3 & 511) << 7)))[lane];
        EDGE2(u0, c0); EDGE2(u1, c1); EDGE2(u2, c2); EDGE2(u3, c3);
    }
    for (; i < i1; ++i) {
        int rc0 = __builtin_amdgcn_readfirstlane(csr_pack[i]);
        unsigned int u0 = ((const unsigned int*)(hb + ((size_t)(rc0 >> 9) << 7)))[lane];
        unsigned int c0 = ((const unsigned int*)(ct + ((rc0 & 511) << 7)))[lane];
        EDGE2(u0, c0);
    }
    float el = 1.0f + eps[l];
    unsigned int un = ((const unsigned int*)(hb + ((size_t)n << 7)))[lane];
    float zx = fmaf(el, bf2f((unsigned short)(un & 0xffffu)), ax);
    float zy = fmaf(el, bf2f((unsigned short)(un >> 16)), ay);
    ((unsigned int*)(zb + ((size_t)n << 7)))[lane] = pack2(zx, zy);
}

// --------------------- GEMM1 (MFMA, swapped operands -> (z@W1)^T fragments)
// stats partials go to 16 spread copies (sl[(bid&15)*768 + ...])
__global__ __launch_bounds__(256) void k_gemm1(
    const unsigned short* __restrict__ zb, const unsigned short* __restrict__ Bp,
    const float* __restrict__ bias, unsigned short* __restrict__ tb,
    float* __restrict__ sl) {
    __shared__ unsigned short As[8192] __attribute__((aligned(16)));  // 16 KB
    int n0 = blockIdx.x * 64;
#pragma unroll
    for (int s = 0; s < 4; ++s) {
        int i = threadIdx.x + s * 256;            // 16B unit; 64 rows x 16 units
        int r = i >> 4, k8 = i & 15;
        short8v v = (short8v)(short)0;
        if (n0 + r < N_NODES) v = ((const short8v*)(zb + (size_t)(n0 + r) * 128))[k8];
        int frag = (r >> 4) * 16 + k8;
        int off = (frag * 128 + (r & 15) * 8) ^ ((k8 & 7) << 3);
        *(short8v*)(&As[off]) = v;
    }
    __syncthreads();
    int lane = threadIdx.x & 63;
    int wid = threadIdx.x >> 6;
    int l15 = lane & 15, kg = lane >> 4;
    int colbase = wid * 64;
    f32x4 acc[4][4];  // [rb][cf]
#pragma unroll
    for (int a = 0; a < 4; ++a)
#pragma unroll
        for (int b = 0; b < 4; ++b) acc[a][b] = (f32x4)(0.f);
#pragma unroll
    for (int k4 = 0; k4 < 4; ++k4) {
        short8v af[4], bf[4];
#pragma unroll
        for (int rb = 0; rb < 4; ++rb)
            af[rb] = *(const short8v*)(&As[((rb * 16 + k4 * 4 + kg) * 128 + l15 * 8) ^
                                           (((k4 * 4 + kg) & 7) << 3)]);
#pragma unroll
        for (int cf = 0; cf < 4; ++cf)
            bf[cf] = *(const short8v*)(Bp + ((k4 * 4 + kg) * 256 + colbase + cf * 16 + l15) * 8);
#pragma unroll
        for (int rb = 0; rb < 4; ++rb)
#pragma unroll
            for (int cf = 0; cf < 4; ++cf)
                acc[rb][cf] = __builtin_amdgcn_mfma_f32_16x16x32_bf16(bf[cf], af[rb],
                                                                      acc[rb][cf], 0, 0, 0);
    }
    float s4[4][4], q4[4][4];
#pragma unroll
    for (int cf = 0; cf < 4; ++cf)
#pragma unroll
        for (int r = 0; r < 4; ++r) { s4[cf][r] = 0.f; q4[cf][r] = 0.f; }
#pragma unroll
    for (int cf = 0; cf < 4; ++cf) {
        int j0 = colbase + cf * 16 + kg * 4;
        float4 b4 = *(const float4*)(bias + j0);
#pragma unroll
        for (int rb = 0; rb < 4; ++rb) {
            int gr = n0 + rb * 16 + l15;
            if (gr < N_NODES) {
                float v0 = acc[rb][cf][0] + b4.x;
                float v1 = acc[rb][cf][1] + b4.y;
                float v2 = acc[rb][cf][2] + b4.z;
                float v3 = acc[rb][cf][3] + b4.w;
                uint2 st;
                st.x = pack2(v0, v1);
                st.y = pack2(v2, v3);
                *(uint2*)(tb + (size_t)gr * 256 + j0) = st;
                s4[cf][0] += v0; q4[cf][0] += v0 * v0;
                s4[cf][1] += v1; q4[cf][1] += v1 * v1;
                s4[cf][2] += v2; q4[cf][2] += v2 * v2;
                s4[cf][3] += v3; q4[cf][3] += v3 * v3;
            }
        }
    }
    float* stats = sl + (size_t)(blockIdx.x & 15) * 768;
    float* part = (float*)As;
    __syncthreads();
#pragma unroll
    for (int cf = 0; cf < 4; ++cf)
#pragma unroll
        for (int r = 0; r < 4; ++r)
            part[(colbase + cf * 16 + kg * 4 + r) * 16 + l15] = s4[cf][r];
    __syncthreads();
    {
        int j = threadIdx.x;
        const float4* pr = (const float4*)(part + j * 16);
        float4 a0 = pr[0], a1 = pr[1], a2 = pr[2], a3 = pr[3];
        float s = a0.x + a0.y + a0.z + a0.w + a1.x + a1.y + a1.z + a1.w +
                  a2.x + a2.y + a2.z + a2.w + a3.x + a3.y + a3.z + a3.w;
        atomicAdd(&stats[j], s);
    }
    __syncthreads();
#pragma unroll
    for (int cf = 0; cf < 4; ++cf)
#pragma unroll
        for (int r = 0; r < 4; ++r)
            part[(colbase + cf * 16 + kg * 4 + r) * 16 + l15] = q4[cf][r];
    __syncthreads();
    {
        int j = threadIdx.x;
        const float4* pr = (const float4*)(part + j * 16);
        float4 a0 = pr[0], a1 = pr[1], a2 = pr[2], a3 = pr[3];
        float s = a0.x + a0.y + a0.z + a0.w + a1.x + a1.y + a1.z + a1.w +
                  a2.x + a2.y + a2.z + a2.w + a3.x + a3.y + a3.z + a3.w;
        atomicAdd(&stats[256 + j], s);
    }
}

// ------- GEMM2 (MFMA, swapped): u = relu(BN1(t))@W2 + b2, fused BN2 stats
// BN1 finalize done in-block: sum 16 spread copies -> LDS -> regs
__global__ __launch_bounds__(256) void k_gemm2(
    const unsigned short* __restrict__ tb, const unsigned short* __restrict__ Bp,
    const float* __restrict__ sl, const float* __restrict__ g1,
    const float* __restrict__ b1g,
    const float* __restrict__ bias, unsigned short* __restrict__ ub,
    float* __restrict__ slw) {
    __shared__ unsigned short As[16384] __attribute__((aligned(16)));  // 32 KB
    int n0 = blockIdx.x * 64;
    int tid = threadIdx.x;
    // ---- BN1 finalize into As-as-float[512], then to regs
    {
        float* sfin = (float*)As;
        float s = 0.f, q = 0.f;
#pragma unroll
        for (int cc = 0; cc < 16; ++cc) {
            s += sl[cc * 768 + tid];
            q += sl[cc * 768 + 256 + tid];
        }
        float m = s * (1.0f / N_NODES);
        float var = q * (1.0f / N_NODES) - m * m;
        float sc = g1[tid] / sqrtf(var + 1e-5f);
        sfin[tid] = sc;
        sfin[256 + tid] = b1g[tid] - m * sc;
    }
    __syncthreads();
    int kb = (tid & 31) * 8;
    float scr[8], shr[8];
    {
        const float* sfin = (const float*)As;
#pragma unroll
        for (int j = 0; j < 8; ++j) {
            scr[j] = sfin[kb + j];
            shr[j] = sfin[256 + kb + j];
        }
    }
    __syncthreads();
#pragma unroll
    for (int s = 0; s < 8; ++s) {
        int i = tid + s * 256;                    // 16B unit; 64 rows x 32 units
        int r = i >> 5, k8 = i & 31;
        short8v v = (short8v)(short)0;
        if (n0 + r < N_NODES) v = ((const short8v*)(tb + (size_t)(n0 + r) * 256))[k8];
        float f0 = fmaxf(fmaf(scr[0], bf2f((unsigned short)v[0]), shr[0]), 0.f);
        float f1 = fmaxf(fmaf(scr[1], bf2f((unsigned short)v[1]), shr[1]), 0.f);
        float f2 = fmaxf(fmaf(scr[2], bf2f((unsigned short)v[2]), shr[2]), 0.f);
        float f3 = fmaxf(fmaf(scr[3], bf2f((unsigned short)v[3]), shr[3]), 0.f);
        float f4 = fmaxf(fmaf(scr[4], bf2f((unsigned short)v[4]), shr[4]), 0.f);
        float f5 = fmaxf(fmaf(scr[5], bf2f((unsigned short)v[5]), shr[5]), 0.f);
        float f6 = fmaxf(fmaf(scr[6], bf2f((unsigned short)v[6]), shr[6]), 0.f);
        float f7 = fmaxf(fmaf(scr[7], bf2f((unsigned short)v[7]), shr[7]), 0.f);
        uint4 ov;
        ov.x = pack2(f0, f1); ov.y = pack2(f2, f3);
        ov.z = pack2(f4, f5); ov.w = pack2(f6, f7);
        int frag = (r >> 4) * 32 + k8;
        int off = (frag * 128 + (r & 15) * 8) ^ ((k8 & 7) << 3);
        *(uint4*)(&As[off]) = ov;
    }
    __syncthreads();
    int lane = threadIdx.x & 63;
    int wid = threadIdx.x >> 6;
    int l15 = lane & 15, kg = lane >> 4;
    int colbase = wid * 32;
    f32x4 acc[4][2];  // [rb][cf]
#pragma unroll
    for (int a = 0; a < 4; ++a) {
        acc[a][0] = (f32x4)(0.f);
        acc[a][1] = (f32x4)(0.f);
    }
#pragma unroll
    for (int k4 = 0; k4 < 8; ++k4) {
        short8v af[4], bf[2];
#pragma unroll
        for (int rb = 0; rb < 4; ++rb)
            af[rb] = *(const short8v*)(&As[((rb * 32 + k4 * 4 + kg) * 128 + l15 * 8) ^
                                           (((k4 * 4 + kg) & 7) << 3)]);
#pragma unroll
        for (int cf = 0; cf < 2; ++cf)
            bf[cf] = *(const short8v*)(Bp + ((k4 * 4 + kg) * 128 + colbase + cf * 16 + l15) * 8);
#pragma unroll
        for (int rb = 0; rb < 4; ++rb)
#pragma unroll
            for (int cf = 0; cf < 2; ++cf)
                acc[rb][cf] = __builtin_amdgcn_mfma_f32_16x16x32_bf16(bf[cf], af[rb],
                                                                      acc[rb][cf], 0, 0, 0);
    }
    float s4[2][4], q4[2][4];
#pragma unroll
    for (int cf = 0; cf < 2; ++cf)
#pragma unroll
        for (int r = 0; r < 4; ++r) { s4[cf][r] = 0.f; q4[cf][r] = 0.f; }
#pragma unroll
    for (int cf = 0; cf < 2; ++cf) {
        int j0 = colbase + cf * 16 + kg * 4;
        float4 b4 = *(const float4*)(bias + j0);
#pragma unroll
        for (int rb = 0; rb < 4; ++rb) {
            int gr = n0 + rb * 16 + l15;
            if (gr < N_NODES) {
                float v0 = acc[rb][cf][0] + b4.x;
                float v1 = acc[rb][cf][1] + b4.y;
                float v2 = acc[rb][cf][2] + b4.z;
                float v3 = acc[rb][cf][3] + b4.w;
                uint2 st;
                st.x = pack2(v0, v1);
                st.y = pack2(v2, v3);
                *(uint2*)(ub + (size_t)gr * 128 + j0) = st;
                s4[cf][0] += v0; q4[cf][0] += v0 * v0;
                s4[cf][1] += v1; q4[cf][1] += v1 * v1;
                s4[cf][2] += v2; q4[cf][2] += v2 * v2;
                s4[cf][3] += v3; q4[cf][3] += v3 * v3;
            }
        }
    }
    float* stats = slw + (size_t)(blockIdx.x & 15) * 768;
    float* part = (float*)As;  // need 128*16 floats = 8 KB
    __syncthreads();
#pragma unroll
    for (int cf = 0; cf < 2; ++cf)
#pragma unroll
        for (int r = 0; r < 4; ++r)
            part[(colbase + cf * 16 + kg * 4 + r) * 16 + l15] = s4[cf][r];
    __syncthreads();
    if (tid < 128) {
        const float4* pr = (const float4*)(part + tid * 16);
        float4 a0 = pr[0], a1 = pr[1], a2 = pr[2], a3 = pr[3];
        float s = a0.x + a0.y + a0.z + a0.w + a1.x + a1.y + a1.z + a1.w +
                  a2.x + a2.y + a2.z + a2.w + a3.x + a3.y + a3.z + a3.w;
        atomicAdd(&stats[512 + tid], s);
    }
    __syncthreads();
#pragma unroll
    for (int cf = 0; cf < 2; ++cf)
#pragma unroll
        for (int r = 0; r < 4; ++r)
            part[(colbase + cf * 16 + kg * 4 + r) * 16 + l15] = q4[cf][r];
    __syncthreads();
    if (tid < 128) {
        const float4* pr = (const float4*)(part + tid * 16);
        float4 a0 = pr[0], a1 = pr[1], a2 = pr[2], a3 = pr[3];
        float s = a0.x + a0.y + a0.z + a0.w + a1.x + a1.y + a1.z + a1.w +
                  a2.x + a2.y + a2.z + a2.w + a3.x + a3.y + a3.z + a3.w;
        atomicAdd(&stats[640 + tid], s);
    }
}

// --------- hb += maybe_relu(BN2(u)); grid-stride (amortized in-block BN2
// finalize). Last layer: fused node head from pre-rounding fp32 values.
__global__ __launch_bounds__(256) void k_update_h(
    unsigned short* __restrict__ hb, const unsigned short* __restrict__ ub,
    const float* __restrict__ sl,
    const float* __restrict__ g2, const float* __restrict__ b2g,
    int relu, int head,
    const int* __restrict__ batch, const float* __restrict__ nW,
    const float* __restrict__ nb, const float* __restrict__ eW,
    float* __restrict__ out, float* __restrict__ p,
    float* __restrict__ q, float* __restrict__ nsc) {
    __shared__ float sfin[256];
    if (threadIdx.x < 128) {
        int j = threadIdx.x;
        float s = 0.f, qq = 0.f;
#pragma unroll
        for (int cc = 0; cc < 16; ++cc) {
            s += sl[cc * 768 + 512 + j];
            qq += sl[cc * 768 + 640 + j];
        }
        float m = s * (1.0f / N_NODES);
        float var = qq * (1.0f / N_NODES) - m * m;
        float sc = g2[j] / sqrtf(var + 1e-5f);
        sfin[j] = sc;
        sfin[128 + j] = b2g[j] - m * sc;
    }
    __syncthreads();
    int kb = (threadIdx.x & 15) * 8;
    float scr[8], shr[8];
#pragma unroll
    for (int j = 0; j < 8; ++j) {
        scr[j] = sfin[kb + j];
        shr[j] = sfin[128 + kb + j];
    }
    float4 wn0, wn1, wa0, wa1, wb0, wb1;
    if (head) {
        wn0 = *(const float4*)(nW + kb);
        wn1 = *(const float4*)(nW + kb + 4);
        wa0 = *(const float4*)(eW + kb);
        wa1 = *(const float4*)(eW + kb + 4);
        wb0 = *(const float4*)(eW + 128 + kb);
        wb1 = *(const float4*)(eW + 128 + kb + 4);
    }
    for (int i = blockIdx.x * 256 + threadIdx.x; i < N_NODES * 16; i += UPD_BLK * 256) {
        uint4 uv = ((const uint4*)ub)[i];
        uint4 hv = ((const uint4*)hb)[i];
        float v0 = fmaf(scr[0], bf2f((unsigned short)(uv.x & 0xffffu)), shr[0]);
        float v1 = fmaf(scr[1], bf2f((unsigned short)(uv.x >> 16)), shr[1]);
        float v2 = fmaf(scr[2], bf2f((unsigned short)(uv.y & 0xffffu)), shr[2]);
        float v3 = fmaf(scr[3], bf2f((unsigned short)(uv.y >> 16)), shr[3]);
        float v4 = fmaf(scr[4], bf2f((unsigned short)(uv.z & 0xffffu)), shr[4]);
        float v5 = fmaf(scr[5], bf2f((unsigned short)(uv.z >> 16)), shr[5]);
        float v6 = fmaf(scr[6], bf2f((unsigned short)(uv.w & 0xffffu)), shr[6]);
        float v7 = fmaf(scr[7], bf2f((unsigned short)(uv.w >> 16)), shr[7]);
        if (relu) {
            v0 = fmaxf(v0, 0.f); v1 = fmaxf(v1, 0.f); v2 = fmaxf(v2, 0.f); v3 = fmaxf(v3, 0.f);
            v4 = fmaxf(v4, 0.f); v5 = fmaxf(v5, 0.f); v6 = fmaxf(v6, 0.f); v7 = fmaxf(v7, 0.f);
        }
        float h0 = bf2f((unsigned short)(hv.x & 0xffffu)) + v0;
        float h1 = bf2f((unsigned short)(hv.x >> 16)) + v1;
        float h2 = bf2f((unsigned short)(hv.y & 0xffffu)) + v2;
        float h3 = bf2f((unsigned short)(hv.y >> 16)) + v3;
        float h4 = bf2f((unsigned short)(hv.z & 0xffffu)) + v4;
        float h5 = bf2f((unsigned short)(hv.z >> 16)) + v5;
        float h6 = bf2f((unsigned short)(hv.w & 0xffffu)) + v6;
        float h7 = bf2f((unsigned short)(hv.w >> 16)) + v7;
        uint4 hp;
        hp.x = pack2(h0, h1); hp.y = pack2(h2, h3);
        hp.z = pack2(h4, h5); hp.w = pack2(h6, h7);
        ((uint4*)hb)[i] = hp;
        if (head) {
            float pn = h0 * wn0.x + h1 * wn0.y + h2 * wn0.z + h3 * wn0.w +
                       h4 * wn1.x + h5 * wn1.y + h6 * wn1.z + h7 * wn1.w;
            float pa = h0 * wa0.x + h1 * wa0.y + h2 * wa0.z + h3 * wa0.w +
                       h4 * wa1.x + h5 * wa1.y + h6 * wa1.z + h7 * wa1.w;
            float pb = h0 * wb0.x + h1 * wb0.y + h2 * wb0.z + h3 * wb0.w +
                       h4 * wb1.x + h5 * wb1.y + h6 * wb1.z + h7 * wb1.w;
#pragma unroll
            for (int off = 1; off < 16; off <<= 1) {
                pn += __shfl_xor(pn, off);
                pa += __shfl_xor(pa, off);
                pb += __shfl_xor(pb, off);
            }
            if ((threadIdx.x & 15) == 0) {
                int gr = i >> 4;
                float nk = 1.f / (1.f + expf(-(pn + nb[0])));
                out[gr] = nk;
                int g = batch[gr];
                float* base = nsc + (size_t)(blockIdx.x & 7) * 8192;
                atomicAdd(&base[g], nk);
                atomicAdd(&base[4096 + g], 1.0f - nk);
                p[gr] = pa;
                q[gr] = pb;
            }
        }
    }
}

// ------------- edge head: LDS-binned seg sums, zero global atomics.
__global__ __launch_bounds__(256) void k_edge_out(
    const int* __restrict__ ei, const int* __restrict__ batch,
    const float* __restrict__ p, const float* __restrict__ q,
    const float* __restrict__ eb, float* __restrict__ out,
    float* __restrict__ esc) {
    __shared__ float bins[8192];  // [2][4096] = 32 KB
    for (int i = threadIdx.x; i < 8192; i += 256) bins[i] = 0.f;
    __syncthreads();
    float ebv = eb[0];
    for (int e = blockIdx.x * 256 + threadIdx.x; e < N_EDGES; e += EOUT_BLK * 256) {
        int r = ei[e], c = ei[N_EDGES + e];
        float ek = 1.f / (1.f + expf(-(p[r] + q[c] + ebv)));
        out[N_NODES + e] = ek;
        int g = batch[r];
        atomicAdd(&bins[g], ek);
        atomicAdd(&bins[4096 + g], 1.0f - ek);
    }
    __syncthreads();
    float* dst = esc + (size_t)blockIdx.x * 8192;
    for (int i = threadIdx.x; i < 8192; i += 256) dst[i] = bins[i];
}

// ------------- reduce the scratch copies into the 4 output segments
__global__ void k_seg_reduce(const float* __restrict__ nsc, const float* __restrict__ esc,
                             float* __restrict__ out) {
    int i = blockIdx.x * 256 + threadIdx.x;   // 0..16383
    if (i >= 16384) return;
    float s = 1e-8f;
    if (i < 8192) {
#pragma unroll
        for (int c = 0; c < 8; ++c) s += nsc[c * 8192 + i];
    } else {
        int j = i - 8192;
        for (int c = 0; c < EOUT_BLK; ++c) s += esc[(size_t)c * 8192 + j];
    }
    out[N_NODES + N_EDGES + i] = s;
}

extern "C" void kernel_launch(void* const* d_in, const int* in_sizes, int n_in,
                              void* d_out, int out_size, void* d_ws, size_t ws_size,
                              hipStream_t stream) {
    const int*   x     = (const int*)d_in[0];
    const int*   ei    = (const int*)d_in[1];
    const int*   ea    = (const int*)d_in[2];
    const int*   batch = (const int*)d_in[3];
    const float* at    = (const float*)d_in[4];
    const float* bt    = (const float*)d_in[5];
    const float* eps   = (const float*)d_in[6];
    const float* W1    = (const float*)d_in[7];
    const float* b1    = (const float*)d_in[8];
    const float* bn1g  = (const float*)d_in[9];
    const float* bn1b  = (const float*)d_in[10];
    const float* W2    = (const float*)d_in[11];
    const float* b2    = (const float*)d_in[12];
    const float* obng  = (const float*)d_in[13];
    const float* obnb  = (const float*)d_in[14];
    const float* nW    = (const float*)d_in[15];
    const float* nb    = (const float*)d_in[16];
    const float* eW    = (const float*)d_in[17];
    const float* eb    = (const float*)d_in[18];
    float* out = (float*)d_out;

    float* ws    = (float*)d_ws;
    float* stats = ws;                       // 3 layers x 16 copies x 768
    float* p     = stats + 3 * 16 * 768;     // N
    float* q     = p + N_NODES;              // N
    float* nsc   = q + N_NODES;              // 8*8192 node seg scratch
    float* esc   = nsc + 8 * 8192;           // EOUT_BLK*8192 edge seg scratch (16 MB)
    unsigned short* hb  = (unsigned short*)(esc + (size_t)EOUT_BLK * 8192);  // N*128 bf16
    unsigned short* zub = hb + 12800000;     // N*128 bf16: z (gemm1 in), then u
    unsigned short* tb  = zub + 12800000;    // N*256 bf16
    unsigned short* Bp1 = tb + 25600000;     // 3*128*256 bf16
    unsigned short* Bp2 = Bp1 + 3 * 32768;   // 3*256*128 bf16
    unsigned short* ct  = Bp2 + 3 * 32768;   // 3*512*128 bf16 combined bond
    int* rowptr  = (int*)(ct + 3 * 65536);   // N+1
    int* cursor  = rowptr + N_NODES + 1;     // N (counts, then cursors)
    int* csr_pack = cursor + N_NODES;        // E  (row<<9 | attr)
    int* bsum    = csr_pack + N_EDGES;       // SCAN_NBLK
    // per-layer stats: sl = stats + l*16*768; copy c at sl + c*768:
    //   [sum256][sq256][osum128@512][osq128@640]

    hipMemsetAsync(stats, 0, 3 * 16 * 768 * sizeof(float), stream);
    hipMemsetAsync(nsc, 0, 8 * 8192 * sizeof(float), stream);
    hipMemsetAsync(cursor, 0, N_NODES * sizeof(int), stream);
    k_atom_encode<<<25000, 256, 0, stream>>>(x, at, hb);
    k_convw<<<768, 256, 0, stream>>>(W1, W2, Bp1, Bp2);
    k_bondc<<<768, 256, 0, stream>>>(bt, ct);

    // CSR of edges grouped by destination (col) — parallel 3-phase scan
    k_hist<<<2344, 256, 0, stream>>>(ei, cursor);
    k_scan_partial<<<SCAN_NBLK, 256, 0, stream>>>(cursor, bsum);
    k_scan_bsum<<<1, 256, 0, stream>>>(bsum, rowptr);
    k_scan_final<<<SCAN_NBLK, 512, 0, stream>>>(bsum, cursor, rowptr);
    k_fill<<<2344, 256, 0, stream>>>(ei, ea, cursor, csr_pack);

    for (int l = 0; l < 3; ++l) {
        float* sl = stats + (size_t)l * 16 * 768;
        k_gather<<<25000, 256, 0, stream>>>(hb, csr_pack, rowptr,
                                            ct + (size_t)l * 65536, eps, l, zub);
        k_gemm1<<<1563, 256, 0, stream>>>(zub, Bp1 + (size_t)l * 32768, b1 + l * 256, tb, sl);
        k_gemm2<<<1563, 256, 0, stream>>>(tb, Bp2 + (size_t)l * 32768, sl,
                                          bn1g + l * 256, bn1b + l * 256,
                                          b2 + l * 128, zub, sl);
        k_update_h<<<UPD_BLK, 256, 0, stream>>>(hb, zub, sl, obng + l * 128, obnb + l * 128,
                                                (l < 2) ? 1 : 0, (l == 2) ? 1 : 0,
                                                batch, nW, nb, eW, out, p, q, nsc);
    }

    k_edge_out<<<EOUT_BLK, 256, 0, stream>>>(ei, batch, p, q, eb, out, esc);
    k_seg_reduce<<<64, 256, 0, stream>>>(nsc, esc, out);
}

// Round 15
// 483.223 us; speedup vs baseline: 7.1819x; 1.0298x over previous
//
#include <hip/hip_runtime.h>
#include <math.h>

#define N_NODES 100000
#define N_EDGES 600000
#define N_GRAPHS 4096
#define SCAN_CHUNK 512
#define SCAN_NBLK 196   // ceil(100000/512)
#define EOUT_BLK 512    // edge_out grid (LDS-binned, scratch copies)
#define UPD_BLK 1024    // update_h grid (grid-stride, amortized BN2 finalize)

typedef __attribute__((ext_vector_type(8))) short short8v;   // 8 bf16 (4 VGPR)
typedef __attribute__((ext_vector_type(4))) float f32x4;

// fp32 pair -> packed bf16 (RNE) via the HW instruction
__device__ __forceinline__ unsigned int pack2(float a, float b) {
    unsigned int r;
    asm("v_cvt_pk_bf16_f32 %0, %1, %2" : "=v"(r) : "v"(a), "v"(b));
    return r;
}
__device__ __forceinline__ unsigned short bf16_rne(float f) {
    unsigned int r;
    asm("v_cvt_pk_bf16_f32 %0, %1, %2" : "=v"(r) : "v"(f), "v"(f));
    return (unsigned short)r;
}
__device__ __forceinline__ float bf2f(unsigned short u) {
    return __uint_as_float(((unsigned int)u) << 16);
}

// ------- atom encoder: wave per node, scalarized x-row, float2 table gathers
__global__ void k_atom_encode(const int* __restrict__ x, const float* __restrict__ at,
                              unsigned short* __restrict__ hb) {
    int lane = threadIdx.x & 63;
    int n = blockIdx.x * 4 + (threadIdx.x >> 6);
    if (n >= N_NODES) return;
    n = __builtin_amdgcn_readfirstlane(n);
    const int* xr = x + n * 9;
    float sx = 0.f, sy = 0.f;
#pragma unroll
    for (int f = 0; f < 9; ++f) {
        int v = __builtin_amdgcn_readfirstlane(xr[f]);
        float2 t = ((const float2*)(at + (f * 100 + v) * 128))[lane];
        sx += t.x;
        sy += t.y;
    }
    ((unsigned int*)(hb + ((size_t)n << 7)))[lane] = pack2(sx, sy);
}

// ------ merged prep: weight pre-swizzle (blocks 0..767) + combined bond table
// (blocks 768..1535): one dispatch for all one-time table work
__global__ void k_prep(const float* __restrict__ W1, const float* __restrict__ W2,
                       const float* __restrict__ bt,
                       unsigned short* __restrict__ Bp1, unsigned short* __restrict__ Bp2,
                       unsigned short* __restrict__ ct) {
    if (blockIdx.x < 768) {
        int idx = blockIdx.x * 256 + threadIdx.x;
        if (idx < 3 * 128 * 256) {
            int l = idx >> 15, r = idx & 32767;
            int k = r >> 8, j = r & 255;
            float v = W1[(size_t)l * 32768 + k * 256 + j];
            Bp1[(size_t)l * 32768 + (((k >> 5) * 4 + ((k >> 3) & 3)) * 256 + j) * 8 + (k & 7)] =
                bf16_rne(v);
        } else if (idx < 6 * 128 * 256) {
            int t = idx - 98304;
            int l = t >> 15, r = t & 32767;
            int k = r >> 7, j = r & 127;
            float v = W2[(size_t)l * 32768 + k * 128 + j];
            Bp2[(size_t)l * 32768 + (((k >> 5) * 4 + ((k >> 3) & 3)) * 128 + j) * 8 + (k & 7)] =
                bf16_rne(v);
        }
    } else {
        int idx = (blockIdx.x - 768) * 256 + threadIdx.x;
        if (idx >= 3 * 512 * 128) return;
        int d = idx & 127;
        int c = (idx >> 7) & 511;
        int l = idx >> 16;
        const float* base = bt + (size_t)l * 3072;
        float v = base[(c >> 6) * 128 + d] + base[1024 + ((c >> 3) & 7) * 128 + d] +
                  base[2048 + (c & 7) * 128 + d];
        ct[idx] = bf16_rne(v);
    }
}

// --------------------------- CSR build (once)
__global__ void k_hist(const int* __restrict__ ei, int* __restrict__ cnt) {
    int e = blockIdx.x * 256 + threadIdx.x;
    if (e < N_EDGES) atomicAdd(&cnt[ei[N_EDGES + e]], 1);
}

__global__ void k_scan_partial(const int* __restrict__ cnt, int* __restrict__ bsum) {
    __shared__ int ls[256];
    int base = blockIdx.x * SCAN_CHUNK;
    int t = threadIdx.x;
    int s = 0;
    for (int i = base + t; i < base + SCAN_CHUNK && i < N_NODES; i += 256) s += cnt[i];
    ls[t] = s;
    __syncthreads();
    for (int off = 128; off; off >>= 1) {
        if (t < off) ls[t] += ls[t + off];
        __syncthreads();
    }
    if (t == 0) bsum[blockIdx.x] = ls[0];
}

__global__ void k_scan_bsum(int* __restrict__ bsum, int* __restrict__ rowptr) {
    __shared__ int ls[256];
    int t = threadIdx.x;
    int v = (t < SCAN_NBLK) ? bsum[t] : 0;
    ls[t] = v;
    __syncthreads();
    for (int off = 1; off < 256; off <<= 1) {
        int x = (t >= off) ? ls[t - off] : 0;
        __syncthreads();
        ls[t] += x;
        __syncthreads();
    }
    if (t < SCAN_NBLK) bsum[t] = ls[t] - v;  // exclusive prefix
    if (t == 255) rowptr[N_NODES] = ls[255];
}

__global__ __launch_bounds__(512) void k_scan_final(const int* __restrict__ bsum,
                                                    int* __restrict__ cnt_cursor,
                                                    int* __restrict__ rowptr) {
    __shared__ int ls[512];
    int base = blockIdx.x * SCAN_CHUNK;
    int t = threadIdx.x;
    int i = base + t;
    int v = (i < N_NODES) ? cnt_cursor[i] : 0;
    ls[t] = v;
    __syncthreads();
    for (int off = 1; off < 512; off <<= 1) {
        int x = (t >= off) ? ls[t - off] : 0;
        __syncthreads();
        ls[t] += x;
        __syncthreads();
    }
    if (i < N_NODES) {
        int excl = bsum[blockIdx.x] + ls[t] - v;
        rowptr[i] = excl;
        cnt_cursor[i] = excl;
    }
}

// fill CSR-ordered packed (row<<9)|attr array — single index stream
__global__ void k_fill(const int* __restrict__ ei, const int* __restrict__ ea,
                       int* __restrict__ cursor, int* __restrict__ csr_pack) {
    int e = blockIdx.x * 256 + threadIdx.x;
    if (e < N_EDGES) {
        int c = ei[N_EDGES + e];
        int pos = atomicAdd(&cursor[c], 1);
        int attr = ea[e * 3] * 64 + ea[e * 3 + 1] * 8 + ea[e * 3 + 2];
        csr_pack[pos] = (ei[e] << 9) | attr;
    }
}

// ---------------------------- gather-aggregate: z = (1+eps)*h + sum relu(msg)
// wave per node; scalarized index stream; self-load hoisted; 4/2/1 tail
#define EDGE2(uu, cc)                                                          \
    {                                                                          \
        ax += fmaxf(bf2f((unsigned short)((uu) & 0xffffu)) +                   \
                    bf2f((unsigned short)((cc) & 0xffffu)), 0.f);              \
        ay += fmaxf(bf2f((unsigned short)((uu) >> 16)) +                       \
                    bf2f((unsigned short)((cc) >> 16)), 0.f);                  \
    }

__global__ void k_gather(const unsigned short* __restrict__ hb,
                         const int* __restrict__ csr_pack,
                         const int* __restrict__ rowptr, const unsigned short* __restrict__ ct,
                         const float* __restrict__ eps, int l,
                         unsigned short* __restrict__ zb) {
    int lane = threadIdx.x & 63;
    int n = blockIdx.x * 4 + (threadIdx.x >> 6);
    if (n >= N_NODES) return;
    n = __builtin_amdgcn_readfirstlane(n);
    int i0 = __builtin_amdgcn_readfirstlane(rowptr[n]);
    int i1 = __builtin_amdgcn_readfirstlane(rowptr[n + 1]);
    // self term issued first — overlaps with the edge chain
    unsigned int un = ((const unsigned int*)(hb + ((size_t)n << 7)))[lane];
    float ax = 0.f, ay = 0.f;
    int i = i0;
    for (; i + 4 <= i1; i += 4) {
        int rc0 = __builtin_amdgcn_readfirstlane(csr_pack[i]);
        int rc1 = __builtin_amdgcn_readfirstlane(csr_pack[i + 1]);
        int rc2 = __builtin_amdgcn_readfirstlane(csr_pack[i + 2]);
        int rc3 = __builtin_amdgcn_readfirstlane(csr_pack[i + 3]);
        unsigned int u0 = ((const unsigned int*)(hb + ((size_t)(rc0 >> 9) << 7)))[lane];
        unsigned int u1 = ((const unsigned int*)(hb + ((size_t)(rc1 >> 9) << 7)))[lane];
        unsigned int u2 = ((const unsigned int*)(hb + ((size_t)(rc2 >> 9) << 7)))[lane];
        unsigned int u3 = ((const unsigned int*)(hb + ((size_t)(rc3 >> 9) << 7)))[lane];
        unsigned int c0 = ((const unsigned int*)(ct + ((rc0 & 511) << 7)))[lane];
        unsigned int c1 = ((const unsigned int*)(ct + ((rc1 & 511) << 7)))[lane];
        unsigned int c2 = ((const unsigned int*)(ct + ((rc2 & 511) << 7)))[lane];
        unsigned int c3 = ((const unsigned int*)(ct + ((rc3 & 511) << 7)))[lane];
        EDGE2(u0, c0); EDGE2(u1, c1); EDGE2(u2, c2); EDGE2(u3, c3);
    }
    if (i + 2 <= i1) {
        int rc0 = __builtin_amdgcn_readfirstlane(csr_pack[i]);
        int rc1 = __builtin_amdgcn_readfirstlane(csr_pack[i + 1]);
        unsigned int u0 = ((const unsigned int*)(hb + ((size_t)(rc0 >> 9) << 7)))[lane];
        unsigned int u1 = ((const unsigned int*)(hb + ((size_t)(rc1 >> 9) << 7)))[lane];
        unsigned int c0 = ((const unsigned int*)(ct + ((rc0 & 511) << 7)))[lane];
        unsigned int c1 = ((const unsigned int*)(ct + ((rc1 & 511) << 7)))[lane];
        EDGE2(u0, c0); EDGE2(u1, c1);
        i += 2;
    }
    if (i < i1) {
        int rc0 = __builtin_amdgcn_readfirstlane(csr_pack[i]);
        unsigned int u0 = ((const unsigned int*)(hb + ((size_t)(rc0 >> 9) << 7)))[lane];
        unsigned int c0 = ((const unsigned int*)(ct + ((rc0 & 511) << 7)))[lane];
        EDGE2(u0, c0);
    }
    float el = 1.0f + eps[l];
    float zx = fmaf(el, bf2f((unsigned short)(un & 0xffffu)), ax);
    float zy = fmaf(el, bf2f((unsigned short)(un >> 16)), ay);
    ((unsigned int*)(zb + ((size_t)n << 7)))[lane] = pack2(zx, zy);
}

// --------------------- GEMM1 (MFMA, swapped operands -> (z@W1)^T fragments)
// stats partials go to 16 spread copies (sl[(bid&15)*768 + ...])
__global__ __launch_bounds__(256) void k_gemm1(
    const unsigned short* __restrict__ zb, const unsigned short* __restrict__ Bp,
    const float* __restrict__ bias, unsigned short* __restrict__ tb,
    float* __restrict__ sl) {
    __shared__ unsigned short As[8192] __attribute__((aligned(16)));  // 16 KB
    int n0 = blockIdx.x * 64;
#pragma unroll
    for (int s = 0; s < 4; ++s) {
        int i = threadIdx.x + s * 256;            // 16B unit; 64 rows x 16 units
        int r = i >> 4, k8 = i & 15;
        short8v v = (short8v)(short)0;
        if (n0 + r < N_NODES) v = ((const short8v*)(zb + (size_t)(n0 + r) * 128))[k8];
        int frag = (r >> 4) * 16 + k8;
        int off = (frag * 128 + (r & 15) * 8) ^ ((k8 & 7) << 3);
        *(short8v*)(&As[off]) = v;
    }
    __syncthreads();
    int lane = threadIdx.x & 63;
    int wid = threadIdx.x >> 6;
    int l15 = lane & 15, kg = lane >> 4;
    int colbase = wid * 64;
    f32x4 acc[4][4];  // [rb][cf]
#pragma unroll
    for (int a = 0; a < 4; ++a)
#pragma unroll
        for (int b = 0; b < 4; ++b) acc[a][b] = (f32x4)(0.f);
#pragma unroll
    for (int k4 = 0; k4 < 4; ++k4) {
        short8v af[4], bf[4];
#pragma unroll
        for (int rb = 0; rb < 4; ++rb)
            af[rb] = *(const short8v*)(&As[((rb * 16 + k4 * 4 + kg) * 128 + l15 * 8) ^
                                           (((k4 * 4 + kg) & 7) << 3)]);
#pragma unroll
        for (int cf = 0; cf < 4; ++cf)
            bf[cf] = *(const short8v*)(Bp + ((k4 * 4 + kg) * 256 + colbase + cf * 16 + l15) * 8);
#pragma unroll
        for (int rb = 0; rb < 4; ++rb)
#pragma unroll
            for (int cf = 0; cf < 4; ++cf)
                acc[rb][cf] = __builtin_amdgcn_mfma_f32_16x16x32_bf16(bf[cf], af[rb],
                                                                      acc[rb][cf], 0, 0, 0);
    }
    float s4[4][4], q4[4][4];
#pragma unroll
    for (int cf = 0; cf < 4; ++cf)
#pragma unroll
        for (int r = 0; r < 4; ++r) { s4[cf][r] = 0.f; q4[cf][r] = 0.f; }
#pragma unroll
    for (int cf = 0; cf < 4; ++cf) {
        int j0 = colbase + cf * 16 + kg * 4;
        float4 b4 = *(const float4*)(bias + j0);
#pragma unroll
        for (int rb = 0; rb < 4; ++rb) {
            int gr = n0 + rb * 16 + l15;
            if (gr < N_NODES) {
                float v0 = acc[rb][cf][0] + b4.x;
                float v1 = acc[rb][cf][1] + b4.y;
                float v2 = acc[rb][cf][2] + b4.z;
                float v3 = acc[rb][cf][3] + b4.w;
                uint2 st;
                st.x = pack2(v0, v1);
                st.y = pack2(v2, v3);
                *(uint2*)(tb + (size_t)gr * 256 + j0) = st;
                s4[cf][0] += v0; q4[cf][0] += v0 * v0;
                s4[cf][1] += v1; q4[cf][1] += v1 * v1;
                s4[cf][2] += v2; q4[cf][2] += v2 * v2;
                s4[cf][3] += v3; q4[cf][3] += v3 * v3;
            }
        }
    }
    float* stats = sl + (size_t)(blockIdx.x & 15) * 768;
    float* part = (float*)As;
    __syncthreads();
#pragma unroll
    for (int cf = 0; cf < 4; ++cf)
#pragma unroll
        for (int r = 0; r < 4; ++r)
            part[(colbase + cf * 16 + kg * 4 + r) * 16 + l15] = s4[cf][r];
    __syncthreads();
    {
        int j = threadIdx.x;
        const float4* pr = (const float4*)(part + j * 16);
        float4 a0 = pr[0], a1 = pr[1], a2 = pr[2], a3 = pr[3];
        float s = a0.x + a0.y + a0.z + a0.w + a1.x + a1.y + a1.z + a1.w +
                  a2.x + a2.y + a2.z + a2.w + a3.x + a3.y + a3.z + a3.w;
        atomicAdd(&stats[j], s);
    }
    __syncthreads();
#pragma unroll
    for (int cf = 0; cf < 4; ++cf)
#pragma unroll
        for (int r = 0; r < 4; ++r)
            part[(colbase + cf * 16 + kg * 4 + r) * 16 + l15] = q4[cf][r];
    __syncthreads();
    {
        int j = threadIdx.x;
        const float4* pr = (const float4*)(part + j * 16);
        float4 a0 = pr[0], a1 = pr[1], a2 = pr[2], a3 = pr[3];
        float s = a0.x + a0.y + a0.z + a0.w + a1.x + a1.y + a1.z + a1.w +
                  a2.x + a2.y + a2.z + a2.w + a3.x + a3.y + a3.z + a3.w;
        atomicAdd(&stats[256 + j], s);
    }
}

// ------- GEMM2 (MFMA, swapped): u = relu(BN1(t))@W2 + b2, fused BN2 stats
// BN1 finalize done in-block: sum 16 spread copies -> LDS -> regs
__global__ __launch_bounds__(256) void k_gemm2(
    const unsigned short* __restrict__ tb, const unsigned short* __restrict__ Bp,
    const float* __restrict__ sl, const float* __restrict__ g1,
    const float* __restrict__ b1g,
    const float* __restrict__ bias, unsigned short* __restrict__ ub,
    float* __restrict__ slw) {
    __shared__ unsigned short As[16384] __attribute__((aligned(16)));  // 32 KB
    int n0 = blockIdx.x * 64;
    int tid = threadIdx.x;
    // ---- BN1 finalize into As-as-float[512], then to regs
    {
        float* sfin = (float*)As;
        float s = 0.f, q = 0.f;
#pragma unroll
        for (int cc = 0; cc < 16; ++cc) {
            s += sl[cc * 768 + tid];
            q += sl[cc * 768 + 256 + tid];
        }
        float m = s * (1.0f / N_NODES);
        float var = q * (1.0f / N_NODES) - m * m;
        float sc = g1[tid] / sqrtf(var + 1e-5f);
        sfin[tid] = sc;
        sfin[256 + tid] = b1g[tid] - m * sc;
    }
    __syncthreads();
    int kb = (tid & 31) * 8;
    float scr[8], shr[8];
    {
        const float* sfin = (const float*)As;
#pragma unroll
        for (int j = 0; j < 8; ++j) {
            scr[j] = sfin[kb + j];
            shr[j] = sfin[256 + kb + j];
        }
    }
    __syncthreads();
#pragma unroll
    for (int s = 0; s < 8; ++s) {
        int i = tid + s * 256;                    // 16B unit; 64 rows x 32 units
        int r = i >> 5, k8 = i & 31;
        short8v v = (short8v)(short)0;
        if (n0 + r < N_NODES) v = ((const short8v*)(tb + (size_t)(n0 + r) * 256))[k8];
        float f0 = fmaxf(fmaf(scr[0], bf2f((unsigned short)v[0]), shr[0]), 0.f);
        float f1 = fmaxf(fmaf(scr[1], bf2f((unsigned short)v[1]), shr[1]), 0.f);
        float f2 = fmaxf(fmaf(scr[2], bf2f((unsigned short)v[2]), shr[2]), 0.f);
        float f3 = fmaxf(fmaf(scr[3], bf2f((unsigned short)v[3]), shr[3]), 0.f);
        float f4 = fmaxf(fmaf(scr[4], bf2f((unsigned short)v[4]), shr[4]), 0.f);
        float f5 = fmaxf(fmaf(scr[5], bf2f((unsigned short)v[5]), shr[5]), 0.f);
        float f6 = fmaxf(fmaf(scr[6], bf2f((unsigned short)v[6]), shr[6]), 0.f);
        float f7 = fmaxf(fmaf(scr[7], bf2f((unsigned short)v[7]), shr[7]), 0.f);
        uint4 ov;
        ov.x = pack2(f0, f1); ov.y = pack2(f2, f3);
        ov.z = pack2(f4, f5); ov.w = pack2(f6, f7);
        int frag = (r >> 4) * 32 + k8;
        int off = (frag * 128 + (r & 15) * 8) ^ ((k8 & 7) << 3);
        *(uint4*)(&As[off]) = ov;
    }
    __syncthreads();
    int lane = threadIdx.x & 63;
    int wid = threadIdx.x >> 6;
    int l15 = lane & 15, kg = lane >> 4;
    int colbase = wid * 32;
    f32x4 acc[4][2];  // [rb][cf]
#pragma unroll
    for (int a = 0; a < 4; ++a) {
        acc[a][0] = (f32x4)(0.f);
        acc[a][1] = (f32x4)(0.f);
    }
#pragma unroll
    for (int k4 = 0; k4 < 8; ++k4) {
        short8v af[4], bf[2];
#pragma unroll
        for (int rb = 0; rb < 4; ++rb)
            af[rb] = *(const short8v*)(&As[((rb * 32 + k4 * 4 + kg) * 128 + l15 * 8) ^
                                           (((k4 * 4 + kg) & 7) << 3)]);
#pragma unroll
        for (int cf = 0; cf < 2; ++cf)
            bf[cf] = *(const short8v*)(Bp + ((k4 * 4 + kg) * 128 + colbase + cf * 16 + l15) * 8);
#pragma unroll
        for (int rb = 0; rb < 4; ++rb)
#pragma unroll
            for (int cf = 0; cf < 2; ++cf)
                acc[rb][cf] = __builtin_amdgcn_mfma_f32_16x16x32_bf16(bf[cf], af[rb],
                                                                      acc[rb][cf], 0, 0, 0);
    }
    float s4[2][4], q4[2][4];
#pragma unroll
    for (int cf = 0; cf < 2; ++cf)
#pragma unroll
        for (int r = 0; r < 4; ++r) { s4[cf][r] = 0.f; q4[cf][r] = 0.f; }
#pragma unroll
    for (int cf = 0; cf < 2; ++cf) {
        int j0 = colbase + cf * 16 + kg * 4;
        float4 b4 = *(const float4*)(bias + j0);
#pragma unroll
        for (int rb = 0; rb < 4; ++rb) {
            int gr = n0 + rb * 16 + l15;
            if (gr < N_NODES) {
                float v0 = acc[rb][cf][0] + b4.x;
                float v1 = acc[rb][cf][1] + b4.y;
                float v2 = acc[rb][cf][2] + b4.z;
                float v3 = acc[rb][cf][3] + b4.w;
                uint2 st;
                st.x = pack2(v0, v1);
                st.y = pack2(v2, v3);
                *(uint2*)(ub + (size_t)gr * 128 + j0) = st;
                s4[cf][0] += v0; q4[cf][0] += v0 * v0;
                s4[cf][1] += v1; q4[cf][1] += v1 * v1;
                s4[cf][2] += v2; q4[cf][2] += v2 * v2;
                s4[cf][3] += v3; q4[cf][3] += v3 * v3;
            }
        }
    }
    float* stats = slw + (size_t)(blockIdx.x & 15) * 768;
    float* part = (float*)As;  // need 128*16 floats = 8 KB
    __syncthreads();
#pragma unroll
    for (int cf = 0; cf < 2; ++cf)
#pragma unroll
        for (int r = 0; r < 4; ++r)
            part[(colbase + cf * 16 + kg * 4 + r) * 16 + l15] = s4[cf][r];
    __syncthreads();
    if (tid < 128) {
        const float4* pr = (const float4*)(part + tid * 16);
        float4 a0 = pr[0], a1 = pr[1], a2 = pr[2], a3 = pr[3];
        float s = a0.x + a0.y + a0.z + a0.w + a1.x + a1.y + a1.z + a1.w +
                  a2.x + a2.y + a2.z + a2.w + a3.x + a3.y + a3.z + a3.w;
        atomicAdd(&stats[512 + tid], s);
    }
    __syncthreads();
#pragma unroll
    for (int cf = 0; cf < 2; ++cf)
#pragma unroll
        for (int r = 0; r < 4; ++r)
            part[(colbase + cf * 16 + kg * 4 + r) * 16 + l15] = q4[cf][r];
    __syncthreads();
    if (tid < 128) {
        const float4* pr = (const float4*)(part + tid * 16);
        float4 a0 = pr[0], a1 = pr[1], a2 = pr[2], a3 = pr[3];
        float s = a0.x + a0.y + a0.z + a0.w + a1.x + a1.y + a1.z + a1.w +
                  a2.x + a2.y + a2.z + a2.w + a3.x + a3.y + a3.z + a3.w;
        atomicAdd(&stats[640 + tid], s);
    }
}

// --------- hb += maybe_relu(BN2(u)); grid-stride (amortized in-block BN2
// finalize). Last layer: fused node head from pre-rounding fp32 values.
__global__ __launch_bounds__(256) void k_update_h(
    unsigned short* __restrict__ hb, const unsigned short* __restrict__ ub,
    const float* __restrict__ sl,
    const float* __restrict__ g2, const float* __restrict__ b2g,
    int relu, int head,
    const int* __restrict__ batch, const float* __restrict__ nW,
    const float* __restrict__ nb, const float* __restrict__ eW,
    float* __restrict__ out, float* __restrict__ p,
    float* __restrict__ q, float* __restrict__ nsc) {
    __shared__ float sfin[256];
    if (threadIdx.x < 128) {
        int j = threadIdx.x;
        float s = 0.f, qq = 0.f;
#pragma unroll
        for (int cc = 0; cc < 16; ++cc) {
            s += sl[cc * 768 + 512 + j];
            qq += sl[cc * 768 + 640 + j];
        }
        float m = s * (1.0f / N_NODES);
        float var = qq * (1.0f / N_NODES) - m * m;
        float sc = g2[j] / sqrtf(var + 1e-5f);
        sfin[j] = sc;
        sfin[128 + j] = b2g[j] - m * sc;
    }
    __syncthreads();
    int kb = (threadIdx.x & 15) * 8;
    float scr[8], shr[8];
#pragma unroll
    for (int j = 0; j < 8; ++j) {
        scr[j] = sfin[kb + j];
        shr[j] = sfin[128 + kb + j];
    }
    float4 wn0, wn1, wa0, wa1, wb0, wb1;
    if (head) {
        wn0 = *(const float4*)(nW + kb);
        wn1 = *(const float4*)(nW + kb + 4);
        wa0 = *(const float4*)(eW + kb);
        wa1 = *(const float4*)(eW + kb + 4);
        wb0 = *(const float4*)(eW + 128 + kb);
        wb1 = *(const float4*)(eW + 128 + kb + 4);
    }
    for (int i = blockIdx.x * 256 + threadIdx.x; i < N_NODES * 16; i += UPD_BLK * 256) {
        uint4 uv = ((const uint4*)ub)[i];
        uint4 hv = ((const uint4*)hb)[i];
        float v0 = fmaf(scr[0], bf2f((unsigned short)(uv.x & 0xffffu)), shr[0]);
        float v1 = fmaf(scr[1], bf2f((unsigned short)(uv.x >> 16)), shr[1]);
        float v2 = fmaf(scr[2], bf2f((unsigned short)(uv.y & 0xffffu)), shr[2]);
        float v3 = fmaf(scr[3], bf2f((unsigned short)(uv.y >> 16)), shr[3]);
        float v4 = fmaf(scr[4], bf2f((unsigned short)(uv.z & 0xffffu)), shr[4]);
        float v5 = fmaf(scr[5], bf2f((unsigned short)(uv.z >> 16)), shr[5]);
        float v6 = fmaf(scr[6], bf2f((unsigned short)(uv.w & 0xffffu)), shr[6]);
        float v7 = fmaf(scr[7], bf2f((unsigned short)(uv.w >> 16)), shr[7]);
        if (relu) {
            v0 = fmaxf(v0, 0.f); v1 = fmaxf(v1, 0.f); v2 = fmaxf(v2, 0.f); v3 = fmaxf(v3, 0.f);
            v4 = fmaxf(v4, 0.f); v5 = fmaxf(v5, 0.f); v6 = fmaxf(v6, 0.f); v7 = fmaxf(v7, 0.f);
        }
        float h0 = bf2f((unsigned short)(hv.x & 0xffffu)) + v0;
        float h1 = bf2f((unsigned short)(hv.x >> 16)) + v1;
        float h2 = bf2f((unsigned short)(hv.y & 0xffffu)) + v2;
        float h3 = bf2f((unsigned short)(hv.y >> 16)) + v3;
        float h4 = bf2f((unsigned short)(hv.z & 0xffffu)) + v4;
        float h5 = bf2f((unsigned short)(hv.z >> 16)) + v5;
        float h6 = bf2f((unsigned short)(hv.w & 0xffffu)) + v6;
        float h7 = bf2f((unsigned short)(hv.w >> 16)) + v7;
        uint4 hp;
        hp.x = pack2(h0, h1); hp.y = pack2(h2, h3);
        hp.z = pack2(h4, h5); hp.w = pack2(h6, h7);
        ((uint4*)hb)[i] = hp;
        if (head) {
            float pn = h0 * wn0.x + h1 * wn0.y + h2 * wn0.z + h3 * wn0.w +
                       h4 * wn1.x + h5 * wn1.y + h6 * wn1.z + h7 * wn1.w;
            float pa = h0 * wa0.x + h1 * wa0.y + h2 * wa0.z + h3 * wa0.w +
                       h4 * wa1.x + h5 * wa1.y + h6 * wa1.z + h7 * wa1.w;
            float pb = h0 * wb0.x + h1 * wb0.y + h2 * wb0.z + h3 * wb0.w +
                       h4 * wb1.x + h5 * wb1.y + h6 * wb1.z + h7 * wb1.w;
#pragma unroll
            for (int off = 1; off < 16; off <<= 1) {
                pn += __shfl_xor(pn, off);
                pa += __shfl_xor(pa, off);
                pb += __shfl_xor(pb, off);
            }
            if ((threadIdx.x & 15) == 0) {
                int gr = i >> 4;
                float nk = 1.f / (1.f + expf(-(pn + nb[0])));
                out[gr] = nk;
                int g = batch[gr];
                float* base = nsc + (size_t)(blockIdx.x & 7) * 8192;
                atomicAdd(&base[g], nk);
                atomicAdd(&base[4096 + g], 1.0f - nk);
                p[gr] = pa;
                q[gr] = pb;
            }
        }
    }
}

// ------------- edge head: LDS-binned seg sums, zero global atomics.
__global__ __launch_bounds__(256) void k_edge_out(
    const int* __restrict__ ei, const int* __restrict__ batch,
    const float* __restrict__ p, const float* __restrict__ q,
    const float* __restrict__ eb, float* __restrict__ out,
    float* __restrict__ esc) {
    __shared__ float bins[8192];  // [2][4096] = 32 KB
    for (int i = threadIdx.x; i < 8192; i += 256) bins[i] = 0.f;
    __syncthreads();
    float ebv = eb[0];
    for (int e = blockIdx.x * 256 + threadIdx.x; e < N_EDGES; e += EOUT_BLK * 256) {
        int r = ei[e], c = ei[N_EDGES + e];
        float ek = 1.f / (1.f + expf(-(p[r] + q[c] + ebv)));
        out[N_NODES + e] = ek;
        int g = batch[r];
        atomicAdd(&bins[g], ek);
        atomicAdd(&bins[4096 + g], 1.0f - ek);
    }
    __syncthreads();
    float* dst = esc + (size_t)blockIdx.x * 8192;
    for (int i = threadIdx.x; i < 8192; i += 256) dst[i] = bins[i];
}

// ------------- reduce the scratch copies into the 4 output segments
__global__ void k_seg_reduce(const float* __restrict__ nsc, const float* __restrict__ esc,
                             float* __restrict__ out) {
    int i = blockIdx.x * 256 + threadIdx.x;   // 0..16383
    if (i >= 16384) return;
    float s = 1e-8f;
    if (i < 8192) {
#pragma unroll
        for (int c = 0; c < 8; ++c) s += nsc[c * 8192 + i];
    } else {
        int j = i - 8192;
        for (int c = 0; c < EOUT_BLK; ++c) s += esc[(size_t)c * 8192 + j];
    }
    out[N_NODES + N_EDGES + i] = s;
}

extern "C" void kernel_launch(void* const* d_in, const int* in_sizes, int n_in,
                              void* d_out, int out_size, void* d_ws, size_t ws_size,
                              hipStream_t stream) {
    const int*   x     = (const int*)d_in[0];
    const int*   ei    = (const int*)d_in[1];
    const int*   ea    = (const int*)d_in[2];
    const int*   batch = (const int*)d_in[3];
    const float* at    = (const float*)d_in[4];
    const float* bt    = (const float*)d_in[5];
    const float* eps   = (const float*)d_in[6];
    const float* W1    = (const float*)d_in[7];
    const float* b1    = (const float*)d_in[8];
    const float* bn1g  = (const float*)d_in[9];
    const float* bn1b  = (const float*)d_in[10];
    const float* W2    = (const float*)d_in[11];
    const float* b2    = (const float*)d_in[12];
    const float* obng  = (const float*)d_in[13];
    const float* obnb  = (const float*)d_in[14];
    const float* nW    = (const float*)d_in[15];
    const float* nb    = (const float*)d_in[16];
    const float* eW    = (const float*)d_in[17];
    const float* eb    = (const float*)d_in[18];
    float* out = (float*)d_out;

    // zero-init region (one memset): [stats 3*16*768][nsc 8*8192][cursor N]
    float* ws    = (float*)d_ws;
    float* stats = ws;                       // 36864 floats
    float* nsc   = stats + 3 * 16 * 768;     // 65536 floats
    int* cursor  = (int*)(nsc + 8 * 8192);   // N ints (counts, then cursors)
    float* p     = (float*)(cursor + N_NODES);  // N
    float* q     = p + N_NODES;              // N
    float* esc   = q + N_NODES;              // EOUT_BLK*8192 edge seg scratch (16 MB)
    unsigned short* hb  = (unsigned short*)(esc + (size_t)EOUT_BLK * 8192);  // N*128 bf16
    unsigned short* zub = hb + 12800000;     // N*128 bf16: z (gemm1 in), then u
    unsigned short* tb  = zub + 12800000;    // N*256 bf16
    unsigned short* Bp1 = tb + 25600000;     // 3*128*256 bf16
    unsigned short* Bp2 = Bp1 + 3 * 32768;   // 3*256*128 bf16
    unsigned short* ct  = Bp2 + 3 * 32768;   // 3*512*128 bf16 combined bond
    int* rowptr  = (int*)(ct + 3 * 65536);   // N+1
    int* csr_pack = rowptr + N_NODES + 1;    // E  (row<<9 | attr)
    int* bsum    = csr_pack + N_EDGES;       // SCAN_NBLK
    // per-layer stats: sl = stats + l*16*768; copy c at sl + c*768:
    //   [sum256][sq256][osum128@512][osq128@640]

    hipMemsetAsync(stats, 0, (3 * 16 * 768 + 8 * 8192 + N_NODES) * 4, stream);
    k_atom_encode<<<25000, 256, 0, stream>>>(x, at, hb);
    k_prep<<<1536, 256, 0, stream>>>(W1, W2, bt, Bp1, Bp2, ct);

    // CSR of edges grouped by destination (col) — parallel 3-phase scan
    k_hist<<<2344, 256, 0, stream>>>(ei, cursor);
    k_scan_partial<<<SCAN_NBLK, 256, 0, stream>>>(cursor, bsum);
    k_scan_bsum<<<1, 256, 0, stream>>>(bsum, rowptr);
    k_scan_final<<<SCAN_NBLK, 512, 0, stream>>>(bsum, cursor, rowptr);
    k_fill<<<2344, 256, 0, stream>>>(ei, ea, cursor, csr_pack);

    for (int l = 0; l < 3; ++l) {
        float* sl = stats + (size_t)l * 16 * 768;
        k_gather<<<25000, 256, 0, stream>>>(hb, csr_pack, rowptr,
                                            ct + (size_t)l * 65536, eps, l, zub);
        k_gemm1<<<1563, 256, 0, stream>>>(zub, Bp1 + (size_t)l * 32768, b1 + l * 256, tb, sl);
        k_gemm2<<<1563, 256, 0, stream>>>(tb, Bp2 + (size_t)l * 32768, sl,
                                          bn1g + l * 256, bn1b + l * 256,
                                          b2 + l * 128, zub, sl);
        k_update_h<<<UPD_BLK, 256, 0, stream>>>(hb, zub, sl, obng + l * 128, obnb + l * 128,
                                                (l < 2) ? 1 : 0, (l == 2) ? 1 : 0,
                                                batch, nW, nb, eW, out, p, q, nsc);
    }

    k_edge_out<<<EOUT_BLK, 256, 0, stream>>>(ei, batch, p, q, eb, out, esc);
    k_seg_reduce<<<64, 256, 0, stream>>>(nsc, esc, out);
}

// Round 16
// 477.245 us; speedup vs baseline: 7.2719x; 1.0125x over previous
//
#include <hip/hip_runtime.h>
#include <math.h>

#define N_NODES 100000
#define N_EDGES 600000
#define N_GRAPHS 4096
#define SCAN_CHUNK 512
#define SCAN_NBLK 196   // ceil(100000/512)
#define EOUT_BLK 512    // edge_out grid (LDS-binned, scratch copies)
#define UPD_BLK 2048    // update_h grid (grid-stride, amortized BN2 finalize)

typedef __attribute__((ext_vector_type(8))) short short8v;   // 8 bf16 (4 VGPR)
typedef __attribute__((ext_vector_type(4))) float f32x4;

// fp32 pair -> packed bf16 (RNE) via the HW instruction
__device__ __forceinline__ unsigned int pack2(float a, float b) {
    unsigned int r;
    asm("v_cvt_pk_bf16_f32 %0, %1, %2" : "=v"(r) : "v"(a), "v"(b));
    return r;
}
__device__ __forceinline__ unsigned short bf16_rne(float f) {
    unsigned int r;
    asm("v_cvt_pk_bf16_f32 %0, %1, %2" : "=v"(r) : "v"(f), "v"(f));
    return (unsigned short)r;
}
__device__ __forceinline__ float bf2f(unsigned short u) {
    return __uint_as_float(((unsigned int)u) << 16);
}

// ------ merged front: three INDEPENDENT one-time jobs co-scheduled in one
// dispatch (single-stream graph capture would otherwise serialize them):
//   blocks [0,25000)      atom encoder (wave/node, scalarized x-row)
//   blocks [25000,27344)  edge-destination histogram
//   blocks [27344,28880)  weight pre-swizzle + combined bond table
__global__ void k_front(const int* __restrict__ x, const float* __restrict__ at,
                        unsigned short* __restrict__ hb,
                        const int* __restrict__ ei, int* __restrict__ cnt,
                        const float* __restrict__ W1, const float* __restrict__ W2,
                        const float* __restrict__ bt,
                        unsigned short* __restrict__ Bp1, unsigned short* __restrict__ Bp2,
                        unsigned short* __restrict__ ct) {
    if (blockIdx.x < 25000) {
        int lane = threadIdx.x & 63;
        int n = blockIdx.x * 4 + (threadIdx.x >> 6);
        n = __builtin_amdgcn_readfirstlane(n);
        const int* xr = x + n * 9;
        float sx = 0.f, sy = 0.f;
#pragma unroll
        for (int f = 0; f < 9; ++f) {
            int v = __builtin_amdgcn_readfirstlane(xr[f]);
            float2 t = ((const float2*)(at + (f * 100 + v) * 128))[lane];
            sx += t.x;
            sy += t.y;
        }
        ((unsigned int*)(hb + ((size_t)n << 7)))[lane] = pack2(sx, sy);
    } else if (blockIdx.x < 27344) {
        int e = (blockIdx.x - 25000) * 256 + threadIdx.x;
        if (e < N_EDGES) atomicAdd(&cnt[ei[N_EDGES + e]], 1);
    } else {
        int pb = blockIdx.x - 27344;
        if (pb < 768) {
            int idx = pb * 256 + threadIdx.x;
            if (idx < 3 * 128 * 256) {
                int l = idx >> 15, r = idx & 32767;
                int k = r >> 8, j = r & 255;
                float v = W1[(size_t)l * 32768 + k * 256 + j];
                Bp1[(size_t)l * 32768 +
                    (((k >> 5) * 4 + ((k >> 3) & 3)) * 256 + j) * 8 + (k & 7)] = bf16_rne(v);
            } else if (idx < 6 * 128 * 256) {
                int t = idx - 98304;
                int l = t >> 15, r = t & 32767;
                int k = r >> 7, j = r & 127;
                float v = W2[(size_t)l * 32768 + k * 128 + j];
                Bp2[(size_t)l * 32768 +
                    (((k >> 5) * 4 + ((k >> 3) & 3)) * 128 + j) * 8 + (k & 7)] = bf16_rne(v);
            }
        } else {
            int idx = (pb - 768) * 256 + threadIdx.x;
            if (idx >= 3 * 512 * 128) return;
            int d = idx & 127;
            int c = (idx >> 7) & 511;
            int l = idx >> 16;
            const float* base = bt + (size_t)l * 3072;
            float v = base[(c >> 6) * 128 + d] + base[1024 + ((c >> 3) & 7) * 128 + d] +
                      base[2048 + (c & 7) * 128 + d];
            ct[idx] = bf16_rne(v);
        }
    }
}

// --------------------------- CSR scan (3-phase)
__global__ void k_scan_partial(const int* __restrict__ cnt, int* __restrict__ bsum) {
    __shared__ int ls[256];
    int base = blockIdx.x * SCAN_CHUNK;
    int t = threadIdx.x;
    int s = 0;
    for (int i = base + t; i < base + SCAN_CHUNK && i < N_NODES; i += 256) s += cnt[i];
    ls[t] = s;
    __syncthreads();
    for (int off = 128; off; off >>= 1) {
        if (t < off) ls[t] += ls[t + off];
        __syncthreads();
    }
    if (t == 0) bsum[blockIdx.x] = ls[0];
}

__global__ void k_scan_bsum(int* __restrict__ bsum, int* __restrict__ rowptr) {
    __shared__ int ls[256];
    int t = threadIdx.x;
    int v = (t < SCAN_NBLK) ? bsum[t] : 0;
    ls[t] = v;
    __syncthreads();
    for (int off = 1; off < 256; off <<= 1) {
        int x = (t >= off) ? ls[t - off] : 0;
        __syncthreads();
        ls[t] += x;
        __syncthreads();
    }
    if (t < SCAN_NBLK) bsum[t] = ls[t] - v;  // exclusive prefix
    if (t == 255) rowptr[N_NODES] = ls[255];
}

__global__ __launch_bounds__(512) void k_scan_final(const int* __restrict__ bsum,
                                                    int* __restrict__ cnt_cursor,
                                                    int* __restrict__ rowptr) {
    __shared__ int ls[512];
    int base = blockIdx.x * SCAN_CHUNK;
    int t = threadIdx.x;
    int i = base + t;
    int v = (i < N_NODES) ? cnt_cursor[i] : 0;
    ls[t] = v;
    __syncthreads();
    for (int off = 1; off < 512; off <<= 1) {
        int x = (t >= off) ? ls[t - off] : 0;
        __syncthreads();
        ls[t] += x;
        __syncthreads();
    }
    if (i < N_NODES) {
        int excl = bsum[blockIdx.x] + ls[t] - v;
        rowptr[i] = excl;
        cnt_cursor[i] = excl;
    }
}

// fill CSR-ordered packed (row<<9)|attr array — single index stream
__global__ void k_fill(const int* __restrict__ ei, const int* __restrict__ ea,
                       int* __restrict__ cursor, int* __restrict__ csr_pack) {
    int e = blockIdx.x * 256 + threadIdx.x;
    if (e < N_EDGES) {
        int c = ei[N_EDGES + e];
        int pos = atomicAdd(&cursor[c], 1);
        int attr = ea[e * 3] * 64 + ea[e * 3 + 1] * 8 + ea[e * 3 + 2];
        csr_pack[pos] = (ei[e] << 9) | attr;
    }
}

// ---------------------------- gather-aggregate: z = (1+eps)*h + sum relu(msg)
// wave per node; scalarized index stream; self-load hoisted; 4/2/1 tail
#define EDGE2(uu, cc)                                                          \
    {                                                                          \
        ax += fmaxf(bf2f((unsigned short)((uu) & 0xffffu)) +                   \
                    bf2f((unsigned short)((cc) & 0xffffu)), 0.f);              \
        ay += fmaxf(bf2f((unsigned short)((uu) >> 16)) +                       \
                    bf2f((unsigned short)((cc) >> 16)), 0.f);                  \
    }

__global__ void k_gather(const unsigned short* __restrict__ hb,
                         const int* __restrict__ csr_pack,
                         const int* __restrict__ rowptr, const unsigned short* __restrict__ ct,
                         const float* __restrict__ eps, int l,
                         unsigned short* __restrict__ zb) {
    int lane = threadIdx.x & 63;
    int n = blockIdx.x * 4 + (threadIdx.x >> 6);
    if (n >= N_NODES) return;
    n = __builtin_amdgcn_readfirstlane(n);
    int i0 = __builtin_amdgcn_readfirstlane(rowptr[n]);
    int i1 = __builtin_amdgcn_readfirstlane(rowptr[n + 1]);
    unsigned int un = ((const unsigned int*)(hb + ((size_t)n << 7)))[lane];
    float ax = 0.f, ay = 0.f;
    int i = i0;
    for (; i + 4 <= i1; i += 4) {
        int rc0 = __builtin_amdgcn_readfirstlane(csr_pack[i]);
        int rc1 = __builtin_amdgcn_readfirstlane(csr_pack[i + 1]);
        int rc2 = __builtin_amdgcn_readfirstlane(csr_pack[i + 2]);
        int rc3 = __builtin_amdgcn_readfirstlane(csr_pack[i + 3]);
        unsigned int u0 = ((const unsigned int*)(hb + ((size_t)(rc0 >> 9) << 7)))[lane];
        unsigned int u1 = ((const unsigned int*)(hb + ((size_t)(rc1 >> 9) << 7)))[lane];
        unsigned int u2 = ((const unsigned int*)(hb + ((size_t)(rc2 >> 9) << 7)))[lane];
        unsigned int u3 = ((const unsigned int*)(hb + ((size_t)(rc3 >> 9) << 7)))[lane];
        unsigned int c0 = ((const unsigned int*)(ct + ((rc0 & 511) << 7)))[lane];
        unsigned int c1 = ((const unsigned int*)(ct + ((rc1 & 511) << 7)))[lane];
        unsigned int c2 = ((const unsigned int*)(ct + ((rc2 & 511) << 7)))[lane];
        unsigned int c3 = ((const unsigned int*)(ct + ((rc3 & 511) << 7)))[lane];
        EDGE2(u0, c0); EDGE2(u1, c1); EDGE2(u2, c2); EDGE2(u3, c3);
    }
    if (i + 2 <= i1) {
        int rc0 = __builtin_amdgcn_readfirstlane(csr_pack[i]);
        int rc1 = __builtin_amdgcn_readfirstlane(csr_pack[i + 1]);
        unsigned int u0 = ((const unsigned int*)(hb + ((size_t)(rc0 >> 9) << 7)))[lane];
        unsigned int u1 = ((const unsigned int*)(hb + ((size_t)(rc1 >> 9) << 7)))[lane];
        unsigned int c0 = ((const unsigned int*)(ct + ((rc0 & 511) << 7)))[lane];
        unsigned int c1 = ((const unsigned int*)(ct + ((rc1 & 511) << 7)))[lane];
        EDGE2(u0, c0); EDGE2(u1, c1);
        i += 2;
    }
    if (i < i1) {
        int rc0 = __builtin_amdgcn_readfirstlane(csr_pack[i]);
        unsigned int u0 = ((const unsigned int*)(hb + ((size_t)(rc0 >> 9) << 7)))[lane];
        unsigned int c0 = ((const unsigned int*)(ct + ((rc0 & 511) << 7)))[lane];
        EDGE2(u0, c0);
    }
    float el = 1.0f + eps[l];
    float zx = fmaf(el, bf2f((unsigned short)(un & 0xffffu)), ax);
    float zy = fmaf(el, bf2f((unsigned short)(un >> 16)), ay);
    ((unsigned int*)(zb + ((size_t)n << 7)))[lane] = pack2(zx, zy);
}

// --------------------- GEMM1 (MFMA, swapped operands -> (z@W1)^T fragments)
// stats partials go to 16 spread copies (sl[(bid&15)*768 + ...])
__global__ __launch_bounds__(256) void k_gemm1(
    const unsigned short* __restrict__ zb, const unsigned short* __restrict__ Bp,
    const float* __restrict__ bias, unsigned short* __restrict__ tb,
    float* __restrict__ sl) {
    __shared__ unsigned short As[8192] __attribute__((aligned(16)));  // 16 KB
    int n0 = blockIdx.x * 64;
#pragma unroll
    for (int s = 0; s < 4; ++s) {
        int i = threadIdx.x + s * 256;            // 16B unit; 64 rows x 16 units
        int r = i >> 4, k8 = i & 15;
        short8v v = (short8v)(short)0;
        if (n0 + r < N_NODES) v = ((const short8v*)(zb + (size_t)(n0 + r) * 128))[k8];
        int frag = (r >> 4) * 16 + k8;
        int off = (frag * 128 + (r & 15) * 8) ^ ((k8 & 7) << 3);
        *(short8v*)(&As[off]) = v;
    }
    __syncthreads();
    int lane = threadIdx.x & 63;
    int wid = threadIdx.x >> 6;
    int l15 = lane & 15, kg = lane >> 4;
    int colbase = wid * 64;
    f32x4 acc[4][4];  // [rb][cf]
#pragma unroll
    for (int a = 0; a < 4; ++a)
#pragma unroll
        for (int b = 0; b < 4; ++b) acc[a][b] = (f32x4)(0.f);
#pragma unroll
    for (int k4 = 0; k4 < 4; ++k4) {
        short8v af[4], bf[4];
#pragma unroll
        for (int rb = 0; rb < 4; ++rb)
            af[rb] = *(const short8v*)(&As[((rb * 16 + k4 * 4 + kg) * 128 + l15 * 8) ^
                                           (((k4 * 4 + kg) & 7) << 3)]);
#pragma unroll
        for (int cf = 0; cf < 4; ++cf)
            bf[cf] = *(const short8v*)(Bp + ((k4 * 4 + kg) * 256 + colbase + cf * 16 + l15) * 8);
#pragma unroll
        for (int rb = 0; rb < 4; ++rb)
#pragma unroll
            for (int cf = 0; cf < 4; ++cf)
                acc[rb][cf] = __builtin_amdgcn_mfma_f32_16x16x32_bf16(bf[cf], af[rb],
                                                                      acc[rb][cf], 0, 0, 0);
    }
    float s4[4][4], q4[4][4];
#pragma unroll
    for (int cf = 0; cf < 4; ++cf)
#pragma unroll
        for (int r = 0; r < 4; ++r) { s4[cf][r] = 0.f; q4[cf][r] = 0.f; }
#pragma unroll
    for (int cf = 0; cf < 4; ++cf) {
        int j0 = colbase + cf * 16 + kg * 4;
        float4 b4 = *(const float4*)(bias + j0);
#pragma unroll
        for (int rb = 0; rb < 4; ++rb) {
            int gr = n0 + rb * 16 + l15;
            if (gr < N_NODES) {
                float v0 = acc[rb][cf][0] + b4.x;
                float v1 = acc[rb][cf][1] + b4.y;
                float v2 = acc[rb][cf][2] + b4.z;
                float v3 = acc[rb][cf][3] + b4.w;
                uint2 st;
                st.x = pack2(v0, v1);
                st.y = pack2(v2, v3);
                *(uint2*)(tb + (size_t)gr * 256 + j0) = st;
                s4[cf][0] += v0; q4[cf][0] += v0 * v0;
                s4[cf][1] += v1; q4[cf][1] += v1 * v1;
                s4[cf][2] += v2; q4[cf][2] += v2 * v2;
                s4[cf][3] += v3; q4[cf][3] += v3 * v3;
            }
        }
    }
    float* stats = sl + (size_t)(blockIdx.x & 15) * 768;
    float* part = (float*)As;
    __syncthreads();
#pragma unroll
    for (int cf = 0; cf < 4; ++cf)
#pragma unroll
        for (int r = 0; r < 4; ++r)
            part[(colbase + cf * 16 + kg * 4 + r) * 16 + l15] = s4[cf][r];
    __syncthreads();
    {
        int j = threadIdx.x;
        const float4* pr = (const float4*)(part + j * 16);
        float4 a0 = pr[0], a1 = pr[1], a2 = pr[2], a3 = pr[3];
        float s = a0.x + a0.y + a0.z + a0.w + a1.x + a1.y + a1.z + a1.w +
                  a2.x + a2.y + a2.z + a2.w + a3.x + a3.y + a3.z + a3.w;
        atomicAdd(&stats[j], s);
    }
    __syncthreads();
#pragma unroll
    for (int cf = 0; cf < 4; ++cf)
#pragma unroll
        for (int r = 0; r < 4; ++r)
            part[(colbase + cf * 16 + kg * 4 + r) * 16 + l15] = q4[cf][r];
    __syncthreads();
    {
        int j = threadIdx.x;
        const float4* pr = (const float4*)(part + j * 16);
        float4 a0 = pr[0], a1 = pr[1], a2 = pr[2], a3 = pr[3];
        float s = a0.x + a0.y + a0.z + a0.w + a1.x + a1.y + a1.z + a1.w +
                  a2.x + a2.y + a2.z + a2.w + a3.x + a3.y + a3.z + a3.w;
        atomicAdd(&stats[256 + j], s);
    }
}

// ------- GEMM2 (MFMA, swapped): u = relu(BN1(t))@W2 + b2, fused BN2 stats
// BN1 finalize done in-block: sum 16 spread copies -> LDS -> regs
__global__ __launch_bounds__(256) void k_gemm2(
    const unsigned short* __restrict__ tb, const unsigned short* __restrict__ Bp,
    const float* __restrict__ sl, const float* __restrict__ g1,
    const float* __restrict__ b1g,
    const float* __restrict__ bias, unsigned short* __restrict__ ub,
    float* __restrict__ slw) {
    __shared__ unsigned short As[16384] __attribute__((aligned(16)));  // 32 KB
    int n0 = blockIdx.x * 64;
    int tid = threadIdx.x;
    {
        float* sfin = (float*)As;
        float s = 0.f, q = 0.f;
#pragma unroll
        for (int cc = 0; cc < 16; ++cc) {
            s += sl[cc * 768 + tid];
            q += sl[cc * 768 + 256 + tid];
        }
        float m = s * (1.0f / N_NODES);
        float var = q * (1.0f / N_NODES) - m * m;
        float sc = g1[tid] / sqrtf(var + 1e-5f);
        sfin[tid] = sc;
        sfin[256 + tid] = b1g[tid] - m * sc;
    }
    __syncthreads();
    int kb = (tid & 31) * 8;
    float scr[8], shr[8];
    {
        const float* sfin = (const float*)As;
#pragma unroll
        for (int j = 0; j < 8; ++j) {
            scr[j] = sfin[kb + j];
            shr[j] = sfin[256 + kb + j];
        }
    }
    __syncthreads();
#pragma unroll
    for (int s = 0; s < 8; ++s) {
        int i = tid + s * 256;                    // 16B unit; 64 rows x 32 units
        int r = i >> 5, k8 = i & 31;
        short8v v = (short8v)(short)0;
        if (n0 + r < N_NODES) v = ((const short8v*)(tb + (size_t)(n0 + r) * 256))[k8];
        float f0 = fmaxf(fmaf(scr[0], bf2f((unsigned short)v[0]), shr[0]), 0.f);
        float f1 = fmaxf(fmaf(scr[1], bf2f((unsigned short)v[1]), shr[1]), 0.f);
        float f2 = fmaxf(fmaf(scr[2], bf2f((unsigned short)v[2]), shr[2]), 0.f);
        float f3 = fmaxf(fmaf(scr[3], bf2f((unsigned short)v[3]), shr[3]), 0.f);
        float f4 = fmaxf(fmaf(scr[4], bf2f((unsigned short)v[4]), shr[4]), 0.f);
        float f5 = fmaxf(fmaf(scr[5], bf2f((unsigned short)v[5]), shr[5]), 0.f);
        float f6 = fmaxf(fmaf(scr[6], bf2f((unsigned short)v[6]), shr[6]), 0.f);
        float f7 = fmaxf(fmaf(scr[7], bf2f((unsigned short)v[7]), shr[7]), 0.f);
        uint4 ov;
        ov.x = pack2(f0, f1); ov.y = pack2(f2, f3);
        ov.z = pack2(f4, f5); ov.w = pack2(f6, f7);
        int frag = (r >> 4) * 32 + k8;
        int off = (frag * 128 + (r & 15) * 8) ^ ((k8 & 7) << 3);
        *(uint4*)(&As[off]) = ov;
    }
    __syncthreads();
    int lane = threadIdx.x & 63;
    int wid = threadIdx.x >> 6;
    int l15 = lane & 15, kg = lane >> 4;
    int colbase = wid * 32;
    f32x4 acc[4][2];  // [rb][cf]
#pragma unroll
    for (int a = 0; a < 4; ++a) {
        acc[a][0] = (f32x4)(0.f);
        acc[a][1] = (f32x4)(0.f);
    }
#pragma unroll
    for (int k4 = 0; k4 < 8; ++k4) {
        short8v af[4], bf[2];
#pragma unroll
        for (int rb = 0; rb < 4; ++rb)
            af[rb] = *(const short8v*)(&As[((rb * 32 + k4 * 4 + kg) * 128 + l15 * 8) ^
                                           (((k4 * 4 + kg) & 7) << 3)]);
#pragma unroll
        for (int cf = 0; cf < 2; ++cf)
            bf[cf] = *(const short8v*)(Bp + ((k4 * 4 + kg) * 128 + colbase + cf * 16 + l15) * 8);
#pragma unroll
        for (int rb = 0; rb < 4; ++rb)
#pragma unroll
            for (int cf = 0; cf < 2; ++cf)
                acc[rb][cf] = __builtin_amdgcn_mfma_f32_16x16x32_bf16(bf[cf], af[rb],
                                                                      acc[rb][cf], 0, 0, 0);
    }
    float s4[2][4], q4[2][4];
#pragma unroll
    for (int cf = 0; cf < 2; ++cf)
#pragma unroll
        for (int r = 0; r < 4; ++r) { s4[cf][r] = 0.f; q4[cf][r] = 0.f; }
#pragma unroll
    for (int cf = 0; cf < 2; ++cf) {
        int j0 = colbase + cf * 16 + kg * 4;
        float4 b4 = *(const float4*)(bias + j0);
#pragma unroll
        for (int rb = 0; rb < 4; ++rb) {
            int gr = n0 + rb * 16 + l15;
            if (gr < N_NODES) {
                float v0 = acc[rb][cf][0] + b4.x;
                float v1 = acc[rb][cf][1] + b4.y;
                float v2 = acc[rb][cf][2] + b4.z;
                float v3 = acc[rb][cf][3] + b4.w;
                uint2 st;
                st.x = pack2(v0, v1);
                st.y = pack2(v2, v3);
                *(uint2*)(ub + (size_t)gr * 128 + j0) = st;
                s4[cf][0] += v0; q4[cf][0] += v0 * v0;
                s4[cf][1] += v1; q4[cf][1] += v1 * v1;
                s4[cf][2] += v2; q4[cf][2] += v2 * v2;
                s4[cf][3] += v3; q4[cf][3] += v3 * v3;
            }
        }
    }
    float* stats = slw + (size_t)(blockIdx.x & 15) * 768;
    float* part = (float*)As;  // need 128*16 floats = 8 KB
    __syncthreads();
#pragma unroll
    for (int cf = 0; cf < 2; ++cf)
#pragma unroll
        for (int r = 0; r < 4; ++r)
            part[(colbase + cf * 16 + kg * 4 + r) * 16 + l15] = s4[cf][r];
    __syncthreads();
    if (tid < 128) {
        const float4* pr = (const float4*)(part + tid * 16);
        float4 a0 = pr[0], a1 = pr[1], a2 = pr[2], a3 = pr[3];
        float s = a0.x + a0.y + a0.z + a0.w + a1.x + a1.y + a1.z + a1.w +
                  a2.x + a2.y + a2.z + a2.w + a3.x + a3.y + a3.z + a3.w;
        atomicAdd(&stats[512 + tid], s);
    }
    __syncthreads();
#pragma unroll
    for (int cf = 0; cf < 2; ++cf)
#pragma unroll
        for (int r = 0; r < 4; ++r)
            part[(colbase + cf * 16 + kg * 4 + r) * 16 + l15] = q4[cf][r];
    __syncthreads();
    if (tid < 128) {
        const float4* pr = (const float4*)(part + tid * 16);
        float4 a0 = pr[0], a1 = pr[1], a2 = pr[2], a3 = pr[3];
        float s = a0.x + a0.y + a0.z + a0.w + a1.x + a1.y + a1.z + a1.w +
                  a2.x + a2.y + a2.z + a2.w + a3.x + a3.y + a3.z + a3.w;
        atomicAdd(&stats[640 + tid], s);
    }
}

// --------- hb += maybe_relu(BN2(u)); grid-stride (amortized in-block BN2
// finalize). Last layer: fused node head from pre-rounding fp32 values.
__global__ __launch_bounds__(256) void k_update_h(
    unsigned short* __restrict__ hb, const unsigned short* __restrict__ ub,
    const float* __restrict__ sl,
    const float* __restrict__ g2, const float* __restrict__ b2g,
    int relu, int head,
    const int* __restrict__ batch, const float* __restrict__ nW,
    const float* __restrict__ nb, const float* __restrict__ eW,
    float* __restrict__ out, float* __restrict__ p,
    float* __restrict__ q, float* __restrict__ nsc) {
    __shared__ float sfin[256];
    if (threadIdx.x < 128) {
        int j = threadIdx.x;
        float s = 0.f, qq = 0.f;
#pragma unroll
        for (int cc = 0; cc < 16; ++cc) {
            s += sl[cc * 768 + 512 + j];
            qq += sl[cc * 768 + 640 + j];
        }
        float m = s * (1.0f / N_NODES);
        float var = qq * (1.0f / N_NODES) - m * m;
        float sc = g2[j] / sqrtf(var + 1e-5f);
        sfin[j] = sc;
        sfin[128 + j] = b2g[j] - m * sc;
    }
    __syncthreads();
    int kb = (threadIdx.x & 15) * 8;
    float scr[8], shr[8];
#pragma unroll
    for (int j = 0; j < 8; ++j) {
        scr[j] = sfin[kb + j];
        shr[j] = sfin[128 + kb + j];
    }
    float4 wn0, wn1, wa0, wa1, wb0, wb1;
    if (head) {
        wn0 = *(const float4*)(nW + kb);
        wn1 = *(const float4*)(nW + kb + 4);
        wa0 = *(const float4*)(eW + kb);
        wa1 = *(const float4*)(eW + kb + 4);
        wb0 = *(const float4*)(eW + 128 + kb);
        wb1 = *(const float4*)(eW + 128 + kb + 4);
    }
    for (int i = blockIdx.x * 256 + threadIdx.x; i < N_NODES * 16; i += UPD_BLK * 256) {
        uint4 uv = ((const uint4*)ub)[i];
        uint4 hv = ((const uint4*)hb)[i];
        float v0 = fmaf(scr[0], bf2f((unsigned short)(uv.x & 0xffffu)), shr[0]);
        float v1 = fmaf(scr[1], bf2f((unsigned short)(uv.x >> 16)), shr[1]);
        float v2 = fmaf(scr[2], bf2f((unsigned short)(uv.y & 0xffffu)), shr[2]);
        float v3 = fmaf(scr[3], bf2f((unsigned short)(uv.y >> 16)), shr[3]);
        float v4 = fmaf(scr[4], bf2f((unsigned short)(uv.z & 0xffffu)), shr[4]);
        float v5 = fmaf(scr[5], bf2f((unsigned short)(uv.z >> 16)), shr[5]);
        float v6 = fmaf(scr[6], bf2f((unsigned short)(uv.w & 0xffffu)), shr[6]);
        float v7 = fmaf(scr[7], bf2f((unsigned short)(uv.w >> 16)), shr[7]);
        if (relu) {
            v0 = fmaxf(v0, 0.f); v1 = fmaxf(v1, 0.f); v2 = fmaxf(v2, 0.f); v3 = fmaxf(v3, 0.f);
            v4 = fmaxf(v4, 0.f); v5 = fmaxf(v5, 0.f); v6 = fmaxf(v6, 0.f); v7 = fmaxf(v7, 0.f);
        }
        float h0 = bf2f((unsigned short)(hv.x & 0xffffu)) + v0;
        float h1 = bf2f((unsigned short)(hv.x >> 16)) + v1;
        float h2 = bf2f((unsigned short)(hv.y & 0xffffu)) + v2;
        float h3 = bf2f((unsigned short)(hv.y >> 16)) + v3;
        float h4 = bf2f((unsigned short)(hv.z & 0xffffu)) + v4;
        float h5 = bf2f((unsigned short)(hv.z >> 16)) + v5;
        float h6 = bf2f((unsigned short)(hv.w & 0xffffu)) + v6;
        float h7 = bf2f((unsigned short)(hv.w >> 16)) + v7;
        uint4 hp;
        hp.x = pack2(h0, h1); hp.y = pack2(h2, h3);
        hp.z = pack2(h4, h5); hp.w = pack2(h6, h7);
        ((uint4*)hb)[i] = hp;
        if (head) {
            float pn = h0 * wn0.x + h1 * wn0.y + h2 * wn0.z + h3 * wn0.w +
                       h4 * wn1.x + h5 * wn1.y + h6 * wn1.z + h7 * wn1.w;
            float pa = h0 * wa0.x + h1 * wa0.y + h2 * wa0.z + h3 * wa0.w +
                       h4 * wa1.x + h5 * wa1.y + h6 * wa1.z + h7 * wa1.w;
            float pb = h0 * wb0.x + h1 * wb0.y + h2 * wb0.z + h3 * wb0.w +
                       h4 * wb1.x + h5 * wb1.y + h6 * wb1.z + h7 * wb1.w;
#pragma unroll
            for (int off = 1; off < 16; off <<= 1) {
                pn += __shfl_xor(pn, off);
                pa += __shfl_xor(pa, off);
                pb += __shfl_xor(pb, off);
            }
            if ((threadIdx.x & 15) == 0) {
                int gr = i >> 4;
                float nk = 1.f / (1.f + expf(-(pn + nb[0])));
                out[gr] = nk;
                int g = batch[gr];
                float* base = nsc + (size_t)(blockIdx.x & 7) * 8192;
                atomicAdd(&base[g], nk);
                atomicAdd(&base[4096 + g], 1.0f - nk);
                p[gr] = pa;
                q[gr] = pb;
            }
        }
    }
}

// ------------- edge head: LDS-binned seg sums, zero global atomics.
__global__ __launch_bounds__(256) void k_edge_out(
    const int* __restrict__ ei, const int* __restrict__ batch,
    const float* __restrict__ p, const float* __restrict__ q,
    const float* __restrict__ eb, float* __restrict__ out,
    float* __restrict__ esc) {
    __shared__ float bins[8192];  // [2][4096] = 32 KB
    for (int i = threadIdx.x; i < 8192; i += 256) bins[i] = 0.f;
    __syncthreads();
    float ebv = eb[0];
    for (int e = blockIdx.x * 256 + threadIdx.x; e < N_EDGES; e += EOUT_BLK * 256) {
        int r = ei[e], c = ei[N_EDGES + e];
        float ek = 1.f / (1.f + expf(-(p[r] + q[c] + ebv)));
        out[N_NODES + e] = ek;
        int g = batch[r];
        atomicAdd(&bins[g], ek);
        atomicAdd(&bins[4096 + g], 1.0f - ek);
    }
    __syncthreads();
    float* dst = esc + (size_t)blockIdx.x * 8192;
    for (int i = threadIdx.x; i < 8192; i += 256) dst[i] = bins[i];
}

// ------------- reduce the scratch copies into the 4 output segments
__global__ void k_seg_reduce(const float* __restrict__ nsc, const float* __restrict__ esc,
                             float* __restrict__ out) {
    int i = blockIdx.x * 256 + threadIdx.x;   // 0..16383
    if (i >= 16384) return;
    float s = 1e-8f;
    if (i < 8192) {
#pragma unroll
        for (int c = 0; c < 8; ++c) s += nsc[c * 8192 + i];
    } else {
        int j = i - 8192;
        for (int c = 0; c < EOUT_BLK; ++c) s += esc[(size_t)c * 8192 + j];
    }
    out[N_NODES + N_EDGES + i] = s;
}

extern "C" void kernel_launch(void* const* d_in, const int* in_sizes, int n_in,
                              void* d_out, int out_size, void* d_ws, size_t ws_size,
                              hipStream_t stream) {
    const int*   x     = (const int*)d_in[0];
    const int*   ei    = (const int*)d_in[1];
    const int*   ea    = (const int*)d_in[2];
    const int*   batch = (const int*)d_in[3];
    const float* at    = (const float*)d_in[4];
    const float* bt    = (const float*)d_in[5];
    const float* eps   = (const float*)d_in[6];
    const float* W1    = (const float*)d_in[7];
    const float* b1    = (const float*)d_in[8];
    const float* bn1g  = (const float*)d_in[9];
    const float* bn1b  = (const float*)d_in[10];
    const float* W2    = (const float*)d_in[11];
    const float* b2    = (const float*)d_in[12];
    const float* obng  = (const float*)d_in[13];
    const float* obnb  = (const float*)d_in[14];
    const float* nW    = (const float*)d_in[15];
    const float* nb    = (const float*)d_in[16];
    const float* eW    = (const float*)d_in[17];
    const float* eb    = (const float*)d_in[18];
    float* out = (float*)d_out;

    // zero-init region (one memset): [stats 3*16*768][nsc 8*8192][cursor N]
    float* ws    = (float*)d_ws;
    float* stats = ws;                       // 36864 floats
    float* nsc   = stats + 3 * 16 * 768;     // 65536 floats
    int* cursor  = (int*)(nsc + 8 * 8192);   // N ints (counts, then cursors)
    float* p     = (float*)(cursor + N_NODES);  // N
    float* q     = p + N_NODES;              // N
    float* esc   = q + N_NODES;              // EOUT_BLK*8192 edge seg scratch (16 MB)
    unsigned short* hb  = (unsigned short*)(esc + (size_t)EOUT_BLK * 8192);  // N*128 bf16
    unsigned short* zub = hb + 12800000;     // N*128 bf16: z (gemm1 in), then u
    unsigned short* tb  = zub + 12800000;    // N*256 bf16
    unsigned short* Bp1 = tb + 25600000;     // 3*128*256 bf16
    unsigned short* Bp2 = Bp1 + 3 * 32768;   // 3*256*128 bf16
    unsigned short* ct  = Bp2 + 3 * 32768;   // 3*512*128 bf16 combined bond
    int* rowptr  = (int*)(ct + 3 * 65536);   // N+1
    int* csr_pack = rowptr + N_NODES + 1;    // E  (row<<9 | attr)
    int* bsum    = csr_pack + N_EDGES;       // SCAN_NBLK
    // per-layer stats: sl = stats + l*16*768; copy c at sl + c*768:
    //   [sum256][sq256][osum128@512][osq128@640]

    hipMemsetAsync(stats, 0, (3 * 16 * 768 + 8 * 8192 + N_NODES) * 4, stream);
    // merged independent front work: atom encode + edge histogram + tables
    k_front<<<28880, 256, 0, stream>>>(x, at, hb, ei, cursor, W1, W2, bt, Bp1, Bp2, ct);

    // CSR of edges grouped by destination (col) — parallel 3-phase scan
    k_scan_partial<<<SCAN_NBLK, 256, 0, stream>>>(cursor, bsum);
    k_scan_bsum<<<1, 256, 0, stream>>>(bsum, rowptr);
    k_scan_final<<<SCAN_NBLK, 512, 0, stream>>>(bsum, cursor, rowptr);
    k_fill<<<2344, 256, 0, stream>>>(ei, ea, cursor, csr_pack);

    for (int l = 0; l < 3; ++l) {
        float* sl = stats + (size_t)l * 16 * 768;
        k_gather<<<25000, 256, 0, stream>>>(hb, csr_pack, rowptr,
                                            ct + (size_t)l * 65536, eps, l, zub);
        k_gemm1<<<1563, 256, 0, stream>>>(zub, Bp1 + (size_t)l * 32768, b1 + l * 256, tb, sl);
        k_gemm2<<<1563, 256, 0, stream>>>(tb, Bp2 + (size_t)l * 32768, sl,
                                          bn1g + l * 256, bn1b + l * 256,
                                          b2 + l * 128, zub, sl);
        k_update_h<<<UPD_BLK, 256, 0, stream>>>(hb, zub, sl, obng + l * 128, obnb + l * 128,
                                                (l < 2) ? 1 : 0, (l == 2) ? 1 : 0,
                                                batch, nW, nb, eW, out, p, q, nsc);
    }

    k_edge_out<<<EOUT_BLK, 256, 0, stream>>>(ei, batch, p, q, eb, out, esc);
    k_seg_reduce<<<64, 256, 0, stream>>>(nsc, esc, out);
}